// Round 3
// baseline (2707.041 us; speedup 1.0000x reference)
//
#include <hip/hip_runtime.h>
#include <cstdint>

// ---------------- problem constants ----------------
constexpr int BATCH  = 8;
constexpr int TSEQ   = 512;
constexpr int SSEQ   = 512;
constexpr int DMODEL = 1024;
constexpr int NHEAD  = 16;
constexpr int NEXP   = 8;
constexpr int CAPE   = 640;
constexpr int NTOK   = BATCH * TSEQ;        // 4096

// ---------------- LayerNorm ----------------
__global__ __launch_bounds__(256) void ln_kernel(const float* __restrict__ in,
    const float* __restrict__ gw, const float* __restrict__ gb, float* __restrict__ out)
{
    int row = blockIdx.x, tid = threadIdx.x;
    const float4 v = *(const float4*)(in + (size_t)row * DMODEL + tid * 4);
    float s  = v.x + v.y + v.z + v.w;
    float ss = v.x*v.x + v.y*v.y + v.z*v.z + v.w*v.w;
#pragma unroll
    for (int o = 1; o < 64; o <<= 1) { s += __shfl_xor(s, o, 64); ss += __shfl_xor(ss, o, 64); }
    __shared__ float rs[4], rss[4];
    int wid = tid >> 6, lane = tid & 63;
    if (lane == 0) { rs[wid] = s; rss[wid] = ss; }
    __syncthreads();
    s  = rs[0] + rs[1] + rs[2] + rs[3];
    ss = rss[0] + rss[1] + rss[2] + rss[3];
    float mean = s * (1.0f / DMODEL);
    float var  = ss * (1.0f / DMODEL) - mean * mean;
    float inv  = rsqrtf(var + 1e-5f);
    float4 w4 = *(const float4*)(gw + tid * 4);
    float4 b4 = *(const float4*)(gb + tid * 4);
    float4 o;
    o.x = (v.x - mean) * inv * w4.x + b4.x;
    o.y = (v.y - mean) * inv * w4.y + b4.y;
    o.z = (v.z - mean) * inv * w4.z + b4.z;
    o.w = (v.w - mean) * inv * w4.w + b4.w;
    *(float4*)(out + (size_t)row * DMODEL + tid * 4) = o;
}

// ---------------- generic fp32 tiled GEMM ----------------
template<bool TRANSB, bool RELU>
__global__ __launch_bounds__(256) void gemm_f32(
    const float* __restrict__ A, const float* __restrict__ Bm,
    const float* __restrict__ bias, const float* __restrict__ res,
    float* __restrict__ C,
    int K, int lda, int ldb, int ldc, int batchH,
    long long sAb, long long sAh, long long sBb, long long sBh,
    long long sCb, long long sCh, long long sBias,
    float alpha)
{
    __shared__ float As[16][68];
    __shared__ float Bs[16][68];
    int z  = blockIdx.z;
    int zb = z / batchH, zh = z - zb * batchH;
    A  += zb * sAb + zh * sAh;
    Bm += zb * sBb + zh * sBh;
    long long coff = zb * sCb + zh * sCh;
    C += coff;
    if (res)  res  += coff;
    if (bias) bias += zb * sBias;

    int rowBase = blockIdx.y << 6, colBase = blockIdx.x << 6;
    int tid = threadIdx.x;
    int ty = tid >> 4, tx = tid & 15;
    int la_k = tid & 15, la_n = tid >> 4;

    float acc[4][4] = {};

    for (int k0 = 0; k0 < K; k0 += 16) {
#pragma unroll
        for (int p = 0; p < 4; ++p) {
            int n = la_n + (p << 4);
            As[la_k][n] = A[(size_t)(rowBase + n) * lda + (k0 + la_k)];
        }
        if (TRANSB) {
#pragma unroll
            for (int p = 0; p < 4; ++p) {
                int m = la_n + (p << 4);
                Bs[la_k][m] = Bm[(size_t)(colBase + m) * ldb + (k0 + la_k)];
            }
        } else {
            int lb_m = tid & 63, lb_k = tid >> 6;
#pragma unroll
            for (int p = 0; p < 4; ++p) {
                int k = lb_k + (p << 2);
                Bs[k][lb_m] = Bm[(size_t)(k0 + k) * ldb + (colBase + lb_m)];
            }
        }
        __syncthreads();
#pragma unroll
        for (int k = 0; k < 16; ++k) {
            float4 a4 = *(const float4*)&As[k][ty << 2];
            float4 b4 = *(const float4*)&Bs[k][tx << 2];
            float ar[4] = {a4.x, a4.y, a4.z, a4.w};
            float br[4] = {b4.x, b4.y, b4.z, b4.w};
#pragma unroll
            for (int i = 0; i < 4; ++i)
#pragma unroll
                for (int j = 0; j < 4; ++j)
                    acc[i][j] = fmaf(ar[i], br[j], acc[i][j]);
        }
        __syncthreads();
    }

    float4 bv = {0.f, 0.f, 0.f, 0.f};
    if (bias) bv = *(const float4*)&bias[colBase + (tx << 2)];
#pragma unroll
    for (int i = 0; i < 4; ++i) {
        int r = rowBase + (ty << 2) + i;
        float4 v;
        v.x = acc[i][0] * alpha + bv.x;
        v.y = acc[i][1] * alpha + bv.y;
        v.z = acc[i][2] * alpha + bv.z;
        v.w = acc[i][3] * alpha + bv.w;
        if (res) {
            float4 rr = *(const float4*)&res[(size_t)r * ldc + colBase + (tx << 2)];
            v.x += rr.x; v.y += rr.y; v.z += rr.z; v.w += rr.w;
        }
        if (RELU) {
            v.x = fmaxf(v.x, 0.f); v.y = fmaxf(v.y, 0.f);
            v.z = fmaxf(v.z, 0.f); v.w = fmaxf(v.w, 0.f);
        }
        *(float4*)&C[(size_t)r * ldc + colBase + (tx << 2)] = v;
    }
}

// ---------------- row softmax over scores [Z][T][S] ----------------
__global__ __launch_bounds__(64) void softmax_rows(float* __restrict__ sc, int causal)
{
    int t = blockIdx.x, z = blockIdx.y, lane = threadIdx.x;
    float* row = sc + ((size_t)z * gridDim.x + t) * SSEQ;
    int limit = causal ? (t + 1) : SSEQ;
    float v[8];
    float mx = -1e30f;
#pragma unroll
    for (int k = 0; k < 8; ++k) {
        int idx = lane + (k << 6);
        float val = (idx < limit) ? row[idx] : -1e30f;
        v[k] = val; mx = fmaxf(mx, val);
    }
#pragma unroll
    for (int o = 1; o < 64; o <<= 1) mx = fmaxf(mx, __shfl_xor(mx, o, 64));
    float sum = 0.f;
#pragma unroll
    for (int k = 0; k < 8; ++k) {
        int idx = lane + (k << 6);
        float p = (idx < limit) ? __expf(v[k] - mx) : 0.f;
        v[k] = p; sum += p;
    }
#pragma unroll
    for (int o = 1; o < 64; o <<= 1) sum += __shfl_xor(sum, o, 64);
    float inv = 1.0f / sum;
#pragma unroll
    for (int k = 0; k < 8; ++k) row[lane + (k << 6)] = v[k] * inv;
}

// ---------------- router ----------------
__global__ __launch_bounds__(256) void router_kernel(
    const float* __restrict__ xf, const float* __restrict__ rw, const float* __restrict__ rb,
    const float* __restrict__ tmask,
    int* __restrict__ eidx, float* __restrict__ gate, int* __restrict__ valid,
    float* __restrict__ partials)
{
    int blk = blockIdx.x;
    int wid = threadIdx.x >> 6, lane = threadIdx.x & 63;
    __shared__ float wpart[4][10];
    float pe[8] = {0,0,0,0,0,0,0,0};
    float zacc = 0.f, nvacc = 0.f;

    for (int i = 0; i < 16; ++i) {
        int tok = blk * 64 + wid * 16 + i;
        const float* xrow = xf + (size_t)tok * DMODEL;
        float acc[8] = {0,0,0,0,0,0,0,0};
#pragma unroll 4
        for (int kk = 0; kk < 16; ++kk) {
            int d = lane + (kk << 6);
            float xd = xrow[d];
            const float4* rp = (const float4*)(rw + (size_t)d * 8);
            float4 r0 = rp[0], r1 = rp[1];
            acc[0] = fmaf(xd, r0.x, acc[0]); acc[1] = fmaf(xd, r0.y, acc[1]);
            acc[2] = fmaf(xd, r0.z, acc[2]); acc[3] = fmaf(xd, r0.w, acc[3]);
            acc[4] = fmaf(xd, r1.x, acc[4]); acc[5] = fmaf(xd, r1.y, acc[5]);
            acc[6] = fmaf(xd, r1.z, acc[6]); acc[7] = fmaf(xd, r1.w, acc[7]);
        }
#pragma unroll
        for (int e = 0; e < 8; ++e)
#pragma unroll
            for (int o = 1; o < 64; o <<= 1) acc[e] += __shfl_xor(acc[e], o, 64);
        if (lane == 0) {
            float l[8]; float m = -1e30f;
#pragma unroll
            for (int e = 0; e < 8; ++e) { l[e] = acc[e] + rb[e]; m = fmaxf(m, l[e]); }
            float se = 0.f;
#pragma unroll
            for (int e = 0; e < 8; ++e) se += expf(l[e] - m);
            int am = 0; float bm = l[0];
#pragma unroll
            for (int e = 1; e < 8; ++e) if (l[e] > bm) { bm = l[e]; am = e; }
            float inv_se = 1.0f / se;
            float g = expf(l[am] - m) * inv_se;
            float vld = (tmask[tok] > 0.f) ? 1.f : 0.f;
            eidx[tok] = am; gate[tok] = g; valid[tok] = (int)vld;
#pragma unroll
            for (int e = 0; e < 8; ++e) pe[e] += expf(l[e] - m) * inv_se * vld;
            float lse = logf(se) + m;
            zacc += lse * lse * vld;
            nvacc += vld;
        }
    }
    if (lane == 0) {
#pragma unroll
        for (int e = 0; e < 8; ++e) wpart[wid][e] = pe[e];
        wpart[wid][8] = zacc; wpart[wid][9] = nvacc;
    }
    __syncthreads();
    if (threadIdx.x == 0) {
        for (int j = 0; j < 10; ++j)
            partials[blk * 10 + j] = wpart[0][j] + wpart[1][j] + wpart[2][j] + wpart[3][j];
    }
}

// ---------------- capacity scan ----------------
__global__ __launch_bounds__(256) void scan_kernel(
    const int* __restrict__ eidx, const int* __restrict__ valid, const float* __restrict__ gate,
    int* __restrict__ pc, float* __restrict__ gk, int* __restrict__ keepf,
    int* __restrict__ counts)
{
    __shared__ int cnt[256][8];
    int tid = threadIdx.x;
    int local[8] = {0,0,0,0,0,0,0,0};
    int base = tid * 16;
    for (int i = 0; i < 16; ++i) { int e = eidx[base + i]; local[e] += valid[base + i]; }
#pragma unroll
    for (int e = 0; e < 8; ++e) cnt[tid][e] = local[e];
    __syncthreads();
    if (tid < 8) {
        int run = 0;
        for (int i = 0; i < 256; ++i) { int t = cnt[i][tid]; cnt[i][tid] = run; run += t; }
        counts[tid] = run;
    }
    __syncthreads();
    int off[8];
#pragma unroll
    for (int e = 0; e < 8; ++e) off[e] = cnt[tid][e];
    for (int i = 0; i < 16; ++i) {
        int tok = base + i;
        int e = eidx[tok], v = valid[tok];
        int pos = off[e]; off[e] += v;
        int kp = (v && pos < CAPE) ? 1 : 0;
        pc[tok]    = (pos < CAPE) ? pos : (CAPE - 1);
        keepf[tok] = kp;
        gk[tok]    = kp ? gate[tok] : 0.f;
    }
}

// ---------------- dispatch (expert-range) ----------------
__global__ __launch_bounds__(256) void dispatch_kernel(const float* __restrict__ tln,
    const int* __restrict__ eidx, const int* __restrict__ pc, const int* __restrict__ keepf,
    float* __restrict__ buf, int e0, int ec)
{
    int tok = blockIdx.x;
    if (!keepf[tok]) return;
    int e = eidx[tok];
    if (e < e0 || e >= e0 + ec) return;
    int p = pc[tok];
    const float4* s = (const float4*)(tln + (size_t)tok * DMODEL);
    float4* d = (float4*)(buf + ((size_t)(e - e0) * CAPE + p) * DMODEL);
    d[threadIdx.x] = s[threadIdx.x];
}

// ---------------- combine add: out += gk * ob ----------------
__global__ __launch_bounds__(256) void combine_add(const float* __restrict__ ob,
    const int* __restrict__ eidx, const int* __restrict__ pc, const float* __restrict__ gk,
    float* __restrict__ out, int e0, int ec)
{
    int tok = blockIdx.x;
    int e = eidx[tok];
    if (e < e0 || e >= e0 + ec) return;
    float g = gk[tok];
    int p = pc[tok];
    float4* o = (float4*)(out + (size_t)tok * DMODEL);
    const float4 ov = ((const float4*)(ob + ((size_t)(e - e0) * CAPE + p) * DMODEL))[threadIdx.x];
    float4 a = o[threadIdx.x];
    a.x += g * ov.x; a.y += g * ov.y; a.z += g * ov.z; a.w += g * ov.w;
    o[threadIdx.x] = a;
}

// ---------------- final scalar losses ----------------
__global__ __launch_bounds__(64) void loss_kernel(const float* __restrict__ partials,
    const int* __restrict__ counts, float* __restrict__ out2)
{
    int lane = threadIdx.x;
    float p[10];
#pragma unroll
    for (int j = 0; j < 10; ++j) p[j] = partials[lane * 10 + j];
#pragma unroll
    for (int j = 0; j < 10; ++j)
#pragma unroll
        for (int o = 1; o < 64; o <<= 1) p[j] += __shfl_xor(p[j], o, 64);
    if (lane == 0) {
        float nv = fmaxf(p[9], 1.f);
        float lb = 0.f;
        for (int e = 0; e < 8; ++e) lb += ((float)counts[e] / nv) * (p[e] / nv);
        lb *= (float)NEXP;
        out2[0] = lb;
        out2[1] = p[8] / nv;
    }
}

// ---------------- host launch ----------------
extern "C" void kernel_launch(void* const* d_in, const int* in_sizes, int n_in,
                              void* d_out, int out_size, void* d_ws, size_t ws_size,
                              hipStream_t stream)
{
    const float* tgt        = (const float*)d_in[0];
    const float* src        = (const float*)d_in[1];
    const float* token_mask = (const float*)d_in[5];
    const float* ln1w = (const float*)d_in[6],  *ln1b = (const float*)d_in[7];
    const float* self_in_w  = (const float*)d_in[8],  *self_in_b  = (const float*)d_in[9];
    const float* self_out_w = (const float*)d_in[10], *self_out_b = (const float*)d_in[11];
    const float* ln2w = (const float*)d_in[12], *ln2b = (const float*)d_in[13];
    const float* enc_in_w   = (const float*)d_in[14], *enc_in_b   = (const float*)d_in[15];
    const float* enc_out_w  = (const float*)d_in[16], *enc_out_b  = (const float*)d_in[17];
    const float* ln3w = (const float*)d_in[18], *ln3b = (const float*)d_in[19];
    const float* rw = (const float*)d_in[20], *rb = (const float*)d_in[21];
    const float* w1 = (const float*)d_in[22], *b1 = (const float*)d_in[23];
    const float* w2 = (const float*)d_in[24], *b2 = (const float*)d_in[25];

    float* out = (float*)d_out;          // residual stream `x` lives HERE
    float* ws  = (float*)d_ws;

    // ---- fixed layout (floats) ----
    float* tln = ws;                         // 4,194,304
    float* ctx = ws + 4194304;               // 4,194,304
    int*   eidxA   = (int*)(ws + 8388608);
    int*   validA  = eidxA + 4096;
    int*   pcA     = validA + 4096;
    int*   keepA   = pcA + 4096;
    int*   countsA = keepA + 4096;           // 16
    float* gateA   = (float*)(countsA + 16);
    float* gkA     = gateA + 4096;
    float* partA   = gkA + 4096;             // 640
    const size_t POOL_OFF = 8425984;         // floats; 16B aligned
    float* pool = ws + POOL_OFF;

    // ---- adaptive chunk plan (pure function of ws_size -> deterministic) ----
    size_t Wf = ws_size / sizeof(float);
    size_t pf = (Wf > POOL_OFF) ? (Wf - POOL_OFF) : 0;

    int bc = 1, hg = 1;  // attention: bc batches, hg heads per score pass
    {
        const int cb[8] = {8,4,2,1,1,1,1,1};
        const int ch[8] = {16,16,16,16,8,4,2,1};
        for (int i = 0; i < 8; ++i) {
            size_t need = (size_t)cb[i] * 1572864ull + (size_t)cb[i] * ch[i] * 262144ull;
            if (need <= pf) { bc = cb[i]; hg = ch[i]; break; }
        }
    }
    int ec = 1, Fc = 1024;  // MoE: ec experts, Fc hidden cols per pass
    {
        const int ce[6] = {8,4,2,1,1,1};
        const int cf[6] = {4096,4096,4096,4096,2048,1024};
        for (int i = 0; i < 6; ++i) {
            size_t need = (size_t)ce[i] * (1310720ull + 640ull * cf[i]);
            if (need <= pf) { ec = ce[i]; Fc = cf[i]; break; }
        }
    }

    const long long TS = (long long)TSEQ * SSEQ;          // 262,144

    // ===== 1) LN1 =====
    ln_kernel<<<NTOK, 256, 0, stream>>>(tgt, ln1w, ln1b, tln);

    // ===== 2-3) self attention: bc batches x hg heads per pass =====
    for (int b0 = 0; b0 < BATCH; b0 += bc) {
        float* qkvC = pool;                                // bc * 512*3072
        float* scC  = pool + (size_t)bc * 1572864;         // bc * hg * T * S
        gemm_f32<true,false><<<dim3(48, bc * 8, 1), 256, 0, stream>>>(
            tln + (size_t)b0 * 512 * 1024, self_in_w, self_in_b, nullptr, qkvC,
            1024, 1024, 1024, 3072, 1, 0,0,0,0,0,0,0, 1.0f);
        for (int h0 = 0; h0 < NHEAD; h0 += hg) {
            gemm_f32<true,false><<<dim3(8, 8, bc * hg), 256, 0, stream>>>(
                qkvC + h0 * 64, qkvC + 1024 + h0 * 64, nullptr, nullptr, scC,
                64, 3072, 3072, SSEQ, hg,
                (long long)512 * 3072, 64, (long long)512 * 3072, 64,
                (long long)hg * TS, TS, 0, 0.125f);
            softmax_rows<<<dim3(TSEQ, bc * hg), 64, 0, stream>>>(scC, 1);
            gemm_f32<false,false><<<dim3(1, 8, bc * hg), 256, 0, stream>>>(
                scC, qkvC + 2048 + h0 * 64, nullptr, nullptr,
                ctx + (size_t)b0 * 512 * 1024 + h0 * 64,
                512, SSEQ, 3072, 1024, hg,
                (long long)hg * TS, TS, (long long)512 * 3072, 64,
                (long long)512 * 1024, 64, 0, 1.0f);
        }
    }

    // ===== 4) self out-proj + residual(tgt) -> out (x) =====
    gemm_f32<true,false><<<dim3(16, 64, 1), 256, 0, stream>>>(
        ctx, self_out_w, self_out_b, tgt, out,
        1024, 1024, 1024, 1024, 1, 0,0,0,0,0,0,0, 1.0f);

    // ===== 5) LN2 =====
    ln_kernel<<<NTOK, 256, 0, stream>>>(out, ln2w, ln2b, tln);

    // ===== 6-7) cross attention =====
    for (int b0 = 0; b0 < BATCH; b0 += bc) {
        float* q2C  = pool;                                // bc * 512*1024
        float* kv2C = pool + (size_t)bc * 524288;          // bc * 512*2048
        float* scC  = pool + (size_t)bc * 1572864;         // bc * hg * T * S
        gemm_f32<true,false><<<dim3(16, bc * 8, 1), 256, 0, stream>>>(
            tln + (size_t)b0 * 512 * 1024, enc_in_w, enc_in_b, nullptr, q2C,
            1024, 1024, 1024, 1024, 1, 0,0,0,0,0,0,0, 1.0f);
        gemm_f32<true,false><<<dim3(32, bc * 8, 1), 256, 0, stream>>>(
            src + (size_t)b0 * 512 * 1024, enc_in_w + (size_t)1024 * 1024, enc_in_b + 1024,
            nullptr, kv2C,
            1024, 1024, 1024, 2048, 1, 0,0,0,0,0,0,0, 1.0f);
        for (int h0 = 0; h0 < NHEAD; h0 += hg) {
            gemm_f32<true,false><<<dim3(8, 8, bc * hg), 256, 0, stream>>>(
                q2C + h0 * 64, kv2C + h0 * 64, nullptr, nullptr, scC,
                64, 1024, 2048, SSEQ, hg,
                (long long)512 * 1024, 64, (long long)512 * 2048, 64,
                (long long)hg * TS, TS, 0, 0.125f);
            softmax_rows<<<dim3(TSEQ, bc * hg), 64, 0, stream>>>(scC, 0);
            gemm_f32<false,false><<<dim3(1, 8, bc * hg), 256, 0, stream>>>(
                scC, kv2C + 1024 + h0 * 64, nullptr, nullptr,
                ctx + (size_t)b0 * 512 * 1024 + h0 * 64,
                512, SSEQ, 2048, 1024, hg,
                (long long)hg * TS, TS, (long long)512 * 2048, 64,
                (long long)512 * 1024, 64, 0, 1.0f);
        }
    }

    // ===== 8) cross out-proj + residual -> out (in place) =====
    gemm_f32<true,false><<<dim3(16, 64, 1), 256, 0, stream>>>(
        ctx, enc_out_w, enc_out_b, out, out,
        1024, 1024, 1024, 1024, 1, 0,0,0,0,0,0,0, 1.0f);

    // ===== 9) LN3 =====
    ln_kernel<<<NTOK, 256, 0, stream>>>(out, ln3w, ln3b, tln);

    // ===== 10) router / scan =====
    router_kernel<<<64, 256, 0, stream>>>(tln, rw, rb, token_mask, eidxA, gateA, validA, partA);
    scan_kernel<<<1, 256, 0, stream>>>(eidxA, validA, gateA, pcA, gkA, keepA, countsA);

    // ===== 11) expert FFN: ec experts x Fc hidden-cols per pass =====
    for (int e0 = 0; e0 < NEXP; e0 += ec) {
        float* bufC = pool;                                    // ec * 640*1024
        float* hC   = pool + (size_t)ec * 655360;              // ec * 640*Fc
        float* obC  = hC   + (size_t)ec * 640 * Fc;            // ec * 640*1024
        hipMemsetAsync(bufC, 0, (size_t)ec * 655360 * sizeof(float), stream);
        dispatch_kernel<<<NTOK, 256, 0, stream>>>(tln, eidxA, pcA, keepA, bufC, e0, ec);
        for (int f0 = 0; f0 < 4096; f0 += Fc) {
            gemm_f32<false,true><<<dim3(Fc / 64, 10, ec), 256, 0, stream>>>(
                bufC, w1 + (size_t)e0 * 4194304 + f0, b1 + (size_t)e0 * 4096 + f0, nullptr, hC,
                1024, 1024, 4096, Fc, 1,
                655360, 0, 4194304, 0, (long long)640 * Fc, 0, 4096, 1.0f);
            gemm_f32<false,false><<<dim3(16, 10, ec), 256, 0, stream>>>(
                hC, w2 + (size_t)e0 * 4194304 + (size_t)f0 * 1024,
                (f0 == 0) ? (b2 + (size_t)e0 * 1024) : nullptr,
                (f0 == 0) ? nullptr : obC,
                obC,
                Fc, Fc, 1024, 1024, 1,
                (long long)640 * Fc, 0, 4194304, 0, 655360, 0, 1024, 1.0f);
        }
        combine_add<<<NTOK, 256, 0, stream>>>(obC, eidxA, pcA, gkA, out, e0, ec);
    }

    // ===== 12) losses =====
    loss_kernel<<<1, 64, 0, stream>>>(partA, countsA, out + (size_t)NTOK * DMODEL);
}

// Round 4
// 1780.261 us; speedup vs baseline: 1.5206x; 1.5206x over previous
//
#include <hip/hip_runtime.h>
#include <cstdint>

// ---------------- problem constants ----------------
constexpr int BATCH  = 8;
constexpr int TSEQ   = 512;
constexpr int SSEQ   = 512;
constexpr int DMODEL = 1024;
constexpr int NHEAD  = 16;
constexpr int NEXP   = 8;
constexpr int CAPE   = 640;
constexpr int NTOK   = BATCH * TSEQ;        // 4096

__device__ __forceinline__ unsigned short f2bf(float f) {
    uint32_t u = __float_as_uint(f);
    uint32_t r = (u + 0x7FFFu + ((u >> 16) & 1u)) >> 16;   // RNE
    return (unsigned short)r;
}

// ---------------- LayerNorm ----------------
__global__ __launch_bounds__(256) void ln_kernel(const float* __restrict__ in,
    const float* __restrict__ gw, const float* __restrict__ gb, float* __restrict__ out)
{
    int row = blockIdx.x, tid = threadIdx.x;
    const float4 v = *(const float4*)(in + (size_t)row * DMODEL + tid * 4);
    float s  = v.x + v.y + v.z + v.w;
    float ss = v.x*v.x + v.y*v.y + v.z*v.z + v.w*v.w;
#pragma unroll
    for (int o = 1; o < 64; o <<= 1) { s += __shfl_xor(s, o, 64); ss += __shfl_xor(ss, o, 64); }
    __shared__ float rs[4], rss[4];
    int wid = tid >> 6, lane = tid & 63;
    if (lane == 0) { rs[wid] = s; rss[wid] = ss; }
    __syncthreads();
    s  = rs[0] + rs[1] + rs[2] + rs[3];
    ss = rss[0] + rss[1] + rss[2] + rss[3];
    float mean = s * (1.0f / DMODEL);
    float var  = ss * (1.0f / DMODEL) - mean * mean;
    float inv  = rsqrtf(var + 1e-5f);
    float4 w4 = *(const float4*)(gw + tid * 4);
    float4 b4 = *(const float4*)(gb + tid * 4);
    float4 o;
    o.x = (v.x - mean) * inv * w4.x + b4.x;
    o.y = (v.y - mean) * inv * w4.y + b4.y;
    o.z = (v.z - mean) * inv * w4.z + b4.z;
    o.w = (v.w - mean) * inv * w4.w + b4.w;
    *(float4*)(out + (size_t)row * DMODEL + tid * 4) = o;
}

// ---------------- generic fp32 tiled GEMM ----------------
template<bool TRANSB, bool RELU>
__global__ __launch_bounds__(256) void gemm_f32(
    const float* __restrict__ A, const float* __restrict__ Bm,
    const float* __restrict__ bias, const float* __restrict__ res,
    float* __restrict__ C,
    int K, int lda, int ldb, int ldc, int batchH,
    long long sAb, long long sAh, long long sBb, long long sBh,
    long long sCb, long long sCh, long long sBias,
    float alpha)
{
    __shared__ float As[16][68];
    __shared__ float Bs[16][68];
    int z  = blockIdx.z;
    int zb = z / batchH, zh = z - zb * batchH;
    A  += zb * sAb + zh * sAh;
    Bm += zb * sBb + zh * sBh;
    long long coff = zb * sCb + zh * sCh;
    C += coff;
    if (res)  res  += coff;
    if (bias) bias += zb * sBias;

    int rowBase = blockIdx.y << 6, colBase = blockIdx.x << 6;
    int tid = threadIdx.x;
    int ty = tid >> 4, tx = tid & 15;
    int la_k = tid & 15, la_n = tid >> 4;

    float acc[4][4] = {};

    for (int k0 = 0; k0 < K; k0 += 16) {
#pragma unroll
        for (int p = 0; p < 4; ++p) {
            int n = la_n + (p << 4);
            As[la_k][n] = A[(size_t)(rowBase + n) * lda + (k0 + la_k)];
        }
        if (TRANSB) {
#pragma unroll
            for (int p = 0; p < 4; ++p) {
                int m = la_n + (p << 4);
                Bs[la_k][m] = Bm[(size_t)(colBase + m) * ldb + (k0 + la_k)];
            }
        } else {
            int lb_m = tid & 63, lb_k = tid >> 6;
#pragma unroll
            for (int p = 0; p < 4; ++p) {
                int k = lb_k + (p << 2);
                Bs[k][lb_m] = Bm[(size_t)(k0 + k) * ldb + (colBase + lb_m)];
            }
        }
        __syncthreads();
#pragma unroll
        for (int k = 0; k < 16; ++k) {
            float4 a4 = *(const float4*)&As[k][ty << 2];
            float4 b4 = *(const float4*)&Bs[k][tx << 2];
            float ar[4] = {a4.x, a4.y, a4.z, a4.w};
            float br[4] = {b4.x, b4.y, b4.z, b4.w};
#pragma unroll
            for (int i = 0; i < 4; ++i)
#pragma unroll
                for (int j = 0; j < 4; ++j)
                    acc[i][j] = fmaf(ar[i], br[j], acc[i][j]);
        }
        __syncthreads();
    }

    float4 bv = {0.f, 0.f, 0.f, 0.f};
    if (bias) bv = *(const float4*)&bias[colBase + (tx << 2)];
#pragma unroll
    for (int i = 0; i < 4; ++i) {
        int r = rowBase + (ty << 2) + i;
        float4 v;
        v.x = acc[i][0] * alpha + bv.x;
        v.y = acc[i][1] * alpha + bv.y;
        v.z = acc[i][2] * alpha + bv.z;
        v.w = acc[i][3] * alpha + bv.w;
        if (res) {
            float4 rr = *(const float4*)&res[(size_t)r * ldc + colBase + (tx << 2)];
            v.x += rr.x; v.y += rr.y; v.z += rr.z; v.w += rr.w;
        }
        if (RELU) {
            v.x = fmaxf(v.x, 0.f); v.y = fmaxf(v.y, 0.f);
            v.z = fmaxf(v.z, 0.f); v.w = fmaxf(v.w, 0.f);
        }
        *(float4*)&C[(size_t)r * ldc + colBase + (tx << 2)] = v;
    }
}

// ---------------- bf16 NT MFMA GEMM: C[M,N] = A[M,K] * Bt[N,K]^T (+bias) ----------------
typedef __attribute__((ext_vector_type(8))) short bfrag;
typedef __attribute__((ext_vector_type(4))) float f32x4;

template<bool RELU, bool OBF16>
__global__ __launch_bounds__(256) void gemm_bf16_nt(
    const unsigned short* __restrict__ A,   // [M][K] bf16
    const unsigned short* __restrict__ Bt,  // [N][K] bf16
    const float* __restrict__ bias,         // [N] fp32
    void* __restrict__ Cv,
    int K, long long sA, long long sB, long long sC, long long sBias, int ldc)
{
    __shared__ unsigned short Al[128 * 32];
    __shared__ unsigned short Bl[128 * 32];
    int z = blockIdx.z;
    A  += (size_t)z * sA;
    Bt += (size_t)z * sB;
    bias += (size_t)z * sBias;
    long long zC = (long long)z * sC;

    int rowBase = blockIdx.y * 128, colBase = blockIdx.x * 128;
    int t = threadIdx.x, lane = t & 63, wid = t >> 6;
    int wr = (wid >> 1) * 64, wc = (wid & 1) * 64;

    // staging chunks: chunk c covers LDS bytes [c*16, c*16+16) = row (c>>2), 16B-quarter (c&3).
    // pre-swizzle: LDS[r][q] holds global [r][q ^ s(r)], s(r) = (r + (r>>2)) & 3
    int c1 = t, c2 = t + 256;
    int r1 = c1 >> 2, q1 = (c1 & 3) ^ ((r1 + (r1 >> 2)) & 3);
    int r2 = c2 >> 2, q2 = (c2 & 3) ^ ((r2 + (r2 >> 2)) & 3);

    const unsigned short* Ag = A  + (size_t)rowBase * K;
    const unsigned short* Bg = Bt + (size_t)colBase * K;

    f32x4 acc[4][4] = {};

    int l15 = lane & 15, g = lane >> 4;

    for (int k0 = 0; k0 < K; k0 += 32) {
        __syncthreads();
        __builtin_amdgcn_global_load_lds(
            (const __attribute__((address_space(1))) void*)(Ag + (size_t)r1 * K + k0 + q1 * 8),
            (__attribute__((address_space(3))) void*)(&Al[c1 * 8]), 16, 0, 0);
        __builtin_amdgcn_global_load_lds(
            (const __attribute__((address_space(1))) void*)(Ag + (size_t)r2 * K + k0 + q2 * 8),
            (__attribute__((address_space(3))) void*)(&Al[c2 * 8]), 16, 0, 0);
        __builtin_amdgcn_global_load_lds(
            (const __attribute__((address_space(1))) void*)(Bg + (size_t)r1 * K + k0 + q1 * 8),
            (__attribute__((address_space(3))) void*)(&Bl[c1 * 8]), 16, 0, 0);
        __builtin_amdgcn_global_load_lds(
            (const __attribute__((address_space(1))) void*)(Bg + (size_t)r2 * K + k0 + q2 * 8),
            (__attribute__((address_space(3))) void*)(&Bl[c2 * 8]), 16, 0, 0);
        __syncthreads();

        bfrag a[4], b[4];
#pragma unroll
        for (int m = 0; m < 4; ++m) {
            int row = wr + m * 16 + l15;
            int sw = (g ^ ((row + (row >> 2)) & 3)) * 8;
            a[m] = *(const bfrag*)&Al[row * 32 + sw];
        }
#pragma unroll
        for (int n = 0; n < 4; ++n) {
            int row = wc + n * 16 + l15;
            int sw = (g ^ ((row + (row >> 2)) & 3)) * 8;
            b[n] = *(const bfrag*)&Bl[row * 32 + sw];
        }
#pragma unroll
        for (int m = 0; m < 4; ++m)
#pragma unroll
            for (int n = 0; n < 4; ++n)
                acc[m][n] = __builtin_amdgcn_mfma_f32_16x16x32_bf16(a[m], b[n], acc[m][n], 0, 0, 0);
    }

    int g4 = g * 4;
#pragma unroll
    for (int m = 0; m < 4; ++m) {
        int row0 = rowBase + wr + m * 16 + g4;
#pragma unroll
        for (int n = 0; n < 4; ++n) {
            int col = colBase + wc + n * 16 + l15;
            float bv = bias[col];
#pragma unroll
            for (int j = 0; j < 4; ++j) {
                float v = acc[m][n][j] + bv;
                if (RELU) v = fmaxf(v, 0.f);
                if (OBF16)
                    ((unsigned short*)Cv)[zC + (size_t)(row0 + j) * ldc + col] = f2bf(v);
                else
                    ((float*)Cv)[zC + (size_t)(row0 + j) * ldc + col] = v;
            }
        }
    }
}

// ---------------- transpose+convert fp32 [R][Cn] -> bf16 [Cn][R] (per z) ----------------
__global__ __launch_bounds__(256) void tcvt_kernel(const float* __restrict__ in,
    unsigned short* __restrict__ out, int R, int Cn)
{
    __shared__ unsigned short tile[64][68];
    size_t zoff = (size_t)blockIdx.z * R * Cn;
    in += zoff; out += zoff;
    int r0 = blockIdx.y * 64, c0 = blockIdx.x * 64;
    int tr = threadIdx.x >> 4, tc = (threadIdx.x & 15) * 4;
#pragma unroll
    for (int i = 0; i < 4; ++i) {
        int r = tr + i * 16;
        float4 v = *(const float4*)&in[(size_t)(r0 + r) * Cn + c0 + tc];
        tile[r][tc + 0] = f2bf(v.x);
        tile[r][tc + 1] = f2bf(v.y);
        tile[r][tc + 2] = f2bf(v.z);
        tile[r][tc + 3] = f2bf(v.w);
    }
    __syncthreads();
#pragma unroll
    for (int i = 0; i < 4; ++i) {
        int c = tr + i * 16;
        ushort4 w;
        w.x = tile[tc + 0][c];
        w.y = tile[tc + 1][c];
        w.z = tile[tc + 2][c];
        w.w = tile[tc + 3][c];
        *(ushort4*)&out[(size_t)(c0 + c) * R + r0 + tc] = w;
    }
}

// ---------------- row softmax over scores [Z][T][S] ----------------
__global__ __launch_bounds__(64) void softmax_rows(float* __restrict__ sc, int causal)
{
    int t = blockIdx.x, z = blockIdx.y, lane = threadIdx.x;
    float* row = sc + ((size_t)z * gridDim.x + t) * SSEQ;
    int limit = causal ? (t + 1) : SSEQ;
    float v[8];
    float mx = -1e30f;
#pragma unroll
    for (int k = 0; k < 8; ++k) {
        int idx = lane + (k << 6);
        float val = (idx < limit) ? row[idx] : -1e30f;
        v[k] = val; mx = fmaxf(mx, val);
    }
#pragma unroll
    for (int o = 1; o < 64; o <<= 1) mx = fmaxf(mx, __shfl_xor(mx, o, 64));
    float sum = 0.f;
#pragma unroll
    for (int k = 0; k < 8; ++k) {
        int idx = lane + (k << 6);
        float p = (idx < limit) ? __expf(v[k] - mx) : 0.f;
        v[k] = p; sum += p;
    }
#pragma unroll
    for (int o = 1; o < 64; o <<= 1) sum += __shfl_xor(sum, o, 64);
    float inv = 1.0f / sum;
#pragma unroll
    for (int k = 0; k < 8; ++k) row[lane + (k << 6)] = v[k] * inv;
}

// ---------------- router ----------------
__global__ __launch_bounds__(256) void router_kernel(
    const float* __restrict__ xf, const float* __restrict__ rw, const float* __restrict__ rb,
    const float* __restrict__ tmask,
    int* __restrict__ eidx, float* __restrict__ gate, int* __restrict__ valid,
    float* __restrict__ partials)
{
    int blk = blockIdx.x;
    int wid = threadIdx.x >> 6, lane = threadIdx.x & 63;
    __shared__ float wpart[4][10];
    float pe[8] = {0,0,0,0,0,0,0,0};
    float zacc = 0.f, nvacc = 0.f;

    for (int i = 0; i < 16; ++i) {
        int tok = blk * 64 + wid * 16 + i;
        const float* xrow = xf + (size_t)tok * DMODEL;
        float acc[8] = {0,0,0,0,0,0,0,0};
#pragma unroll 4
        for (int kk = 0; kk < 16; ++kk) {
            int d = lane + (kk << 6);
            float xd = xrow[d];
            const float4* rp = (const float4*)(rw + (size_t)d * 8);
            float4 r0 = rp[0], r1 = rp[1];
            acc[0] = fmaf(xd, r0.x, acc[0]); acc[1] = fmaf(xd, r0.y, acc[1]);
            acc[2] = fmaf(xd, r0.z, acc[2]); acc[3] = fmaf(xd, r0.w, acc[3]);
            acc[4] = fmaf(xd, r1.x, acc[4]); acc[5] = fmaf(xd, r1.y, acc[5]);
            acc[6] = fmaf(xd, r1.z, acc[6]); acc[7] = fmaf(xd, r1.w, acc[7]);
        }
#pragma unroll
        for (int e = 0; e < 8; ++e)
#pragma unroll
            for (int o = 1; o < 64; o <<= 1) acc[e] += __shfl_xor(acc[e], o, 64);
        if (lane == 0) {
            float l[8]; float m = -1e30f;
#pragma unroll
            for (int e = 0; e < 8; ++e) { l[e] = acc[e] + rb[e]; m = fmaxf(m, l[e]); }
            float se = 0.f;
#pragma unroll
            for (int e = 0; e < 8; ++e) se += expf(l[e] - m);
            int am = 0; float bm = l[0];
#pragma unroll
            for (int e = 1; e < 8; ++e) if (l[e] > bm) { bm = l[e]; am = e; }
            float inv_se = 1.0f / se;
            float g = expf(l[am] - m) * inv_se;
            float vld = (tmask[tok] > 0.f) ? 1.f : 0.f;
            eidx[tok] = am; gate[tok] = g; valid[tok] = (int)vld;
#pragma unroll
            for (int e = 0; e < 8; ++e) pe[e] += expf(l[e] - m) * inv_se * vld;
            float lse = logf(se) + m;
            zacc += lse * lse * vld;
            nvacc += vld;
        }
    }
    if (lane == 0) {
#pragma unroll
        for (int e = 0; e < 8; ++e) wpart[wid][e] = pe[e];
        wpart[wid][8] = zacc; wpart[wid][9] = nvacc;
    }
    __syncthreads();
    if (threadIdx.x == 0) {
        for (int j = 0; j < 10; ++j)
            partials[blk * 10 + j] = wpart[0][j] + wpart[1][j] + wpart[2][j] + wpart[3][j];
    }
}

// ---------------- capacity scan ----------------
__global__ __launch_bounds__(256) void scan_kernel(
    const int* __restrict__ eidx, const int* __restrict__ valid, const float* __restrict__ gate,
    int* __restrict__ pc, float* __restrict__ gk, int* __restrict__ keepf,
    int* __restrict__ counts)
{
    __shared__ int cnt[256][8];
    int tid = threadIdx.x;
    int local[8] = {0,0,0,0,0,0,0,0};
    int base = tid * 16;
    for (int i = 0; i < 16; ++i) { int e = eidx[base + i]; local[e] += valid[base + i]; }
#pragma unroll
    for (int e = 0; e < 8; ++e) cnt[tid][e] = local[e];
    __syncthreads();
    if (tid < 8) {
        int run = 0;
        for (int i = 0; i < 256; ++i) { int t = cnt[i][tid]; cnt[i][tid] = run; run += t; }
        counts[tid] = run;
    }
    __syncthreads();
    int off[8];
#pragma unroll
    for (int e = 0; e < 8; ++e) off[e] = cnt[tid][e];
    for (int i = 0; i < 16; ++i) {
        int tok = base + i;
        int e = eidx[tok], v = valid[tok];
        int pos = off[e]; off[e] += v;
        int kp = (v && pos < CAPE) ? 1 : 0;
        pc[tok]    = (pos < CAPE) ? pos : (CAPE - 1);
        keepf[tok] = kp;
        gk[tok]    = kp ? gate[tok] : 0.f;
    }
}

// ---------------- dispatch (expert-range) -> bf16 buffers ----------------
__global__ __launch_bounds__(256) void dispatch_bf16(const float* __restrict__ tln,
    const int* __restrict__ eidx, const int* __restrict__ pc, const int* __restrict__ keepf,
    unsigned short* __restrict__ buf, int e0, int ec)
{
    int tok = blockIdx.x;
    if (!keepf[tok]) return;
    int e = eidx[tok];
    if (e < e0 || e >= e0 + ec) return;
    int p = pc[tok];
    const float4 v = ((const float4*)(tln + (size_t)tok * DMODEL))[threadIdx.x];
    ushort4 o;
    o.x = f2bf(v.x); o.y = f2bf(v.y); o.z = f2bf(v.z); o.w = f2bf(v.w);
    ((ushort4*)(buf + ((size_t)(e - e0) * CAPE + p) * DMODEL))[threadIdx.x] = o;
}

// ---------------- combine add: out += gk * ob ----------------
__global__ __launch_bounds__(256) void combine_add(const float* __restrict__ ob,
    const int* __restrict__ eidx, const int* __restrict__ pc, const float* __restrict__ gk,
    float* __restrict__ out, int e0, int ec)
{
    int tok = blockIdx.x;
    int e = eidx[tok];
    if (e < e0 || e >= e0 + ec) return;
    float g = gk[tok];
    int p = pc[tok];
    float4* o = (float4*)(out + (size_t)tok * DMODEL);
    const float4 ov = ((const float4*)(ob + ((size_t)(e - e0) * CAPE + p) * DMODEL))[threadIdx.x];
    float4 a = o[threadIdx.x];
    a.x += g * ov.x; a.y += g * ov.y; a.z += g * ov.z; a.w += g * ov.w;
    o[threadIdx.x] = a;
}

// ---------------- final scalar losses ----------------
__global__ __launch_bounds__(64) void loss_kernel(const float* __restrict__ partials,
    const int* __restrict__ counts, float* __restrict__ out2)
{
    int lane = threadIdx.x;
    float p[10];
#pragma unroll
    for (int j = 0; j < 10; ++j) p[j] = partials[lane * 10 + j];
#pragma unroll
    for (int j = 0; j < 10; ++j)
#pragma unroll
        for (int o = 1; o < 64; o <<= 1) p[j] += __shfl_xor(p[j], o, 64);
    if (lane == 0) {
        float nv = fmaxf(p[9], 1.f);
        float lb = 0.f;
        for (int e = 0; e < 8; ++e) lb += ((float)counts[e] / nv) * (p[e] / nv);
        lb *= (float)NEXP;
        out2[0] = lb;
        out2[1] = p[8] / nv;
    }
}

// ---------------- host launch ----------------
extern "C" void kernel_launch(void* const* d_in, const int* in_sizes, int n_in,
                              void* d_out, int out_size, void* d_ws, size_t ws_size,
                              hipStream_t stream)
{
    const float* tgt        = (const float*)d_in[0];
    const float* src        = (const float*)d_in[1];
    const float* token_mask = (const float*)d_in[5];
    const float* ln1w = (const float*)d_in[6],  *ln1b = (const float*)d_in[7];
    const float* self_in_w  = (const float*)d_in[8],  *self_in_b  = (const float*)d_in[9];
    const float* self_out_w = (const float*)d_in[10], *self_out_b = (const float*)d_in[11];
    const float* ln2w = (const float*)d_in[12], *ln2b = (const float*)d_in[13];
    const float* enc_in_w   = (const float*)d_in[14], *enc_in_b   = (const float*)d_in[15];
    const float* enc_out_w  = (const float*)d_in[16], *enc_out_b  = (const float*)d_in[17];
    const float* ln3w = (const float*)d_in[18], *ln3b = (const float*)d_in[19];
    const float* rw = (const float*)d_in[20], *rb = (const float*)d_in[21];
    const float* w1 = (const float*)d_in[22], *b1 = (const float*)d_in[23];
    const float* w2 = (const float*)d_in[24], *b2 = (const float*)d_in[25];

    float* out = (float*)d_out;          // residual stream `x` lives HERE
    float* ws  = (float*)d_ws;

    // ---- fixed layout (floats) ----
    float* tln = ws;                         // 4,194,304
    float* ctx = ws + 4194304;               // 4,194,304
    int*   eidxA   = (int*)(ws + 8388608);
    int*   validA  = eidxA + 4096;
    int*   pcA     = validA + 4096;
    int*   keepA   = pcA + 4096;
    int*   countsA = keepA + 4096;           // 16
    float* gateA   = (float*)(countsA + 16);
    float* gkA     = gateA + 4096;
    float* partA   = gkA + 4096;             // 640
    const size_t POOL_OFF = 8425984;         // floats; 16B aligned
    float* pool = ws + POOL_OFF;

    // ---- adaptive chunk plan (pure function of ws_size -> deterministic) ----
    size_t Wf = ws_size / sizeof(float);
    size_t pf = (Wf > POOL_OFF) ? (Wf - POOL_OFF) : 0;

    int bc = 1, hg = 1;  // attention: bc batches, hg heads per score pass
    {
        const int cb[8] = {8,4,2,1,1,1,1,1};
        const int ch[8] = {16,16,16,16,8,4,2,1};
        for (int i = 0; i < 8; ++i) {
            size_t need = (size_t)cb[i] * 1572864ull + (size_t)cb[i] * ch[i] * 262144ull;
            if (need <= pf) { bc = cb[i]; hg = ch[i]; break; }
        }
    }
    int ec = 1;          // MoE: experts per pass; needs ec*6,488,064 pool floats
    for (int c = 8; c >= 1; c >>= 1)
        if ((size_t)c * 6488064ull <= pf) { ec = c; break; }

    const long long TS = (long long)TSEQ * SSEQ;          // 262,144

    // ===== 1) LN1 =====
    ln_kernel<<<NTOK, 256, 0, stream>>>(tgt, ln1w, ln1b, tln);

    // ===== 2-3) self attention: bc batches x hg heads per pass =====
    for (int b0 = 0; b0 < BATCH; b0 += bc) {
        float* qkvC = pool;                                // bc * 512*3072
        float* scC  = pool + (size_t)bc * 1572864;         // bc * hg * T * S
        gemm_f32<true,false><<<dim3(48, bc * 8, 1), 256, 0, stream>>>(
            tln + (size_t)b0 * 512 * 1024, self_in_w, self_in_b, nullptr, qkvC,
            1024, 1024, 1024, 3072, 1, 0,0,0,0,0,0,0, 1.0f);
        for (int h0 = 0; h0 < NHEAD; h0 += hg) {
            gemm_f32<true,false><<<dim3(8, 8, bc * hg), 256, 0, stream>>>(
                qkvC + h0 * 64, qkvC + 1024 + h0 * 64, nullptr, nullptr, scC,
                64, 3072, 3072, SSEQ, hg,
                (long long)512 * 3072, 64, (long long)512 * 3072, 64,
                (long long)hg * TS, TS, 0, 0.125f);
            softmax_rows<<<dim3(TSEQ, bc * hg), 64, 0, stream>>>(scC, 1);
            gemm_f32<false,false><<<dim3(1, 8, bc * hg), 256, 0, stream>>>(
                scC, qkvC + 2048 + h0 * 64, nullptr, nullptr,
                ctx + (size_t)b0 * 512 * 1024 + h0 * 64,
                512, SSEQ, 3072, 1024, hg,
                (long long)hg * TS, TS, (long long)512 * 3072, 64,
                (long long)512 * 1024, 64, 0, 1.0f);
        }
    }

    // ===== 4) self out-proj + residual(tgt) -> out (x) =====
    gemm_f32<true,false><<<dim3(16, 64, 1), 256, 0, stream>>>(
        ctx, self_out_w, self_out_b, tgt, out,
        1024, 1024, 1024, 1024, 1, 0,0,0,0,0,0,0, 1.0f);

    // ===== 5) LN2 =====
    ln_kernel<<<NTOK, 256, 0, stream>>>(out, ln2w, ln2b, tln);

    // ===== 6-7) cross attention =====
    for (int b0 = 0; b0 < BATCH; b0 += bc) {
        float* q2C  = pool;                                // bc * 512*1024
        float* kv2C = pool + (size_t)bc * 524288;          // bc * 512*2048
        float* scC  = pool + (size_t)bc * 1572864;         // bc * hg * T * S
        gemm_f32<true,false><<<dim3(16, bc * 8, 1), 256, 0, stream>>>(
            tln + (size_t)b0 * 512 * 1024, enc_in_w, enc_in_b, nullptr, q2C,
            1024, 1024, 1024, 1024, 1, 0,0,0,0,0,0,0, 1.0f);
        gemm_f32<true,false><<<dim3(32, bc * 8, 1), 256, 0, stream>>>(
            src + (size_t)b0 * 512 * 1024, enc_in_w + (size_t)1024 * 1024, enc_in_b + 1024,
            nullptr, kv2C,
            1024, 1024, 1024, 2048, 1, 0,0,0,0,0,0,0, 1.0f);
        for (int h0 = 0; h0 < NHEAD; h0 += hg) {
            gemm_f32<true,false><<<dim3(8, 8, bc * hg), 256, 0, stream>>>(
                q2C + h0 * 64, kv2C + h0 * 64, nullptr, nullptr, scC,
                64, 1024, 2048, SSEQ, hg,
                (long long)512 * 1024, 64, (long long)512 * 2048, 64,
                (long long)hg * TS, TS, 0, 0.125f);
            softmax_rows<<<dim3(TSEQ, bc * hg), 64, 0, stream>>>(scC, 0);
            gemm_f32<false,false><<<dim3(1, 8, bc * hg), 256, 0, stream>>>(
                scC, kv2C + 1024 + h0 * 64, nullptr, nullptr,
                ctx + (size_t)b0 * 512 * 1024 + h0 * 64,
                512, SSEQ, 2048, 1024, hg,
                (long long)hg * TS, TS, (long long)512 * 2048, 64,
                (long long)512 * 1024, 64, 0, 1.0f);
        }
    }

    // ===== 8) cross out-proj + residual -> out (in place) =====
    gemm_f32<true,false><<<dim3(16, 64, 1), 256, 0, stream>>>(
        ctx, enc_out_w, enc_out_b, out, out,
        1024, 1024, 1024, 1024, 1, 0,0,0,0,0,0,0, 1.0f);

    // ===== 9) LN3 =====
    ln_kernel<<<NTOK, 256, 0, stream>>>(out, ln3w, ln3b, tln);

    // ===== 10) router / scan =====
    router_kernel<<<64, 256, 0, stream>>>(tln, rw, rb, token_mask, eidxA, gateA, validA, partA);
    scan_kernel<<<1, 256, 0, stream>>>(eidxA, validA, gateA, pcA, gkA, keepA, countsA);

    // ===== 11) expert FFN via bf16 MFMA, ec experts per pass =====
    // pool layout per pass (floats):
    //   w1t  : ec*2,097,152   (bf16 [4096][1024] per expert)
    //   w2t  : ec*2,097,152   (bf16 [1024][4096] per expert)
    //   bufB : ec*327,680     (bf16 [640][1024])
    //   hB   : ec*1,310,720   (bf16 [640][4096])
    //   obC  : ec*655,360     (fp32 [640][1024])
    for (int e0 = 0; e0 < NEXP; e0 += ec) {
        unsigned short* w1t  = (unsigned short*)pool;
        unsigned short* w2t  = (unsigned short*)(pool + (size_t)ec * 2097152);
        unsigned short* bufB = (unsigned short*)(pool + (size_t)ec * 4194304);
        unsigned short* hB   = (unsigned short*)(pool + (size_t)ec * 4521984);
        float*          obC  =                   pool + (size_t)ec * 5832704;

        tcvt_kernel<<<dim3(64, 16, ec), 256, 0, stream>>>(
            w1 + (size_t)e0 * 4194304, w1t, 1024, 4096);
        tcvt_kernel<<<dim3(16, 64, ec), 256, 0, stream>>>(
            w2 + (size_t)e0 * 4194304, w2t, 4096, 1024);
        hipMemsetAsync(bufB, 0, (size_t)ec * 655360 * sizeof(unsigned short), stream);
        dispatch_bf16<<<NTOK, 256, 0, stream>>>(tln, eidxA, pcA, keepA, bufB, e0, ec);

        gemm_bf16_nt<true, true><<<dim3(32, 5, ec), 256, 0, stream>>>(
            bufB, w1t, b1 + (size_t)e0 * 4096, hB,
            1024, 655360LL, 4194304LL, 2621440LL, 4096LL, 4096);
        gemm_bf16_nt<false, false><<<dim3(8, 5, ec), 256, 0, stream>>>(
            hB, w2t, b2 + (size_t)e0 * 1024, obC,
            4096, 2621440LL, 4194304LL, 655360LL, 1024LL, 1024);

        combine_add<<<NTOK, 256, 0, stream>>>(obC, eidxA, pcA, gkA, out, e0, ec);
    }

    // ===== 12) losses =====
    loss_kernel<<<1, 64, 0, stream>>>(partA, countsA, out + (size_t)NTOK * DMODEL);
}

// Round 5
// 1132.447 us; speedup vs baseline: 2.3904x; 1.5720x over previous
//
#include <hip/hip_runtime.h>
#include <cstdint>

// ---------------- problem constants ----------------
constexpr int BATCH  = 8;
constexpr int TSEQ   = 512;
constexpr int SSEQ   = 512;
constexpr int DMODEL = 1024;
constexpr int NHEAD  = 16;
constexpr int NEXP   = 8;
constexpr int CAPE   = 640;
constexpr int NTOK   = BATCH * TSEQ;        // 4096

__device__ __forceinline__ unsigned short f2bf(float f) {
    uint32_t u = __float_as_uint(f);
    uint32_t r = (u + 0x7FFFu + ((u >> 16) & 1u)) >> 16;   // RNE
    return (unsigned short)r;
}

typedef __attribute__((ext_vector_type(8))) short bfrag;
typedef __attribute__((ext_vector_type(8))) _Float16 hfrag;
typedef __attribute__((ext_vector_type(4))) float f32x4;

// ---------------- LayerNorm ----------------
__global__ __launch_bounds__(256) void ln_kernel(const float* __restrict__ in,
    const float* __restrict__ gw, const float* __restrict__ gb, float* __restrict__ out)
{
    int row = blockIdx.x, tid = threadIdx.x;
    const float4 v = *(const float4*)(in + (size_t)row * DMODEL + tid * 4);
    float s  = v.x + v.y + v.z + v.w;
    float ss = v.x*v.x + v.y*v.y + v.z*v.z + v.w*v.w;
#pragma unroll
    for (int o = 1; o < 64; o <<= 1) { s += __shfl_xor(s, o, 64); ss += __shfl_xor(ss, o, 64); }
    __shared__ float rs[4], rss[4];
    int wid = tid >> 6, lane = tid & 63;
    if (lane == 0) { rs[wid] = s; rss[wid] = ss; }
    __syncthreads();
    s  = rs[0] + rs[1] + rs[2] + rs[3];
    ss = rss[0] + rss[1] + rss[2] + rss[3];
    float mean = s * (1.0f / DMODEL);
    float var  = ss * (1.0f / DMODEL) - mean * mean;
    float inv  = rsqrtf(var + 1e-5f);
    float4 w4 = *(const float4*)(gw + tid * 4);
    float4 b4 = *(const float4*)(gb + tid * 4);
    float4 o;
    o.x = (v.x - mean) * inv * w4.x + b4.x;
    o.y = (v.y - mean) * inv * w4.y + b4.y;
    o.z = (v.z - mean) * inv * w4.z + b4.z;
    o.w = (v.w - mean) * inv * w4.w + b4.w;
    *(float4*)(out + (size_t)row * DMODEL + tid * 4) = o;
}

// ---------------- fp32 -> fp16 hi/lo split (elementwise) ----------------
__global__ __launch_bounds__(256) void split_f16(const float* __restrict__ in,
    _Float16* __restrict__ hi, _Float16* __restrict__ lo, int n8)
{
    int i = blockIdx.x * 256 + threadIdx.x;
    if (i >= n8) return;
    const float4* p = (const float4*)in + 2 * (size_t)i;
    float4 v0 = p[0], v1 = p[1];
    float vv[8] = {v0.x, v0.y, v0.z, v0.w, v1.x, v1.y, v1.z, v1.w};
    hfrag h, l;
#pragma unroll
    for (int j = 0; j < 8; ++j) {
        _Float16 hj = (_Float16)vv[j];
        h[j] = hj;
        l[j] = (_Float16)(vv[j] - (float)hj);
    }
    ((hfrag*)hi)[i] = h;
    ((hfrag*)lo)[i] = l;
}

// ---------------- fp16x2 (3-product) NT MFMA GEMM: fp32-accurate ----------------
// C[M,N] = (Ahi+Alo)[M,K] * (Bhi+Blo)[N,K]^T + bias (+res); drop lo*lo.
template<bool HASRES>
__global__ __launch_bounds__(256) void gemm_f16x2_nt(
    const _Float16* __restrict__ Ahi, const _Float16* __restrict__ Alo,
    const _Float16* __restrict__ Bhi, const _Float16* __restrict__ Blo,
    const float* __restrict__ bias, const float* __restrict__ res,
    float* __restrict__ C, int K, int ldc)
{
    __shared__ _Float16 AhL[4096], AlL[4096], BhL[4096], BlL[4096];
    int rowBase = blockIdx.y * 128, colBase = blockIdx.x * 128;
    int t = threadIdx.x, lane = t & 63, wid = t >> 6;
    int wr = (wid >> 1) * 64, wc = (wid & 1) * 64;
    int c1 = t, c2 = t + 256;
    int r1 = c1 >> 2, q1 = (c1 & 3) ^ ((r1 + (r1 >> 2)) & 3);
    int r2 = c2 >> 2, q2 = (c2 & 3) ^ ((r2 + (r2 >> 2)) & 3);
    const _Float16* Ah = Ahi + (size_t)rowBase * K;
    const _Float16* Al = Alo + (size_t)rowBase * K;
    const _Float16* Bh = Bhi + (size_t)colBase * K;
    const _Float16* Bl = Blo + (size_t)colBase * K;
    f32x4 acc[4][4] = {};
    int l15 = lane & 15, g = lane >> 4;

    for (int k0 = 0; k0 < K; k0 += 32) {
        __syncthreads();
#define GLL(SRC, DST) __builtin_amdgcn_global_load_lds( \
        (const __attribute__((address_space(1))) void*)(SRC), \
        (__attribute__((address_space(3))) void*)(DST), 16, 0, 0)
        GLL(Ah + (size_t)r1 * K + k0 + q1 * 8, &AhL[c1 * 8]);
        GLL(Ah + (size_t)r2 * K + k0 + q2 * 8, &AhL[c2 * 8]);
        GLL(Al + (size_t)r1 * K + k0 + q1 * 8, &AlL[c1 * 8]);
        GLL(Al + (size_t)r2 * K + k0 + q2 * 8, &AlL[c2 * 8]);
        GLL(Bh + (size_t)r1 * K + k0 + q1 * 8, &BhL[c1 * 8]);
        GLL(Bh + (size_t)r2 * K + k0 + q2 * 8, &BhL[c2 * 8]);
        GLL(Bl + (size_t)r1 * K + k0 + q1 * 8, &BlL[c1 * 8]);
        GLL(Bl + (size_t)r2 * K + k0 + q2 * 8, &BlL[c2 * 8]);
#undef GLL
        __syncthreads();

        hfrag bh[4], bl[4];
#pragma unroll
        for (int n = 0; n < 4; ++n) {
            int row = wc + n * 16 + l15;
            int sw = (g ^ ((row + (row >> 2)) & 3)) * 8;
            bh[n] = *(const hfrag*)&BhL[row * 32 + sw];
            bl[n] = *(const hfrag*)&BlL[row * 32 + sw];
        }
#pragma unroll
        for (int m = 0; m < 4; ++m) {
            int row = wr + m * 16 + l15;
            int sw = (g ^ ((row + (row >> 2)) & 3)) * 8;
            hfrag ah = *(const hfrag*)&AhL[row * 32 + sw];
            hfrag al = *(const hfrag*)&AlL[row * 32 + sw];
#pragma unroll
            for (int n = 0; n < 4; ++n) {
                acc[m][n] = __builtin_amdgcn_mfma_f32_16x16x32_f16(ah, bh[n], acc[m][n], 0, 0, 0);
                acc[m][n] = __builtin_amdgcn_mfma_f32_16x16x32_f16(ah, bl[n], acc[m][n], 0, 0, 0);
                acc[m][n] = __builtin_amdgcn_mfma_f32_16x16x32_f16(al, bh[n], acc[m][n], 0, 0, 0);
            }
        }
    }

    int g4 = g * 4;
#pragma unroll
    for (int m = 0; m < 4; ++m) {
        int row0 = rowBase + wr + m * 16 + g4;
#pragma unroll
        for (int n = 0; n < 4; ++n) {
            int col = colBase + wc + n * 16 + l15;
            float bv = bias[col];
#pragma unroll
            for (int j = 0; j < 4; ++j) {
                float v = acc[m][n][j] + bv;
                if (HASRES) v += res[(size_t)(row0 + j) * ldc + col];
                C[(size_t)(row0 + j) * ldc + col] = v;
            }
        }
    }
}

// ---------------- generic fp32 tiled GEMM (attention core) ----------------
template<bool TRANSB, bool RELU>
__global__ __launch_bounds__(256) void gemm_f32(
    const float* __restrict__ A, const float* __restrict__ Bm,
    const float* __restrict__ bias, const float* __restrict__ res,
    float* __restrict__ C,
    int K, int lda, int ldb, int ldc, int batchH,
    long long sAb, long long sAh, long long sBb, long long sBh,
    long long sCb, long long sCh, long long sBias,
    float alpha)
{
    __shared__ float As[16][68];
    __shared__ float Bs[16][68];
    int z  = blockIdx.z;
    int zb = z / batchH, zh = z - zb * batchH;
    A  += zb * sAb + zh * sAh;
    Bm += zb * sBb + zh * sBh;
    long long coff = zb * sCb + zh * sCh;
    C += coff;
    if (res)  res  += coff;
    if (bias) bias += zb * sBias;

    int rowBase = blockIdx.y << 6, colBase = blockIdx.x << 6;
    int tid = threadIdx.x;
    int ty = tid >> 4, tx = tid & 15;
    int la_k = tid & 15, la_n = tid >> 4;

    float acc[4][4] = {};

    for (int k0 = 0; k0 < K; k0 += 16) {
#pragma unroll
        for (int p = 0; p < 4; ++p) {
            int n = la_n + (p << 4);
            As[la_k][n] = A[(size_t)(rowBase + n) * lda + (k0 + la_k)];
        }
        if (TRANSB) {
#pragma unroll
            for (int p = 0; p < 4; ++p) {
                int m = la_n + (p << 4);
                Bs[la_k][m] = Bm[(size_t)(colBase + m) * ldb + (k0 + la_k)];
            }
        } else {
            int lb_m = tid & 63, lb_k = tid >> 6;
#pragma unroll
            for (int p = 0; p < 4; ++p) {
                int k = lb_k + (p << 2);
                Bs[k][lb_m] = Bm[(size_t)(k0 + k) * ldb + (colBase + lb_m)];
            }
        }
        __syncthreads();
#pragma unroll
        for (int k = 0; k < 16; ++k) {
            float4 a4 = *(const float4*)&As[k][ty << 2];
            float4 b4 = *(const float4*)&Bs[k][tx << 2];
            float ar[4] = {a4.x, a4.y, a4.z, a4.w};
            float br[4] = {b4.x, b4.y, b4.z, b4.w};
#pragma unroll
            for (int i = 0; i < 4; ++i)
#pragma unroll
                for (int j = 0; j < 4; ++j)
                    acc[i][j] = fmaf(ar[i], br[j], acc[i][j]);
        }
        __syncthreads();
    }

    float4 bv = {0.f, 0.f, 0.f, 0.f};
    if (bias) bv = *(const float4*)&bias[colBase + (tx << 2)];
#pragma unroll
    for (int i = 0; i < 4; ++i) {
        int r = rowBase + (ty << 2) + i;
        float4 v;
        v.x = acc[i][0] * alpha + bv.x;
        v.y = acc[i][1] * alpha + bv.y;
        v.z = acc[i][2] * alpha + bv.z;
        v.w = acc[i][3] * alpha + bv.w;
        if (res) {
            float4 rr = *(const float4*)&res[(size_t)r * ldc + colBase + (tx << 2)];
            v.x += rr.x; v.y += rr.y; v.z += rr.z; v.w += rr.w;
        }
        if (RELU) {
            v.x = fmaxf(v.x, 0.f); v.y = fmaxf(v.y, 0.f);
            v.z = fmaxf(v.z, 0.f); v.w = fmaxf(v.w, 0.f);
        }
        *(float4*)&C[(size_t)r * ldc + colBase + (tx << 2)] = v;
    }
}

// ---------------- bf16 NT MFMA GEMM (MoE) ----------------
template<bool RELU, bool OBF16>
__global__ __launch_bounds__(256) void gemm_bf16_nt(
    const unsigned short* __restrict__ A,   // [M][K] bf16
    const unsigned short* __restrict__ Bt,  // [N][K] bf16
    const float* __restrict__ bias,         // [N] fp32
    void* __restrict__ Cv,
    int K, long long sA, long long sB, long long sC, long long sBias, int ldc)
{
    __shared__ unsigned short Al[128 * 32];
    __shared__ unsigned short Bl[128 * 32];
    int z = blockIdx.z;
    A  += (size_t)z * sA;
    Bt += (size_t)z * sB;
    bias += (size_t)z * sBias;
    long long zC = (long long)z * sC;

    int rowBase = blockIdx.y * 128, colBase = blockIdx.x * 128;
    int t = threadIdx.x, lane = t & 63, wid = t >> 6;
    int wr = (wid >> 1) * 64, wc = (wid & 1) * 64;

    int c1 = t, c2 = t + 256;
    int r1 = c1 >> 2, q1 = (c1 & 3) ^ ((r1 + (r1 >> 2)) & 3);
    int r2 = c2 >> 2, q2 = (c2 & 3) ^ ((r2 + (r2 >> 2)) & 3);

    const unsigned short* Ag = A  + (size_t)rowBase * K;
    const unsigned short* Bg = Bt + (size_t)colBase * K;

    f32x4 acc[4][4] = {};
    int l15 = lane & 15, g = lane >> 4;

    for (int k0 = 0; k0 < K; k0 += 32) {
        __syncthreads();
        __builtin_amdgcn_global_load_lds(
            (const __attribute__((address_space(1))) void*)(Ag + (size_t)r1 * K + k0 + q1 * 8),
            (__attribute__((address_space(3))) void*)(&Al[c1 * 8]), 16, 0, 0);
        __builtin_amdgcn_global_load_lds(
            (const __attribute__((address_space(1))) void*)(Ag + (size_t)r2 * K + k0 + q2 * 8),
            (__attribute__((address_space(3))) void*)(&Al[c2 * 8]), 16, 0, 0);
        __builtin_amdgcn_global_load_lds(
            (const __attribute__((address_space(1))) void*)(Bg + (size_t)r1 * K + k0 + q1 * 8),
            (__attribute__((address_space(3))) void*)(&Bl[c1 * 8]), 16, 0, 0);
        __builtin_amdgcn_global_load_lds(
            (const __attribute__((address_space(1))) void*)(Bg + (size_t)r2 * K + k0 + q2 * 8),
            (__attribute__((address_space(3))) void*)(&Bl[c2 * 8]), 16, 0, 0);
        __syncthreads();

        bfrag a[4], b[4];
#pragma unroll
        for (int m = 0; m < 4; ++m) {
            int row = wr + m * 16 + l15;
            int sw = (g ^ ((row + (row >> 2)) & 3)) * 8;
            a[m] = *(const bfrag*)&Al[row * 32 + sw];
        }
#pragma unroll
        for (int n = 0; n < 4; ++n) {
            int row = wc + n * 16 + l15;
            int sw = (g ^ ((row + (row >> 2)) & 3)) * 8;
            b[n] = *(const bfrag*)&Bl[row * 32 + sw];
        }
#pragma unroll
        for (int m = 0; m < 4; ++m)
#pragma unroll
            for (int n = 0; n < 4; ++n)
                acc[m][n] = __builtin_amdgcn_mfma_f32_16x16x32_bf16(a[m], b[n], acc[m][n], 0, 0, 0);
    }

    int g4 = g * 4;
#pragma unroll
    for (int m = 0; m < 4; ++m) {
        int row0 = rowBase + wr + m * 16 + g4;
#pragma unroll
        for (int n = 0; n < 4; ++n) {
            int col = colBase + wc + n * 16 + l15;
            float bv = bias[col];
#pragma unroll
            for (int j = 0; j < 4; ++j) {
                float v = acc[m][n][j] + bv;
                if (RELU) v = fmaxf(v, 0.f);
                if (OBF16)
                    ((unsigned short*)Cv)[zC + (size_t)(row0 + j) * ldc + col] = f2bf(v);
                else
                    ((float*)Cv)[zC + (size_t)(row0 + j) * ldc + col] = v;
            }
        }
    }
}

// ---------------- transpose+convert fp32 [R][Cn] -> bf16 [Cn][R] (per z) ----------------
__global__ __launch_bounds__(256) void tcvt_kernel(const float* __restrict__ in,
    unsigned short* __restrict__ out, int R, int Cn)
{
    __shared__ unsigned short tile[64][68];
    size_t zoff = (size_t)blockIdx.z * R * Cn;
    in += zoff; out += zoff;
    int r0 = blockIdx.y * 64, c0 = blockIdx.x * 64;
    int tr = threadIdx.x >> 4, tc = (threadIdx.x & 15) * 4;
#pragma unroll
    for (int i = 0; i < 4; ++i) {
        int r = tr + i * 16;
        float4 v = *(const float4*)&in[(size_t)(r0 + r) * Cn + c0 + tc];
        tile[r][tc + 0] = f2bf(v.x);
        tile[r][tc + 1] = f2bf(v.y);
        tile[r][tc + 2] = f2bf(v.z);
        tile[r][tc + 3] = f2bf(v.w);
    }
    __syncthreads();
#pragma unroll
    for (int i = 0; i < 4; ++i) {
        int c = tr + i * 16;
        ushort4 w;
        w.x = tile[tc + 0][c];
        w.y = tile[tc + 1][c];
        w.z = tile[tc + 2][c];
        w.w = tile[tc + 3][c];
        *(ushort4*)&out[(size_t)(c0 + c) * R + r0 + tc] = w;
    }
}

// ---------------- row softmax over scores [Z][T][S] ----------------
__global__ __launch_bounds__(64) void softmax_rows(float* __restrict__ sc, int causal)
{
    int t = blockIdx.x, z = blockIdx.y, lane = threadIdx.x;
    float* row = sc + ((size_t)z * gridDim.x + t) * SSEQ;
    int limit = causal ? (t + 1) : SSEQ;
    float v[8];
    float mx = -1e30f;
#pragma unroll
    for (int k = 0; k < 8; ++k) {
        int idx = lane + (k << 6);
        float val = (idx < limit) ? row[idx] : -1e30f;
        v[k] = val; mx = fmaxf(mx, val);
    }
#pragma unroll
    for (int o = 1; o < 64; o <<= 1) mx = fmaxf(mx, __shfl_xor(mx, o, 64));
    float sum = 0.f;
#pragma unroll
    for (int k = 0; k < 8; ++k) {
        int idx = lane + (k << 6);
        float p = (idx < limit) ? __expf(v[k] - mx) : 0.f;
        v[k] = p; sum += p;
    }
#pragma unroll
    for (int o = 1; o < 64; o <<= 1) sum += __shfl_xor(sum, o, 64);
    float inv = 1.0f / sum;
#pragma unroll
    for (int k = 0; k < 8; ++k) row[lane + (k << 6)] = v[k] * inv;
}

// ---------------- router ----------------
__global__ __launch_bounds__(256) void router_kernel(
    const float* __restrict__ xf, const float* __restrict__ rw, const float* __restrict__ rb,
    const float* __restrict__ tmask,
    int* __restrict__ eidx, float* __restrict__ gate, int* __restrict__ valid,
    float* __restrict__ partials)
{
    int blk = blockIdx.x;
    int wid = threadIdx.x >> 6, lane = threadIdx.x & 63;
    __shared__ float wpart[4][10];
    float pe[8] = {0,0,0,0,0,0,0,0};
    float zacc = 0.f, nvacc = 0.f;

    for (int i = 0; i < 16; ++i) {
        int tok = blk * 64 + wid * 16 + i;
        const float* xrow = xf + (size_t)tok * DMODEL;
        float acc[8] = {0,0,0,0,0,0,0,0};
#pragma unroll 4
        for (int kk = 0; kk < 16; ++kk) {
            int d = lane + (kk << 6);
            float xd = xrow[d];
            const float4* rp = (const float4*)(rw + (size_t)d * 8);
            float4 r0 = rp[0], r1 = rp[1];
            acc[0] = fmaf(xd, r0.x, acc[0]); acc[1] = fmaf(xd, r0.y, acc[1]);
            acc[2] = fmaf(xd, r0.z, acc[2]); acc[3] = fmaf(xd, r0.w, acc[3]);
            acc[4] = fmaf(xd, r1.x, acc[4]); acc[5] = fmaf(xd, r1.y, acc[5]);
            acc[6] = fmaf(xd, r1.z, acc[6]); acc[7] = fmaf(xd, r1.w, acc[7]);
        }
#pragma unroll
        for (int e = 0; e < 8; ++e)
#pragma unroll
            for (int o = 1; o < 64; o <<= 1) acc[e] += __shfl_xor(acc[e], o, 64);
        if (lane == 0) {
            float l[8]; float m = -1e30f;
#pragma unroll
            for (int e = 0; e < 8; ++e) { l[e] = acc[e] + rb[e]; m = fmaxf(m, l[e]); }
            float se = 0.f;
#pragma unroll
            for (int e = 0; e < 8; ++e) se += expf(l[e] - m);
            int am = 0; float bm = l[0];
#pragma unroll
            for (int e = 1; e < 8; ++e) if (l[e] > bm) { bm = l[e]; am = e; }
            float inv_se = 1.0f / se;
            float g = expf(l[am] - m) * inv_se;
            float vld = (tmask[tok] > 0.f) ? 1.f : 0.f;
            eidx[tok] = am; gate[tok] = g; valid[tok] = (int)vld;
#pragma unroll
            for (int e = 0; e < 8; ++e) pe[e] += expf(l[e] - m) * inv_se * vld;
            float lse = logf(se) + m;
            zacc += lse * lse * vld;
            nvacc += vld;
        }
    }
    if (lane == 0) {
#pragma unroll
        for (int e = 0; e < 8; ++e) wpart[wid][e] = pe[e];
        wpart[wid][8] = zacc; wpart[wid][9] = nvacc;
    }
    __syncthreads();
    if (threadIdx.x == 0) {
        for (int j = 0; j < 10; ++j)
            partials[blk * 10 + j] = wpart[0][j] + wpart[1][j] + wpart[2][j] + wpart[3][j];
    }
}

// ---------------- capacity scan ----------------
__global__ __launch_bounds__(256) void scan_kernel(
    const int* __restrict__ eidx, const int* __restrict__ valid, const float* __restrict__ gate,
    int* __restrict__ pc, float* __restrict__ gk, int* __restrict__ keepf,
    int* __restrict__ counts)
{
    __shared__ int cnt[256][8];
    int tid = threadIdx.x;
    int local[8] = {0,0,0,0,0,0,0,0};
    int base = tid * 16;
    for (int i = 0; i < 16; ++i) { int e = eidx[base + i]; local[e] += valid[base + i]; }
#pragma unroll
    for (int e = 0; e < 8; ++e) cnt[tid][e] = local[e];
    __syncthreads();
    if (tid < 8) {
        int run = 0;
        for (int i = 0; i < 256; ++i) { int t = cnt[i][tid]; cnt[i][tid] = run; run += t; }
        counts[tid] = run;
    }
    __syncthreads();
    int off[8];
#pragma unroll
    for (int e = 0; e < 8; ++e) off[e] = cnt[tid][e];
    for (int i = 0; i < 16; ++i) {
        int tok = base + i;
        int e = eidx[tok], v = valid[tok];
        int pos = off[e]; off[e] += v;
        int kp = (v && pos < CAPE) ? 1 : 0;
        pc[tok]    = (pos < CAPE) ? pos : (CAPE - 1);
        keepf[tok] = kp;
        gk[tok]    = kp ? gate[tok] : 0.f;
    }
}

// ---------------- dispatch (expert-range) -> bf16 buffers ----------------
__global__ __launch_bounds__(256) void dispatch_bf16(const float* __restrict__ tln,
    const int* __restrict__ eidx, const int* __restrict__ pc, const int* __restrict__ keepf,
    unsigned short* __restrict__ buf, int e0, int ec)
{
    int tok = blockIdx.x;
    if (!keepf[tok]) return;
    int e = eidx[tok];
    if (e < e0 || e >= e0 + ec) return;
    int p = pc[tok];
    const float4 v = ((const float4*)(tln + (size_t)tok * DMODEL))[threadIdx.x];
    ushort4 o;
    o.x = f2bf(v.x); o.y = f2bf(v.y); o.z = f2bf(v.z); o.w = f2bf(v.w);
    ((ushort4*)(buf + ((size_t)(e - e0) * CAPE + p) * DMODEL))[threadIdx.x] = o;
}

// ---------------- combine add: out += gk * ob ----------------
__global__ __launch_bounds__(256) void combine_add(const float* __restrict__ ob,
    const int* __restrict__ eidx, const int* __restrict__ pc, const float* __restrict__ gk,
    float* __restrict__ out, int e0, int ec)
{
    int tok = blockIdx.x;
    int e = eidx[tok];
    if (e < e0 || e >= e0 + ec) return;
    float g = gk[tok];
    int p = pc[tok];
    float4* o = (float4*)(out + (size_t)tok * DMODEL);
    const float4 ov = ((const float4*)(ob + ((size_t)(e - e0) * CAPE + p) * DMODEL))[threadIdx.x];
    float4 a = o[threadIdx.x];
    a.x += g * ov.x; a.y += g * ov.y; a.z += g * ov.z; a.w += g * ov.w;
    o[threadIdx.x] = a;
}

// ---------------- final scalar losses ----------------
__global__ __launch_bounds__(64) void loss_kernel(const float* __restrict__ partials,
    const int* __restrict__ counts, float* __restrict__ out2)
{
    int lane = threadIdx.x;
    float p[10];
#pragma unroll
    for (int j = 0; j < 10; ++j) p[j] = partials[lane * 10 + j];
#pragma unroll
    for (int j = 0; j < 10; ++j)
#pragma unroll
        for (int o = 1; o < 64; o <<= 1) p[j] += __shfl_xor(p[j], o, 64);
    if (lane == 0) {
        float nv = fmaxf(p[9], 1.f);
        float lb = 0.f;
        for (int e = 0; e < 8; ++e) lb += ((float)counts[e] / nv) * (p[e] / nv);
        lb *= (float)NEXP;
        out2[0] = lb;
        out2[1] = p[8] / nv;
    }
}

// ---------------- host launch ----------------
extern "C" void kernel_launch(void* const* d_in, const int* in_sizes, int n_in,
                              void* d_out, int out_size, void* d_ws, size_t ws_size,
                              hipStream_t stream)
{
    const float* tgt        = (const float*)d_in[0];
    const float* src        = (const float*)d_in[1];
    const float* token_mask = (const float*)d_in[5];
    const float* ln1w = (const float*)d_in[6],  *ln1b = (const float*)d_in[7];
    const float* self_in_w  = (const float*)d_in[8],  *self_in_b  = (const float*)d_in[9];
    const float* self_out_w = (const float*)d_in[10], *self_out_b = (const float*)d_in[11];
    const float* ln2w = (const float*)d_in[12], *ln2b = (const float*)d_in[13];
    const float* enc_in_w   = (const float*)d_in[14], *enc_in_b   = (const float*)d_in[15];
    const float* enc_out_w  = (const float*)d_in[16], *enc_out_b  = (const float*)d_in[17];
    const float* ln3w = (const float*)d_in[18], *ln3b = (const float*)d_in[19];
    const float* rw = (const float*)d_in[20], *rb = (const float*)d_in[21];
    const float* w1 = (const float*)d_in[22], *b1 = (const float*)d_in[23];
    const float* w2 = (const float*)d_in[24], *b2 = (const float*)d_in[25];

    float* out = (float*)d_out;          // residual stream `x` lives HERE
    float* ws  = (float*)d_ws;

    // ---- fixed layout (floats) ----
    float* tln = ws;                         // 4,194,304
    float* ctx = ws + 4194304;               // 4,194,304
    int*   eidxA   = (int*)(ws + 8388608);
    int*   validA  = eidxA + 4096;
    int*   pcA     = validA + 4096;
    int*   keepA   = pcA + 4096;
    int*   countsA = keepA + 4096;           // 16
    float* gateA   = (float*)(countsA + 16);
    float* gkA     = gateA + 4096;
    float* partA   = gkA + 4096;             // 640
    const size_t POOL_OFF = 8425984;         // floats; 16B aligned
    float* pool = ws + POOL_OFF;

    // ---- adaptive plan (pure function of ws_size) ----
    size_t Wf = ws_size / sizeof(float);
    size_t pf = (Wf > POOL_OFF) ? (Wf - POOL_OFF) : 0;
    const size_t BIGBUF = 12582912;          // qkv | q2+kv2 region (floats)
    size_t availX = (pf > BIGBUF) ? (pf - BIGBUF) : 0;

    int bc = 1, hg = 1;  // scores chunking: bc batches x hg heads
    {
        const int cb[8] = {8,4,2,1,1,1,1,1};
        const int ch[8] = {16,16,16,16,8,4,2,1};
        for (int i = 0; i < 8; ++i) {
            size_t need = (size_t)cb[i] * ch[i] * 262144ull;
            if (need <= availX) { bc = cb[i]; hg = ch[i]; break; }
        }
    }
    int ec = 1;          // MoE: experts per pass
    for (int c = 8; c >= 1; c >>= 1)
        if ((size_t)c * 6488064ull <= pf) { ec = c; break; }

    const long long TS = (long long)TSEQ * SSEQ;

    float* P0 = pool;
    float* X  = pool + BIGBUF;

    // ================= self attention =================
    ln_kernel<<<NTOK, 256, 0, stream>>>(tgt, ln1w, ln1b, tln);

    // splits: tln -> (thi,tlo); self_in_w -> (whi,wlo)   [region X]
    _Float16* thi = (_Float16*)X;
    _Float16* tlo = (_Float16*)(X + 2097152);
    _Float16* whi = (_Float16*)(X + 4194304);
    _Float16* wlo = (_Float16*)(X + 5767168);
    split_f16<<<2048, 256, 0, stream>>>(tln, thi, tlo, 524288);
    split_f16<<<1536, 256, 0, stream>>>(self_in_w, whi, wlo, 393216);

    float* qkv = P0;   // [4096,3072] fp32
    gemm_f16x2_nt<false><<<dim3(24, 32, 1), 256, 0, stream>>>(
        thi, tlo, whi, wlo, self_in_b, nullptr, qkv, 1024, 3072);

    // scores/PV chunks  [scores in region X; splits dead]
    float* scX = X;
    for (int b0 = 0; b0 < BATCH; b0 += bc)
        for (int h0 = 0; h0 < NHEAD; h0 += hg) {
            gemm_f32<true,false><<<dim3(8, 8, bc * hg), 256, 0, stream>>>(
                qkv + (size_t)b0 * 512 * 3072 + h0 * 64,
                qkv + (size_t)b0 * 512 * 3072 + 1024 + h0 * 64,
                nullptr, nullptr, scX,
                64, 3072, 3072, SSEQ, hg,
                (long long)512 * 3072, 64, (long long)512 * 3072, 64,
                (long long)hg * TS, TS, 0, 0.125f);
            softmax_rows<<<dim3(TSEQ, bc * hg), 64, 0, stream>>>(scX, 1);
            gemm_f32<false,false><<<dim3(1, 8, bc * hg), 256, 0, stream>>>(
                scX, qkv + (size_t)b0 * 512 * 3072 + 2048 + h0 * 64, nullptr, nullptr,
                ctx + (size_t)b0 * 512 * 1024 + h0 * 64,
                512, SSEQ, 3072, 1024, hg,
                (long long)hg * TS, TS, (long long)512 * 3072, 64,
                (long long)512 * 1024, 64, 0, 1.0f);
        }

    // out-proj 1 + residual(tgt) -> out   [splits in P0; qkv dead]
    _Float16* chi  = (_Float16*)P0;
    _Float16* clo  = (_Float16*)(P0 + 2097152);
    _Float16* owhi = (_Float16*)(P0 + 4194304);
    _Float16* owlo = (_Float16*)(P0 + 4718592);
    split_f16<<<2048, 256, 0, stream>>>(ctx, chi, clo, 524288);
    split_f16<<<512, 256, 0, stream>>>(self_out_w, owhi, owlo, 131072);
    gemm_f16x2_nt<true><<<dim3(8, 32, 1), 256, 0, stream>>>(
        chi, clo, owhi, owlo, self_out_b, tgt, out, 1024, 1024);

    // ================= cross attention =================
    ln_kernel<<<NTOK, 256, 0, stream>>>(out, ln2w, ln2b, tln);

    _Float16* thi2 = (_Float16*)X;
    _Float16* tlo2 = (_Float16*)(X + 2097152);
    _Float16* shi  = (_Float16*)(X + 4194304);
    _Float16* slo  = (_Float16*)(X + 6291456);
    _Float16* ehi  = (_Float16*)(X + 8388608);
    _Float16* elo  = (_Float16*)(X + 9961472);
    split_f16<<<2048, 256, 0, stream>>>(tln, thi2, tlo2, 524288);
    split_f16<<<2048, 256, 0, stream>>>(src, shi, slo, 524288);
    split_f16<<<1536, 256, 0, stream>>>(enc_in_w, ehi, elo, 393216);

    float* q2  = P0;               // [4096,1024]
    float* kv2 = P0 + 4194304;     // [4096,2048]
    gemm_f16x2_nt<false><<<dim3(8, 32, 1), 256, 0, stream>>>(
        thi2, tlo2, ehi, elo, enc_in_b, nullptr, q2, 1024, 1024);
    gemm_f16x2_nt<false><<<dim3(16, 32, 1), 256, 0, stream>>>(
        shi, slo, ehi + (size_t)1024 * 1024, elo + (size_t)1024 * 1024,
        enc_in_b + 1024, nullptr, kv2, 1024, 2048);

    for (int b0 = 0; b0 < BATCH; b0 += bc)
        for (int h0 = 0; h0 < NHEAD; h0 += hg) {
            gemm_f32<true,false><<<dim3(8, 8, bc * hg), 256, 0, stream>>>(
                q2  + (size_t)b0 * 512 * 1024 + h0 * 64,
                kv2 + (size_t)b0 * 512 * 2048 + h0 * 64,
                nullptr, nullptr, scX,
                64, 1024, 2048, SSEQ, hg,
                (long long)512 * 1024, 64, (long long)512 * 2048, 64,
                (long long)hg * TS, TS, 0, 0.125f);
            softmax_rows<<<dim3(TSEQ, bc * hg), 64, 0, stream>>>(scX, 0);
            gemm_f32<false,false><<<dim3(1, 8, bc * hg), 256, 0, stream>>>(
                scX, kv2 + (size_t)b0 * 512 * 2048 + 1024 + h0 * 64, nullptr, nullptr,
                ctx + (size_t)b0 * 512 * 1024 + h0 * 64,
                512, SSEQ, 2048, 1024, hg,
                (long long)hg * TS, TS, (long long)512 * 2048, 64,
                (long long)512 * 1024, 64, 0, 1.0f);
        }

    // out-proj 2 + residual -> out (in place)
    split_f16<<<2048, 256, 0, stream>>>(ctx, chi, clo, 524288);
    split_f16<<<512, 256, 0, stream>>>(enc_out_w, owhi, owlo, 131072);
    gemm_f16x2_nt<true><<<dim3(8, 32, 1), 256, 0, stream>>>(
        chi, clo, owhi, owlo, enc_out_b, out, out, 1024, 1024);

    // ================= MoE =================
    ln_kernel<<<NTOK, 256, 0, stream>>>(out, ln3w, ln3b, tln);
    router_kernel<<<64, 256, 0, stream>>>(tln, rw, rb, token_mask, eidxA, gateA, validA, partA);
    scan_kernel<<<1, 256, 0, stream>>>(eidxA, validA, gateA, pcA, gkA, keepA, countsA);

    for (int e0 = 0; e0 < NEXP; e0 += ec) {
        unsigned short* w1t  = (unsigned short*)P0;
        unsigned short* w2t  = (unsigned short*)(P0 + (size_t)ec * 2097152);
        unsigned short* bufB = (unsigned short*)(P0 + (size_t)ec * 4194304);
        unsigned short* hB   = (unsigned short*)(P0 + (size_t)ec * 4521984);
        float*          obC  =                   P0 + (size_t)ec * 5832704;

        tcvt_kernel<<<dim3(64, 16, ec), 256, 0, stream>>>(
            w1 + (size_t)e0 * 4194304, w1t, 1024, 4096);
        tcvt_kernel<<<dim3(16, 64, ec), 256, 0, stream>>>(
            w2 + (size_t)e0 * 4194304, w2t, 4096, 1024);
        hipMemsetAsync(bufB, 0, (size_t)ec * 655360 * sizeof(unsigned short), stream);
        dispatch_bf16<<<NTOK, 256, 0, stream>>>(tln, eidxA, pcA, keepA, bufB, e0, ec);

        gemm_bf16_nt<true, true><<<dim3(32, 5, ec), 256, 0, stream>>>(
            bufB, w1t, b1 + (size_t)e0 * 4096, hB,
            1024, 655360LL, 4194304LL, 2621440LL, 4096LL, 4096);
        gemm_bf16_nt<false, false><<<dim3(8, 5, ec), 256, 0, stream>>>(
            hB, w2t, b2 + (size_t)e0 * 1024, obC,
            4096, 2621440LL, 4194304LL, 655360LL, 1024LL, 1024);

        combine_add<<<NTOK, 256, 0, stream>>>(obC, eidxA, pcA, gkA, out, e0, ec);
    }

    // ===== losses =====
    loss_kernel<<<1, 64, 0, stream>>>(partA, countsA, out + (size_t)NTOK * DMODEL);
}

// Round 6
// 1091.914 us; speedup vs baseline: 2.4792x; 1.0371x over previous
//
#include <hip/hip_runtime.h>
#include <cstdint>

// ---------------- problem constants ----------------
constexpr int BATCH  = 8;
constexpr int TSEQ   = 512;
constexpr int DMODEL = 1024;
constexpr int NEXP   = 8;
constexpr int CAPE   = 640;
constexpr int NTOK   = BATCH * TSEQ;        // 4096

typedef _Float16 h16;
typedef __attribute__((ext_vector_type(8))) short bfrag;
typedef __attribute__((ext_vector_type(8))) _Float16 hfrag;
typedef __attribute__((ext_vector_type(4))) float f32x4;

__device__ __forceinline__ unsigned short f2bf(float f) {
    uint32_t u = __float_as_uint(f);
    uint32_t r = (u + 0x7FFFu + ((u >> 16) & 1u)) >> 16;   // RNE
    return (unsigned short)r;
}

#define GLL16(SRC, DST) __builtin_amdgcn_global_load_lds( \
    (const __attribute__((address_space(1))) void*)(SRC), \
    (__attribute__((address_space(3))) void*)(DST), 16, 0, 0)

// ---------------- LayerNorm ----------------
__global__ __launch_bounds__(256) void ln_kernel(const float* __restrict__ in,
    const float* __restrict__ gw, const float* __restrict__ gb, float* __restrict__ out)
{
    int row = blockIdx.x, tid = threadIdx.x;
    const float4 v = *(const float4*)(in + (size_t)row * DMODEL + tid * 4);
    float s  = v.x + v.y + v.z + v.w;
    float ss = v.x*v.x + v.y*v.y + v.z*v.z + v.w*v.w;
#pragma unroll
    for (int o = 1; o < 64; o <<= 1) { s += __shfl_xor(s, o, 64); ss += __shfl_xor(ss, o, 64); }
    __shared__ float rs[4], rss[4];
    int wid = tid >> 6, lane = tid & 63;
    if (lane == 0) { rs[wid] = s; rss[wid] = ss; }
    __syncthreads();
    s  = rs[0] + rs[1] + rs[2] + rs[3];
    ss = rss[0] + rss[1] + rss[2] + rss[3];
    float mean = s * (1.0f / DMODEL);
    float var  = ss * (1.0f / DMODEL) - mean * mean;
    float inv  = rsqrtf(var + 1e-5f);
    float4 w4 = *(const float4*)(gw + tid * 4);
    float4 b4 = *(const float4*)(gb + tid * 4);
    float4 o;
    o.x = (v.x - mean) * inv * w4.x + b4.x;
    o.y = (v.y - mean) * inv * w4.y + b4.y;
    o.z = (v.z - mean) * inv * w4.z + b4.z;
    o.w = (v.w - mean) * inv * w4.w + b4.w;
    *(float4*)(out + (size_t)row * DMODEL + tid * 4) = o;
}

// ---------------- fp32 -> fp16 hi/lo split ----------------
__global__ __launch_bounds__(256) void split_f16(const float* __restrict__ in,
    h16* __restrict__ hi, h16* __restrict__ lo, int n8)
{
    int i = blockIdx.x * 256 + threadIdx.x;
    if (i >= n8) return;
    const float4* p = (const float4*)in + 2 * (size_t)i;
    float4 v0 = p[0], v1 = p[1];
    float vv[8] = {v0.x, v0.y, v0.z, v0.w, v1.x, v1.y, v1.z, v1.w};
    hfrag h, l;
#pragma unroll
    for (int j = 0; j < 8; ++j) {
        h16 hj = (h16)vv[j];
        h[j] = hj;
        l[j] = (h16)(vv[j] - (float)hj);
    }
    ((hfrag*)hi)[i] = h;
    ((hfrag*)lo)[i] = l;
}

// ---------------- fp16x2 (3-product) NT MFMA GEMM ----------------
// OMODE: 0 = fp32 out, 1 = fp32 out + res, 2 = f16 hi/lo pair out
template<int OMODE>
__global__ __launch_bounds__(256) void gemm_f16x2_nt(
    const h16* __restrict__ Ahi, const h16* __restrict__ Alo, int lda,
    const h16* __restrict__ Bhi, const h16* __restrict__ Blo, int ldb,
    const float* __restrict__ bias, const float* __restrict__ res,
    float* __restrict__ C, h16* __restrict__ Chi, h16* __restrict__ Clo,
    int K, int ldc)
{
    __shared__ h16 AhL[4096], AlL[4096], BhL[4096], BlL[4096];
    int rowBase = blockIdx.y * 128, colBase = blockIdx.x * 128;
    int t = threadIdx.x, lane = t & 63, wid = t >> 6;
    int wr = (wid >> 1) * 64, wc = (wid & 1) * 64;
    int c1 = t, c2 = t + 256;
    int r1 = c1 >> 2, q1 = (c1 & 3) ^ ((r1 + (r1 >> 2)) & 3);
    int r2 = c2 >> 2, q2 = (c2 & 3) ^ ((r2 + (r2 >> 2)) & 3);
    const h16* Ah = Ahi + (size_t)rowBase * lda;
    const h16* Al = Alo + (size_t)rowBase * lda;
    const h16* Bh = Bhi + (size_t)colBase * ldb;
    const h16* Bl = Blo + (size_t)colBase * ldb;
    f32x4 acc[4][4] = {};
    int l15 = lane & 15, g = lane >> 4;

    for (int k0 = 0; k0 < K; k0 += 32) {
        __syncthreads();
        GLL16(Ah + (size_t)r1 * lda + k0 + q1 * 8, &AhL[c1 * 8]);
        GLL16(Ah + (size_t)r2 * lda + k0 + q2 * 8, &AhL[c2 * 8]);
        GLL16(Al + (size_t)r1 * lda + k0 + q1 * 8, &AlL[c1 * 8]);
        GLL16(Al + (size_t)r2 * lda + k0 + q2 * 8, &AlL[c2 * 8]);
        GLL16(Bh + (size_t)r1 * ldb + k0 + q1 * 8, &BhL[c1 * 8]);
        GLL16(Bh + (size_t)r2 * ldb + k0 + q2 * 8, &BhL[c2 * 8]);
        GLL16(Bl + (size_t)r1 * ldb + k0 + q1 * 8, &BlL[c1 * 8]);
        GLL16(Bl + (size_t)r2 * ldb + k0 + q2 * 8, &BlL[c2 * 8]);
        __syncthreads();

        hfrag bh[4], bl[4];
#pragma unroll
        for (int n = 0; n < 4; ++n) {
            int row = wc + n * 16 + l15;
            int sw = (g ^ ((row + (row >> 2)) & 3)) * 8;
            bh[n] = *(const hfrag*)&BhL[row * 32 + sw];
            bl[n] = *(const hfrag*)&BlL[row * 32 + sw];
        }
#pragma unroll
        for (int m = 0; m < 4; ++m) {
            int row = wr + m * 16 + l15;
            int sw = (g ^ ((row + (row >> 2)) & 3)) * 8;
            hfrag ah = *(const hfrag*)&AhL[row * 32 + sw];
            hfrag al = *(const hfrag*)&AlL[row * 32 + sw];
#pragma unroll
            for (int n = 0; n < 4; ++n) {
                acc[m][n] = __builtin_amdgcn_mfma_f32_16x16x32_f16(ah, bh[n], acc[m][n], 0, 0, 0);
                acc[m][n] = __builtin_amdgcn_mfma_f32_16x16x32_f16(ah, bl[n], acc[m][n], 0, 0, 0);
                acc[m][n] = __builtin_amdgcn_mfma_f32_16x16x32_f16(al, bh[n], acc[m][n], 0, 0, 0);
            }
        }
    }

    int g4 = g * 4;
#pragma unroll
    for (int m = 0; m < 4; ++m) {
        int row0 = rowBase + wr + m * 16 + g4;
#pragma unroll
        for (int n = 0; n < 4; ++n) {
            int col = colBase + wc + n * 16 + l15;
            float bv = bias[col];
#pragma unroll
            for (int j = 0; j < 4; ++j) {
                float v = acc[m][n][j] + bv;
                if (OMODE == 1) v += res[(size_t)(row0 + j) * ldc + col];
                if (OMODE < 2) {
                    C[(size_t)(row0 + j) * ldc + col] = v;
                } else {
                    h16 hh = (h16)v;
                    Chi[(size_t)(row0 + j) * ldc + col] = hh;
                    Clo[(size_t)(row0 + j) * ldc + col] = (h16)(v - (float)hh);
                }
            }
        }
    }
}

// ---------------- attention QK^T (f16x2, K=64, strided heads) ----------------
template<bool CAUSAL>
__global__ __launch_bounds__(256) void attn_qk(
    const h16* __restrict__ Qh, const h16* __restrict__ Ql, int lda,
    const h16* __restrict__ Kh, const h16* __restrict__ Kl, int ldb,
    h16* __restrict__ Sh, h16* __restrict__ Sl, int zoff)
{
    int rowBase = blockIdx.y * 128, colBase = blockIdx.x * 128;
    if (CAUSAL && colBase >= rowBase + 128) return;
    __shared__ h16 AhL[4096], AlL[4096], BhL[4096], BlL[4096];
    int z = blockIdx.z;
    int bh_ = zoff + z, b = bh_ >> 4, h = bh_ & 15;
    const h16* Ah = Qh + (size_t)(b * 512 + rowBase) * lda + h * 64;
    const h16* Al = Ql + (size_t)(b * 512 + rowBase) * lda + h * 64;
    const h16* Bh = Kh + (size_t)(b * 512 + colBase) * ldb + h * 64;
    const h16* Bl = Kl + (size_t)(b * 512 + colBase) * ldb + h * 64;
    int t = threadIdx.x, lane = t & 63, wid = t >> 6;
    int wr = (wid >> 1) * 64, wc = (wid & 1) * 64;
    int c1 = t, c2 = t + 256;
    int r1 = c1 >> 2, q1 = (c1 & 3) ^ ((r1 + (r1 >> 2)) & 3);
    int r2 = c2 >> 2, q2 = (c2 & 3) ^ ((r2 + (r2 >> 2)) & 3);
    f32x4 acc[4][4] = {};
    int l15 = lane & 15, g = lane >> 4;

    for (int k0 = 0; k0 < 64; k0 += 32) {
        __syncthreads();
        GLL16(Ah + (size_t)r1 * lda + k0 + q1 * 8, &AhL[c1 * 8]);
        GLL16(Ah + (size_t)r2 * lda + k0 + q2 * 8, &AhL[c2 * 8]);
        GLL16(Al + (size_t)r1 * lda + k0 + q1 * 8, &AlL[c1 * 8]);
        GLL16(Al + (size_t)r2 * lda + k0 + q2 * 8, &AlL[c2 * 8]);
        GLL16(Bh + (size_t)r1 * ldb + k0 + q1 * 8, &BhL[c1 * 8]);
        GLL16(Bh + (size_t)r2 * ldb + k0 + q2 * 8, &BhL[c2 * 8]);
        GLL16(Bl + (size_t)r1 * ldb + k0 + q1 * 8, &BlL[c1 * 8]);
        GLL16(Bl + (size_t)r2 * ldb + k0 + q2 * 8, &BlL[c2 * 8]);
        __syncthreads();

        hfrag bh[4], bl[4];
#pragma unroll
        for (int n = 0; n < 4; ++n) {
            int row = wc + n * 16 + l15;
            int sw = (g ^ ((row + (row >> 2)) & 3)) * 8;
            bh[n] = *(const hfrag*)&BhL[row * 32 + sw];
            bl[n] = *(const hfrag*)&BlL[row * 32 + sw];
        }
#pragma unroll
        for (int m = 0; m < 4; ++m) {
            int row = wr + m * 16 + l15;
            int sw = (g ^ ((row + (row >> 2)) & 3)) * 8;
            hfrag ah = *(const hfrag*)&AhL[row * 32 + sw];
            hfrag al = *(const hfrag*)&AlL[row * 32 + sw];
#pragma unroll
            for (int n = 0; n < 4; ++n) {
                acc[m][n] = __builtin_amdgcn_mfma_f32_16x16x32_f16(ah, bh[n], acc[m][n], 0, 0, 0);
                acc[m][n] = __builtin_amdgcn_mfma_f32_16x16x32_f16(ah, bl[n], acc[m][n], 0, 0, 0);
                acc[m][n] = __builtin_amdgcn_mfma_f32_16x16x32_f16(al, bh[n], acc[m][n], 0, 0, 0);
            }
        }
    }

    size_t sbase = (size_t)z * 262144;
    int g4 = g * 4;
#pragma unroll
    for (int m = 0; m < 4; ++m) {
        int row0 = rowBase + wr + m * 16 + g4;
#pragma unroll
        for (int n = 0; n < 4; ++n) {
            int col = colBase + wc + n * 16 + l15;
#pragma unroll
            for (int j = 0; j < 4; ++j) {
                float v = acc[m][n][j] * 0.125f;
                h16 hh = (h16)v;
                Sh[sbase + (size_t)(row0 + j) * 512 + col] = hh;
                Sl[sbase + (size_t)(row0 + j) * 512 + col] = (h16)(v - (float)hh);
            }
        }
    }
}

// ---------------- softmax over hi/lo rows, in place ----------------
__global__ __launch_bounds__(64) void softmax_hl(h16* __restrict__ Sh, h16* __restrict__ Sl, int causal)
{
    int t = blockIdx.x, z = blockIdx.y, lane = threadIdx.x;
    size_t base = ((size_t)z * 512 + t) * 512;
    int limit = causal ? (t + 1) : 512;
    float v[8];
    float mx = -1e30f;
#pragma unroll
    for (int k = 0; k < 8; ++k) {
        int idx = lane + (k << 6);
        float s = (float)Sh[base + idx] + (float)Sl[base + idx];
        float val = (idx < limit) ? s : -1e30f;
        v[k] = val; mx = fmaxf(mx, val);
    }
#pragma unroll
    for (int o = 1; o < 64; o <<= 1) mx = fmaxf(mx, __shfl_xor(mx, o, 64));
    float sum = 0.f;
#pragma unroll
    for (int k = 0; k < 8; ++k) {
        int idx = lane + (k << 6);
        float p = (idx < limit) ? __expf(v[k] - mx) : 0.f;
        v[k] = p; sum += p;
    }
#pragma unroll
    for (int o = 1; o < 64; o <<= 1) sum += __shfl_xor(sum, o, 64);
    float inv = 1.0f / sum;
#pragma unroll
    for (int k = 0; k < 8; ++k) {
        int idx = lane + (k << 6);
        float p = v[k] * inv;
        h16 hh = (h16)p;
        Sh[base + idx] = hh;
        Sl[base + idx] = (h16)(p - (float)hh);
    }
}

// ---------------- PV: C[t,d] = P[t,s] * vT[d,s]^T  (64x64 tile, K=512) ----------------
__global__ __launch_bounds__(256) void attn_pv(
    const h16* __restrict__ Ph, const h16* __restrict__ Pl,
    const h16* __restrict__ Vh, const h16* __restrict__ Vl,
    h16* __restrict__ Ch, h16* __restrict__ Cl, int bh0)
{
    __shared__ h16 PhL[2048], PlL[2048], VhL[2048], VlL[2048];
    int z = blockIdx.z, bh_ = bh0 + z;
    int rowBase = blockIdx.x * 64;
    const h16* Pa = Ph + (size_t)z * 262144 + (size_t)rowBase * 512;
    const h16* Pb = Pl + (size_t)z * 262144 + (size_t)rowBase * 512;
    const h16* Va = Vh + (size_t)z * 32768;
    const h16* Vb = Vl + (size_t)z * 32768;
    int t = threadIdx.x, lane = t & 63, wid = t >> 6;
    int r = t >> 2, q = (t & 3) ^ ((r + (r >> 2)) & 3);
    f32x4 acc[4] = {};
    int l15 = lane & 15, g = lane >> 4;

    for (int k0 = 0; k0 < 512; k0 += 32) {
        __syncthreads();
        GLL16(Pa + (size_t)r * 512 + k0 + q * 8, &PhL[t * 8]);
        GLL16(Pb + (size_t)r * 512 + k0 + q * 8, &PlL[t * 8]);
        GLL16(Va + (size_t)r * 512 + k0 + q * 8, &VhL[t * 8]);
        GLL16(Vb + (size_t)r * 512 + k0 + q * 8, &VlL[t * 8]);
        __syncthreads();

        int arow = wid * 16 + l15;
        int asw = (g ^ ((arow + (arow >> 2)) & 3)) * 8;
        hfrag ah = *(const hfrag*)&PhL[arow * 32 + asw];
        hfrag al = *(const hfrag*)&PlL[arow * 32 + asw];
#pragma unroll
        for (int n = 0; n < 4; ++n) {
            int brow = n * 16 + l15;
            int bsw = (g ^ ((brow + (brow >> 2)) & 3)) * 8;
            hfrag bh = *(const hfrag*)&VhL[brow * 32 + bsw];
            hfrag bl = *(const hfrag*)&VlL[brow * 32 + bsw];
            acc[n] = __builtin_amdgcn_mfma_f32_16x16x32_f16(ah, bh, acc[n], 0, 0, 0);
            acc[n] = __builtin_amdgcn_mfma_f32_16x16x32_f16(ah, bl, acc[n], 0, 0, 0);
            acc[n] = __builtin_amdgcn_mfma_f32_16x16x32_f16(al, bh, acc[n], 0, 0, 0);
        }
    }

    int brow = (bh_ >> 4) * 512 + rowBase + wid * 16 + g * 4;
    int bcol = (bh_ & 15) * 64;
#pragma unroll
    for (int n = 0; n < 4; ++n) {
        int col = bcol + n * 16 + l15;
#pragma unroll
        for (int j = 0; j < 4; ++j) {
            float v = acc[n][j];
            h16 hh = (h16)v;
            Ch[(size_t)(brow + j) * 1024 + col] = hh;
            Cl[(size_t)(brow + j) * 1024 + col] = (h16)(v - (float)hh);
        }
    }
}

// ---------------- V-transpose: in[(b*512+t)*ld + h*64 + d] -> out[z*32768 + d*512 + t] ----------------
__global__ __launch_bounds__(256) void vt_split(
    const h16* __restrict__ inh, const h16* __restrict__ inl, int ld,
    h16* __restrict__ oh, h16* __restrict__ ol)
{
    __shared__ h16 tile[64][68];
    int z = blockIdx.z, b = z >> 4, h = z & 15;
    size_t ibase = ((size_t)b * 512 + blockIdx.x * 64) * ld + h * 64;
    size_t obase = (size_t)z * 32768 + blockIdx.x * 64;
    int tr = threadIdx.x >> 4, tc = (threadIdx.x & 15) * 4;
    const h16* src[2] = {inh, inl};
    h16* dst[2] = {oh, ol};
#pragma unroll
    for (int s = 0; s < 2; ++s) {
        __syncthreads();
#pragma unroll
        for (int i = 0; i < 4; ++i) {
            int tt = tr + i * 16;
            short4 v = *(const short4*)(src[s] + ibase + (size_t)tt * ld + tc);
            tile[tt][tc + 0] = ((h16*)&v)[0];
            tile[tt][tc + 1] = ((h16*)&v)[1];
            tile[tt][tc + 2] = ((h16*)&v)[2];
            tile[tt][tc + 3] = ((h16*)&v)[3];
        }
        __syncthreads();
#pragma unroll
        for (int i = 0; i < 4; ++i) {
            int d = tr + i * 16;
            h16 w[4] = {tile[tc + 0][d], tile[tc + 1][d], tile[tc + 2][d], tile[tc + 3][d]};
            *(short4*)(dst[s] + obase + (size_t)d * 512 + tc) = *(short4*)w;
        }
    }
}

// ---------------- bf16 NT MFMA GEMM (MoE) ----------------
template<bool RELU, bool OBF16>
__global__ __launch_bounds__(256) void gemm_bf16_nt(
    const unsigned short* __restrict__ A,   // [M][K] bf16
    const unsigned short* __restrict__ Bt,  // [N][K] bf16
    const float* __restrict__ bias,         // [N] fp32
    void* __restrict__ Cv,
    int K, long long sA, long long sB, long long sC, long long sBias, int ldc)
{
    __shared__ unsigned short Al[128 * 32];
    __shared__ unsigned short Bl[128 * 32];
    int z = blockIdx.z;
    A  += (size_t)z * sA;
    Bt += (size_t)z * sB;
    bias += (size_t)z * sBias;
    long long zC = (long long)z * sC;

    int rowBase = blockIdx.y * 128, colBase = blockIdx.x * 128;
    int t = threadIdx.x, lane = t & 63, wid = t >> 6;
    int wr = (wid >> 1) * 64, wc = (wid & 1) * 64;

    int c1 = t, c2 = t + 256;
    int r1 = c1 >> 2, q1 = (c1 & 3) ^ ((r1 + (r1 >> 2)) & 3);
    int r2 = c2 >> 2, q2 = (c2 & 3) ^ ((r2 + (r2 >> 2)) & 3);

    const unsigned short* Ag = A  + (size_t)rowBase * K;
    const unsigned short* Bg = Bt + (size_t)colBase * K;

    f32x4 acc[4][4] = {};
    int l15 = lane & 15, g = lane >> 4;

    for (int k0 = 0; k0 < K; k0 += 32) {
        __syncthreads();
        GLL16(Ag + (size_t)r1 * K + k0 + q1 * 8, &Al[c1 * 8]);
        GLL16(Ag + (size_t)r2 * K + k0 + q2 * 8, &Al[c2 * 8]);
        GLL16(Bg + (size_t)r1 * K + k0 + q1 * 8, &Bl[c1 * 8]);
        GLL16(Bg + (size_t)r2 * K + k0 + q2 * 8, &Bl[c2 * 8]);
        __syncthreads();

        bfrag a[4], b[4];
#pragma unroll
        for (int m = 0; m < 4; ++m) {
            int row = wr + m * 16 + l15;
            int sw = (g ^ ((row + (row >> 2)) & 3)) * 8;
            a[m] = *(const bfrag*)&Al[row * 32 + sw];
        }
#pragma unroll
        for (int n = 0; n < 4; ++n) {
            int row = wc + n * 16 + l15;
            int sw = (g ^ ((row + (row >> 2)) & 3)) * 8;
            b[n] = *(const bfrag*)&Bl[row * 32 + sw];
        }
#pragma unroll
        for (int m = 0; m < 4; ++m)
#pragma unroll
            for (int n = 0; n < 4; ++n)
                acc[m][n] = __builtin_amdgcn_mfma_f32_16x16x32_bf16(a[m], b[n], acc[m][n], 0, 0, 0);
    }

    int g4 = g * 4;
#pragma unroll
    for (int m = 0; m < 4; ++m) {
        int row0 = rowBase + wr + m * 16 + g4;
#pragma unroll
        for (int n = 0; n < 4; ++n) {
            int col = colBase + wc + n * 16 + l15;
            float bv = bias[col];
#pragma unroll
            for (int j = 0; j < 4; ++j) {
                float v = acc[m][n][j] + bv;
                if (RELU) v = fmaxf(v, 0.f);
                if (OBF16)
                    ((unsigned short*)Cv)[zC + (size_t)(row0 + j) * ldc + col] = f2bf(v);
                else
                    ((float*)Cv)[zC + (size_t)(row0 + j) * ldc + col] = v;
            }
        }
    }
}

// ---------------- transpose+convert fp32 [R][Cn] -> bf16 [Cn][R] (per z) ----------------
__global__ __launch_bounds__(256) void tcvt_kernel(const float* __restrict__ in,
    unsigned short* __restrict__ out, int R, int Cn)
{
    __shared__ unsigned short tile[64][68];
    size_t zoff = (size_t)blockIdx.z * R * Cn;
    in += zoff; out += zoff;
    int r0 = blockIdx.y * 64, c0 = blockIdx.x * 64;
    int tr = threadIdx.x >> 4, tc = (threadIdx.x & 15) * 4;
#pragma unroll
    for (int i = 0; i < 4; ++i) {
        int r = tr + i * 16;
        float4 v = *(const float4*)&in[(size_t)(r0 + r) * Cn + c0 + tc];
        tile[r][tc + 0] = f2bf(v.x);
        tile[r][tc + 1] = f2bf(v.y);
        tile[r][tc + 2] = f2bf(v.z);
        tile[r][tc + 3] = f2bf(v.w);
    }
    __syncthreads();
#pragma unroll
    for (int i = 0; i < 4; ++i) {
        int c = tr + i * 16;
        ushort4 w;
        w.x = tile[tc + 0][c];
        w.y = tile[tc + 1][c];
        w.z = tile[tc + 2][c];
        w.w = tile[tc + 3][c];
        *(ushort4*)&out[(size_t)(c0 + c) * R + r0 + tc] = w;
    }
}

// ---------------- router ----------------
__global__ __launch_bounds__(256) void router_kernel(
    const float* __restrict__ xf, const float* __restrict__ rw, const float* __restrict__ rb,
    const float* __restrict__ tmask,
    int* __restrict__ eidx, float* __restrict__ gate, int* __restrict__ valid,
    float* __restrict__ partials)
{
    int blk = blockIdx.x;
    int wid = threadIdx.x >> 6, lane = threadIdx.x & 63;
    __shared__ float wpart[4][10];
    float pe[8] = {0,0,0,0,0,0,0,0};
    float zacc = 0.f, nvacc = 0.f;

    for (int i = 0; i < 16; ++i) {
        int tok = blk * 64 + wid * 16 + i;
        const float* xrow = xf + (size_t)tok * DMODEL;
        float acc[8] = {0,0,0,0,0,0,0,0};
#pragma unroll 4
        for (int kk = 0; kk < 16; ++kk) {
            int d = lane + (kk << 6);
            float xd = xrow[d];
            const float4* rp = (const float4*)(rw + (size_t)d * 8);
            float4 r0 = rp[0], r1 = rp[1];
            acc[0] = fmaf(xd, r0.x, acc[0]); acc[1] = fmaf(xd, r0.y, acc[1]);
            acc[2] = fmaf(xd, r0.z, acc[2]); acc[3] = fmaf(xd, r0.w, acc[3]);
            acc[4] = fmaf(xd, r1.x, acc[4]); acc[5] = fmaf(xd, r1.y, acc[5]);
            acc[6] = fmaf(xd, r1.z, acc[6]); acc[7] = fmaf(xd, r1.w, acc[7]);
        }
#pragma unroll
        for (int e = 0; e < 8; ++e)
#pragma unroll
            for (int o = 1; o < 64; o <<= 1) acc[e] += __shfl_xor(acc[e], o, 64);
        if (lane == 0) {
            float l[8]; float m = -1e30f;
#pragma unroll
            for (int e = 0; e < 8; ++e) { l[e] = acc[e] + rb[e]; m = fmaxf(m, l[e]); }
            float se = 0.f;
#pragma unroll
            for (int e = 0; e < 8; ++e) se += expf(l[e] - m);
            int am = 0; float bm = l[0];
#pragma unroll
            for (int e = 1; e < 8; ++e) if (l[e] > bm) { bm = l[e]; am = e; }
            float inv_se = 1.0f / se;
            float g = expf(l[am] - m) * inv_se;
            float vld = (tmask[tok] > 0.f) ? 1.f : 0.f;
            eidx[tok] = am; gate[tok] = g; valid[tok] = (int)vld;
#pragma unroll
            for (int e = 0; e < 8; ++e) pe[e] += expf(l[e] - m) * inv_se * vld;
            float lse = logf(se) + m;
            zacc += lse * lse * vld;
            nvacc += vld;
        }
    }
    if (lane == 0) {
#pragma unroll
        for (int e = 0; e < 8; ++e) wpart[wid][e] = pe[e];
        wpart[wid][8] = zacc; wpart[wid][9] = nvacc;
    }
    __syncthreads();
    if (threadIdx.x == 0) {
        for (int j = 0; j < 10; ++j)
            partials[blk * 10 + j] = wpart[0][j] + wpart[1][j] + wpart[2][j] + wpart[3][j];
    }
}

// ---------------- capacity scan ----------------
__global__ __launch_bounds__(256) void scan_kernel(
    const int* __restrict__ eidx, const int* __restrict__ valid, const float* __restrict__ gate,
    int* __restrict__ pc, float* __restrict__ gk, int* __restrict__ keepf,
    int* __restrict__ counts)
{
    __shared__ int cnt[256][8];
    int tid = threadIdx.x;
    int local[8] = {0,0,0,0,0,0,0,0};
    int base = tid * 16;
    for (int i = 0; i < 16; ++i) { int e = eidx[base + i]; local[e] += valid[base + i]; }
#pragma unroll
    for (int e = 0; e < 8; ++e) cnt[tid][e] = local[e];
    __syncthreads();
    if (tid < 8) {
        int run = 0;
        for (int i = 0; i < 256; ++i) { int t = cnt[i][tid]; cnt[i][tid] = run; run += t; }
        counts[tid] = run;
    }
    __syncthreads();
    int off[8];
#pragma unroll
    for (int e = 0; e < 8; ++e) off[e] = cnt[tid][e];
    for (int i = 0; i < 16; ++i) {
        int tok = base + i;
        int e = eidx[tok], v = valid[tok];
        int pos = off[e]; off[e] += v;
        int kp = (v && pos < CAPE) ? 1 : 0;
        pc[tok]    = (pos < CAPE) ? pos : (CAPE - 1);
        keepf[tok] = kp;
        gk[tok]    = kp ? gate[tok] : 0.f;
    }
}

// ---------------- dispatch (expert-range) -> bf16 buffers ----------------
__global__ __launch_bounds__(256) void dispatch_bf16(const float* __restrict__ tln,
    const int* __restrict__ eidx, const int* __restrict__ pc, const int* __restrict__ keepf,
    unsigned short* __restrict__ buf, int e0, int ec)
{
    int tok = blockIdx.x;
    if (!keepf[tok]) return;
    int e = eidx[tok];
    if (e < e0 || e >= e0 + ec) return;
    int p = pc[tok];
    const float4 v = ((const float4*)(tln + (size_t)tok * DMODEL))[threadIdx.x];
    ushort4 o;
    o.x = f2bf(v.x); o.y = f2bf(v.y); o.z = f2bf(v.z); o.w = f2bf(v.w);
    ((ushort4*)(buf + ((size_t)(e - e0) * CAPE + p) * DMODEL))[threadIdx.x] = o;
}

// ---------------- combine add: out += gk * ob ----------------
__global__ __launch_bounds__(256) void combine_add(const float* __restrict__ ob,
    const int* __restrict__ eidx, const int* __restrict__ pc, const float* __restrict__ gk,
    float* __restrict__ out, int e0, int ec)
{
    int tok = blockIdx.x;
    int e = eidx[tok];
    if (e < e0 || e >= e0 + ec) return;
    float g = gk[tok];
    int p = pc[tok];
    float4* o = (float4*)(out + (size_t)tok * DMODEL);
    const float4 ov = ((const float4*)(ob + ((size_t)(e - e0) * CAPE + p) * DMODEL))[threadIdx.x];
    float4 a = o[threadIdx.x];
    a.x += g * ov.x; a.y += g * ov.y; a.z += g * ov.z; a.w += g * ov.w;
    o[threadIdx.x] = a;
}

// ---------------- final scalar losses ----------------
__global__ __launch_bounds__(64) void loss_kernel(const float* __restrict__ partials,
    const int* __restrict__ counts, float* __restrict__ out2)
{
    int lane = threadIdx.x;
    float p[10];
#pragma unroll
    for (int j = 0; j < 10; ++j) p[j] = partials[lane * 10 + j];
#pragma unroll
    for (int j = 0; j < 10; ++j)
#pragma unroll
        for (int o = 1; o < 64; o <<= 1) p[j] += __shfl_xor(p[j], o, 64);
    if (lane == 0) {
        float nv = fmaxf(p[9], 1.f);
        float lb = 0.f;
        for (int e = 0; e < 8; ++e) lb += ((float)counts[e] / nv) * (p[e] / nv);
        lb *= (float)NEXP;
        out2[0] = lb;
        out2[1] = p[8] / nv;
    }
}

// ---------------- host launch ----------------
extern "C" void kernel_launch(void* const* d_in, const int* in_sizes, int n_in,
                              void* d_out, int out_size, void* d_ws, size_t ws_size,
                              hipStream_t stream)
{
    const float* tgt        = (const float*)d_in[0];
    const float* src        = (const float*)d_in[1];
    const float* token_mask = (const float*)d_in[5];
    const float* ln1w = (const float*)d_in[6],  *ln1b = (const float*)d_in[7];
    const float* self_in_w  = (const float*)d_in[8],  *self_in_b  = (const float*)d_in[9];
    const float* self_out_w = (const float*)d_in[10], *self_out_b = (const float*)d_in[11];
    const float* ln2w = (const float*)d_in[12], *ln2b = (const float*)d_in[13];
    const float* enc_in_w   = (const float*)d_in[14], *enc_in_b   = (const float*)d_in[15];
    const float* enc_out_w  = (const float*)d_in[16], *enc_out_b  = (const float*)d_in[17];
    const float* ln3w = (const float*)d_in[18], *ln3b = (const float*)d_in[19];
    const float* rw = (const float*)d_in[20], *rb = (const float*)d_in[21];
    const float* w1 = (const float*)d_in[22], *b1 = (const float*)d_in[23];
    const float* w2 = (const float*)d_in[24], *b2 = (const float*)d_in[25];

    float* out = (float*)d_out;          // residual stream lives HERE
    float* ws  = (float*)d_ws;

    // ---- fixed layout (floats) ----
    float* tln = ws;                         // 4,194,304
    float* ctx = ws + 4194304;               // 4,194,304 (holds ctx hi/lo f16)
    int*   eidxA   = (int*)(ws + 8388608);
    int*   validA  = eidxA + 4096;
    int*   pcA     = validA + 4096;
    int*   keepA   = pcA + 4096;
    int*   countsA = keepA + 4096;           // 16
    float* gateA   = (float*)(countsA + 16);
    float* gkA     = gateA + 4096;
    float* partA   = gkA + 4096;             // 640
    const size_t POOL_OFF = 8425984;         // floats
    float* pool = ws + POOL_OFF;

    size_t Wf = ws_size / sizeof(float);
    size_t pf = (Wf > POOL_OFF) ? (Wf - POOL_OFF) : 0;

    // ---- tiers: bg = batches per attention group, zc = score z-chunk ----
    int bg, zc;
    if      (pf >= 25165824) { bg = 8; zc = 32; }
    else if (pf >= 24117248) { bg = 8; zc = 16; }
    else if (pf >= 13631488) { bg = 4; zc = 16; }
    else                     { bg = 2; zc = 16; }
    int ec = 1;
    for (int c = 8; c >= 1; c >>= 1)
        if ((size_t)c * 6488064ull <= pf) { ec = c; break; }

    float* qreg = pool;
    float* vreg = qreg + (size_t)bg * 1572864;
    float* sreg = vreg + (size_t)bg * 524288;

    h16* ctxh = (h16*)ctx;
    h16* ctxl = ctxh + 4194304;   // f16 elements

    // ================= self attention =================
    ln_kernel<<<NTOK, 256, 0, stream>>>(tgt, ln1w, ln1b, tln);

    for (int g0 = 0; g0 < BATCH; g0 += bg) {
        h16* sb  = (h16*)sreg;
        h16* thi = sb,                      *tlo = sb + (size_t)bg * 524288;
        h16* whi = sb + (size_t)bg * 1048576, *wlo = whi + 3145728;
        split_f16<<<bg * 256, 256, 0, stream>>>(tln + (size_t)g0 * 524288, thi, tlo, bg * 65536);
        split_f16<<<1536, 256, 0, stream>>>(self_in_w, whi, wlo, 393216);

        h16* qkvh = (h16*)qreg, *qkvl = qkvh + (size_t)bg * 1572864;
        gemm_f16x2_nt<2><<<dim3(24, bg * 4, 1), 256, 0, stream>>>(
            thi, tlo, 1024, whi, wlo, 1024, self_in_b, nullptr,
            nullptr, qkvh, qkvl, 1024, 3072);

        h16* vth = (h16*)vreg, *vtl = vth + (size_t)bg * 524288;
        vt_split<<<dim3(8, 1, bg * 16), 256, 0, stream>>>(qkvh + 2048, qkvl + 2048, 3072, vth, vtl);

        h16* sh = sb, *sl = sh + (size_t)zc * 262144;
        for (int c0 = 0; c0 < bg * 16; c0 += zc) {
            attn_qk<true><<<dim3(4, 4, zc), 256, 0, stream>>>(
                qkvh, qkvl, 3072, qkvh + 1024, qkvl + 1024, 3072, sh, sl, c0);
            softmax_hl<<<dim3(512, zc), 64, 0, stream>>>(sh, sl, 1);
            attn_pv<<<dim3(8, 1, zc), 256, 0, stream>>>(
                sh, sl, vth + (size_t)c0 * 32768, vtl + (size_t)c0 * 32768,
                ctxh, ctxl, g0 * 16 + c0);
        }
    }
    {
        h16* sb = (h16*)sreg;
        h16* owhi = sb, *owlo = sb + 1048576;
        split_f16<<<512, 256, 0, stream>>>(self_out_w, owhi, owlo, 131072);
        gemm_f16x2_nt<1><<<dim3(8, 32, 1), 256, 0, stream>>>(
            ctxh, ctxl, 1024, owhi, owlo, 1024, self_out_b, tgt,
            out, nullptr, nullptr, 1024, 1024);
    }

    // ================= cross attention =================
    ln_kernel<<<NTOK, 256, 0, stream>>>(out, ln2w, ln2b, tln);

    for (int g0 = 0; g0 < BATCH; g0 += bg) {
        h16* sb  = (h16*)sreg;
        h16* thi = sb,                      *tlo = sb + (size_t)bg * 524288;
        h16* ehi = sb + (size_t)bg * 1048576, *elo = ehi + 3145728;
        split_f16<<<bg * 256, 256, 0, stream>>>(tln + (size_t)g0 * 524288, thi, tlo, bg * 65536);
        split_f16<<<1536, 256, 0, stream>>>(enc_in_w, ehi, elo, 393216);

        h16* q2h  = (h16*)qreg,              *q2l  = q2h + (size_t)bg * 524288;
        h16* kv2h = q2h + (size_t)bg * 1048576, *kv2l = kv2h + (size_t)bg * 1048576;
        gemm_f16x2_nt<2><<<dim3(8, bg * 4, 1), 256, 0, stream>>>(
            thi, tlo, 1024, ehi, elo, 1024, enc_in_b, nullptr,
            nullptr, q2h, q2l, 1024, 1024);

        split_f16<<<bg * 256, 256, 0, stream>>>(src + (size_t)g0 * 524288, thi, tlo, bg * 65536);
        gemm_f16x2_nt<2><<<dim3(16, bg * 4, 1), 256, 0, stream>>>(
            thi, tlo, 1024, ehi + 1048576, elo + 1048576, 1024, enc_in_b + 1024, nullptr,
            nullptr, kv2h, kv2l, 1024, 2048);

        h16* vth = (h16*)vreg, *vtl = vth + (size_t)bg * 524288;
        vt_split<<<dim3(8, 1, bg * 16), 256, 0, stream>>>(kv2h + 1024, kv2l + 1024, 2048, vth, vtl);

        h16* sh = sb, *sl = sh + (size_t)zc * 262144;
        for (int c0 = 0; c0 < bg * 16; c0 += zc) {
            attn_qk<false><<<dim3(4, 4, zc), 256, 0, stream>>>(
                q2h, q2l, 1024, kv2h, kv2l, 2048, sh, sl, c0);
            softmax_hl<<<dim3(512, zc), 64, 0, stream>>>(sh, sl, 0);
            attn_pv<<<dim3(8, 1, zc), 256, 0, stream>>>(
                sh, sl, vth + (size_t)c0 * 32768, vtl + (size_t)c0 * 32768,
                ctxh, ctxl, g0 * 16 + c0);
        }
    }
    {
        h16* sb = (h16*)sreg;
        h16* owhi = sb, *owlo = sb + 1048576;
        split_f16<<<512, 256, 0, stream>>>(enc_out_w, owhi, owlo, 131072);
        gemm_f16x2_nt<1><<<dim3(8, 32, 1), 256, 0, stream>>>(
            ctxh, ctxl, 1024, owhi, owlo, 1024, enc_out_b, out,
            out, nullptr, nullptr, 1024, 1024);
    }

    // ================= MoE =================
    ln_kernel<<<NTOK, 256, 0, stream>>>(out, ln3w, ln3b, tln);
    router_kernel<<<64, 256, 0, stream>>>(tln, rw, rb, token_mask, eidxA, gateA, validA, partA);
    scan_kernel<<<1, 256, 0, stream>>>(eidxA, validA, gateA, pcA, gkA, keepA, countsA);

    for (int e0 = 0; e0 < NEXP; e0 += ec) {
        unsigned short* w1t  = (unsigned short*)pool;
        unsigned short* w2t  = (unsigned short*)(pool + (size_t)ec * 2097152);
        unsigned short* bufB = (unsigned short*)(pool + (size_t)ec * 4194304);
        unsigned short* hB   = (unsigned short*)(pool + (size_t)ec * 4521984);
        float*          obC  =                   pool + (size_t)ec * 5832704;

        tcvt_kernel<<<dim3(64, 16, ec), 256, 0, stream>>>(
            w1 + (size_t)e0 * 4194304, w1t, 1024, 4096);
        tcvt_kernel<<<dim3(16, 64, ec), 256, 0, stream>>>(
            w2 + (size_t)e0 * 4194304, w2t, 4096, 1024);
        hipMemsetAsync(bufB, 0, (size_t)ec * 655360 * sizeof(unsigned short), stream);
        dispatch_bf16<<<NTOK, 256, 0, stream>>>(tln, eidxA, pcA, keepA, bufB, e0, ec);

        gemm_bf16_nt<true, true><<<dim3(32, 5, ec), 256, 0, stream>>>(
            bufB, w1t, b1 + (size_t)e0 * 4096, hB,
            1024, 655360LL, 4194304LL, 2621440LL, 4096LL, 4096);
        gemm_bf16_nt<false, false><<<dim3(8, 5, ec), 256, 0, stream>>>(
            hB, w2t, b2 + (size_t)e0 * 1024, obC,
            4096, 2621440LL, 4194304LL, 655360LL, 1024LL, 1024);

        combine_add<<<NTOK, 256, 0, stream>>>(obC, eidxA, pcA, gkA, out, e0, ec);
    }

    // ===== losses =====
    loss_kernel<<<1, 64, 0, stream>>>(partA, countsA, out + (size_t)NTOK * DMODEL);
}

// Round 7
// 1068.948 us; speedup vs baseline: 2.5324x; 1.0215x over previous
//
#include <hip/hip_runtime.h>
#include <cstdint>

// ---------------- problem constants ----------------
constexpr int BATCH  = 8;
constexpr int TSEQ   = 512;
constexpr int DMODEL = 1024;
constexpr int NEXP   = 8;
constexpr int CAPE   = 640;
constexpr int NTOK   = BATCH * TSEQ;        // 4096

typedef _Float16 h16;
typedef __attribute__((ext_vector_type(8))) short bfrag;
typedef __attribute__((ext_vector_type(8))) _Float16 hfrag;
typedef __attribute__((ext_vector_type(4))) float f32x4;

__device__ __forceinline__ unsigned short f2bf(float f) {
    uint32_t u = __float_as_uint(f);
    uint32_t r = (u + 0x7FFFu + ((u >> 16) & 1u)) >> 16;   // RNE
    return (unsigned short)r;
}
__device__ __forceinline__ float bf2f(unsigned short b) {
    return __uint_as_float((uint32_t)b << 16);
}

#define GLL16(SRC, DST) __builtin_amdgcn_global_load_lds( \
    (const __attribute__((address_space(1))) void*)(SRC), \
    (__attribute__((address_space(3))) void*)(DST), 16, 0, 0)

// ---------------- LayerNorm ----------------
__global__ __launch_bounds__(256) void ln_kernel(const float* __restrict__ in,
    const float* __restrict__ gw, const float* __restrict__ gb, float* __restrict__ out)
{
    int row = blockIdx.x, tid = threadIdx.x;
    const float4 v = *(const float4*)(in + (size_t)row * DMODEL + tid * 4);
    float s  = v.x + v.y + v.z + v.w;
    float ss = v.x*v.x + v.y*v.y + v.z*v.z + v.w*v.w;
#pragma unroll
    for (int o = 1; o < 64; o <<= 1) { s += __shfl_xor(s, o, 64); ss += __shfl_xor(ss, o, 64); }
    __shared__ float rs[4], rss[4];
    int wid = tid >> 6, lane = tid & 63;
    if (lane == 0) { rs[wid] = s; rss[wid] = ss; }
    __syncthreads();
    s  = rs[0] + rs[1] + rs[2] + rs[3];
    ss = rss[0] + rss[1] + rss[2] + rss[3];
    float mean = s * (1.0f / DMODEL);
    float var  = ss * (1.0f / DMODEL) - mean * mean;
    float inv  = rsqrtf(var + 1e-5f);
    float4 w4 = *(const float4*)(gw + tid * 4);
    float4 b4 = *(const float4*)(gb + tid * 4);
    float4 o;
    o.x = (v.x - mean) * inv * w4.x + b4.x;
    o.y = (v.y - mean) * inv * w4.y + b4.y;
    o.z = (v.z - mean) * inv * w4.z + b4.z;
    o.w = (v.w - mean) * inv * w4.w + b4.w;
    *(float4*)(out + (size_t)row * DMODEL + tid * 4) = o;
}

// ---------------- fp32 -> fp16 hi/lo split ----------------
__global__ __launch_bounds__(256) void split_f16(const float* __restrict__ in,
    h16* __restrict__ hi, h16* __restrict__ lo, int n8)
{
    int i = blockIdx.x * 256 + threadIdx.x;
    if (i >= n8) return;
    const float4* p = (const float4*)in + 2 * (size_t)i;
    float4 v0 = p[0], v1 = p[1];
    float vv[8] = {v0.x, v0.y, v0.z, v0.w, v1.x, v1.y, v1.z, v1.w};
    hfrag h, l;
#pragma unroll
    for (int j = 0; j < 8; ++j) {
        h16 hj = (h16)vv[j];
        h[j] = hj;
        l[j] = (h16)(vv[j] - (float)hj);
    }
    ((hfrag*)hi)[i] = h;
    ((hfrag*)lo)[i] = l;
}

// ---------------- fp16x2 (3-product) NT MFMA GEMM ----------------
// OMODE: 0 = fp32 out, 1 = fp32 out + res, 2 = f16 hi/lo pair out
template<int OMODE>
__global__ __launch_bounds__(256) void gemm_f16x2_nt(
    const h16* __restrict__ Ahi, const h16* __restrict__ Alo, int lda,
    const h16* __restrict__ Bhi, const h16* __restrict__ Blo, int ldb,
    const float* __restrict__ bias, const float* __restrict__ res,
    float* __restrict__ C, h16* __restrict__ Chi, h16* __restrict__ Clo,
    int K, int ldc)
{
    __shared__ h16 AhL[4096], AlL[4096], BhL[4096], BlL[4096];
    int rowBase = blockIdx.y * 128, colBase = blockIdx.x * 128;
    int t = threadIdx.x, lane = t & 63, wid = t >> 6;
    int wr = (wid >> 1) * 64, wc = (wid & 1) * 64;
    int c1 = t, c2 = t + 256;
    int r1 = c1 >> 2, q1 = (c1 & 3) ^ ((r1 + (r1 >> 2)) & 3);
    int r2 = c2 >> 2, q2 = (c2 & 3) ^ ((r2 + (r2 >> 2)) & 3);
    const h16* Ah = Ahi + (size_t)rowBase * lda;
    const h16* Al = Alo + (size_t)rowBase * lda;
    const h16* Bh = Bhi + (size_t)colBase * ldb;
    const h16* Bl = Blo + (size_t)colBase * ldb;
    f32x4 acc[4][4] = {};
    int l15 = lane & 15, g = lane >> 4;

    for (int k0 = 0; k0 < K; k0 += 32) {
        __syncthreads();
        GLL16(Ah + (size_t)r1 * lda + k0 + q1 * 8, &AhL[c1 * 8]);
        GLL16(Ah + (size_t)r2 * lda + k0 + q2 * 8, &AhL[c2 * 8]);
        GLL16(Al + (size_t)r1 * lda + k0 + q1 * 8, &AlL[c1 * 8]);
        GLL16(Al + (size_t)r2 * lda + k0 + q2 * 8, &AlL[c2 * 8]);
        GLL16(Bh + (size_t)r1 * ldb + k0 + q1 * 8, &BhL[c1 * 8]);
        GLL16(Bh + (size_t)r2 * ldb + k0 + q2 * 8, &BhL[c2 * 8]);
        GLL16(Bl + (size_t)r1 * ldb + k0 + q1 * 8, &BlL[c1 * 8]);
        GLL16(Bl + (size_t)r2 * ldb + k0 + q2 * 8, &BlL[c2 * 8]);
        __syncthreads();

        hfrag bh[4], bl[4];
#pragma unroll
        for (int n = 0; n < 4; ++n) {
            int row = wc + n * 16 + l15;
            int sw = (g ^ ((row + (row >> 2)) & 3)) * 8;
            bh[n] = *(const hfrag*)&BhL[row * 32 + sw];
            bl[n] = *(const hfrag*)&BlL[row * 32 + sw];
        }
#pragma unroll
        for (int m = 0; m < 4; ++m) {
            int row = wr + m * 16 + l15;
            int sw = (g ^ ((row + (row >> 2)) & 3)) * 8;
            hfrag ah = *(const hfrag*)&AhL[row * 32 + sw];
            hfrag al = *(const hfrag*)&AlL[row * 32 + sw];
#pragma unroll
            for (int n = 0; n < 4; ++n) {
                acc[m][n] = __builtin_amdgcn_mfma_f32_16x16x32_f16(ah, bh[n], acc[m][n], 0, 0, 0);
                acc[m][n] = __builtin_amdgcn_mfma_f32_16x16x32_f16(ah, bl[n], acc[m][n], 0, 0, 0);
                acc[m][n] = __builtin_amdgcn_mfma_f32_16x16x32_f16(al, bh[n], acc[m][n], 0, 0, 0);
            }
        }
    }

    int g4 = g * 4;
#pragma unroll
    for (int m = 0; m < 4; ++m) {
        int row0 = rowBase + wr + m * 16 + g4;
#pragma unroll
        for (int n = 0; n < 4; ++n) {
            int col = colBase + wc + n * 16 + l15;
            float bv = bias[col];
#pragma unroll
            for (int j = 0; j < 4; ++j) {
                float v = acc[m][n][j] + bv;
                if (OMODE == 1) v += res[(size_t)(row0 + j) * ldc + col];
                if (OMODE < 2) {
                    C[(size_t)(row0 + j) * ldc + col] = v;
                } else {
                    h16 hh = (h16)v;
                    Chi[(size_t)(row0 + j) * ldc + col] = hh;
                    Clo[(size_t)(row0 + j) * ldc + col] = (h16)(v - (float)hh);
                }
            }
        }
    }
}

// ---------------- attention QK^T (f16x2, K=64, strided heads) ----------------
template<bool CAUSAL>
__global__ __launch_bounds__(256) void attn_qk(
    const h16* __restrict__ Qh, const h16* __restrict__ Ql, int lda,
    const h16* __restrict__ Kh, const h16* __restrict__ Kl, int ldb,
    h16* __restrict__ Sh, h16* __restrict__ Sl, int zoff)
{
    int rowBase = blockIdx.y * 128, colBase = blockIdx.x * 128;
    if (CAUSAL && colBase >= rowBase + 128) return;
    __shared__ h16 AhL[4096], AlL[4096], BhL[4096], BlL[4096];
    int z = blockIdx.z;
    int bh_ = zoff + z, b = bh_ >> 4, h = bh_ & 15;
    const h16* Ah = Qh + (size_t)(b * 512 + rowBase) * lda + h * 64;
    const h16* Al = Ql + (size_t)(b * 512 + rowBase) * lda + h * 64;
    const h16* Bh = Kh + (size_t)(b * 512 + colBase) * ldb + h * 64;
    const h16* Bl = Kl + (size_t)(b * 512 + colBase) * ldb + h * 64;
    int t = threadIdx.x, lane = t & 63, wid = t >> 6;
    int wr = (wid >> 1) * 64, wc = (wid & 1) * 64;
    int c1 = t, c2 = t + 256;
    int r1 = c1 >> 2, q1 = (c1 & 3) ^ ((r1 + (r1 >> 2)) & 3);
    int r2 = c2 >> 2, q2 = (c2 & 3) ^ ((r2 + (r2 >> 2)) & 3);
    f32x4 acc[4][4] = {};
    int l15 = lane & 15, g = lane >> 4;

    for (int k0 = 0; k0 < 64; k0 += 32) {
        __syncthreads();
        GLL16(Ah + (size_t)r1 * lda + k0 + q1 * 8, &AhL[c1 * 8]);
        GLL16(Ah + (size_t)r2 * lda + k0 + q2 * 8, &AhL[c2 * 8]);
        GLL16(Al + (size_t)r1 * lda + k0 + q1 * 8, &AlL[c1 * 8]);
        GLL16(Al + (size_t)r2 * lda + k0 + q2 * 8, &AlL[c2 * 8]);
        GLL16(Bh + (size_t)r1 * ldb + k0 + q1 * 8, &BhL[c1 * 8]);
        GLL16(Bh + (size_t)r2 * ldb + k0 + q2 * 8, &BhL[c2 * 8]);
        GLL16(Bl + (size_t)r1 * ldb + k0 + q1 * 8, &BlL[c1 * 8]);
        GLL16(Bl + (size_t)r2 * ldb + k0 + q2 * 8, &BlL[c2 * 8]);
        __syncthreads();

        hfrag bh[4], bl[4];
#pragma unroll
        for (int n = 0; n < 4; ++n) {
            int row = wc + n * 16 + l15;
            int sw = (g ^ ((row + (row >> 2)) & 3)) * 8;
            bh[n] = *(const hfrag*)&BhL[row * 32 + sw];
            bl[n] = *(const hfrag*)&BlL[row * 32 + sw];
        }
#pragma unroll
        for (int m = 0; m < 4; ++m) {
            int row = wr + m * 16 + l15;
            int sw = (g ^ ((row + (row >> 2)) & 3)) * 8;
            hfrag ah = *(const hfrag*)&AhL[row * 32 + sw];
            hfrag al = *(const hfrag*)&AlL[row * 32 + sw];
#pragma unroll
            for (int n = 0; n < 4; ++n) {
                acc[m][n] = __builtin_amdgcn_mfma_f32_16x16x32_f16(ah, bh[n], acc[m][n], 0, 0, 0);
                acc[m][n] = __builtin_amdgcn_mfma_f32_16x16x32_f16(ah, bl[n], acc[m][n], 0, 0, 0);
                acc[m][n] = __builtin_amdgcn_mfma_f32_16x16x32_f16(al, bh[n], acc[m][n], 0, 0, 0);
            }
        }
    }

    size_t sbase = (size_t)z * 262144;
    int g4 = g * 4;
#pragma unroll
    for (int m = 0; m < 4; ++m) {
        int row0 = rowBase + wr + m * 16 + g4;
#pragma unroll
        for (int n = 0; n < 4; ++n) {
            int col = colBase + wc + n * 16 + l15;
#pragma unroll
            for (int j = 0; j < 4; ++j) {
                float v = acc[m][n][j] * 0.125f;
                h16 hh = (h16)v;
                Sh[sbase + (size_t)(row0 + j) * 512 + col] = hh;
                Sl[sbase + (size_t)(row0 + j) * 512 + col] = (h16)(v - (float)hh);
            }
        }
    }
}

// ---------------- softmax over hi/lo rows, in place ----------------
__global__ __launch_bounds__(64) void softmax_hl(h16* __restrict__ Sh, h16* __restrict__ Sl, int causal)
{
    int t = blockIdx.x, z = blockIdx.y, lane = threadIdx.x;
    size_t base = ((size_t)z * 512 + t) * 512;
    int limit = causal ? (t + 1) : 512;
    float v[8];
    float mx = -1e30f;
#pragma unroll
    for (int k = 0; k < 8; ++k) {
        int idx = lane + (k << 6);
        float s = (float)Sh[base + idx] + (float)Sl[base + idx];
        float val = (idx < limit) ? s : -1e30f;
        v[k] = val; mx = fmaxf(mx, val);
    }
#pragma unroll
    for (int o = 1; o < 64; o <<= 1) mx = fmaxf(mx, __shfl_xor(mx, o, 64));
    float sum = 0.f;
#pragma unroll
    for (int k = 0; k < 8; ++k) {
        int idx = lane + (k << 6);
        float p = (idx < limit) ? __expf(v[k] - mx) : 0.f;
        v[k] = p; sum += p;
    }
#pragma unroll
    for (int o = 1; o < 64; o <<= 1) sum += __shfl_xor(sum, o, 64);
    float inv = 1.0f / sum;
#pragma unroll
    for (int k = 0; k < 8; ++k) {
        int idx = lane + (k << 6);
        float p = v[k] * inv;
        h16 hh = (h16)p;
        Sh[base + idx] = hh;
        Sl[base + idx] = (h16)(p - (float)hh);
    }
}

// ---------------- PV: C[t,d] = P[t,s] * vT[d,s]^T  (64x64 tile, K=512) ----------------
__global__ __launch_bounds__(256) void attn_pv(
    const h16* __restrict__ Ph, const h16* __restrict__ Pl,
    const h16* __restrict__ Vh, const h16* __restrict__ Vl,
    h16* __restrict__ Ch, h16* __restrict__ Cl, int bh0)
{
    __shared__ h16 PhL[2048], PlL[2048], VhL[2048], VlL[2048];
    int z = blockIdx.z, bh_ = bh0 + z;
    int rowBase = blockIdx.x * 64;
    const h16* Pa = Ph + (size_t)z * 262144 + (size_t)rowBase * 512;
    const h16* Pb = Pl + (size_t)z * 262144 + (size_t)rowBase * 512;
    const h16* Va = Vh + (size_t)z * 32768;
    const h16* Vb = Vl + (size_t)z * 32768;
    int t = threadIdx.x, lane = t & 63, wid = t >> 6;
    int r = t >> 2, q = (t & 3) ^ ((r + (r >> 2)) & 3);
    f32x4 acc[4] = {};
    int l15 = lane & 15, g = lane >> 4;

    for (int k0 = 0; k0 < 512; k0 += 32) {
        __syncthreads();
        GLL16(Pa + (size_t)r * 512 + k0 + q * 8, &PhL[t * 8]);
        GLL16(Pb + (size_t)r * 512 + k0 + q * 8, &PlL[t * 8]);
        GLL16(Va + (size_t)r * 512 + k0 + q * 8, &VhL[t * 8]);
        GLL16(Vb + (size_t)r * 512 + k0 + q * 8, &VlL[t * 8]);
        __syncthreads();

        int arow = wid * 16 + l15;
        int asw = (g ^ ((arow + (arow >> 2)) & 3)) * 8;
        hfrag ah = *(const hfrag*)&PhL[arow * 32 + asw];
        hfrag al = *(const hfrag*)&PlL[arow * 32 + asw];
#pragma unroll
        for (int n = 0; n < 4; ++n) {
            int brow = n * 16 + l15;
            int bsw = (g ^ ((brow + (brow >> 2)) & 3)) * 8;
            hfrag bh = *(const hfrag*)&VhL[brow * 32 + bsw];
            hfrag bl = *(const hfrag*)&VlL[brow * 32 + bsw];
            acc[n] = __builtin_amdgcn_mfma_f32_16x16x32_f16(ah, bh, acc[n], 0, 0, 0);
            acc[n] = __builtin_amdgcn_mfma_f32_16x16x32_f16(ah, bl, acc[n], 0, 0, 0);
            acc[n] = __builtin_amdgcn_mfma_f32_16x16x32_f16(al, bh, acc[n], 0, 0, 0);
        }
    }

    int brow = (bh_ >> 4) * 512 + rowBase + wid * 16 + g * 4;
    int bcol = (bh_ & 15) * 64;
#pragma unroll
    for (int n = 0; n < 4; ++n) {
        int col = bcol + n * 16 + l15;
#pragma unroll
        for (int j = 0; j < 4; ++j) {
            float v = acc[n][j];
            h16 hh = (h16)v;
            Ch[(size_t)(brow + j) * 1024 + col] = hh;
            Cl[(size_t)(brow + j) * 1024 + col] = (h16)(v - (float)hh);
        }
    }
}

// ---------------- V-transpose ----------------
__global__ __launch_bounds__(256) void vt_split(
    const h16* __restrict__ inh, const h16* __restrict__ inl, int ld,
    h16* __restrict__ oh, h16* __restrict__ ol)
{
    __shared__ h16 tile[64][68];
    int z = blockIdx.z, b = z >> 4, h = z & 15;
    size_t ibase = ((size_t)b * 512 + blockIdx.x * 64) * ld + h * 64;
    size_t obase = (size_t)z * 32768 + blockIdx.x * 64;
    int tr = threadIdx.x >> 4, tc = (threadIdx.x & 15) * 4;
    const h16* src[2] = {inh, inl};
    h16* dst[2] = {oh, ol};
#pragma unroll
    for (int s = 0; s < 2; ++s) {
        __syncthreads();
#pragma unroll
        for (int i = 0; i < 4; ++i) {
            int tt = tr + i * 16;
            short4 v = *(const short4*)(src[s] + ibase + (size_t)tt * ld + tc);
            tile[tt][tc + 0] = ((h16*)&v)[0];
            tile[tt][tc + 1] = ((h16*)&v)[1];
            tile[tt][tc + 2] = ((h16*)&v)[2];
            tile[tt][tc + 3] = ((h16*)&v)[3];
        }
        __syncthreads();
#pragma unroll
        for (int i = 0; i < 4; ++i) {
            int d = tr + i * 16;
            h16 w[4] = {tile[tc + 0][d], tile[tc + 1][d], tile[tc + 2][d], tile[tc + 3][d]};
            *(short4*)(dst[s] + obase + (size_t)d * 512 + tc) = *(short4*)w;
        }
    }
}

// ---------------- bf16 NT MFMA GEMM (MoE), tile 128 x TN ----------------
template<int TN, bool RELU, bool OBF16>
__global__ __launch_bounds__(256) void gemm_bf16_nt(
    const unsigned short* __restrict__ A,   // [M][K] bf16
    const unsigned short* __restrict__ Bt,  // [N][K] bf16
    const float* __restrict__ bias,         // [N] fp32
    void* __restrict__ Cv,
    int K, long long sA, long long sB, long long sC, long long sBias, int ldc)
{
    constexpr int NFR = TN / 32;
    __shared__ unsigned short Al[128 * 32];
    __shared__ unsigned short Bl[TN * 32];
    int z = blockIdx.z;
    A  += (size_t)z * sA;
    Bt += (size_t)z * sB;
    bias += (size_t)z * sBias;
    long long zC = (long long)z * sC;

    int rowBase = blockIdx.y * 128, colBase = blockIdx.x * TN;
    int t = threadIdx.x, lane = t & 63, wid = t >> 6;
    int wr = (wid >> 1) * 64, wc = (wid & 1) * (TN / 2);

    int c1 = t, c2 = t + 256;
    int r1 = c1 >> 2, q1 = (c1 & 3) ^ ((r1 + (r1 >> 2)) & 3);
    int r2 = c2 >> 2, q2 = (c2 & 3) ^ ((r2 + (r2 >> 2)) & 3);

    const unsigned short* Ag = A  + (size_t)rowBase * K;
    const unsigned short* Bg = Bt + (size_t)colBase * K;

    f32x4 acc[4][NFR] = {};
    int l15 = lane & 15, g = lane >> 4;

    for (int k0 = 0; k0 < K; k0 += 32) {
        __syncthreads();
        GLL16(Ag + (size_t)r1 * K + k0 + q1 * 8, &Al[c1 * 8]);
        GLL16(Ag + (size_t)r2 * K + k0 + q2 * 8, &Al[c2 * 8]);
        GLL16(Bg + (size_t)r1 * K + k0 + q1 * 8, &Bl[c1 * 8]);
        if (TN == 128)
            GLL16(Bg + (size_t)r2 * K + k0 + q2 * 8, &Bl[c2 * 8]);
        __syncthreads();

        bfrag a[4], b[NFR];
#pragma unroll
        for (int m = 0; m < 4; ++m) {
            int row = wr + m * 16 + l15;
            int sw = (g ^ ((row + (row >> 2)) & 3)) * 8;
            a[m] = *(const bfrag*)&Al[row * 32 + sw];
        }
#pragma unroll
        for (int n = 0; n < NFR; ++n) {
            int row = wc + n * 16 + l15;
            int sw = (g ^ ((row + (row >> 2)) & 3)) * 8;
            b[n] = *(const bfrag*)&Bl[row * 32 + sw];
        }
#pragma unroll
        for (int m = 0; m < 4; ++m)
#pragma unroll
            for (int n = 0; n < NFR; ++n)
                acc[m][n] = __builtin_amdgcn_mfma_f32_16x16x32_bf16(a[m], b[n], acc[m][n], 0, 0, 0);
    }

    int g4 = g * 4;
#pragma unroll
    for (int m = 0; m < 4; ++m) {
        int row0 = rowBase + wr + m * 16 + g4;
#pragma unroll
        for (int n = 0; n < NFR; ++n) {
            int col = colBase + wc + n * 16 + l15;
            float bv = bias[col];
#pragma unroll
            for (int j = 0; j < 4; ++j) {
                float v = acc[m][n][j] + bv;
                if (RELU) v = fmaxf(v, 0.f);
                if (OBF16)
                    ((unsigned short*)Cv)[zC + (size_t)(row0 + j) * ldc + col] = f2bf(v);
                else
                    ((float*)Cv)[zC + (size_t)(row0 + j) * ldc + col] = v;
            }
        }
    }
}

// ---------------- transpose+convert fp32 [R][Cn] -> bf16 [Cn][R] (per z) ----------------
__global__ __launch_bounds__(256) void tcvt_kernel(const float* __restrict__ in,
    unsigned short* __restrict__ out, int R, int Cn)
{
    __shared__ unsigned short tile[64][68];
    size_t zoff = (size_t)blockIdx.z * R * Cn;
    in += zoff; out += zoff;
    int r0 = blockIdx.y * 64, c0 = blockIdx.x * 64;
    int tr = threadIdx.x >> 4, tc = (threadIdx.x & 15) * 4;
#pragma unroll
    for (int i = 0; i < 4; ++i) {
        int r = tr + i * 16;
        float4 v = *(const float4*)&in[(size_t)(r0 + r) * Cn + c0 + tc];
        tile[r][tc + 0] = f2bf(v.x);
        tile[r][tc + 1] = f2bf(v.y);
        tile[r][tc + 2] = f2bf(v.z);
        tile[r][tc + 3] = f2bf(v.w);
    }
    __syncthreads();
#pragma unroll
    for (int i = 0; i < 4; ++i) {
        int c = tr + i * 16;
        ushort4 w;
        w.x = tile[tc + 0][c];
        w.y = tile[tc + 1][c];
        w.z = tile[tc + 2][c];
        w.w = tile[tc + 3][c];
        *(ushort4*)&out[(size_t)(c0 + c) * R + r0 + tc] = w;
    }
}

// ---------------- router ----------------
__global__ __launch_bounds__(256) void router_kernel(
    const float* __restrict__ xf, const float* __restrict__ rw, const float* __restrict__ rb,
    const float* __restrict__ tmask,
    int* __restrict__ eidx, float* __restrict__ gate, int* __restrict__ valid,
    float* __restrict__ partials)
{
    int blk = blockIdx.x;
    int wid = threadIdx.x >> 6, lane = threadIdx.x & 63;
    __shared__ float wpart[4][10];
    float pe[8] = {0,0,0,0,0,0,0,0};
    float zacc = 0.f, nvacc = 0.f;

    for (int i = 0; i < 16; ++i) {
        int tok = blk * 64 + wid * 16 + i;
        const float* xrow = xf + (size_t)tok * DMODEL;
        float acc[8] = {0,0,0,0,0,0,0,0};
#pragma unroll 4
        for (int kk = 0; kk < 16; ++kk) {
            int d = lane + (kk << 6);
            float xd = xrow[d];
            const float4* rp = (const float4*)(rw + (size_t)d * 8);
            float4 r0 = rp[0], r1 = rp[1];
            acc[0] = fmaf(xd, r0.x, acc[0]); acc[1] = fmaf(xd, r0.y, acc[1]);
            acc[2] = fmaf(xd, r0.z, acc[2]); acc[3] = fmaf(xd, r0.w, acc[3]);
            acc[4] = fmaf(xd, r1.x, acc[4]); acc[5] = fmaf(xd, r1.y, acc[5]);
            acc[6] = fmaf(xd, r1.z, acc[6]); acc[7] = fmaf(xd, r1.w, acc[7]);
        }
#pragma unroll
        for (int e = 0; e < 8; ++e)
#pragma unroll
            for (int o = 1; o < 64; o <<= 1) acc[e] += __shfl_xor(acc[e], o, 64);
        if (lane == 0) {
            float l[8]; float m = -1e30f;
#pragma unroll
            for (int e = 0; e < 8; ++e) { l[e] = acc[e] + rb[e]; m = fmaxf(m, l[e]); }
            float se = 0.f;
#pragma unroll
            for (int e = 0; e < 8; ++e) se += expf(l[e] - m);
            int am = 0; float bm = l[0];
#pragma unroll
            for (int e = 1; e < 8; ++e) if (l[e] > bm) { bm = l[e]; am = e; }
            float inv_se = 1.0f / se;
            float g = expf(l[am] - m) * inv_se;
            float vld = (tmask[tok] > 0.f) ? 1.f : 0.f;
            eidx[tok] = am; gate[tok] = g; valid[tok] = (int)vld;
#pragma unroll
            for (int e = 0; e < 8; ++e) pe[e] += expf(l[e] - m) * inv_se * vld;
            float lse = logf(se) + m;
            zacc += lse * lse * vld;
            nvacc += vld;
        }
    }
    if (lane == 0) {
#pragma unroll
        for (int e = 0; e < 8; ++e) wpart[wid][e] = pe[e];
        wpart[wid][8] = zacc; wpart[wid][9] = nvacc;
    }
    __syncthreads();
    if (threadIdx.x == 0) {
        for (int j = 0; j < 10; ++j)
            partials[blk * 10 + j] = wpart[0][j] + wpart[1][j] + wpart[2][j] + wpart[3][j];
    }
}

// ---------------- capacity scan ----------------
__global__ __launch_bounds__(256) void scan_kernel(
    const int* __restrict__ eidx, const int* __restrict__ valid, const float* __restrict__ gate,
    int* __restrict__ pc, float* __restrict__ gk, int* __restrict__ keepf,
    int* __restrict__ counts)
{
    __shared__ int cnt[256][8];
    int tid = threadIdx.x;
    int local[8] = {0,0,0,0,0,0,0,0};
    int base = tid * 16;
    for (int i = 0; i < 16; ++i) { int e = eidx[base + i]; local[e] += valid[base + i]; }
#pragma unroll
    for (int e = 0; e < 8; ++e) cnt[tid][e] = local[e];
    __syncthreads();
    if (tid < 8) {
        int run = 0;
        for (int i = 0; i < 256; ++i) { int t = cnt[i][tid]; cnt[i][tid] = run; run += t; }
        counts[tid] = run;
    }
    __syncthreads();
    int off[8];
#pragma unroll
    for (int e = 0; e < 8; ++e) off[e] = cnt[tid][e];
    for (int i = 0; i < 16; ++i) {
        int tok = base + i;
        int e = eidx[tok], v = valid[tok];
        int pos = off[e]; off[e] += v;
        int kp = (v && pos < CAPE) ? 1 : 0;
        pc[tok]    = (pos < CAPE) ? pos : (CAPE - 1);
        keepf[tok] = kp;
        gk[tok]    = kp ? gate[tok] : 0.f;
    }
}

// ---------------- dispatch (expert-range) -> bf16 buffers ----------------
__global__ __launch_bounds__(256) void dispatch_bf16(const float* __restrict__ tln,
    const int* __restrict__ eidx, const int* __restrict__ pc, const int* __restrict__ keepf,
    unsigned short* __restrict__ buf, int e0, int ec)
{
    int tok = blockIdx.x;
    if (!keepf[tok]) return;
    int e = eidx[tok];
    if (e < e0 || e >= e0 + ec) return;
    int p = pc[tok];
    const float4 v = ((const float4*)(tln + (size_t)tok * DMODEL))[threadIdx.x];
    ushort4 o;
    o.x = f2bf(v.x); o.y = f2bf(v.y); o.z = f2bf(v.z); o.w = f2bf(v.w);
    ((ushort4*)(buf + ((size_t)(e - e0) * CAPE + p) * DMODEL))[threadIdx.x] = o;
}

// ---------------- combine add: out += gk * ob (bf16 ob) ----------------
__global__ __launch_bounds__(256) void combine_bf16(const unsigned short* __restrict__ ob,
    const int* __restrict__ eidx, const int* __restrict__ pc, const float* __restrict__ gk,
    float* __restrict__ out, int e0, int ec)
{
    int tok = blockIdx.x;
    int e = eidx[tok];
    if (e < e0 || e >= e0 + ec) return;
    float g = gk[tok];
    int p = pc[tok];
    float4* o = (float4*)(out + (size_t)tok * DMODEL);
    const ushort4 u = ((const ushort4*)(ob + ((size_t)(e - e0) * CAPE + p) * DMODEL))[threadIdx.x];
    float4 a = o[threadIdx.x];
    a.x += g * bf2f(u.x); a.y += g * bf2f(u.y);
    a.z += g * bf2f(u.z); a.w += g * bf2f(u.w);
    o[threadIdx.x] = a;
}

// ---------------- final scalar losses ----------------
__global__ __launch_bounds__(64) void loss_kernel(const float* __restrict__ partials,
    const int* __restrict__ counts, float* __restrict__ out2)
{
    int lane = threadIdx.x;
    float p[10];
#pragma unroll
    for (int j = 0; j < 10; ++j) p[j] = partials[lane * 10 + j];
#pragma unroll
    for (int j = 0; j < 10; ++j)
#pragma unroll
        for (int o = 1; o < 64; o <<= 1) p[j] += __shfl_xor(p[j], o, 64);
    if (lane == 0) {
        float nv = fmaxf(p[9], 1.f);
        float lb = 0.f;
        for (int e = 0; e < 8; ++e) lb += ((float)counts[e] / nv) * (p[e] / nv);
        lb *= (float)NEXP;
        out2[0] = lb;
        out2[1] = p[8] / nv;
    }
}

// ---------------- host launch ----------------
extern "C" void kernel_launch(void* const* d_in, const int* in_sizes, int n_in,
                              void* d_out, int out_size, void* d_ws, size_t ws_size,
                              hipStream_t stream)
{
    const float* tgt        = (const float*)d_in[0];
    const float* src        = (const float*)d_in[1];
    const float* token_mask = (const float*)d_in[5];
    const float* ln1w = (const float*)d_in[6],  *ln1b = (const float*)d_in[7];
    const float* self_in_w  = (const float*)d_in[8],  *self_in_b  = (const float*)d_in[9];
    const float* self_out_w = (const float*)d_in[10], *self_out_b = (const float*)d_in[11];
    const float* ln2w = (const float*)d_in[12], *ln2b = (const float*)d_in[13];
    const float* enc_in_w   = (const float*)d_in[14], *enc_in_b   = (const float*)d_in[15];
    const float* enc_out_w  = (const float*)d_in[16], *enc_out_b  = (const float*)d_in[17];
    const float* ln3w = (const float*)d_in[18], *ln3b = (const float*)d_in[19];
    const float* rw = (const float*)d_in[20], *rb = (const float*)d_in[21];
    const float* w1 = (const float*)d_in[22], *b1 = (const float*)d_in[23];
    const float* w2 = (const float*)d_in[24], *b2 = (const float*)d_in[25];

    float* out = (float*)d_out;          // residual stream lives HERE
    float* ws  = (float*)d_ws;

    // ---- fixed layout (floats) ----
    float* tln = ws;                         // 4,194,304
    float* ctx = ws + 4194304;               // 4,194,304 (holds ctx hi/lo f16)
    int*   eidxA   = (int*)(ws + 8388608);
    int*   validA  = eidxA + 4096;
    int*   pcA     = validA + 4096;
    int*   keepA   = pcA + 4096;
    int*   countsA = keepA + 4096;           // 16
    float* gateA   = (float*)(countsA + 16);
    float* gkA     = gateA + 4096;
    float* partA   = gkA + 4096;             // 640
    const size_t POOL_OFF = 8425984;         // floats
    float* pool = ws + POOL_OFF;

    size_t Wf = ws_size / sizeof(float);
    size_t pf = (Wf > POOL_OFF) ? (Wf - POOL_OFF) : 0;

    // ---- tiers: bg = batches per attention group, zc = score z-chunk ----
    int bg, zc;
    if      (pf >= 25165824) { bg = 8; zc = 32; }
    else if (pf >= 24117248) { bg = 8; zc = 16; }
    else if (pf >= 13631488) { bg = 4; zc = 16; }
    else                     { bg = 2; zc = 16; }
    // MoE: experts per chunk; per expert needs 3,735,552 pool floats
    int ecs = 1;
    for (int c = 8; c >= 1; c >>= 1)
        if ((size_t)c * 3735552ull <= pf) { ecs = c; break; }

    float* qreg = pool;
    float* vreg = qreg + (size_t)bg * 1572864;
    float* sreg = vreg + (size_t)bg * 524288;

    h16* ctxh = (h16*)ctx;
    h16* ctxl = ctxh + 4194304;   // f16 elements

    // ================= self attention =================
    ln_kernel<<<NTOK, 256, 0, stream>>>(tgt, ln1w, ln1b, tln);

    for (int g0 = 0; g0 < BATCH; g0 += bg) {
        h16* sb  = (h16*)sreg;
        h16* thi = sb,                      *tlo = sb + (size_t)bg * 524288;
        h16* whi = sb + (size_t)bg * 1048576, *wlo = whi + 3145728;
        split_f16<<<bg * 256, 256, 0, stream>>>(tln + (size_t)g0 * 524288, thi, tlo, bg * 65536);
        split_f16<<<1536, 256, 0, stream>>>(self_in_w, whi, wlo, 393216);

        h16* qkvh = (h16*)qreg, *qkvl = qkvh + (size_t)bg * 1572864;
        gemm_f16x2_nt<2><<<dim3(24, bg * 4, 1), 256, 0, stream>>>(
            thi, tlo, 1024, whi, wlo, 1024, self_in_b, nullptr,
            nullptr, qkvh, qkvl, 1024, 3072);

        h16* vth = (h16*)vreg, *vtl = vth + (size_t)bg * 524288;
        vt_split<<<dim3(8, 1, bg * 16), 256, 0, stream>>>(qkvh + 2048, qkvl + 2048, 3072, vth, vtl);

        h16* sh = sb, *sl = sh + (size_t)zc * 262144;
        for (int c0 = 0; c0 < bg * 16; c0 += zc) {
            attn_qk<true><<<dim3(4, 4, zc), 256, 0, stream>>>(
                qkvh, qkvl, 3072, qkvh + 1024, qkvl + 1024, 3072, sh, sl, c0);
            softmax_hl<<<dim3(512, zc), 64, 0, stream>>>(sh, sl, 1);
            attn_pv<<<dim3(8, 1, zc), 256, 0, stream>>>(
                sh, sl, vth + (size_t)c0 * 32768, vtl + (size_t)c0 * 32768,
                ctxh, ctxl, g0 * 16 + c0);
        }
    }
    {
        h16* sb = (h16*)sreg;
        h16* owhi = sb, *owlo = sb + 1048576;
        split_f16<<<512, 256, 0, stream>>>(self_out_w, owhi, owlo, 131072);
        gemm_f16x2_nt<1><<<dim3(8, 32, 1), 256, 0, stream>>>(
            ctxh, ctxl, 1024, owhi, owlo, 1024, self_out_b, tgt,
            out, nullptr, nullptr, 1024, 1024);
    }

    // ================= cross attention =================
    ln_kernel<<<NTOK, 256, 0, stream>>>(out, ln2w, ln2b, tln);

    for (int g0 = 0; g0 < BATCH; g0 += bg) {
        h16* sb  = (h16*)sreg;
        h16* thi = sb,                      *tlo = sb + (size_t)bg * 524288;
        h16* ehi = sb + (size_t)bg * 1048576, *elo = ehi + 3145728;
        split_f16<<<bg * 256, 256, 0, stream>>>(tln + (size_t)g0 * 524288, thi, tlo, bg * 65536);
        split_f16<<<1536, 256, 0, stream>>>(enc_in_w, ehi, elo, 393216);

        h16* q2h  = (h16*)qreg,              *q2l  = q2h + (size_t)bg * 524288;
        h16* kv2h = q2h + (size_t)bg * 1048576, *kv2l = kv2h + (size_t)bg * 1048576;
        gemm_f16x2_nt<2><<<dim3(8, bg * 4, 1), 256, 0, stream>>>(
            thi, tlo, 1024, ehi, elo, 1024, enc_in_b, nullptr,
            nullptr, q2h, q2l, 1024, 1024);

        split_f16<<<bg * 256, 256, 0, stream>>>(src + (size_t)g0 * 524288, thi, tlo, bg * 65536);
        gemm_f16x2_nt<2><<<dim3(16, bg * 4, 1), 256, 0, stream>>>(
            thi, tlo, 1024, ehi + 1048576, elo + 1048576, 1024, enc_in_b + 1024, nullptr,
            nullptr, kv2h, kv2l, 1024, 2048);

        h16* vth = (h16*)vreg, *vtl = vth + (size_t)bg * 524288;
        vt_split<<<dim3(8, 1, bg * 16), 256, 0, stream>>>(kv2h + 1024, kv2l + 1024, 2048, vth, vtl);

        h16* sh = sb, *sl = sh + (size_t)zc * 262144;
        for (int c0 = 0; c0 < bg * 16; c0 += zc) {
            attn_qk<false><<<dim3(4, 4, zc), 256, 0, stream>>>(
                q2h, q2l, 1024, kv2h, kv2l, 2048, sh, sl, c0);
            softmax_hl<<<dim3(512, zc), 64, 0, stream>>>(sh, sl, 0);
            attn_pv<<<dim3(8, 1, zc), 256, 0, stream>>>(
                sh, sl, vth + (size_t)c0 * 32768, vtl + (size_t)c0 * 32768,
                ctxh, ctxl, g0 * 16 + c0);
        }
    }
    {
        h16* sb = (h16*)sreg;
        h16* owhi = sb, *owlo = sb + 1048576;
        split_f16<<<512, 256, 0, stream>>>(enc_out_w, owhi, owlo, 131072);
        gemm_f16x2_nt<1><<<dim3(8, 32, 1), 256, 0, stream>>>(
            ctxh, ctxl, 1024, owhi, owlo, 1024, enc_out_b, out,
            out, nullptr, nullptr, 1024, 1024);
    }

    // ================= MoE =================
    ln_kernel<<<NTOK, 256, 0, stream>>>(out, ln3w, ln3b, tln);
    router_kernel<<<64, 256, 0, stream>>>(tln, rw, rb, token_mask, eidxA, gateA, validA, partA);
    scan_kernel<<<1, 256, 0, stream>>>(eidxA, validA, gateA, pcA, gkA, keepA, countsA);

    // per-chunk pool layout (floats):
    //   wt   : ecs*2,097,152  (bf16 w1t then w2t, reused)
    //   hB   : ecs*1,310,720  (bf16 [640][4096])
    //   bufB : ecs*327,680    (bf16 [640][1024]); obB (bf16) overlays bufB
    for (int e0 = 0; e0 < NEXP; e0 += ecs) {
        unsigned short* wt   = (unsigned short*)pool;
        unsigned short* hB   = (unsigned short*)(pool + (size_t)ecs * 2097152);
        unsigned short* bufB = (unsigned short*)(pool + (size_t)ecs * 3407872);
        unsigned short* obB  = bufB;   // overlay: bufB dead after w1 GEMM

        // w1 phase
        tcvt_kernel<<<dim3(64, 16, ecs), 256, 0, stream>>>(
            w1 + (size_t)e0 * 4194304, wt, 1024, 4096);
        hipMemsetAsync(bufB, 0, (size_t)ecs * 655360 * sizeof(unsigned short), stream);
        dispatch_bf16<<<NTOK, 256, 0, stream>>>(tln, eidxA, pcA, keepA, bufB, e0, ecs);
        gemm_bf16_nt<128, true, true><<<dim3(32, 5, ecs), 256, 0, stream>>>(
            bufB, wt, b1 + (size_t)e0 * 4096, hB,
            1024, 655360LL, 4194304LL, 2621440LL, 4096LL, 4096);

        // w2 phase (wt reused)
        tcvt_kernel<<<dim3(16, 64, ecs), 256, 0, stream>>>(
            w2 + (size_t)e0 * 4194304, wt, 4096, 1024);
        gemm_bf16_nt<64, false, true><<<dim3(16, 5, ecs), 256, 0, stream>>>(
            hB, wt, b2 + (size_t)e0 * 1024, obB,
            4096, 2621440LL, 4194304LL, 655360LL, 1024LL, 1024);

        combine_bf16<<<NTOK, 256, 0, stream>>>(obB, eidxA, pcA, gkA, out, e0, ecs);
    }

    // ===== losses =====
    loss_kernel<<<1, 64, 0, stream>>>(partA, countsA, out + (size_t)NTOK * DMODEL);
}

// Round 8
// 1057.802 us; speedup vs baseline: 2.5591x; 1.0105x over previous
//
#include <hip/hip_runtime.h>
#include <cstdint>

// ---------------- problem constants ----------------
constexpr int BATCH  = 8;
constexpr int TSEQ   = 512;
constexpr int DMODEL = 1024;
constexpr int NEXP   = 8;
constexpr int CAPE   = 640;
constexpr int NTOK   = BATCH * TSEQ;        // 4096

typedef _Float16 h16;
typedef __attribute__((ext_vector_type(8))) short bfrag;
typedef __attribute__((ext_vector_type(8))) _Float16 hfrag;
typedef __attribute__((ext_vector_type(4))) float f32x4;

__device__ __forceinline__ unsigned short f2bf(float f) {
    uint32_t u = __float_as_uint(f);
    uint32_t r = (u + 0x7FFFu + ((u >> 16) & 1u)) >> 16;   // RNE
    return (unsigned short)r;
}
__device__ __forceinline__ float bf2f(unsigned short b) {
    return __uint_as_float((uint32_t)b << 16);
}

#define GLL16(SRC, DST) __builtin_amdgcn_global_load_lds( \
    (const __attribute__((address_space(1))) void*)(SRC), \
    (__attribute__((address_space(3))) void*)(DST), 16, 0, 0)

// ---------------- LayerNorm: MODE 0 -> fp32 out; MODE 1 -> f16 hi/lo out ----------------
template<int MODE>
__global__ __launch_bounds__(256) void ln_kernel(const float* __restrict__ in,
    const float* __restrict__ gw, const float* __restrict__ gb,
    float* __restrict__ out, h16* __restrict__ ohi, h16* __restrict__ olo)
{
    int row = blockIdx.x, tid = threadIdx.x;
    const float4 v = *(const float4*)(in + (size_t)row * DMODEL + tid * 4);
    float s  = v.x + v.y + v.z + v.w;
    float ss = v.x*v.x + v.y*v.y + v.z*v.z + v.w*v.w;
#pragma unroll
    for (int o = 1; o < 64; o <<= 1) { s += __shfl_xor(s, o, 64); ss += __shfl_xor(ss, o, 64); }
    __shared__ float rs[4], rss[4];
    int wid = tid >> 6, lane = tid & 63;
    if (lane == 0) { rs[wid] = s; rss[wid] = ss; }
    __syncthreads();
    s  = rs[0] + rs[1] + rs[2] + rs[3];
    ss = rss[0] + rss[1] + rss[2] + rss[3];
    float mean = s * (1.0f / DMODEL);
    float var  = ss * (1.0f / DMODEL) - mean * mean;
    float inv  = rsqrtf(var + 1e-5f);
    float4 w4 = *(const float4*)(gw + tid * 4);
    float4 b4 = *(const float4*)(gb + tid * 4);
    float o[4];
    o[0] = (v.x - mean) * inv * w4.x + b4.x;
    o[1] = (v.y - mean) * inv * w4.y + b4.y;
    o[2] = (v.z - mean) * inv * w4.z + b4.z;
    o[3] = (v.w - mean) * inv * w4.w + b4.w;
    if (MODE == 0) {
        float4 f = {o[0], o[1], o[2], o[3]};
        *(float4*)(out + (size_t)row * DMODEL + tid * 4) = f;
    } else {
        short4 hv, lv;
#pragma unroll
        for (int j = 0; j < 4; ++j) {
            h16 hh = (h16)o[j];
            ((h16*)&hv)[j] = hh;
            ((h16*)&lv)[j] = (h16)(o[j] - (float)hh);
        }
        *(short4*)(ohi + (size_t)row * DMODEL + tid * 4) = hv;
        *(short4*)(olo + (size_t)row * DMODEL + tid * 4) = lv;
    }
}

// ---------------- fp32 -> fp16 hi/lo split ----------------
__global__ __launch_bounds__(256) void split_f16(const float* __restrict__ in,
    h16* __restrict__ hi, h16* __restrict__ lo, int n8)
{
    int i = blockIdx.x * 256 + threadIdx.x;
    if (i >= n8) return;
    const float4* p = (const float4*)in + 2 * (size_t)i;
    float4 v0 = p[0], v1 = p[1];
    float vv[8] = {v0.x, v0.y, v0.z, v0.w, v1.x, v1.y, v1.z, v1.w};
    hfrag h, l;
#pragma unroll
    for (int j = 0; j < 8; ++j) {
        h16 hj = (h16)vv[j];
        h[j] = hj;
        l[j] = (h16)(vv[j] - (float)hj);
    }
    ((hfrag*)hi)[i] = h;
    ((hfrag*)lo)[i] = l;
}

// ---------------- fp16x2 (3-product) NT MFMA GEMM ----------------
// OMODE: 0 = fp32 out, 1 = fp32 out + res, 2 = f16 hi/lo pair out
template<int OMODE>
__global__ __launch_bounds__(256) void gemm_f16x2_nt(
    const h16* __restrict__ Ahi, const h16* __restrict__ Alo, int lda,
    const h16* __restrict__ Bhi, const h16* __restrict__ Blo, int ldb,
    const float* __restrict__ bias, const float* __restrict__ res,
    float* __restrict__ C, h16* __restrict__ Chi, h16* __restrict__ Clo,
    int K, int ldc)
{
    __shared__ h16 AhL[4096], AlL[4096], BhL[4096], BlL[4096];
    int rowBase = blockIdx.y * 128, colBase = blockIdx.x * 128;
    int t = threadIdx.x, lane = t & 63, wid = t >> 6;
    int wr = (wid >> 1) * 64, wc = (wid & 1) * 64;
    int c1 = t, c2 = t + 256;
    int r1 = c1 >> 2, q1 = (c1 & 3) ^ ((r1 + (r1 >> 2)) & 3);
    int r2 = c2 >> 2, q2 = (c2 & 3) ^ ((r2 + (r2 >> 2)) & 3);
    const h16* Ah = Ahi + (size_t)rowBase * lda;
    const h16* Al = Alo + (size_t)rowBase * lda;
    const h16* Bh = Bhi + (size_t)colBase * ldb;
    const h16* Bl = Blo + (size_t)colBase * ldb;
    f32x4 acc[4][4] = {};
    int l15 = lane & 15, g = lane >> 4;

    for (int k0 = 0; k0 < K; k0 += 32) {
        __syncthreads();
        GLL16(Ah + (size_t)r1 * lda + k0 + q1 * 8, &AhL[c1 * 8]);
        GLL16(Ah + (size_t)r2 * lda + k0 + q2 * 8, &AhL[c2 * 8]);
        GLL16(Al + (size_t)r1 * lda + k0 + q1 * 8, &AlL[c1 * 8]);
        GLL16(Al + (size_t)r2 * lda + k0 + q2 * 8, &AlL[c2 * 8]);
        GLL16(Bh + (size_t)r1 * ldb + k0 + q1 * 8, &BhL[c1 * 8]);
        GLL16(Bh + (size_t)r2 * ldb + k0 + q2 * 8, &BhL[c2 * 8]);
        GLL16(Bl + (size_t)r1 * ldb + k0 + q1 * 8, &BlL[c1 * 8]);
        GLL16(Bl + (size_t)r2 * ldb + k0 + q2 * 8, &BlL[c2 * 8]);
        __syncthreads();

        hfrag bh[4], bl[4];
#pragma unroll
        for (int n = 0; n < 4; ++n) {
            int row = wc + n * 16 + l15;
            int sw = (g ^ ((row + (row >> 2)) & 3)) * 8;
            bh[n] = *(const hfrag*)&BhL[row * 32 + sw];
            bl[n] = *(const hfrag*)&BlL[row * 32 + sw];
        }
#pragma unroll
        for (int m = 0; m < 4; ++m) {
            int row = wr + m * 16 + l15;
            int sw = (g ^ ((row + (row >> 2)) & 3)) * 8;
            hfrag ah = *(const hfrag*)&AhL[row * 32 + sw];
            hfrag al = *(const hfrag*)&AlL[row * 32 + sw];
#pragma unroll
            for (int n = 0; n < 4; ++n) {
                acc[m][n] = __builtin_amdgcn_mfma_f32_16x16x32_f16(ah, bh[n], acc[m][n], 0, 0, 0);
                acc[m][n] = __builtin_amdgcn_mfma_f32_16x16x32_f16(ah, bl[n], acc[m][n], 0, 0, 0);
                acc[m][n] = __builtin_amdgcn_mfma_f32_16x16x32_f16(al, bh[n], acc[m][n], 0, 0, 0);
            }
        }
    }

    int g4 = g * 4;
#pragma unroll
    for (int m = 0; m < 4; ++m) {
        int row0 = rowBase + wr + m * 16 + g4;
#pragma unroll
        for (int n = 0; n < 4; ++n) {
            int col = colBase + wc + n * 16 + l15;
            float bv = bias[col];
#pragma unroll
            for (int j = 0; j < 4; ++j) {
                float v = acc[m][n][j] + bv;
                if (OMODE == 1) v += res[(size_t)(row0 + j) * ldc + col];
                if (OMODE < 2) {
                    C[(size_t)(row0 + j) * ldc + col] = v;
                } else {
                    h16 hh = (h16)v;
                    Chi[(size_t)(row0 + j) * ldc + col] = hh;
                    Clo[(size_t)(row0 + j) * ldc + col] = (h16)(v - (float)hh);
                }
            }
        }
    }
}

// ---------------- attention QK^T (f16x2, K=64, strided heads) ----------------
template<bool CAUSAL>
__global__ __launch_bounds__(256) void attn_qk(
    const h16* __restrict__ Qh, const h16* __restrict__ Ql, int lda,
    const h16* __restrict__ Kh, const h16* __restrict__ Kl, int ldb,
    h16* __restrict__ Sh, h16* __restrict__ Sl, int zoff)
{
    int rowBase = blockIdx.y * 128, colBase = blockIdx.x * 128;
    if (CAUSAL && colBase >= rowBase + 128) return;
    __shared__ h16 AhL[4096], AlL[4096], BhL[4096], BlL[4096];
    int z = blockIdx.z;
    int bh_ = zoff + z, b = bh_ >> 4, h = bh_ & 15;
    const h16* Ah = Qh + (size_t)(b * 512 + rowBase) * lda + h * 64;
    const h16* Al = Ql + (size_t)(b * 512 + rowBase) * lda + h * 64;
    const h16* Bh = Kh + (size_t)(b * 512 + colBase) * ldb + h * 64;
    const h16* Bl = Kl + (size_t)(b * 512 + colBase) * ldb + h * 64;
    int t = threadIdx.x, lane = t & 63, wid = t >> 6;
    int wr = (wid >> 1) * 64, wc = (wid & 1) * 64;
    int c1 = t, c2 = t + 256;
    int r1 = c1 >> 2, q1 = (c1 & 3) ^ ((r1 + (r1 >> 2)) & 3);
    int r2 = c2 >> 2, q2 = (c2 & 3) ^ ((r2 + (r2 >> 2)) & 3);
    f32x4 acc[4][4] = {};
    int l15 = lane & 15, g = lane >> 4;

    for (int k0 = 0; k0 < 64; k0 += 32) {
        __syncthreads();
        GLL16(Ah + (size_t)r1 * lda + k0 + q1 * 8, &AhL[c1 * 8]);
        GLL16(Ah + (size_t)r2 * lda + k0 + q2 * 8, &AhL[c2 * 8]);
        GLL16(Al + (size_t)r1 * lda + k0 + q1 * 8, &AlL[c1 * 8]);
        GLL16(Al + (size_t)r2 * lda + k0 + q2 * 8, &AlL[c2 * 8]);
        GLL16(Bh + (size_t)r1 * ldb + k0 + q1 * 8, &BhL[c1 * 8]);
        GLL16(Bh + (size_t)r2 * ldb + k0 + q2 * 8, &BhL[c2 * 8]);
        GLL16(Bl + (size_t)r1 * ldb + k0 + q1 * 8, &BlL[c1 * 8]);
        GLL16(Bl + (size_t)r2 * ldb + k0 + q2 * 8, &BlL[c2 * 8]);
        __syncthreads();

        hfrag bh[4], bl[4];
#pragma unroll
        for (int n = 0; n < 4; ++n) {
            int row = wc + n * 16 + l15;
            int sw = (g ^ ((row + (row >> 2)) & 3)) * 8;
            bh[n] = *(const hfrag*)&BhL[row * 32 + sw];
            bl[n] = *(const hfrag*)&BlL[row * 32 + sw];
        }
#pragma unroll
        for (int m = 0; m < 4; ++m) {
            int row = wr + m * 16 + l15;
            int sw = (g ^ ((row + (row >> 2)) & 3)) * 8;
            hfrag ah = *(const hfrag*)&AhL[row * 32 + sw];
            hfrag al = *(const hfrag*)&AlL[row * 32 + sw];
#pragma unroll
            for (int n = 0; n < 4; ++n) {
                acc[m][n] = __builtin_amdgcn_mfma_f32_16x16x32_f16(ah, bh[n], acc[m][n], 0, 0, 0);
                acc[m][n] = __builtin_amdgcn_mfma_f32_16x16x32_f16(ah, bl[n], acc[m][n], 0, 0, 0);
                acc[m][n] = __builtin_amdgcn_mfma_f32_16x16x32_f16(al, bh[n], acc[m][n], 0, 0, 0);
            }
        }
    }

    size_t sbase = (size_t)z * 262144;
    int g4 = g * 4;
#pragma unroll
    for (int m = 0; m < 4; ++m) {
        int row0 = rowBase + wr + m * 16 + g4;
#pragma unroll
        for (int n = 0; n < 4; ++n) {
            int col = colBase + wc + n * 16 + l15;
#pragma unroll
            for (int j = 0; j < 4; ++j) {
                float v = acc[m][n][j] * 0.125f;
                h16 hh = (h16)v;
                Sh[sbase + (size_t)(row0 + j) * 512 + col] = hh;
                Sl[sbase + (size_t)(row0 + j) * 512 + col] = (h16)(v - (float)hh);
            }
        }
    }
}

// ---------------- softmax over hi/lo rows, in place (4 rows/block) ----------------
__global__ __launch_bounds__(256) void softmax_hl(h16* __restrict__ Sh, h16* __restrict__ Sl, int causal)
{
    int z = blockIdx.y;
    int wid = threadIdx.x >> 6, lane = threadIdx.x & 63;
    int t = blockIdx.x * 4 + wid;
    size_t base = ((size_t)z * 512 + t) * 512;
    int limit = causal ? (t + 1) : 512;
    float v[8];
    float mx = -1e30f;
#pragma unroll
    for (int k = 0; k < 8; ++k) {
        int idx = lane + (k << 6);
        float s = (float)Sh[base + idx] + (float)Sl[base + idx];
        float val = (idx < limit) ? s : -1e30f;
        v[k] = val; mx = fmaxf(mx, val);
    }
#pragma unroll
    for (int o = 1; o < 64; o <<= 1) mx = fmaxf(mx, __shfl_xor(mx, o, 64));
    float sum = 0.f;
#pragma unroll
    for (int k = 0; k < 8; ++k) {
        int idx = lane + (k << 6);
        float p = (idx < limit) ? __expf(v[k] - mx) : 0.f;
        v[k] = p; sum += p;
    }
#pragma unroll
    for (int o = 1; o < 64; o <<= 1) sum += __shfl_xor(sum, o, 64);
    float inv = 1.0f / sum;
#pragma unroll
    for (int k = 0; k < 8; ++k) {
        int idx = lane + (k << 6);
        float p = v[k] * inv;
        h16 hh = (h16)p;
        Sh[base + idx] = hh;
        Sl[base + idx] = (h16)(p - (float)hh);
    }
}

// ---------------- PV: C[t,d] = P[t,s] * vT[d,s]^T  (64x64 tile, K=512) ----------------
__global__ __launch_bounds__(256) void attn_pv(
    const h16* __restrict__ Ph, const h16* __restrict__ Pl,
    const h16* __restrict__ Vh, const h16* __restrict__ Vl,
    h16* __restrict__ Ch, h16* __restrict__ Cl, int bh0)
{
    __shared__ h16 PhL[2048], PlL[2048], VhL[2048], VlL[2048];
    int z = blockIdx.z, bh_ = bh0 + z;
    int rowBase = blockIdx.x * 64;
    const h16* Pa = Ph + (size_t)z * 262144 + (size_t)rowBase * 512;
    const h16* Pb = Pl + (size_t)z * 262144 + (size_t)rowBase * 512;
    const h16* Va = Vh + (size_t)z * 32768;
    const h16* Vb = Vl + (size_t)z * 32768;
    int t = threadIdx.x, lane = t & 63, wid = t >> 6;
    int r = t >> 2, q = (t & 3) ^ ((r + (r >> 2)) & 3);
    f32x4 acc[4] = {};
    int l15 = lane & 15, g = lane >> 4;

    for (int k0 = 0; k0 < 512; k0 += 32) {
        __syncthreads();
        GLL16(Pa + (size_t)r * 512 + k0 + q * 8, &PhL[t * 8]);
        GLL16(Pb + (size_t)r * 512 + k0 + q * 8, &PlL[t * 8]);
        GLL16(Va + (size_t)r * 512 + k0 + q * 8, &VhL[t * 8]);
        GLL16(Vb + (size_t)r * 512 + k0 + q * 8, &VlL[t * 8]);
        __syncthreads();

        int arow = wid * 16 + l15;
        int asw = (g ^ ((arow + (arow >> 2)) & 3)) * 8;
        hfrag ah = *(const hfrag*)&PhL[arow * 32 + asw];
        hfrag al = *(const hfrag*)&PlL[arow * 32 + asw];
#pragma unroll
        for (int n = 0; n < 4; ++n) {
            int brow = n * 16 + l15;
            int bsw = (g ^ ((brow + (brow >> 2)) & 3)) * 8;
            hfrag bh = *(const hfrag*)&VhL[brow * 32 + bsw];
            hfrag bl = *(const hfrag*)&VlL[brow * 32 + bsw];
            acc[n] = __builtin_amdgcn_mfma_f32_16x16x32_f16(ah, bh, acc[n], 0, 0, 0);
            acc[n] = __builtin_amdgcn_mfma_f32_16x16x32_f16(ah, bl, acc[n], 0, 0, 0);
            acc[n] = __builtin_amdgcn_mfma_f32_16x16x32_f16(al, bh, acc[n], 0, 0, 0);
        }
    }

    int brow = (bh_ >> 4) * 512 + rowBase + wid * 16 + g * 4;
    int bcol = (bh_ & 15) * 64;
#pragma unroll
    for (int n = 0; n < 4; ++n) {
        int col = bcol + n * 16 + l15;
#pragma unroll
        for (int j = 0; j < 4; ++j) {
            float v = acc[n][j];
            h16 hh = (h16)v;
            Ch[(size_t)(brow + j) * 1024 + col] = hh;
            Cl[(size_t)(brow + j) * 1024 + col] = (h16)(v - (float)hh);
        }
    }
}

// ---------------- V-transpose ----------------
__global__ __launch_bounds__(256) void vt_split(
    const h16* __restrict__ inh, const h16* __restrict__ inl, int ld,
    h16* __restrict__ oh, h16* __restrict__ ol)
{
    __shared__ h16 tile[64][68];
    int z = blockIdx.z, b = z >> 4, h = z & 15;
    size_t ibase = ((size_t)b * 512 + blockIdx.x * 64) * ld + h * 64;
    size_t obase = (size_t)z * 32768 + blockIdx.x * 64;
    int tr = threadIdx.x >> 4, tc = (threadIdx.x & 15) * 4;
    const h16* src[2] = {inh, inl};
    h16* dst[2] = {oh, ol};
#pragma unroll
    for (int s = 0; s < 2; ++s) {
        __syncthreads();
#pragma unroll
        for (int i = 0; i < 4; ++i) {
            int tt = tr + i * 16;
            short4 v = *(const short4*)(src[s] + ibase + (size_t)tt * ld + tc);
            tile[tt][tc + 0] = ((h16*)&v)[0];
            tile[tt][tc + 1] = ((h16*)&v)[1];
            tile[tt][tc + 2] = ((h16*)&v)[2];
            tile[tt][tc + 3] = ((h16*)&v)[3];
        }
        __syncthreads();
#pragma unroll
        for (int i = 0; i < 4; ++i) {
            int d = tr + i * 16;
            h16 w[4] = {tile[tc + 0][d], tile[tc + 1][d], tile[tc + 2][d], tile[tc + 3][d]};
            *(short4*)(dst[s] + obase + (size_t)d * 512 + tc) = *(short4*)w;
        }
    }
}

// ---------------- bf16 NT MFMA GEMM (MoE), flat grid, expert->XCD pinned ----------------
// id -> e = id & emask (XCD pinning via id%8 round-robin), t = id >> elog;
// ROWFAST: rows consecutive within a column (w1: B col-slice + tiny A stay in XCD L2)
template<int TN, bool RELU, bool ROWFAST>
__global__ __launch_bounds__(256) void gemm_bf16_moe(
    const unsigned short* __restrict__ A,   // [M][K] bf16, per expert
    const unsigned short* __restrict__ Bt,  // [N][K] bf16, per expert
    const float* __restrict__ bias,         // [N] fp32, per expert
    unsigned short* __restrict__ C,         // bf16 out
    int K, long long sA, long long sB, long long sC, long long sBias, int ldc,
    int emask, int elog, int nrow, int ncol)
{
    constexpr int NFR = TN / 32;
    __shared__ unsigned short Al[128 * 32];
    __shared__ unsigned short Bl[TN * 32];
    int id = blockIdx.x;
    int e = id & emask;
    int tb = id >> elog;
    int row, col;
    if (ROWFAST) { row = tb % nrow; col = tb / nrow; }
    else         { col = tb % ncol; row = tb / ncol; }

    A    += (size_t)e * sA;
    Bt   += (size_t)e * sB;
    bias += (size_t)e * sBias;
    long long zC = (long long)e * sC;

    int rowBase = row * 128, colBase = col * TN;
    int t = threadIdx.x, lane = t & 63, wid = t >> 6;
    int wr = (wid >> 1) * 64, wc = (wid & 1) * (TN / 2);

    int c1 = t, c2 = t + 256;
    int r1 = c1 >> 2, q1 = (c1 & 3) ^ ((r1 + (r1 >> 2)) & 3);
    int r2 = c2 >> 2, q2 = (c2 & 3) ^ ((r2 + (r2 >> 2)) & 3);

    const unsigned short* Ag = A  + (size_t)rowBase * K;
    const unsigned short* Bg = Bt + (size_t)colBase * K;

    f32x4 acc[4][NFR] = {};
    int l15 = lane & 15, g = lane >> 4;

    for (int k0 = 0; k0 < K; k0 += 32) {
        __syncthreads();
        GLL16(Ag + (size_t)r1 * K + k0 + q1 * 8, &Al[c1 * 8]);
        GLL16(Ag + (size_t)r2 * K + k0 + q2 * 8, &Al[c2 * 8]);
        GLL16(Bg + (size_t)r1 * K + k0 + q1 * 8, &Bl[c1 * 8]);
        if (TN == 128)
            GLL16(Bg + (size_t)r2 * K + k0 + q2 * 8, &Bl[c2 * 8]);
        __syncthreads();

        bfrag a[4], b[NFR];
#pragma unroll
        for (int m = 0; m < 4; ++m) {
            int rr = wr + m * 16 + l15;
            int sw = (g ^ ((rr + (rr >> 2)) & 3)) * 8;
            a[m] = *(const bfrag*)&Al[rr * 32 + sw];
        }
#pragma unroll
        for (int n = 0; n < NFR; ++n) {
            int rr = wc + n * 16 + l15;
            int sw = (g ^ ((rr + (rr >> 2)) & 3)) * 8;
            b[n] = *(const bfrag*)&Bl[rr * 32 + sw];
        }
#pragma unroll
        for (int m = 0; m < 4; ++m)
#pragma unroll
            for (int n = 0; n < NFR; ++n)
                acc[m][n] = __builtin_amdgcn_mfma_f32_16x16x32_bf16(a[m], b[n], acc[m][n], 0, 0, 0);
    }

    int g4 = g * 4;
#pragma unroll
    for (int m = 0; m < 4; ++m) {
        int row0 = rowBase + wr + m * 16 + g4;
#pragma unroll
        for (int n = 0; n < NFR; ++n) {
            int cc = colBase + wc + n * 16 + l15;
            float bv = bias[cc];
#pragma unroll
            for (int j = 0; j < 4; ++j) {
                float v = acc[m][n][j] + bv;
                if (RELU) v = fmaxf(v, 0.f);
                C[zC + (size_t)(row0 + j) * ldc + cc] = f2bf(v);
            }
        }
    }
}

// ---------------- transpose+convert fp32 [R][Cn] -> bf16 [Cn][R] (per z) ----------------
__global__ __launch_bounds__(256) void tcvt_kernel(const float* __restrict__ in,
    unsigned short* __restrict__ out, int R, int Cn)
{
    __shared__ unsigned short tile[64][68];
    size_t zoff = (size_t)blockIdx.z * R * Cn;
    in += zoff; out += zoff;
    int r0 = blockIdx.y * 64, c0 = blockIdx.x * 64;
    int tr = threadIdx.x >> 4, tc = (threadIdx.x & 15) * 4;
#pragma unroll
    for (int i = 0; i < 4; ++i) {
        int r = tr + i * 16;
        float4 v = *(const float4*)&in[(size_t)(r0 + r) * Cn + c0 + tc];
        tile[r][tc + 0] = f2bf(v.x);
        tile[r][tc + 1] = f2bf(v.y);
        tile[r][tc + 2] = f2bf(v.z);
        tile[r][tc + 3] = f2bf(v.w);
    }
    __syncthreads();
#pragma unroll
    for (int i = 0; i < 4; ++i) {
        int c = tr + i * 16;
        ushort4 w;
        w.x = tile[tc + 0][c];
        w.y = tile[tc + 1][c];
        w.z = tile[tc + 2][c];
        w.w = tile[tc + 3][c];
        *(ushort4*)&out[(size_t)(c0 + c) * R + r0 + tc] = w;
    }
}

// ---------------- router ----------------
__global__ __launch_bounds__(256) void router_kernel(
    const float* __restrict__ xf, const float* __restrict__ rw, const float* __restrict__ rb,
    const float* __restrict__ tmask,
    int* __restrict__ eidx, float* __restrict__ gate, int* __restrict__ valid,
    float* __restrict__ partials)
{
    int blk = blockIdx.x;
    int wid = threadIdx.x >> 6, lane = threadIdx.x & 63;
    __shared__ float wpart[4][10];
    float pe[8] = {0,0,0,0,0,0,0,0};
    float zacc = 0.f, nvacc = 0.f;

    for (int i = 0; i < 16; ++i) {
        int tok = blk * 64 + wid * 16 + i;
        const float* xrow = xf + (size_t)tok * DMODEL;
        float acc[8] = {0,0,0,0,0,0,0,0};
#pragma unroll 4
        for (int kk = 0; kk < 16; ++kk) {
            int d = lane + (kk << 6);
            float xd = xrow[d];
            const float4* rp = (const float4*)(rw + (size_t)d * 8);
            float4 r0 = rp[0], r1 = rp[1];
            acc[0] = fmaf(xd, r0.x, acc[0]); acc[1] = fmaf(xd, r0.y, acc[1]);
            acc[2] = fmaf(xd, r0.z, acc[2]); acc[3] = fmaf(xd, r0.w, acc[3]);
            acc[4] = fmaf(xd, r1.x, acc[4]); acc[5] = fmaf(xd, r1.y, acc[5]);
            acc[6] = fmaf(xd, r1.z, acc[6]); acc[7] = fmaf(xd, r1.w, acc[7]);
        }
#pragma unroll
        for (int e = 0; e < 8; ++e)
#pragma unroll
            for (int o = 1; o < 64; o <<= 1) acc[e] += __shfl_xor(acc[e], o, 64);
        if (lane == 0) {
            float l[8]; float m = -1e30f;
#pragma unroll
            for (int e = 0; e < 8; ++e) { l[e] = acc[e] + rb[e]; m = fmaxf(m, l[e]); }
            float se = 0.f;
#pragma unroll
            for (int e = 0; e < 8; ++e) se += expf(l[e] - m);
            int am = 0; float bm = l[0];
#pragma unroll
            for (int e = 1; e < 8; ++e) if (l[e] > bm) { bm = l[e]; am = e; }
            float inv_se = 1.0f / se;
            float g = expf(l[am] - m) * inv_se;
            float vld = (tmask[tok] > 0.f) ? 1.f : 0.f;
            eidx[tok] = am; gate[tok] = g; valid[tok] = (int)vld;
#pragma unroll
            for (int e = 0; e < 8; ++e) pe[e] += expf(l[e] - m) * inv_se * vld;
            float lse = logf(se) + m;
            zacc += lse * lse * vld;
            nvacc += vld;
        }
    }
    if (lane == 0) {
#pragma unroll
        for (int e = 0; e < 8; ++e) wpart[wid][e] = pe[e];
        wpart[wid][8] = zacc; wpart[wid][9] = nvacc;
    }
    __syncthreads();
    if (threadIdx.x == 0) {
        for (int j = 0; j < 10; ++j)
            partials[blk * 10 + j] = wpart[0][j] + wpart[1][j] + wpart[2][j] + wpart[3][j];
    }
}

// ---------------- capacity scan ----------------
__global__ __launch_bounds__(256) void scan_kernel(
    const int* __restrict__ eidx, const int* __restrict__ valid, const float* __restrict__ gate,
    int* __restrict__ pc, float* __restrict__ gk, int* __restrict__ keepf,
    int* __restrict__ counts)
{
    __shared__ int cnt[256][8];
    int tid = threadIdx.x;
    int local[8] = {0,0,0,0,0,0,0,0};
    int base = tid * 16;
    for (int i = 0; i < 16; ++i) { int e = eidx[base + i]; local[e] += valid[base + i]; }
#pragma unroll
    for (int e = 0; e < 8; ++e) cnt[tid][e] = local[e];
    __syncthreads();
    if (tid < 8) {
        int run = 0;
        for (int i = 0; i < 256; ++i) { int t = cnt[i][tid]; cnt[i][tid] = run; run += t; }
        counts[tid] = run;
    }
    __syncthreads();
    int off[8];
#pragma unroll
    for (int e = 0; e < 8; ++e) off[e] = cnt[tid][e];
    for (int i = 0; i < 16; ++i) {
        int tok = base + i;
        int e = eidx[tok], v = valid[tok];
        int pos = off[e]; off[e] += v;
        int kp = (v && pos < CAPE) ? 1 : 0;
        pc[tok]    = (pos < CAPE) ? pos : (CAPE - 1);
        keepf[tok] = kp;
        gk[tok]    = kp ? gate[tok] : 0.f;
    }
}

// ---------------- dispatch (expert-range) -> bf16 buffers ----------------
__global__ __launch_bounds__(256) void dispatch_bf16(const float* __restrict__ tln,
    const int* __restrict__ eidx, const int* __restrict__ pc, const int* __restrict__ keepf,
    unsigned short* __restrict__ buf, int e0, int ec)
{
    int tok = blockIdx.x;
    if (!keepf[tok]) return;
    int e = eidx[tok];
    if (e < e0 || e >= e0 + ec) return;
    int p = pc[tok];
    const float4 v = ((const float4*)(tln + (size_t)tok * DMODEL))[threadIdx.x];
    ushort4 o;
    o.x = f2bf(v.x); o.y = f2bf(v.y); o.z = f2bf(v.z); o.w = f2bf(v.w);
    ((ushort4*)(buf + ((size_t)(e - e0) * CAPE + p) * DMODEL))[threadIdx.x] = o;
}

// ---------------- combine add: out += gk * ob (bf16 ob) ----------------
__global__ __launch_bounds__(256) void combine_bf16(const unsigned short* __restrict__ ob,
    const int* __restrict__ eidx, const int* __restrict__ pc, const float* __restrict__ gk,
    float* __restrict__ out, int e0, int ec)
{
    int tok = blockIdx.x;
    int e = eidx[tok];
    if (e < e0 || e >= e0 + ec) return;
    float g = gk[tok];
    int p = pc[tok];
    float4* o = (float4*)(out + (size_t)tok * DMODEL);
    const ushort4 u = ((const ushort4*)(ob + ((size_t)(e - e0) * CAPE + p) * DMODEL))[threadIdx.x];
    float4 a = o[threadIdx.x];
    a.x += g * bf2f(u.x); a.y += g * bf2f(u.y);
    a.z += g * bf2f(u.z); a.w += g * bf2f(u.w);
    o[threadIdx.x] = a;
}

// ---------------- final scalar losses ----------------
__global__ __launch_bounds__(64) void loss_kernel(const float* __restrict__ partials,
    const int* __restrict__ counts, float* __restrict__ out2)
{
    int lane = threadIdx.x;
    float p[10];
#pragma unroll
    for (int j = 0; j < 10; ++j) p[j] = partials[lane * 10 + j];
#pragma unroll
    for (int j = 0; j < 10; ++j)
#pragma unroll
        for (int o = 1; o < 64; o <<= 1) p[j] += __shfl_xor(p[j], o, 64);
    if (lane == 0) {
        float nv = fmaxf(p[9], 1.f);
        float lb = 0.f;
        for (int e = 0; e < 8; ++e) lb += ((float)counts[e] / nv) * (p[e] / nv);
        lb *= (float)NEXP;
        out2[0] = lb;
        out2[1] = p[8] / nv;
    }
}

// ---------------- host launch ----------------
extern "C" void kernel_launch(void* const* d_in, const int* in_sizes, int n_in,
                              void* d_out, int out_size, void* d_ws, size_t ws_size,
                              hipStream_t stream)
{
    const float* tgt        = (const float*)d_in[0];
    const float* src        = (const float*)d_in[1];
    const float* token_mask = (const float*)d_in[5];
    const float* ln1w = (const float*)d_in[6],  *ln1b = (const float*)d_in[7];
    const float* self_in_w  = (const float*)d_in[8],  *self_in_b  = (const float*)d_in[9];
    const float* self_out_w = (const float*)d_in[10], *self_out_b = (const float*)d_in[11];
    const float* ln2w = (const float*)d_in[12], *ln2b = (const float*)d_in[13];
    const float* enc_in_w   = (const float*)d_in[14], *enc_in_b   = (const float*)d_in[15];
    const float* enc_out_w  = (const float*)d_in[16], *enc_out_b  = (const float*)d_in[17];
    const float* ln3w = (const float*)d_in[18], *ln3b = (const float*)d_in[19];
    const float* rw = (const float*)d_in[20], *rb = (const float*)d_in[21];
    const float* w1 = (const float*)d_in[22], *b1 = (const float*)d_in[23];
    const float* w2 = (const float*)d_in[24], *b2 = (const float*)d_in[25];

    float* out = (float*)d_out;          // residual stream lives HERE
    float* ws  = (float*)d_ws;

    // ---- fixed layout (floats) ----
    float* tln = ws;                         // 4,194,304 (fp32 for ln3; f16 hi/lo for ln1/ln2)
    float* ctx = ws + 4194304;               // 4,194,304 (ctx hi/lo f16)
    int*   eidxA   = (int*)(ws + 8388608);
    int*   validA  = eidxA + 4096;
    int*   pcA     = validA + 4096;
    int*   keepA   = pcA + 4096;
    int*   countsA = keepA + 4096;           // 16
    float* gateA   = (float*)(countsA + 16);
    float* gkA     = gateA + 4096;
    float* partA   = gkA + 4096;             // 640
    const size_t POOL_OFF = 8425984;         // floats
    float* pool = ws + POOL_OFF;

    size_t Wf = ws_size / sizeof(float);
    size_t pf = (Wf > POOL_OFF) ? (Wf - POOL_OFF) : 0;

    // ---- tiers: bg = batches per attention group, zc = score z-chunk ----
    int bg, zc;
    if      (pf >= 25165824) { bg = 8; zc = 32; }
    else if (pf >= 24117248) { bg = 8; zc = 16; }
    else if (pf >= 13631488) { bg = 4; zc = 16; }
    else                     { bg = 2; zc = 16; }
    // MoE: experts per chunk (power of 2); per expert needs 3,735,552 pool floats
    int ecs = 1;
    for (int c = 8; c >= 1; c >>= 1)
        if ((size_t)c * 3735552ull <= pf) { ecs = c; break; }
    int elog = (ecs == 8) ? 3 : (ecs == 4) ? 2 : (ecs == 2) ? 1 : 0;

    float* qreg = pool;
    float* vreg = qreg + (size_t)bg * 1572864;
    float* sreg = vreg + (size_t)bg * 524288;

    h16* tlnh = (h16*)tln;
    h16* tlnl = tlnh + 4194304;
    h16* ctxh = (h16*)ctx;
    h16* ctxl = ctxh + 4194304;

    // ================= self attention =================
    ln_kernel<1><<<NTOK, 256, 0, stream>>>(tgt, ln1w, ln1b, nullptr, tlnh, tlnl);

    for (int g0 = 0; g0 < BATCH; g0 += bg) {
        h16* sb  = (h16*)sreg;
        h16* whi = sb, *wlo = sb + 3145728;
        split_f16<<<1536, 256, 0, stream>>>(self_in_w, whi, wlo, 393216);

        h16* qkvh = (h16*)qreg, *qkvl = qkvh + (size_t)bg * 1572864;
        gemm_f16x2_nt<2><<<dim3(24, bg * 4, 1), 256, 0, stream>>>(
            tlnh + (size_t)g0 * 524288, tlnl + (size_t)g0 * 524288, 1024,
            whi, wlo, 1024, self_in_b, nullptr,
            nullptr, qkvh, qkvl, 1024, 3072);

        h16* vth = (h16*)vreg, *vtl = vth + (size_t)bg * 524288;
        vt_split<<<dim3(8, 1, bg * 16), 256, 0, stream>>>(qkvh + 2048, qkvl + 2048, 3072, vth, vtl);

        h16* sh = sb, *sl = sh + (size_t)zc * 262144;
        for (int c0 = 0; c0 < bg * 16; c0 += zc) {
            attn_qk<true><<<dim3(4, 4, zc), 256, 0, stream>>>(
                qkvh, qkvl, 3072, qkvh + 1024, qkvl + 1024, 3072, sh, sl, c0);
            softmax_hl<<<dim3(128, zc), 256, 0, stream>>>(sh, sl, 1);
            attn_pv<<<dim3(8, 1, zc), 256, 0, stream>>>(
                sh, sl, vth + (size_t)c0 * 32768, vtl + (size_t)c0 * 32768,
                ctxh, ctxl, g0 * 16 + c0);
        }
    }
    {
        h16* sb = (h16*)sreg;
        h16* owhi = sb, *owlo = sb + 1048576;
        split_f16<<<512, 256, 0, stream>>>(self_out_w, owhi, owlo, 131072);
        gemm_f16x2_nt<1><<<dim3(8, 32, 1), 256, 0, stream>>>(
            ctxh, ctxl, 1024, owhi, owlo, 1024, self_out_b, tgt,
            out, nullptr, nullptr, 1024, 1024);
    }

    // ================= cross attention =================
    ln_kernel<1><<<NTOK, 256, 0, stream>>>(out, ln2w, ln2b, nullptr, tlnh, tlnl);

    for (int g0 = 0; g0 < BATCH; g0 += bg) {
        h16* sb  = (h16*)sreg;
        h16* shi = sb, *slo = sb + (size_t)bg * 524288;
        h16* ehi = sb + (size_t)bg * 1048576, *elo = ehi + 3145728;
        split_f16<<<bg * 256, 256, 0, stream>>>(src + (size_t)g0 * 524288, shi, slo, bg * 65536);
        split_f16<<<1536, 256, 0, stream>>>(enc_in_w, ehi, elo, 393216);

        h16* q2h  = (h16*)qreg,                 *q2l  = q2h + (size_t)bg * 524288;
        h16* kv2h = q2h + (size_t)bg * 1048576, *kv2l = kv2h + (size_t)bg * 1048576;
        gemm_f16x2_nt<2><<<dim3(8, bg * 4, 1), 256, 0, stream>>>(
            tlnh + (size_t)g0 * 524288, tlnl + (size_t)g0 * 524288, 1024,
            ehi, elo, 1024, enc_in_b, nullptr,
            nullptr, q2h, q2l, 1024, 1024);
        gemm_f16x2_nt<2><<<dim3(16, bg * 4, 1), 256, 0, stream>>>(
            shi, slo, 1024, ehi + 1048576, elo + 1048576, 1024, enc_in_b + 1024, nullptr,
            nullptr, kv2h, kv2l, 1024, 2048);

        h16* vth = (h16*)vreg, *vtl = vth + (size_t)bg * 524288;
        vt_split<<<dim3(8, 1, bg * 16), 256, 0, stream>>>(kv2h + 1024, kv2l + 1024, 2048, vth, vtl);

        h16* sh = sb, *sl = sh + (size_t)zc * 262144;
        for (int c0 = 0; c0 < bg * 16; c0 += zc) {
            attn_qk<false><<<dim3(4, 4, zc), 256, 0, stream>>>(
                q2h, q2l, 1024, kv2h, kv2l, 2048, sh, sl, c0);
            softmax_hl<<<dim3(128, zc), 256, 0, stream>>>(sh, sl, 0);
            attn_pv<<<dim3(8, 1, zc), 256, 0, stream>>>(
                sh, sl, vth + (size_t)c0 * 32768, vtl + (size_t)c0 * 32768,
                ctxh, ctxl, g0 * 16 + c0);
        }
    }
    {
        h16* sb = (h16*)sreg;
        h16* owhi = sb, *owlo = sb + 1048576;
        split_f16<<<512, 256, 0, stream>>>(enc_out_w, owhi, owlo, 131072);
        gemm_f16x2_nt<1><<<dim3(8, 32, 1), 256, 0, stream>>>(
            ctxh, ctxl, 1024, owhi, owlo, 1024, enc_out_b, out,
            out, nullptr, nullptr, 1024, 1024);
    }

    // ================= MoE =================
    ln_kernel<0><<<NTOK, 256, 0, stream>>>(out, ln3w, ln3b, tln, nullptr, nullptr);
    router_kernel<<<64, 256, 0, stream>>>(tln, rw, rb, token_mask, eidxA, gateA, validA, partA);
    scan_kernel<<<1, 256, 0, stream>>>(eidxA, validA, gateA, pcA, gkA, keepA, countsA);

    // per-chunk pool layout (floats):
    //   wt   : ecs*2,097,152  (bf16 w1t then w2t, reused)
    //   hB   : ecs*1,310,720  (bf16 [640][4096])
    //   bufB : ecs*327,680    (bf16 [640][1024]); obB overlays bufB
    for (int e0 = 0; e0 < NEXP; e0 += ecs) {
        unsigned short* wt   = (unsigned short*)pool;
        unsigned short* hB   = (unsigned short*)(pool + (size_t)ecs * 2097152);
        unsigned short* bufB = (unsigned short*)(pool + (size_t)ecs * 3407872);
        unsigned short* obB  = bufB;   // overlay: bufB dead after w1 GEMM

        // w1 phase (no memset: garbage rows are row-local and never combined)
        tcvt_kernel<<<dim3(64, 16, ecs), 256, 0, stream>>>(
            w1 + (size_t)e0 * 4194304, wt, 1024, 4096);
        dispatch_bf16<<<NTOK, 256, 0, stream>>>(tln, eidxA, pcA, keepA, bufB, e0, ecs);
        gemm_bf16_moe<128, true, true><<<ecs * 5 * 32, 256, 0, stream>>>(
            bufB, wt, b1 + (size_t)e0 * 4096, hB,
            1024, 655360LL, 4194304LL, 2621440LL, 4096LL, 4096,
            ecs - 1, elog, 5, 32);

        // w2 phase (wt reused)
        tcvt_kernel<<<dim3(16, 64, ecs), 256, 0, stream>>>(
            w2 + (size_t)e0 * 4194304, wt, 4096, 1024);
        gemm_bf16_moe<64, false, false><<<ecs * 5 * 16, 256, 0, stream>>>(
            hB, wt, b2 + (size_t)e0 * 1024, obB,
            4096, 2621440LL, 4194304LL, 655360LL, 1024LL, 1024,
            ecs - 1, elog, 5, 16);

        combine_bf16<<<NTOK, 256, 0, stream>>>(obB, eidxA, pcA, gkA, out, e0, ecs);
    }

    // ===== losses =====
    loss_kernel<<<1, 64, 0, stream>>>(partA, countsA, out + (size_t)NTOK * DMODEL);
}

// Round 9
// 1024.077 us; speedup vs baseline: 2.6434x; 1.0329x over previous
//
#include <hip/hip_runtime.h>
#include <cstdint>

// ---------------- problem constants ----------------
constexpr int BATCH  = 8;
constexpr int TSEQ   = 512;
constexpr int DMODEL = 1024;
constexpr int NEXP   = 8;
constexpr int CAPE   = 640;
constexpr int NTOK   = BATCH * TSEQ;        // 4096

typedef _Float16 h16;
typedef __attribute__((ext_vector_type(8))) short bfrag;
typedef __attribute__((ext_vector_type(8))) _Float16 hfrag;
typedef __attribute__((ext_vector_type(4))) float f32x4;

__device__ __forceinline__ unsigned short f2bf(float f) {
    uint32_t u = __float_as_uint(f);
    uint32_t r = (u + 0x7FFFu + ((u >> 16) & 1u)) >> 16;   // RNE
    return (unsigned short)r;
}
__device__ __forceinline__ float bf2f(unsigned short b) {
    return __uint_as_float((uint32_t)b << 16);
}

#define GLL16(SRC, DST) __builtin_amdgcn_global_load_lds( \
    (const __attribute__((address_space(1))) void*)(SRC), \
    (__attribute__((address_space(3))) void*)(DST), 16, 0, 0)

// ---------------- LayerNorm: MODE 0 -> fp32 out; MODE 1 -> f16 hi/lo out ----------------
template<int MODE>
__global__ __launch_bounds__(256) void ln_kernel(const float* __restrict__ in,
    const float* __restrict__ gw, const float* __restrict__ gb,
    float* __restrict__ out, h16* __restrict__ ohi, h16* __restrict__ olo)
{
    int row = blockIdx.x, tid = threadIdx.x;
    const float4 v = *(const float4*)(in + (size_t)row * DMODEL + tid * 4);
    float s  = v.x + v.y + v.z + v.w;
    float ss = v.x*v.x + v.y*v.y + v.z*v.z + v.w*v.w;
#pragma unroll
    for (int o = 1; o < 64; o <<= 1) { s += __shfl_xor(s, o, 64); ss += __shfl_xor(ss, o, 64); }
    __shared__ float rs[4], rss[4];
    int wid = tid >> 6, lane = tid & 63;
    if (lane == 0) { rs[wid] = s; rss[wid] = ss; }
    __syncthreads();
    s  = rs[0] + rs[1] + rs[2] + rs[3];
    ss = rss[0] + rss[1] + rss[2] + rss[3];
    float mean = s * (1.0f / DMODEL);
    float var  = ss * (1.0f / DMODEL) - mean * mean;
    float inv  = rsqrtf(var + 1e-5f);
    float4 w4 = *(const float4*)(gw + tid * 4);
    float4 b4 = *(const float4*)(gb + tid * 4);
    float o[4];
    o[0] = (v.x - mean) * inv * w4.x + b4.x;
    o[1] = (v.y - mean) * inv * w4.y + b4.y;
    o[2] = (v.z - mean) * inv * w4.z + b4.z;
    o[3] = (v.w - mean) * inv * w4.w + b4.w;
    if (MODE == 0) {
        float4 f = {o[0], o[1], o[2], o[3]};
        *(float4*)(out + (size_t)row * DMODEL + tid * 4) = f;
    } else {
        short4 hv, lv;
#pragma unroll
        for (int j = 0; j < 4; ++j) {
            h16 hh = (h16)o[j];
            ((h16*)&hv)[j] = hh;
            ((h16*)&lv)[j] = (h16)(o[j] - (float)hh);
        }
        *(short4*)(ohi + (size_t)row * DMODEL + tid * 4) = hv;
        *(short4*)(olo + (size_t)row * DMODEL + tid * 4) = lv;
    }
}

// ---------------- fp32 -> fp16 hi/lo split ----------------
__global__ __launch_bounds__(256) void split_f16(const float* __restrict__ in,
    h16* __restrict__ hi, h16* __restrict__ lo, int n8)
{
    int i = blockIdx.x * 256 + threadIdx.x;
    if (i >= n8) return;
    const float4* p = (const float4*)in + 2 * (size_t)i;
    float4 v0 = p[0], v1 = p[1];
    float vv[8] = {v0.x, v0.y, v0.z, v0.w, v1.x, v1.y, v1.z, v1.w};
    hfrag h, l;
#pragma unroll
    for (int j = 0; j < 8; ++j) {
        h16 hj = (h16)vv[j];
        h[j] = hj;
        l[j] = (h16)(vv[j] - (float)hj);
    }
    ((hfrag*)hi)[i] = h;
    ((hfrag*)lo)[i] = l;
}

// ---------------- fp16x2 (3-product) NT MFMA GEMM ----------------
// OMODE: 0 = fp32 out, 1 = fp32 out + res, 2 = f16 hi/lo pair out
template<int OMODE>
__global__ __launch_bounds__(256) void gemm_f16x2_nt(
    const h16* __restrict__ Ahi, const h16* __restrict__ Alo, int lda,
    const h16* __restrict__ Bhi, const h16* __restrict__ Blo, int ldb,
    const float* __restrict__ bias, const float* __restrict__ res,
    float* __restrict__ C, h16* __restrict__ Chi, h16* __restrict__ Clo,
    int K, int ldc)
{
    __shared__ h16 AhL[4096], AlL[4096], BhL[4096], BlL[4096];
    int rowBase = blockIdx.y * 128, colBase = blockIdx.x * 128;
    int t = threadIdx.x, lane = t & 63, wid = t >> 6;
    int wr = (wid >> 1) * 64, wc = (wid & 1) * 64;
    int c1 = t, c2 = t + 256;
    int r1 = c1 >> 2, q1 = (c1 & 3) ^ ((r1 + (r1 >> 2)) & 3);
    int r2 = c2 >> 2, q2 = (c2 & 3) ^ ((r2 + (r2 >> 2)) & 3);
    const h16* Ah = Ahi + (size_t)rowBase * lda;
    const h16* Al = Alo + (size_t)rowBase * lda;
    const h16* Bh = Bhi + (size_t)colBase * ldb;
    const h16* Bl = Blo + (size_t)colBase * ldb;
    f32x4 acc[4][4] = {};
    int l15 = lane & 15, g = lane >> 4;

    for (int k0 = 0; k0 < K; k0 += 32) {
        __syncthreads();
        GLL16(Ah + (size_t)r1 * lda + k0 + q1 * 8, &AhL[c1 * 8]);
        GLL16(Ah + (size_t)r2 * lda + k0 + q2 * 8, &AhL[c2 * 8]);
        GLL16(Al + (size_t)r1 * lda + k0 + q1 * 8, &AlL[c1 * 8]);
        GLL16(Al + (size_t)r2 * lda + k0 + q2 * 8, &AlL[c2 * 8]);
        GLL16(Bh + (size_t)r1 * ldb + k0 + q1 * 8, &BhL[c1 * 8]);
        GLL16(Bh + (size_t)r2 * ldb + k0 + q2 * 8, &BhL[c2 * 8]);
        GLL16(Bl + (size_t)r1 * ldb + k0 + q1 * 8, &BlL[c1 * 8]);
        GLL16(Bl + (size_t)r2 * ldb + k0 + q2 * 8, &BlL[c2 * 8]);
        __syncthreads();

        hfrag bh[4], bl[4];
#pragma unroll
        for (int n = 0; n < 4; ++n) {
            int row = wc + n * 16 + l15;
            int sw = (g ^ ((row + (row >> 2)) & 3)) * 8;
            bh[n] = *(const hfrag*)&BhL[row * 32 + sw];
            bl[n] = *(const hfrag*)&BlL[row * 32 + sw];
        }
#pragma unroll
        for (int m = 0; m < 4; ++m) {
            int row = wr + m * 16 + l15;
            int sw = (g ^ ((row + (row >> 2)) & 3)) * 8;
            hfrag ah = *(const hfrag*)&AhL[row * 32 + sw];
            hfrag al = *(const hfrag*)&AlL[row * 32 + sw];
#pragma unroll
            for (int n = 0; n < 4; ++n) {
                acc[m][n] = __builtin_amdgcn_mfma_f32_16x16x32_f16(ah, bh[n], acc[m][n], 0, 0, 0);
                acc[m][n] = __builtin_amdgcn_mfma_f32_16x16x32_f16(ah, bl[n], acc[m][n], 0, 0, 0);
                acc[m][n] = __builtin_amdgcn_mfma_f32_16x16x32_f16(al, bh[n], acc[m][n], 0, 0, 0);
            }
        }
    }

    int g4 = g * 4;
#pragma unroll
    for (int m = 0; m < 4; ++m) {
        int row0 = rowBase + wr + m * 16 + g4;
#pragma unroll
        for (int n = 0; n < 4; ++n) {
            int col = colBase + wc + n * 16 + l15;
            float bv = bias[col];
#pragma unroll
            for (int j = 0; j < 4; ++j) {
                float v = acc[m][n][j] + bv;
                if (OMODE == 1) v += res[(size_t)(row0 + j) * ldc + col];
                if (OMODE < 2) {
                    C[(size_t)(row0 + j) * ldc + col] = v;
                } else {
                    h16 hh = (h16)v;
                    Chi[(size_t)(row0 + j) * ldc + col] = hh;
                    Clo[(size_t)(row0 + j) * ldc + col] = (h16)(v - (float)hh);
                }
            }
        }
    }
}

// ---------------- attention QK^T (f16x2, K=64, strided heads) ----------------
template<bool CAUSAL>
__global__ __launch_bounds__(256) void attn_qk(
    const h16* __restrict__ Qh, const h16* __restrict__ Ql, int lda,
    const h16* __restrict__ Kh, const h16* __restrict__ Kl, int ldb,
    h16* __restrict__ Sh, h16* __restrict__ Sl, int zoff)
{
    int rowBase = blockIdx.y * 128, colBase = blockIdx.x * 128;
    if (CAUSAL && colBase >= rowBase + 128) return;
    __shared__ h16 AhL[4096], AlL[4096], BhL[4096], BlL[4096];
    int z = blockIdx.z;
    int bh_ = zoff + z, b = bh_ >> 4, h = bh_ & 15;
    const h16* Ah = Qh + (size_t)(b * 512 + rowBase) * lda + h * 64;
    const h16* Al = Ql + (size_t)(b * 512 + rowBase) * lda + h * 64;
    const h16* Bh = Kh + (size_t)(b * 512 + colBase) * ldb + h * 64;
    const h16* Bl = Kl + (size_t)(b * 512 + colBase) * ldb + h * 64;
    int t = threadIdx.x, lane = t & 63, wid = t >> 6;
    int wr = (wid >> 1) * 64, wc = (wid & 1) * 64;
    int c1 = t, c2 = t + 256;
    int r1 = c1 >> 2, q1 = (c1 & 3) ^ ((r1 + (r1 >> 2)) & 3);
    int r2 = c2 >> 2, q2 = (c2 & 3) ^ ((r2 + (r2 >> 2)) & 3);
    f32x4 acc[4][4] = {};
    int l15 = lane & 15, g = lane >> 4;

    for (int k0 = 0; k0 < 64; k0 += 32) {
        __syncthreads();
        GLL16(Ah + (size_t)r1 * lda + k0 + q1 * 8, &AhL[c1 * 8]);
        GLL16(Ah + (size_t)r2 * lda + k0 + q2 * 8, &AhL[c2 * 8]);
        GLL16(Al + (size_t)r1 * lda + k0 + q1 * 8, &AlL[c1 * 8]);
        GLL16(Al + (size_t)r2 * lda + k0 + q2 * 8, &AlL[c2 * 8]);
        GLL16(Bh + (size_t)r1 * ldb + k0 + q1 * 8, &BhL[c1 * 8]);
        GLL16(Bh + (size_t)r2 * ldb + k0 + q2 * 8, &BhL[c2 * 8]);
        GLL16(Bl + (size_t)r1 * ldb + k0 + q1 * 8, &BlL[c1 * 8]);
        GLL16(Bl + (size_t)r2 * ldb + k0 + q2 * 8, &BlL[c2 * 8]);
        __syncthreads();

        hfrag bh[4], bl[4];
#pragma unroll
        for (int n = 0; n < 4; ++n) {
            int row = wc + n * 16 + l15;
            int sw = (g ^ ((row + (row >> 2)) & 3)) * 8;
            bh[n] = *(const hfrag*)&BhL[row * 32 + sw];
            bl[n] = *(const hfrag*)&BlL[row * 32 + sw];
        }
#pragma unroll
        for (int m = 0; m < 4; ++m) {
            int row = wr + m * 16 + l15;
            int sw = (g ^ ((row + (row >> 2)) & 3)) * 8;
            hfrag ah = *(const hfrag*)&AhL[row * 32 + sw];
            hfrag al = *(const hfrag*)&AlL[row * 32 + sw];
#pragma unroll
            for (int n = 0; n < 4; ++n) {
                acc[m][n] = __builtin_amdgcn_mfma_f32_16x16x32_f16(ah, bh[n], acc[m][n], 0, 0, 0);
                acc[m][n] = __builtin_amdgcn_mfma_f32_16x16x32_f16(ah, bl[n], acc[m][n], 0, 0, 0);
                acc[m][n] = __builtin_amdgcn_mfma_f32_16x16x32_f16(al, bh[n], acc[m][n], 0, 0, 0);
            }
        }
    }

    size_t sbase = (size_t)z * 262144;
    int g4 = g * 4;
#pragma unroll
    for (int m = 0; m < 4; ++m) {
        int row0 = rowBase + wr + m * 16 + g4;
#pragma unroll
        for (int n = 0; n < 4; ++n) {
            int col = colBase + wc + n * 16 + l15;
#pragma unroll
            for (int j = 0; j < 4; ++j) {
                float v = acc[m][n][j] * 0.125f;
                h16 hh = (h16)v;
                Sh[sbase + (size_t)(row0 + j) * 512 + col] = hh;
                Sl[sbase + (size_t)(row0 + j) * 512 + col] = (h16)(v - (float)hh);
            }
        }
    }
}

// ---------------- softmax over hi/lo rows, in place (4 rows/block) ----------------
__global__ __launch_bounds__(256) void softmax_hl(h16* __restrict__ Sh, h16* __restrict__ Sl, int causal)
{
    int z = blockIdx.y;
    int wid = threadIdx.x >> 6, lane = threadIdx.x & 63;
    int t = blockIdx.x * 4 + wid;
    size_t base = ((size_t)z * 512 + t) * 512;
    int limit = causal ? (t + 1) : 512;
    float v[8];
    float mx = -1e30f;
#pragma unroll
    for (int k = 0; k < 8; ++k) {
        int idx = lane + (k << 6);
        float s = (float)Sh[base + idx] + (float)Sl[base + idx];
        float val = (idx < limit) ? s : -1e30f;
        v[k] = val; mx = fmaxf(mx, val);
    }
#pragma unroll
    for (int o = 1; o < 64; o <<= 1) mx = fmaxf(mx, __shfl_xor(mx, o, 64));
    float sum = 0.f;
#pragma unroll
    for (int k = 0; k < 8; ++k) {
        int idx = lane + (k << 6);
        float p = (idx < limit) ? __expf(v[k] - mx) : 0.f;
        v[k] = p; sum += p;
    }
#pragma unroll
    for (int o = 1; o < 64; o <<= 1) sum += __shfl_xor(sum, o, 64);
    float inv = 1.0f / sum;
#pragma unroll
    for (int k = 0; k < 8; ++k) {
        int idx = lane + (k << 6);
        float p = v[k] * inv;
        h16 hh = (h16)p;
        Sh[base + idx] = hh;
        Sl[base + idx] = (h16)(p - (float)hh);
    }
}

// ---------------- PV: C[t,d] = P[t,s] * vT[d,s]^T  (64x64 tile, BK=64, K=512) ----------------
__global__ __launch_bounds__(256) void attn_pv(
    const h16* __restrict__ Ph, const h16* __restrict__ Pl,
    const h16* __restrict__ Vh, const h16* __restrict__ Vl,
    h16* __restrict__ Ch, h16* __restrict__ Cl, int bh0)
{
    __shared__ h16 PhL[4096], PlL[4096], VhL[4096], VlL[4096];
    int z = blockIdx.z, bh_ = bh0 + z;
    int rowBase = blockIdx.x * 64;
    const h16* Pa = Ph + (size_t)z * 262144 + (size_t)rowBase * 512;
    const h16* Pb = Pl + (size_t)z * 262144 + (size_t)rowBase * 512;
    const h16* Va = Vh + (size_t)z * 32768;
    const h16* Vb = Vl + (size_t)z * 32768;
    int t = threadIdx.x, lane = t & 63, wid = t >> 6;
    f32x4 acc[4] = {};
    int l15 = lane & 15, g = lane >> 4;

    for (int k0 = 0; k0 < 512; k0 += 64) {
        __syncthreads();
#pragma unroll
        for (int cc = 0; cc < 2; ++cc) {
            int c = t + cc * 256;
            int r = c >> 3, sq = (c & 7) ^ (r & 7);
            GLL16(Pa + (size_t)r * 512 + k0 + sq * 8, &PhL[c * 8]);
            GLL16(Pb + (size_t)r * 512 + k0 + sq * 8, &PlL[c * 8]);
            GLL16(Va + (size_t)r * 512 + k0 + sq * 8, &VhL[c * 8]);
            GLL16(Vb + (size_t)r * 512 + k0 + sq * 8, &VlL[c * 8]);
        }
        __syncthreads();

        int arow = wid * 16 + l15;
#pragma unroll
        for (int kk = 0; kk < 2; ++kk) {
            int aq = ((kk << 2) | g) ^ (arow & 7);
            hfrag ah = *(const hfrag*)&PhL[arow * 64 + aq * 8];
            hfrag al = *(const hfrag*)&PlL[arow * 64 + aq * 8];
#pragma unroll
            for (int n = 0; n < 4; ++n) {
                int brow = n * 16 + l15;
                int bq = ((kk << 2) | g) ^ (brow & 7);
                hfrag bh = *(const hfrag*)&VhL[brow * 64 + bq * 8];
                hfrag bl = *(const hfrag*)&VlL[brow * 64 + bq * 8];
                acc[n] = __builtin_amdgcn_mfma_f32_16x16x32_f16(ah, bh, acc[n], 0, 0, 0);
                acc[n] = __builtin_amdgcn_mfma_f32_16x16x32_f16(ah, bl, acc[n], 0, 0, 0);
                acc[n] = __builtin_amdgcn_mfma_f32_16x16x32_f16(al, bh, acc[n], 0, 0, 0);
            }
        }
    }

    int brow = (bh_ >> 4) * 512 + rowBase + wid * 16 + g * 4;
    int bcol = (bh_ & 15) * 64;
#pragma unroll
    for (int n = 0; n < 4; ++n) {
        int col = bcol + n * 16 + l15;
#pragma unroll
        for (int j = 0; j < 4; ++j) {
            float v = acc[n][j];
            h16 hh = (h16)v;
            Ch[(size_t)(brow + j) * 1024 + col] = hh;
            Cl[(size_t)(brow + j) * 1024 + col] = (h16)(v - (float)hh);
        }
    }
}

// ---------------- V-transpose ----------------
__global__ __launch_bounds__(256) void vt_split(
    const h16* __restrict__ inh, const h16* __restrict__ inl, int ld,
    h16* __restrict__ oh, h16* __restrict__ ol)
{
    __shared__ h16 tile[64][68];
    int z = blockIdx.z, b = z >> 4, h = z & 15;
    size_t ibase = ((size_t)b * 512 + blockIdx.x * 64) * ld + h * 64;
    size_t obase = (size_t)z * 32768 + blockIdx.x * 64;
    int tr = threadIdx.x >> 4, tc = (threadIdx.x & 15) * 4;
    const h16* src[2] = {inh, inl};
    h16* dst[2] = {oh, ol};
#pragma unroll
    for (int s = 0; s < 2; ++s) {
        __syncthreads();
#pragma unroll
        for (int i = 0; i < 4; ++i) {
            int tt = tr + i * 16;
            short4 v = *(const short4*)(src[s] + ibase + (size_t)tt * ld + tc);
            tile[tt][tc + 0] = ((h16*)&v)[0];
            tile[tt][tc + 1] = ((h16*)&v)[1];
            tile[tt][tc + 2] = ((h16*)&v)[2];
            tile[tt][tc + 3] = ((h16*)&v)[3];
        }
        __syncthreads();
#pragma unroll
        for (int i = 0; i < 4; ++i) {
            int d = tr + i * 16;
            h16 w[4] = {tile[tc + 0][d], tile[tc + 1][d], tile[tc + 2][d], tile[tc + 3][d]};
            *(short4*)(dst[s] + obase + (size_t)d * 512 + tc) = *(short4*)w;
        }
    }
}

// ---------------- bf16 NT MFMA GEMM (MoE), BK=64, flat grid, expert->XCD pinned ----------------
template<int TN, bool RELU, bool ROWFAST>
__global__ __launch_bounds__(256) void gemm_bf16_moe(
    const unsigned short* __restrict__ A,   // [M][K] bf16, per expert
    const unsigned short* __restrict__ Bt,  // [N][K] bf16, per expert
    const float* __restrict__ bias,         // [N] fp32, per expert
    unsigned short* __restrict__ C,         // bf16 out
    int K, long long sA, long long sB, long long sC, long long sBias, int ldc,
    int emask, int elog, int nrow, int ncol)
{
    constexpr int NFR = TN / 32;
    __shared__ unsigned short Al[128 * 64];
    __shared__ unsigned short Bl[TN * 64];
    int id = blockIdx.x;
    int e = id & emask;
    int tb = id >> elog;
    int row, col;
    if (ROWFAST) { row = tb % nrow; col = tb / nrow; }
    else         { col = tb % ncol; row = tb / ncol; }

    A    += (size_t)e * sA;
    Bt   += (size_t)e * sB;
    bias += (size_t)e * sBias;
    long long zC = (long long)e * sC;

    int rowBase = row * 128, colBase = col * TN;
    int t = threadIdx.x, lane = t & 63, wid = t >> 6;
    int wr = (wid >> 1) * 64, wc = (wid & 1) * (TN / 2);

    const unsigned short* Ag = A  + (size_t)rowBase * K;
    const unsigned short* Bg = Bt + (size_t)colBase * K;

    f32x4 acc[4][NFR] = {};
    int l15 = lane & 15, g = lane >> 4;

    for (int k0 = 0; k0 < K; k0 += 64) {
        __syncthreads();
#pragma unroll
        for (int cc = 0; cc < 4; ++cc) {
            int c = t + cc * 256;
            int r = c >> 3, sq = (c & 7) ^ (r & 7);
            GLL16(Ag + (size_t)r * K + k0 + sq * 8, &Al[c * 8]);
        }
#pragma unroll
        for (int cc = 0; cc < TN / 32; ++cc) {
            int c = t + cc * 256;
            int r = c >> 3, sq = (c & 7) ^ (r & 7);
            GLL16(Bg + (size_t)r * K + k0 + sq * 8, &Bl[c * 8]);
        }
        __syncthreads();

        bfrag b[2][NFR];
#pragma unroll
        for (int kk = 0; kk < 2; ++kk)
#pragma unroll
            for (int n = 0; n < NFR; ++n) {
                int rr = wc + n * 16 + l15;
                int q = ((kk << 2) | g) ^ (rr & 7);
                b[kk][n] = *(const bfrag*)&Bl[rr * 64 + q * 8];
            }
#pragma unroll
        for (int m = 0; m < 4; ++m) {
            int rr = wr + m * 16 + l15;
#pragma unroll
            for (int kk = 0; kk < 2; ++kk) {
                int q = ((kk << 2) | g) ^ (rr & 7);
                bfrag a = *(const bfrag*)&Al[rr * 64 + q * 8];
#pragma unroll
                for (int n = 0; n < NFR; ++n)
                    acc[m][n] = __builtin_amdgcn_mfma_f32_16x16x32_bf16(a, b[kk][n], acc[m][n], 0, 0, 0);
            }
        }
    }

    int g4 = g * 4;
#pragma unroll
    for (int m = 0; m < 4; ++m) {
        int row0 = rowBase + wr + m * 16 + g4;
#pragma unroll
        for (int n = 0; n < NFR; ++n) {
            int cc = colBase + wc + n * 16 + l15;
            float bv = bias[cc];
#pragma unroll
            for (int j = 0; j < 4; ++j) {
                float v = acc[m][n][j] + bv;
                if (RELU) v = fmaxf(v, 0.f);
                C[zC + (size_t)(row0 + j) * ldc + cc] = f2bf(v);
            }
        }
    }
}

// ---------------- transpose+convert fp32 [R][Cn] -> bf16 [Cn][R] (per z) ----------------
__global__ __launch_bounds__(256) void tcvt_kernel(const float* __restrict__ in,
    unsigned short* __restrict__ out, int R, int Cn)
{
    __shared__ unsigned short tile[64][68];
    size_t zoff = (size_t)blockIdx.z * R * Cn;
    in += zoff; out += zoff;
    int r0 = blockIdx.y * 64, c0 = blockIdx.x * 64;
    int tr = threadIdx.x >> 4, tc = (threadIdx.x & 15) * 4;
#pragma unroll
    for (int i = 0; i < 4; ++i) {
        int r = tr + i * 16;
        float4 v = *(const float4*)&in[(size_t)(r0 + r) * Cn + c0 + tc];
        tile[r][tc + 0] = f2bf(v.x);
        tile[r][tc + 1] = f2bf(v.y);
        tile[r][tc + 2] = f2bf(v.z);
        tile[r][tc + 3] = f2bf(v.w);
    }
    __syncthreads();
#pragma unroll
    for (int i = 0; i < 4; ++i) {
        int c = tr + i * 16;
        ushort4 w;
        w.x = tile[tc + 0][c];
        w.y = tile[tc + 1][c];
        w.z = tile[tc + 2][c];
        w.w = tile[tc + 3][c];
        *(ushort4*)&out[(size_t)(c0 + c) * R + r0 + tc] = w;
    }
}

// ---------------- router ----------------
__global__ __launch_bounds__(256) void router_kernel(
    const float* __restrict__ xf, const float* __restrict__ rw, const float* __restrict__ rb,
    const float* __restrict__ tmask,
    int* __restrict__ eidx, float* __restrict__ gate, int* __restrict__ valid,
    float* __restrict__ partials)
{
    int blk = blockIdx.x;
    int wid = threadIdx.x >> 6, lane = threadIdx.x & 63;
    __shared__ float wpart[4][10];
    float pe[8] = {0,0,0,0,0,0,0,0};
    float zacc = 0.f, nvacc = 0.f;

    for (int i = 0; i < 16; ++i) {
        int tok = blk * 64 + wid * 16 + i;
        const float* xrow = xf + (size_t)tok * DMODEL;
        float acc[8] = {0,0,0,0,0,0,0,0};
#pragma unroll 4
        for (int kk = 0; kk < 16; ++kk) {
            int d = lane + (kk << 6);
            float xd = xrow[d];
            const float4* rp = (const float4*)(rw + (size_t)d * 8);
            float4 r0 = rp[0], r1 = rp[1];
            acc[0] = fmaf(xd, r0.x, acc[0]); acc[1] = fmaf(xd, r0.y, acc[1]);
            acc[2] = fmaf(xd, r0.z, acc[2]); acc[3] = fmaf(xd, r0.w, acc[3]);
            acc[4] = fmaf(xd, r1.x, acc[4]); acc[5] = fmaf(xd, r1.y, acc[5]);
            acc[6] = fmaf(xd, r1.z, acc[6]); acc[7] = fmaf(xd, r1.w, acc[7]);
        }
#pragma unroll
        for (int e = 0; e < 8; ++e)
#pragma unroll
            for (int o = 1; o < 64; o <<= 1) acc[e] += __shfl_xor(acc[e], o, 64);
        if (lane == 0) {
            float l[8]; float m = -1e30f;
#pragma unroll
            for (int e = 0; e < 8; ++e) { l[e] = acc[e] + rb[e]; m = fmaxf(m, l[e]); }
            float se = 0.f;
#pragma unroll
            for (int e = 0; e < 8; ++e) se += expf(l[e] - m);
            int am = 0; float bm = l[0];
#pragma unroll
            for (int e = 1; e < 8; ++e) if (l[e] > bm) { bm = l[e]; am = e; }
            float inv_se = 1.0f / se;
            float g = expf(l[am] - m) * inv_se;
            float vld = (tmask[tok] > 0.f) ? 1.f : 0.f;
            eidx[tok] = am; gate[tok] = g; valid[tok] = (int)vld;
#pragma unroll
            for (int e = 0; e < 8; ++e) pe[e] += expf(l[e] - m) * inv_se * vld;
            float lse = logf(se) + m;
            zacc += lse * lse * vld;
            nvacc += vld;
        }
    }
    if (lane == 0) {
#pragma unroll
        for (int e = 0; e < 8; ++e) wpart[wid][e] = pe[e];
        wpart[wid][8] = zacc; wpart[wid][9] = nvacc;
    }
    __syncthreads();
    if (threadIdx.x == 0) {
        for (int j = 0; j < 10; ++j)
            partials[blk * 10 + j] = wpart[0][j] + wpart[1][j] + wpart[2][j] + wpart[3][j];
    }
}

// ---------------- capacity scan ----------------
__global__ __launch_bounds__(256) void scan_kernel(
    const int* __restrict__ eidx, const int* __restrict__ valid, const float* __restrict__ gate,
    int* __restrict__ pc, float* __restrict__ gk, int* __restrict__ keepf,
    int* __restrict__ counts)
{
    __shared__ int cnt[256][8];
    int tid = threadIdx.x;
    int local[8] = {0,0,0,0,0,0,0,0};
    int base = tid * 16;
    for (int i = 0; i < 16; ++i) { int e = eidx[base + i]; local[e] += valid[base + i]; }
#pragma unroll
    for (int e = 0; e < 8; ++e) cnt[tid][e] = local[e];
    __syncthreads();
    if (tid < 8) {
        int run = 0;
        for (int i = 0; i < 256; ++i) { int t = cnt[i][tid]; cnt[i][tid] = run; run += t; }
        counts[tid] = run;
    }
    __syncthreads();
    int off[8];
#pragma unroll
    for (int e = 0; e < 8; ++e) off[e] = cnt[tid][e];
    for (int i = 0; i < 16; ++i) {
        int tok = base + i;
        int e = eidx[tok], v = valid[tok];
        int pos = off[e]; off[e] += v;
        int kp = (v && pos < CAPE) ? 1 : 0;
        pc[tok]    = (pos < CAPE) ? pos : (CAPE - 1);
        keepf[tok] = kp;
        gk[tok]    = kp ? gate[tok] : 0.f;
    }
}

// ---------------- dispatch (expert-range) -> bf16 buffers ----------------
__global__ __launch_bounds__(256) void dispatch_bf16(const float* __restrict__ tln,
    const int* __restrict__ eidx, const int* __restrict__ pc, const int* __restrict__ keepf,
    unsigned short* __restrict__ buf, int e0, int ec)
{
    int tok = blockIdx.x;
    if (!keepf[tok]) return;
    int e = eidx[tok];
    if (e < e0 || e >= e0 + ec) return;
    int p = pc[tok];
    const float4 v = ((const float4*)(tln + (size_t)tok * DMODEL))[threadIdx.x];
    ushort4 o;
    o.x = f2bf(v.x); o.y = f2bf(v.y); o.z = f2bf(v.z); o.w = f2bf(v.w);
    ((ushort4*)(buf + ((size_t)(e - e0) * CAPE + p) * DMODEL))[threadIdx.x] = o;
}

// ---------------- combine add: out += gk * ob (bf16 ob) ----------------
__global__ __launch_bounds__(256) void combine_bf16(const unsigned short* __restrict__ ob,
    const int* __restrict__ eidx, const int* __restrict__ pc, const float* __restrict__ gk,
    float* __restrict__ out, int e0, int ec)
{
    int tok = blockIdx.x;
    int e = eidx[tok];
    if (e < e0 || e >= e0 + ec) return;
    float g = gk[tok];
    int p = pc[tok];
    float4* o = (float4*)(out + (size_t)tok * DMODEL);
    const ushort4 u = ((const ushort4*)(ob + ((size_t)(e - e0) * CAPE + p) * DMODEL))[threadIdx.x];
    float4 a = o[threadIdx.x];
    a.x += g * bf2f(u.x); a.y += g * bf2f(u.y);
    a.z += g * bf2f(u.z); a.w += g * bf2f(u.w);
    o[threadIdx.x] = a;
}

// ---------------- final scalar losses ----------------
__global__ __launch_bounds__(64) void loss_kernel(const float* __restrict__ partials,
    const int* __restrict__ counts, float* __restrict__ out2)
{
    int lane = threadIdx.x;
    float p[10];
#pragma unroll
    for (int j = 0; j < 10; ++j) p[j] = partials[lane * 10 + j];
#pragma unroll
    for (int j = 0; j < 10; ++j)
#pragma unroll
        for (int o = 1; o < 64; o <<= 1) p[j] += __shfl_xor(p[j], o, 64);
    if (lane == 0) {
        float nv = fmaxf(p[9], 1.f);
        float lb = 0.f;
        for (int e = 0; e < 8; ++e) lb += ((float)counts[e] / nv) * (p[e] / nv);
        lb *= (float)NEXP;
        out2[0] = lb;
        out2[1] = p[8] / nv;
    }
}

// ---------------- host launch ----------------
extern "C" void kernel_launch(void* const* d_in, const int* in_sizes, int n_in,
                              void* d_out, int out_size, void* d_ws, size_t ws_size,
                              hipStream_t stream)
{
    const float* tgt        = (const float*)d_in[0];
    const float* src        = (const float*)d_in[1];
    const float* token_mask = (const float*)d_in[5];
    const float* ln1w = (const float*)d_in[6],  *ln1b = (const float*)d_in[7];
    const float* self_in_w  = (const float*)d_in[8],  *self_in_b  = (const float*)d_in[9];
    const float* self_out_w = (const float*)d_in[10], *self_out_b = (const float*)d_in[11];
    const float* ln2w = (const float*)d_in[12], *ln2b = (const float*)d_in[13];
    const float* enc_in_w   = (const float*)d_in[14], *enc_in_b   = (const float*)d_in[15];
    const float* enc_out_w  = (const float*)d_in[16], *enc_out_b  = (const float*)d_in[17];
    const float* ln3w = (const float*)d_in[18], *ln3b = (const float*)d_in[19];
    const float* rw = (const float*)d_in[20], *rb = (const float*)d_in[21];
    const float* w1 = (const float*)d_in[22], *b1 = (const float*)d_in[23];
    const float* w2 = (const float*)d_in[24], *b2 = (const float*)d_in[25];

    float* out = (float*)d_out;          // residual stream lives HERE
    float* ws  = (float*)d_ws;

    // ---- fixed layout (floats) ----
    float* tln = ws;                         // 4,194,304 (fp32 for ln3; f16 hi/lo for ln1/ln2)
    float* ctx = ws + 4194304;               // 4,194,304 (ctx hi/lo f16)
    int*   eidxA   = (int*)(ws + 8388608);
    int*   validA  = eidxA + 4096;
    int*   pcA     = validA + 4096;
    int*   keepA   = pcA + 4096;
    int*   countsA = keepA + 4096;           // 16
    float* gateA   = (float*)(countsA + 16);
    float* gkA     = gateA + 4096;
    float* partA   = gkA + 4096;             // 640
    const size_t POOL_OFF = 8425984;         // floats
    float* pool = ws + POOL_OFF;

    size_t Wf = ws_size / sizeof(float);
    size_t pf = (Wf > POOL_OFF) ? (Wf - POOL_OFF) : 0;

    // ---- tiers: bg = batches per attention group, zc = score z-chunk ----
    int bg, zc;
    if      (pf >= 25165824) { bg = 8; zc = 32; }
    else if (pf >= 24117248) { bg = 8; zc = 16; }
    else if (pf >= 13631488) { bg = 4; zc = 16; }
    else                     { bg = 2; zc = 16; }
    // MoE: experts per chunk (power of 2); per expert needs 3,735,552 pool floats
    int ecs = 1;
    for (int c = 8; c >= 1; c >>= 1)
        if ((size_t)c * 3735552ull <= pf) { ecs = c; break; }
    int elog = (ecs == 8) ? 3 : (ecs == 4) ? 2 : (ecs == 2) ? 1 : 0;

    float* qreg = pool;
    float* vreg = qreg + (size_t)bg * 1572864;
    float* sreg = vreg + (size_t)bg * 524288;

    h16* tlnh = (h16*)tln;
    h16* tlnl = tlnh + 4194304;
    h16* ctxh = (h16*)ctx;
    h16* ctxl = ctxh + 4194304;

    // ================= self attention =================
    ln_kernel<1><<<NTOK, 256, 0, stream>>>(tgt, ln1w, ln1b, nullptr, tlnh, tlnl);

    for (int g0 = 0; g0 < BATCH; g0 += bg) {
        h16* sb  = (h16*)sreg;
        h16* whi = sb, *wlo = sb + 3145728;
        split_f16<<<1536, 256, 0, stream>>>(self_in_w, whi, wlo, 393216);

        h16* qkvh = (h16*)qreg, *qkvl = qkvh + (size_t)bg * 1572864;
        gemm_f16x2_nt<2><<<dim3(24, bg * 4, 1), 256, 0, stream>>>(
            tlnh + (size_t)g0 * 524288, tlnl + (size_t)g0 * 524288, 1024,
            whi, wlo, 1024, self_in_b, nullptr,
            nullptr, qkvh, qkvl, 1024, 3072);

        h16* vth = (h16*)vreg, *vtl = vth + (size_t)bg * 524288;
        vt_split<<<dim3(8, 1, bg * 16), 256, 0, stream>>>(qkvh + 2048, qkvl + 2048, 3072, vth, vtl);

        h16* sh = sb, *sl = sh + (size_t)zc * 262144;
        for (int c0 = 0; c0 < bg * 16; c0 += zc) {
            attn_qk<true><<<dim3(4, 4, zc), 256, 0, stream>>>(
                qkvh, qkvl, 3072, qkvh + 1024, qkvl + 1024, 3072, sh, sl, c0);
            softmax_hl<<<dim3(128, zc), 256, 0, stream>>>(sh, sl, 1);
            attn_pv<<<dim3(8, 1, zc), 256, 0, stream>>>(
                sh, sl, vth + (size_t)c0 * 32768, vtl + (size_t)c0 * 32768,
                ctxh, ctxl, g0 * 16 + c0);
        }
    }
    {
        h16* sb = (h16*)sreg;
        h16* owhi = sb, *owlo = sb + 1048576;
        split_f16<<<512, 256, 0, stream>>>(self_out_w, owhi, owlo, 131072);
        gemm_f16x2_nt<1><<<dim3(8, 32, 1), 256, 0, stream>>>(
            ctxh, ctxl, 1024, owhi, owlo, 1024, self_out_b, tgt,
            out, nullptr, nullptr, 1024, 1024);
    }

    // ================= cross attention =================
    ln_kernel<1><<<NTOK, 256, 0, stream>>>(out, ln2w, ln2b, nullptr, tlnh, tlnl);

    for (int g0 = 0; g0 < BATCH; g0 += bg) {
        h16* sb  = (h16*)sreg;
        h16* shi = sb, *slo = sb + (size_t)bg * 524288;
        h16* ehi = sb + (size_t)bg * 1048576, *elo = ehi + 3145728;
        split_f16<<<bg * 256, 256, 0, stream>>>(src + (size_t)g0 * 524288, shi, slo, bg * 65536);
        split_f16<<<1536, 256, 0, stream>>>(enc_in_w, ehi, elo, 393216);

        h16* q2h  = (h16*)qreg,                 *q2l  = q2h + (size_t)bg * 524288;
        h16* kv2h = q2h + (size_t)bg * 1048576, *kv2l = kv2h + (size_t)bg * 1048576;
        gemm_f16x2_nt<2><<<dim3(8, bg * 4, 1), 256, 0, stream>>>(
            tlnh + (size_t)g0 * 524288, tlnl + (size_t)g0 * 524288, 1024,
            ehi, elo, 1024, enc_in_b, nullptr,
            nullptr, q2h, q2l, 1024, 1024);
        gemm_f16x2_nt<2><<<dim3(16, bg * 4, 1), 256, 0, stream>>>(
            shi, slo, 1024, ehi + 1048576, elo + 1048576, 1024, enc_in_b + 1024, nullptr,
            nullptr, kv2h, kv2l, 1024, 2048);

        h16* vth = (h16*)vreg, *vtl = vth + (size_t)bg * 524288;
        vt_split<<<dim3(8, 1, bg * 16), 256, 0, stream>>>(kv2h + 1024, kv2l + 1024, 2048, vth, vtl);

        h16* sh = sb, *sl = sh + (size_t)zc * 262144;
        for (int c0 = 0; c0 < bg * 16; c0 += zc) {
            attn_qk<false><<<dim3(4, 4, zc), 256, 0, stream>>>(
                q2h, q2l, 1024, kv2h, kv2l, 2048, sh, sl, c0);
            softmax_hl<<<dim3(128, zc), 256, 0, stream>>>(sh, sl, 0);
            attn_pv<<<dim3(8, 1, zc), 256, 0, stream>>>(
                sh, sl, vth + (size_t)c0 * 32768, vtl + (size_t)c0 * 32768,
                ctxh, ctxl, g0 * 16 + c0);
        }
    }
    {
        h16* sb = (h16*)sreg;
        h16* owhi = sb, *owlo = sb + 1048576;
        split_f16<<<512, 256, 0, stream>>>(enc_out_w, owhi, owlo, 131072);
        gemm_f16x2_nt<1><<<dim3(8, 32, 1), 256, 0, stream>>>(
            ctxh, ctxl, 1024, owhi, owlo, 1024, enc_out_b, out,
            out, nullptr, nullptr, 1024, 1024);
    }

    // ================= MoE =================
    ln_kernel<0><<<NTOK, 256, 0, stream>>>(out, ln3w, ln3b, tln, nullptr, nullptr);
    router_kernel<<<64, 256, 0, stream>>>(tln, rw, rb, token_mask, eidxA, gateA, validA, partA);
    scan_kernel<<<1, 256, 0, stream>>>(eidxA, validA, gateA, pcA, gkA, keepA, countsA);

    // per-chunk pool layout (floats):
    //   wt   : ecs*2,097,152  (bf16 w1t then w2t, reused)
    //   hB   : ecs*1,310,720  (bf16 [640][4096])
    //   bufB : ecs*327,680    (bf16 [640][1024]); obB overlays bufB
    for (int e0 = 0; e0 < NEXP; e0 += ecs) {
        unsigned short* wt   = (unsigned short*)pool;
        unsigned short* hB   = (unsigned short*)(pool + (size_t)ecs * 2097152);
        unsigned short* bufB = (unsigned short*)(pool + (size_t)ecs * 3407872);
        unsigned short* obB  = bufB;   // overlay: bufB dead after w1 GEMM

        // w1 phase (no memset: garbage rows are row-local and never combined)
        tcvt_kernel<<<dim3(64, 16, ecs), 256, 0, stream>>>(
            w1 + (size_t)e0 * 4194304, wt, 1024, 4096);
        dispatch_bf16<<<NTOK, 256, 0, stream>>>(tln, eidxA, pcA, keepA, bufB, e0, ecs);
        gemm_bf16_moe<128, true, true><<<ecs * 5 * 32, 256, 0, stream>>>(
            bufB, wt, b1 + (size_t)e0 * 4096, hB,
            1024, 655360LL, 4194304LL, 2621440LL, 4096LL, 4096,
            ecs - 1, elog, 5, 32);

        // w2 phase (wt reused)
        tcvt_kernel<<<dim3(16, 64, ecs), 256, 0, stream>>>(
            w2 + (size_t)e0 * 4194304, wt, 4096, 1024);
        gemm_bf16_moe<64, false, false><<<ecs * 5 * 16, 256, 0, stream>>>(
            hB, wt, b2 + (size_t)e0 * 1024, obB,
            4096, 2621440LL, 4194304LL, 655360LL, 1024LL, 1024,
            ecs - 1, elog, 5, 16);

        combine_bf16<<<NTOK, 256, 0, stream>>>(obB, eidxA, pcA, gkA, out, e0, ecs);
    }

    // ===== losses =====
    loss_kernel<<<1, 64, 0, stream>>>(partA, countsA, out + (size_t)NTOK * DMODEL);
}

// Round 10
// 944.531 us; speedup vs baseline: 2.8660x; 1.0842x over previous
//
#include <hip/hip_runtime.h>
#include <cstdint>

// ---------------- problem constants ----------------
constexpr int BATCH  = 8;
constexpr int TSEQ   = 512;
constexpr int DMODEL = 1024;
constexpr int NEXP   = 8;
constexpr int CAPE   = 640;
constexpr int NTOK   = BATCH * TSEQ;        // 4096

typedef _Float16 h16;
typedef __attribute__((ext_vector_type(8))) short bfrag;
typedef __attribute__((ext_vector_type(8))) _Float16 hfrag;
typedef __attribute__((ext_vector_type(4))) float f32x4;

__device__ __forceinline__ unsigned short f2bf(float f) {
    uint32_t u = __float_as_uint(f);
    uint32_t r = (u + 0x7FFFu + ((u >> 16) & 1u)) >> 16;   // RNE
    return (unsigned short)r;
}
__device__ __forceinline__ float bf2f(unsigned short b) {
    return __uint_as_float((uint32_t)b << 16);
}

#define GLL16(SRC, DST) __builtin_amdgcn_global_load_lds( \
    (const __attribute__((address_space(1))) void*)(SRC), \
    (__attribute__((address_space(3))) void*)(DST), 16, 0, 0)

// ---------------- LayerNorm: MODE 0 -> fp32 out; MODE 1 -> f16 hi/lo out ----------------
template<int MODE>
__global__ __launch_bounds__(256) void ln_kernel(const float* __restrict__ in,
    const float* __restrict__ gw, const float* __restrict__ gb,
    float* __restrict__ out, h16* __restrict__ ohi, h16* __restrict__ olo)
{
    int row = blockIdx.x, tid = threadIdx.x;
    const float4 v = *(const float4*)(in + (size_t)row * DMODEL + tid * 4);
    float s  = v.x + v.y + v.z + v.w;
    float ss = v.x*v.x + v.y*v.y + v.z*v.z + v.w*v.w;
#pragma unroll
    for (int o = 1; o < 64; o <<= 1) { s += __shfl_xor(s, o, 64); ss += __shfl_xor(ss, o, 64); }
    __shared__ float rs[4], rss[4];
    int wid = tid >> 6, lane = tid & 63;
    if (lane == 0) { rs[wid] = s; rss[wid] = ss; }
    __syncthreads();
    s  = rs[0] + rs[1] + rs[2] + rs[3];
    ss = rss[0] + rss[1] + rss[2] + rss[3];
    float mean = s * (1.0f / DMODEL);
    float var  = ss * (1.0f / DMODEL) - mean * mean;
    float inv  = rsqrtf(var + 1e-5f);
    float4 w4 = *(const float4*)(gw + tid * 4);
    float4 b4 = *(const float4*)(gb + tid * 4);
    float o[4];
    o[0] = (v.x - mean) * inv * w4.x + b4.x;
    o[1] = (v.y - mean) * inv * w4.y + b4.y;
    o[2] = (v.z - mean) * inv * w4.z + b4.z;
    o[3] = (v.w - mean) * inv * w4.w + b4.w;
    if (MODE == 0) {
        float4 f = {o[0], o[1], o[2], o[3]};
        *(float4*)(out + (size_t)row * DMODEL + tid * 4) = f;
    } else {
        short4 hv, lv;
#pragma unroll
        for (int j = 0; j < 4; ++j) {
            h16 hh = (h16)o[j];
            ((h16*)&hv)[j] = hh;
            ((h16*)&lv)[j] = (h16)(o[j] - (float)hh);
        }
        *(short4*)(ohi + (size_t)row * DMODEL + tid * 4) = hv;
        *(short4*)(olo + (size_t)row * DMODEL + tid * 4) = lv;
    }
}

// ---------------- fp32 -> fp16 hi/lo split ----------------
__global__ __launch_bounds__(256) void split_f16(const float* __restrict__ in,
    h16* __restrict__ hi, h16* __restrict__ lo, int n8)
{
    int i = blockIdx.x * 256 + threadIdx.x;
    if (i >= n8) return;
    const float4* p = (const float4*)in + 2 * (size_t)i;
    float4 v0 = p[0], v1 = p[1];
    float vv[8] = {v0.x, v0.y, v0.z, v0.w, v1.x, v1.y, v1.z, v1.w};
    hfrag h, l;
#pragma unroll
    for (int j = 0; j < 8; ++j) {
        h16 hj = (h16)vv[j];
        h[j] = hj;
        l[j] = (h16)(vv[j] - (float)hj);
    }
    ((hfrag*)hi)[i] = h;
    ((hfrag*)lo)[i] = l;
}

// ---------------- fp16x2 (3-product) NT MFMA GEMM, BK=64 ----------------
// OMODE: 0 = fp32 out, 1 = fp32 out + res, 2 = f16 hi/lo pair out
template<int OMODE>
__global__ __launch_bounds__(256) void gemm_f16x2_nt(
    const h16* __restrict__ Ahi, const h16* __restrict__ Alo, int lda,
    const h16* __restrict__ Bhi, const h16* __restrict__ Blo, int ldb,
    const float* __restrict__ bias, const float* __restrict__ res,
    float* __restrict__ C, h16* __restrict__ Chi, h16* __restrict__ Clo,
    int K, int ldc)
{
    __shared__ h16 AhL[8192], AlL[8192], BhL[8192], BlL[8192];   // 128x64 each, 64KB
    int rowBase = blockIdx.y * 128, colBase = blockIdx.x * 128;
    int t = threadIdx.x, lane = t & 63, wid = t >> 6;
    int wr = (wid >> 1) * 64, wc = (wid & 1) * 64;
    const h16* Ah = Ahi + (size_t)rowBase * lda;
    const h16* Al = Alo + (size_t)rowBase * lda;
    const h16* Bh = Bhi + (size_t)colBase * ldb;
    const h16* Bl = Blo + (size_t)colBase * ldb;
    f32x4 acc[4][4] = {};
    int l15 = lane & 15, g = lane >> 4;

    for (int k0 = 0; k0 < K; k0 += 64) {
        __syncthreads();
#pragma unroll
        for (int cc = 0; cc < 4; ++cc) {
            int c = t + cc * 256;
            int r = c >> 3, sq = (c & 7) ^ (r & 7);
            GLL16(Ah + (size_t)r * lda + k0 + sq * 8, &AhL[c * 8]);
            GLL16(Al + (size_t)r * lda + k0 + sq * 8, &AlL[c * 8]);
            GLL16(Bh + (size_t)r * ldb + k0 + sq * 8, &BhL[c * 8]);
            GLL16(Bl + (size_t)r * ldb + k0 + sq * 8, &BlL[c * 8]);
        }
        __syncthreads();

#pragma unroll
        for (int kk = 0; kk < 2; ++kk) {
            hfrag bh[4], bl[4];
#pragma unroll
            for (int n = 0; n < 4; ++n) {
                int rr = wc + n * 16 + l15;
                int q = ((kk << 2) | g) ^ (rr & 7);
                bh[n] = *(const hfrag*)&BhL[rr * 64 + q * 8];
                bl[n] = *(const hfrag*)&BlL[rr * 64 + q * 8];
            }
#pragma unroll
            for (int m = 0; m < 4; ++m) {
                int rr = wr + m * 16 + l15;
                int q = ((kk << 2) | g) ^ (rr & 7);
                hfrag ah = *(const hfrag*)&AhL[rr * 64 + q * 8];
                hfrag al = *(const hfrag*)&AlL[rr * 64 + q * 8];
#pragma unroll
                for (int n = 0; n < 4; ++n) {
                    acc[m][n] = __builtin_amdgcn_mfma_f32_16x16x32_f16(ah, bh[n], acc[m][n], 0, 0, 0);
                    acc[m][n] = __builtin_amdgcn_mfma_f32_16x16x32_f16(ah, bl[n], acc[m][n], 0, 0, 0);
                    acc[m][n] = __builtin_amdgcn_mfma_f32_16x16x32_f16(al, bh[n], acc[m][n], 0, 0, 0);
                }
            }
        }
    }

    int g4 = g * 4;
#pragma unroll
    for (int m = 0; m < 4; ++m) {
        int row0 = rowBase + wr + m * 16 + g4;
#pragma unroll
        for (int n = 0; n < 4; ++n) {
            int col = colBase + wc + n * 16 + l15;
            float bv = bias[col];
#pragma unroll
            for (int j = 0; j < 4; ++j) {
                float v = acc[m][n][j] + bv;
                if (OMODE == 1) v += res[(size_t)(row0 + j) * ldc + col];
                if (OMODE < 2) {
                    C[(size_t)(row0 + j) * ldc + col] = v;
                } else {
                    h16 hh = (h16)v;
                    Chi[(size_t)(row0 + j) * ldc + col] = hh;
                    Clo[(size_t)(row0 + j) * ldc + col] = (h16)(v - (float)hh);
                }
            }
        }
    }
}

// ---------------- attention QK^T (f16x2, K=64, strided heads) ----------------
template<bool CAUSAL>
__global__ __launch_bounds__(256) void attn_qk(
    const h16* __restrict__ Qh, const h16* __restrict__ Ql, int lda,
    const h16* __restrict__ Kh, const h16* __restrict__ Kl, int ldb,
    h16* __restrict__ Sh, h16* __restrict__ Sl, int zoff)
{
    int rowBase = blockIdx.y * 128, colBase = blockIdx.x * 128;
    if (CAUSAL && colBase >= rowBase + 128) return;
    __shared__ h16 AhL[4096], AlL[4096], BhL[4096], BlL[4096];
    int z = blockIdx.z;
    int bh_ = zoff + z, b = bh_ >> 4, h = bh_ & 15;
    const h16* Ah = Qh + (size_t)(b * 512 + rowBase) * lda + h * 64;
    const h16* Al = Ql + (size_t)(b * 512 + rowBase) * lda + h * 64;
    const h16* Bh = Kh + (size_t)(b * 512 + colBase) * ldb + h * 64;
    const h16* Bl = Kl + (size_t)(b * 512 + colBase) * ldb + h * 64;
    int t = threadIdx.x, lane = t & 63, wid = t >> 6;
    int wr = (wid >> 1) * 64, wc = (wid & 1) * 64;
    int c1 = t, c2 = t + 256;
    int r1 = c1 >> 2, q1 = (c1 & 3) ^ ((r1 + (r1 >> 2)) & 3);
    int r2 = c2 >> 2, q2 = (c2 & 3) ^ ((r2 + (r2 >> 2)) & 3);
    f32x4 acc[4][4] = {};
    int l15 = lane & 15, g = lane >> 4;

    for (int k0 = 0; k0 < 64; k0 += 32) {
        __syncthreads();
        GLL16(Ah + (size_t)r1 * lda + k0 + q1 * 8, &AhL[c1 * 8]);
        GLL16(Ah + (size_t)r2 * lda + k0 + q2 * 8, &AhL[c2 * 8]);
        GLL16(Al + (size_t)r1 * lda + k0 + q1 * 8, &AlL[c1 * 8]);
        GLL16(Al + (size_t)r2 * lda + k0 + q2 * 8, &AlL[c2 * 8]);
        GLL16(Bh + (size_t)r1 * ldb + k0 + q1 * 8, &BhL[c1 * 8]);
        GLL16(Bh + (size_t)r2 * ldb + k0 + q2 * 8, &BhL[c2 * 8]);
        GLL16(Bl + (size_t)r1 * ldb + k0 + q1 * 8, &BlL[c1 * 8]);
        GLL16(Bl + (size_t)r2 * ldb + k0 + q2 * 8, &BlL[c2 * 8]);
        __syncthreads();

        hfrag bh[4], bl[4];
#pragma unroll
        for (int n = 0; n < 4; ++n) {
            int row = wc + n * 16 + l15;
            int sw = (g ^ ((row + (row >> 2)) & 3)) * 8;
            bh[n] = *(const hfrag*)&BhL[row * 32 + sw];
            bl[n] = *(const hfrag*)&BlL[row * 32 + sw];
        }
#pragma unroll
        for (int m = 0; m < 4; ++m) {
            int row = wr + m * 16 + l15;
            int sw = (g ^ ((row + (row >> 2)) & 3)) * 8;
            hfrag ah = *(const hfrag*)&AhL[row * 32 + sw];
            hfrag al = *(const hfrag*)&AlL[row * 32 + sw];
#pragma unroll
            for (int n = 0; n < 4; ++n) {
                acc[m][n] = __builtin_amdgcn_mfma_f32_16x16x32_f16(ah, bh[n], acc[m][n], 0, 0, 0);
                acc[m][n] = __builtin_amdgcn_mfma_f32_16x16x32_f16(ah, bl[n], acc[m][n], 0, 0, 0);
                acc[m][n] = __builtin_amdgcn_mfma_f32_16x16x32_f16(al, bh[n], acc[m][n], 0, 0, 0);
            }
        }
    }

    size_t sbase = (size_t)z * 262144;
    int g4 = g * 4;
#pragma unroll
    for (int m = 0; m < 4; ++m) {
        int row0 = rowBase + wr + m * 16 + g4;
#pragma unroll
        for (int n = 0; n < 4; ++n) {
            int col = colBase + wc + n * 16 + l15;
#pragma unroll
            for (int j = 0; j < 4; ++j) {
                float v = acc[m][n][j] * 0.125f;
                h16 hh = (h16)v;
                Sh[sbase + (size_t)(row0 + j) * 512 + col] = hh;
                Sl[sbase + (size_t)(row0 + j) * 512 + col] = (h16)(v - (float)hh);
            }
        }
    }
}

// ---------------- fused softmax+PV: O[t,d] = softmax(S[t,:]) * V  (64 rows/block) ----------------
template<bool CAUSAL>
__global__ __launch_bounds__(256) void attn_pv(
    const h16* __restrict__ Shg, const h16* __restrict__ Slg,
    const h16* __restrict__ Vh, const h16* __restrict__ Vl,
    h16* __restrict__ Ch, h16* __restrict__ Cl, int bh0)
{
    __shared__ h16 ShL[4096], SlL[4096], VhL[4096], VlL[4096];
    __shared__ float mS[64], iS[64];
    int z = blockIdx.z, bh_ = bh0 + z;
    int rowBase = blockIdx.x * 64;
    const h16* Sa = Shg + (size_t)z * 262144 + (size_t)rowBase * 512;
    const h16* Sb = Slg + (size_t)z * 262144 + (size_t)rowBase * 512;
    const h16* Va = Vh + (size_t)z * 32768;
    const h16* Vb = Vl + (size_t)z * 32768;
    int t = threadIdx.x, lane = t & 63, wid = t >> 6;
    int l15 = lane & 15, g = lane >> 4;

    // ---- pass 1: per-row max & sum(exp) (4 lanes per row, strided cols) ----
    {
        int tr = t >> 2, tq = t & 3;
        int limit = CAUSAL ? (rowBase + tr + 1) : 512;
        float m = -1e30f, l = 0.f;
        const h16* rh = Sa + (size_t)tr * 512;
        const h16* rl = Sb + (size_t)tr * 512;
        for (int c = 0; c < 16; ++c) {
            int col0 = tq * 8 + c * 32;
            if (col0 >= limit) break;
            hfrag hv = *(const hfrag*)(rh + col0);
            hfrag lv = *(const hfrag*)(rl + col0);
            float s[8]; float cm = -1e30f;
#pragma unroll
            for (int j = 0; j < 8; ++j) {
                float sv = (float)hv[j] + (float)lv[j];
                s[j] = (col0 + j < limit) ? sv : -1e30f;
                cm = fmaxf(cm, s[j]);
            }
            if (cm > m) { l *= __expf(m - cm); m = cm; }
#pragma unroll
            for (int j = 0; j < 8; ++j) l += __expf(s[j] - m);
        }
#pragma unroll
        for (int o = 1; o < 4; o <<= 1) {
            float mo = __shfl_xor(m, o, 64);
            float lo2 = __shfl_xor(l, o, 64);
            float mc = fmaxf(m, mo);
            l = l * __expf(m - mc) + lo2 * __expf(mo - mc);
            m = mc;
        }
        if (tq == 0) { mS[tr] = m; iS[tr] = 1.0f / l; }
    }
    __syncthreads();

    // ---- pass 2: K-loop, transform S->P in registers, 3-product MFMA ----
    int arow = wid * 16 + l15;
    float am = mS[arow], ai = iS[arow];
    int alim = CAUSAL ? (rowBase + arow + 1) : 512;
    int kend = CAUSAL ? (rowBase + 64) : 512;
    f32x4 acc[4] = {};

    for (int k0 = 0; k0 < kend; k0 += 64) {
        __syncthreads();
#pragma unroll
        for (int cc = 0; cc < 2; ++cc) {
            int c = t + cc * 256;
            int r = c >> 3, sq = (c & 7) ^ (r & 7);
            GLL16(Sa + (size_t)r * 512 + k0 + sq * 8, &ShL[c * 8]);
            GLL16(Sb + (size_t)r * 512 + k0 + sq * 8, &SlL[c * 8]);
            GLL16(Va + (size_t)r * 512 + k0 + sq * 8, &VhL[c * 8]);
            GLL16(Vb + (size_t)r * 512 + k0 + sq * 8, &VlL[c * 8]);
        }
        __syncthreads();

#pragma unroll
        for (int kk = 0; kk < 2; ++kk) {
            int chunk = (kk << 2) | g;
            int aq = chunk ^ (arow & 7);
            hfrag sh_ = *(const hfrag*)&ShL[arow * 64 + aq * 8];
            hfrag sl_ = *(const hfrag*)&SlL[arow * 64 + aq * 8];
            int cbase = k0 + chunk * 8;
            hfrag ph, pl;
#pragma unroll
            for (int j = 0; j < 8; ++j) {
                float s = (float)sh_[j] + (float)sl_[j];
                float p = __expf(s - am) * ai;
                p = (cbase + j < alim) ? p : 0.f;
                h16 hh = (h16)p;
                ph[j] = hh;
                pl[j] = (h16)(p - (float)hh);
            }
#pragma unroll
            for (int n = 0; n < 4; ++n) {
                int brow = n * 16 + l15;
                int bq = chunk ^ (brow & 7);
                hfrag bh = *(const hfrag*)&VhL[brow * 64 + bq * 8];
                hfrag bl = *(const hfrag*)&VlL[brow * 64 + bq * 8];
                acc[n] = __builtin_amdgcn_mfma_f32_16x16x32_f16(ph, bh, acc[n], 0, 0, 0);
                acc[n] = __builtin_amdgcn_mfma_f32_16x16x32_f16(ph, bl, acc[n], 0, 0, 0);
                acc[n] = __builtin_amdgcn_mfma_f32_16x16x32_f16(pl, bh, acc[n], 0, 0, 0);
            }
        }
    }

    int brow = (bh_ >> 4) * 512 + rowBase + wid * 16 + g * 4;
    int bcol = (bh_ & 15) * 64;
#pragma unroll
    for (int n = 0; n < 4; ++n) {
        int col = bcol + n * 16 + l15;
#pragma unroll
        for (int j = 0; j < 4; ++j) {
            float v = acc[n][j];
            h16 hh = (h16)v;
            Ch[(size_t)(brow + j) * 1024 + col] = hh;
            Cl[(size_t)(brow + j) * 1024 + col] = (h16)(v - (float)hh);
        }
    }
}

// ---------------- V-transpose ----------------
__global__ __launch_bounds__(256) void vt_split(
    const h16* __restrict__ inh, const h16* __restrict__ inl, int ld,
    h16* __restrict__ oh, h16* __restrict__ ol)
{
    __shared__ h16 tile[64][68];
    int z = blockIdx.z, b = z >> 4, h = z & 15;
    size_t ibase = ((size_t)b * 512 + blockIdx.x * 64) * ld + h * 64;
    size_t obase = (size_t)z * 32768 + blockIdx.x * 64;
    int tr = threadIdx.x >> 4, tc = (threadIdx.x & 15) * 4;
    const h16* src[2] = {inh, inl};
    h16* dst[2] = {oh, ol};
#pragma unroll
    for (int s = 0; s < 2; ++s) {
        __syncthreads();
#pragma unroll
        for (int i = 0; i < 4; ++i) {
            int tt = tr + i * 16;
            short4 v = *(const short4*)(src[s] + ibase + (size_t)tt * ld + tc);
            tile[tt][tc + 0] = ((h16*)&v)[0];
            tile[tt][tc + 1] = ((h16*)&v)[1];
            tile[tt][tc + 2] = ((h16*)&v)[2];
            tile[tt][tc + 3] = ((h16*)&v)[3];
        }
        __syncthreads();
#pragma unroll
        for (int i = 0; i < 4; ++i) {
            int d = tr + i * 16;
            h16 w[4] = {tile[tc + 0][d], tile[tc + 1][d], tile[tc + 2][d], tile[tc + 3][d]};
            *(short4*)(dst[s] + obase + (size_t)d * 512 + tc) = *(short4*)w;
        }
    }
}

// ---------------- bf16 NT MFMA GEMM (MoE), BK=64, flat grid, expert->XCD pinned ----------------
template<int TN, bool RELU, bool ROWFAST>
__global__ __launch_bounds__(256) void gemm_bf16_moe(
    const unsigned short* __restrict__ A,
    const unsigned short* __restrict__ Bt,
    const float* __restrict__ bias,
    unsigned short* __restrict__ C,
    int K, long long sA, long long sB, long long sC, long long sBias, int ldc,
    int emask, int elog, int nrow, int ncol)
{
    constexpr int NFR = TN / 32;
    __shared__ unsigned short Al[128 * 64];
    __shared__ unsigned short Bl[TN * 64];
    int id = blockIdx.x;
    int e = id & emask;
    int tb = id >> elog;
    int row, col;
    if (ROWFAST) { row = tb % nrow; col = tb / nrow; }
    else         { col = tb % ncol; row = tb / ncol; }

    A    += (size_t)e * sA;
    Bt   += (size_t)e * sB;
    bias += (size_t)e * sBias;
    long long zC = (long long)e * sC;

    int rowBase = row * 128, colBase = col * TN;
    int t = threadIdx.x, lane = t & 63, wid = t >> 6;
    int wr = (wid >> 1) * 64, wc = (wid & 1) * (TN / 2);

    const unsigned short* Ag = A  + (size_t)rowBase * K;
    const unsigned short* Bg = Bt + (size_t)colBase * K;

    f32x4 acc[4][NFR] = {};
    int l15 = lane & 15, g = lane >> 4;

    for (int k0 = 0; k0 < K; k0 += 64) {
        __syncthreads();
#pragma unroll
        for (int cc = 0; cc < 4; ++cc) {
            int c = t + cc * 256;
            int r = c >> 3, sq = (c & 7) ^ (r & 7);
            GLL16(Ag + (size_t)r * K + k0 + sq * 8, &Al[c * 8]);
        }
#pragma unroll
        for (int cc = 0; cc < TN / 32; ++cc) {
            int c = t + cc * 256;
            int r = c >> 3, sq = (c & 7) ^ (r & 7);
            GLL16(Bg + (size_t)r * K + k0 + sq * 8, &Bl[c * 8]);
        }
        __syncthreads();

        bfrag b[2][NFR];
#pragma unroll
        for (int kk = 0; kk < 2; ++kk)
#pragma unroll
            for (int n = 0; n < NFR; ++n) {
                int rr = wc + n * 16 + l15;
                int q = ((kk << 2) | g) ^ (rr & 7);
                b[kk][n] = *(const bfrag*)&Bl[rr * 64 + q * 8];
            }
#pragma unroll
        for (int m = 0; m < 4; ++m) {
            int rr = wr + m * 16 + l15;
#pragma unroll
            for (int kk = 0; kk < 2; ++kk) {
                int q = ((kk << 2) | g) ^ (rr & 7);
                bfrag a = *(const bfrag*)&Al[rr * 64 + q * 8];
#pragma unroll
                for (int n = 0; n < NFR; ++n)
                    acc[m][n] = __builtin_amdgcn_mfma_f32_16x16x32_bf16(a, b[kk][n], acc[m][n], 0, 0, 0);
            }
        }
    }

    int g4 = g * 4;
#pragma unroll
    for (int m = 0; m < 4; ++m) {
        int row0 = rowBase + wr + m * 16 + g4;
#pragma unroll
        for (int n = 0; n < NFR; ++n) {
            int cc = colBase + wc + n * 16 + l15;
            float bv = bias[cc];
#pragma unroll
            for (int j = 0; j < 4; ++j) {
                float v = acc[m][n][j] + bv;
                if (RELU) v = fmaxf(v, 0.f);
                C[zC + (size_t)(row0 + j) * ldc + cc] = f2bf(v);
            }
        }
    }
}

// ---------------- transpose+convert fp32 [R][Cn] -> bf16 [Cn][R] (per z) ----------------
__global__ __launch_bounds__(256) void tcvt_kernel(const float* __restrict__ in,
    unsigned short* __restrict__ out, int R, int Cn)
{
    __shared__ unsigned short tile[64][68];
    size_t zoff = (size_t)blockIdx.z * R * Cn;
    in += zoff; out += zoff;
    int r0 = blockIdx.y * 64, c0 = blockIdx.x * 64;
    int tr = threadIdx.x >> 4, tc = (threadIdx.x & 15) * 4;
#pragma unroll
    for (int i = 0; i < 4; ++i) {
        int r = tr + i * 16;
        float4 v = *(const float4*)&in[(size_t)(r0 + r) * Cn + c0 + tc];
        tile[r][tc + 0] = f2bf(v.x);
        tile[r][tc + 1] = f2bf(v.y);
        tile[r][tc + 2] = f2bf(v.z);
        tile[r][tc + 3] = f2bf(v.w);
    }
    __syncthreads();
#pragma unroll
    for (int i = 0; i < 4; ++i) {
        int c = tr + i * 16;
        ushort4 w;
        w.x = tile[tc + 0][c];
        w.y = tile[tc + 1][c];
        w.z = tile[tc + 2][c];
        w.w = tile[tc + 3][c];
        *(ushort4*)&out[(size_t)(c0 + c) * R + r0 + tc] = w;
    }
}

// ---------------- router ----------------
__global__ __launch_bounds__(256) void router_kernel(
    const float* __restrict__ xf, const float* __restrict__ rw, const float* __restrict__ rb,
    const float* __restrict__ tmask,
    int* __restrict__ eidx, float* __restrict__ gate, int* __restrict__ valid,
    float* __restrict__ partials)
{
    int blk = blockIdx.x;
    int wid = threadIdx.x >> 6, lane = threadIdx.x & 63;
    __shared__ float wpart[4][10];
    float pe[8] = {0,0,0,0,0,0,0,0};
    float zacc = 0.f, nvacc = 0.f;

    for (int i = 0; i < 16; ++i) {
        int tok = blk * 64 + wid * 16 + i;
        const float* xrow = xf + (size_t)tok * DMODEL;
        float acc[8] = {0,0,0,0,0,0,0,0};
#pragma unroll 4
        for (int kk = 0; kk < 16; ++kk) {
            int d = lane + (kk << 6);
            float xd = xrow[d];
            const float4* rp = (const float4*)(rw + (size_t)d * 8);
            float4 r0 = rp[0], r1 = rp[1];
            acc[0] = fmaf(xd, r0.x, acc[0]); acc[1] = fmaf(xd, r0.y, acc[1]);
            acc[2] = fmaf(xd, r0.z, acc[2]); acc[3] = fmaf(xd, r0.w, acc[3]);
            acc[4] = fmaf(xd, r1.x, acc[4]); acc[5] = fmaf(xd, r1.y, acc[5]);
            acc[6] = fmaf(xd, r1.z, acc[6]); acc[7] = fmaf(xd, r1.w, acc[7]);
        }
#pragma unroll
        for (int e = 0; e < 8; ++e)
#pragma unroll
            for (int o = 1; o < 64; o <<= 1) acc[e] += __shfl_xor(acc[e], o, 64);
        if (lane == 0) {
            float l[8]; float m = -1e30f;
#pragma unroll
            for (int e = 0; e < 8; ++e) { l[e] = acc[e] + rb[e]; m = fmaxf(m, l[e]); }
            float se = 0.f;
#pragma unroll
            for (int e = 0; e < 8; ++e) se += expf(l[e] - m);
            int am = 0; float bm = l[0];
#pragma unroll
            for (int e = 1; e < 8; ++e) if (l[e] > bm) { bm = l[e]; am = e; }
            float inv_se = 1.0f / se;
            float g = expf(l[am] - m) * inv_se;
            float vld = (tmask[tok] > 0.f) ? 1.f : 0.f;
            eidx[tok] = am; gate[tok] = g; valid[tok] = (int)vld;
#pragma unroll
            for (int e = 0; e < 8; ++e) pe[e] += expf(l[e] - m) * inv_se * vld;
            float lse = logf(se) + m;
            zacc += lse * lse * vld;
            nvacc += vld;
        }
    }
    if (lane == 0) {
#pragma unroll
        for (int e = 0; e < 8; ++e) wpart[wid][e] = pe[e];
        wpart[wid][8] = zacc; wpart[wid][9] = nvacc;
    }
    __syncthreads();
    if (threadIdx.x == 0) {
        for (int j = 0; j < 10; ++j)
            partials[blk * 10 + j] = wpart[0][j] + wpart[1][j] + wpart[2][j] + wpart[3][j];
    }
}

// ---------------- capacity scan ----------------
__global__ __launch_bounds__(256) void scan_kernel(
    const int* __restrict__ eidx, const int* __restrict__ valid, const float* __restrict__ gate,
    int* __restrict__ pc, float* __restrict__ gk, int* __restrict__ keepf,
    int* __restrict__ counts)
{
    __shared__ int cnt[256][8];
    int tid = threadIdx.x;
    int local[8] = {0,0,0,0,0,0,0,0};
    int base = tid * 16;
    for (int i = 0; i < 16; ++i) { int e = eidx[base + i]; local[e] += valid[base + i]; }
#pragma unroll
    for (int e = 0; e < 8; ++e) cnt[tid][e] = local[e];
    __syncthreads();
    if (tid < 8) {
        int run = 0;
        for (int i = 0; i < 256; ++i) { int t = cnt[i][tid]; cnt[i][tid] = run; run += t; }
        counts[tid] = run;
    }
    __syncthreads();
    int off[8];
#pragma unroll
    for (int e = 0; e < 8; ++e) off[e] = cnt[tid][e];
    for (int i = 0; i < 16; ++i) {
        int tok = base + i;
        int e = eidx[tok], v = valid[tok];
        int pos = off[e]; off[e] += v;
        int kp = (v && pos < CAPE) ? 1 : 0;
        pc[tok]    = (pos < CAPE) ? pos : (CAPE - 1);
        keepf[tok] = kp;
        gk[tok]    = kp ? gate[tok] : 0.f;
    }
}

// ---------------- dispatch (expert-range) -> bf16 buffers ----------------
__global__ __launch_bounds__(256) void dispatch_bf16(const float* __restrict__ tln,
    const int* __restrict__ eidx, const int* __restrict__ pc, const int* __restrict__ keepf,
    unsigned short* __restrict__ buf, int e0, int ec)
{
    int tok = blockIdx.x;
    if (!keepf[tok]) return;
    int e = eidx[tok];
    if (e < e0 || e >= e0 + ec) return;
    int p = pc[tok];
    const float4 v = ((const float4*)(tln + (size_t)tok * DMODEL))[threadIdx.x];
    ushort4 o;
    o.x = f2bf(v.x); o.y = f2bf(v.y); o.z = f2bf(v.z); o.w = f2bf(v.w);
    ((ushort4*)(buf + ((size_t)(e - e0) * CAPE + p) * DMODEL))[threadIdx.x] = o;
}

// ---------------- combine add: out += gk * ob (bf16 ob) ----------------
__global__ __launch_bounds__(256) void combine_bf16(const unsigned short* __restrict__ ob,
    const int* __restrict__ eidx, const int* __restrict__ pc, const float* __restrict__ gk,
    float* __restrict__ out, int e0, int ec)
{
    int tok = blockIdx.x;
    int e = eidx[tok];
    if (e < e0 || e >= e0 + ec) return;
    float g = gk[tok];
    int p = pc[tok];
    float4* o = (float4*)(out + (size_t)tok * DMODEL);
    const ushort4 u = ((const ushort4*)(ob + ((size_t)(e - e0) * CAPE + p) * DMODEL))[threadIdx.x];
    float4 a = o[threadIdx.x];
    a.x += g * bf2f(u.x); a.y += g * bf2f(u.y);
    a.z += g * bf2f(u.z); a.w += g * bf2f(u.w);
    o[threadIdx.x] = a;
}

// ---------------- final scalar losses ----------------
__global__ __launch_bounds__(64) void loss_kernel(const float* __restrict__ partials,
    const int* __restrict__ counts, float* __restrict__ out2)
{
    int lane = threadIdx.x;
    float p[10];
#pragma unroll
    for (int j = 0; j < 10; ++j) p[j] = partials[lane * 10 + j];
#pragma unroll
    for (int j = 0; j < 10; ++j)
#pragma unroll
        for (int o = 1; o < 64; o <<= 1) p[j] += __shfl_xor(p[j], o, 64);
    if (lane == 0) {
        float nv = fmaxf(p[9], 1.f);
        float lb = 0.f;
        for (int e = 0; e < 8; ++e) lb += ((float)counts[e] / nv) * (p[e] / nv);
        lb *= (float)NEXP;
        out2[0] = lb;
        out2[1] = p[8] / nv;
    }
}

// ---------------- host launch ----------------
extern "C" void kernel_launch(void* const* d_in, const int* in_sizes, int n_in,
                              void* d_out, int out_size, void* d_ws, size_t ws_size,
                              hipStream_t stream)
{
    const float* tgt        = (const float*)d_in[0];
    const float* src        = (const float*)d_in[1];
    const float* token_mask = (const float*)d_in[5];
    const float* ln1w = (const float*)d_in[6],  *ln1b = (const float*)d_in[7];
    const float* self_in_w  = (const float*)d_in[8],  *self_in_b  = (const float*)d_in[9];
    const float* self_out_w = (const float*)d_in[10], *self_out_b = (const float*)d_in[11];
    const float* ln2w = (const float*)d_in[12], *ln2b = (const float*)d_in[13];
    const float* enc_in_w   = (const float*)d_in[14], *enc_in_b   = (const float*)d_in[15];
    const float* enc_out_w  = (const float*)d_in[16], *enc_out_b  = (const float*)d_in[17];
    const float* ln3w = (const float*)d_in[18], *ln3b = (const float*)d_in[19];
    const float* rw = (const float*)d_in[20], *rb = (const float*)d_in[21];
    const float* w1 = (const float*)d_in[22], *b1 = (const float*)d_in[23];
    const float* w2 = (const float*)d_in[24], *b2 = (const float*)d_in[25];

    float* out = (float*)d_out;          // residual stream lives HERE
    float* ws  = (float*)d_ws;

    // ---- fixed layout (floats) ----
    float* tln = ws;                         // 4,194,304
    float* ctx = ws + 4194304;               // 4,194,304 (ctx hi/lo f16)
    int*   eidxA   = (int*)(ws + 8388608);
    int*   validA  = eidxA + 4096;
    int*   pcA     = validA + 4096;
    int*   keepA   = pcA + 4096;
    int*   countsA = keepA + 4096;           // 16
    float* gateA   = (float*)(countsA + 16);
    float* gkA     = gateA + 4096;
    float* partA   = gkA + 4096;             // 640
    const size_t POOL_OFF = 8425984;         // floats
    float* pool = ws + POOL_OFF;

    size_t Wf = ws_size / sizeof(float);
    size_t pf = (Wf > POOL_OFF) ? (Wf - POOL_OFF) : 0;

    int bg, zc;
    if      (pf >= 25165824) { bg = 8; zc = 32; }
    else if (pf >= 24117248) { bg = 8; zc = 16; }
    else if (pf >= 13631488) { bg = 4; zc = 16; }
    else                     { bg = 2; zc = 16; }
    int ecs = 1;
    for (int c = 8; c >= 1; c >>= 1)
        if ((size_t)c * 3735552ull <= pf) { ecs = c; break; }
    int elog = (ecs == 8) ? 3 : (ecs == 4) ? 2 : (ecs == 2) ? 1 : 0;

    float* qreg = pool;
    float* vreg = qreg + (size_t)bg * 1572864;
    float* sreg = vreg + (size_t)bg * 524288;

    h16* tlnh = (h16*)tln;
    h16* tlnl = tlnh + 4194304;
    h16* ctxh = (h16*)ctx;
    h16* ctxl = ctxh + 4194304;

    // ================= self attention =================
    ln_kernel<1><<<NTOK, 256, 0, stream>>>(tgt, ln1w, ln1b, nullptr, tlnh, tlnl);

    for (int g0 = 0; g0 < BATCH; g0 += bg) {
        h16* sb  = (h16*)sreg;
        h16* whi = sb, *wlo = sb + 3145728;
        split_f16<<<1536, 256, 0, stream>>>(self_in_w, whi, wlo, 393216);

        h16* qkvh = (h16*)qreg, *qkvl = qkvh + (size_t)bg * 1572864;
        gemm_f16x2_nt<2><<<dim3(24, bg * 4, 1), 256, 0, stream>>>(
            tlnh + (size_t)g0 * 524288, tlnl + (size_t)g0 * 524288, 1024,
            whi, wlo, 1024, self_in_b, nullptr,
            nullptr, qkvh, qkvl, 1024, 3072);

        h16* vth = (h16*)vreg, *vtl = vth + (size_t)bg * 524288;
        vt_split<<<dim3(8, 1, bg * 16), 256, 0, stream>>>(qkvh + 2048, qkvl + 2048, 3072, vth, vtl);

        h16* sh = sb, *sl = sh + (size_t)zc * 262144;
        for (int c0 = 0; c0 < bg * 16; c0 += zc) {
            attn_qk<true><<<dim3(4, 4, zc), 256, 0, stream>>>(
                qkvh, qkvl, 3072, qkvh + 1024, qkvl + 1024, 3072, sh, sl, c0);
            attn_pv<true><<<dim3(8, 1, zc), 256, 0, stream>>>(
                sh, sl, vth + (size_t)c0 * 32768, vtl + (size_t)c0 * 32768,
                ctxh, ctxl, g0 * 16 + c0);
        }
    }
    {
        h16* sb = (h16*)sreg;
        h16* owhi = sb, *owlo = sb + 1048576;
        split_f16<<<512, 256, 0, stream>>>(self_out_w, owhi, owlo, 131072);
        gemm_f16x2_nt<1><<<dim3(8, 32, 1), 256, 0, stream>>>(
            ctxh, ctxl, 1024, owhi, owlo, 1024, self_out_b, tgt,
            out, nullptr, nullptr, 1024, 1024);
    }

    // ================= cross attention =================
    ln_kernel<1><<<NTOK, 256, 0, stream>>>(out, ln2w, ln2b, nullptr, tlnh, tlnl);

    for (int g0 = 0; g0 < BATCH; g0 += bg) {
        h16* sb  = (h16*)sreg;
        h16* shi = sb, *slo = sb + (size_t)bg * 524288;
        h16* ehi = sb + (size_t)bg * 1048576, *elo = ehi + 3145728;
        split_f16<<<bg * 256, 256, 0, stream>>>(src + (size_t)g0 * 524288, shi, slo, bg * 65536);
        split_f16<<<1536, 256, 0, stream>>>(enc_in_w, ehi, elo, 393216);

        h16* q2h  = (h16*)qreg,                 *q2l  = q2h + (size_t)bg * 524288;
        h16* kv2h = q2h + (size_t)bg * 1048576, *kv2l = kv2h + (size_t)bg * 1048576;
        gemm_f16x2_nt<2><<<dim3(8, bg * 4, 1), 256, 0, stream>>>(
            tlnh + (size_t)g0 * 524288, tlnl + (size_t)g0 * 524288, 1024,
            ehi, elo, 1024, enc_in_b, nullptr,
            nullptr, q2h, q2l, 1024, 1024);
        gemm_f16x2_nt<2><<<dim3(16, bg * 4, 1), 256, 0, stream>>>(
            shi, slo, 1024, ehi + 1048576, elo + 1048576, 1024, enc_in_b + 1024, nullptr,
            nullptr, kv2h, kv2l, 1024, 2048);

        h16* vth = (h16*)vreg, *vtl = vth + (size_t)bg * 524288;
        vt_split<<<dim3(8, 1, bg * 16), 256, 0, stream>>>(kv2h + 1024, kv2l + 1024, 2048, vth, vtl);

        h16* sh = sb, *sl = sh + (size_t)zc * 262144;
        for (int c0 = 0; c0 < bg * 16; c0 += zc) {
            attn_qk<false><<<dim3(4, 4, zc), 256, 0, stream>>>(
                q2h, q2l, 1024, kv2h, kv2l, 2048, sh, sl, c0);
            attn_pv<false><<<dim3(8, 1, zc), 256, 0, stream>>>(
                sh, sl, vth + (size_t)c0 * 32768, vtl + (size_t)c0 * 32768,
                ctxh, ctxl, g0 * 16 + c0);
        }
    }
    {
        h16* sb = (h16*)sreg;
        h16* owhi = sb, *owlo = sb + 1048576;
        split_f16<<<512, 256, 0, stream>>>(enc_out_w, owhi, owlo, 131072);
        gemm_f16x2_nt<1><<<dim3(8, 32, 1), 256, 0, stream>>>(
            ctxh, ctxl, 1024, owhi, owlo, 1024, enc_out_b, out,
            out, nullptr, nullptr, 1024, 1024);
    }

    // ================= MoE =================
    ln_kernel<0><<<NTOK, 256, 0, stream>>>(out, ln3w, ln3b, tln, nullptr, nullptr);
    router_kernel<<<64, 256, 0, stream>>>(tln, rw, rb, token_mask, eidxA, gateA, validA, partA);
    scan_kernel<<<1, 256, 0, stream>>>(eidxA, validA, gateA, pcA, gkA, keepA, countsA);

    for (int e0 = 0; e0 < NEXP; e0 += ecs) {
        unsigned short* wt   = (unsigned short*)pool;
        unsigned short* hB   = (unsigned short*)(pool + (size_t)ecs * 2097152);
        unsigned short* bufB = (unsigned short*)(pool + (size_t)ecs * 3407872);
        unsigned short* obB  = bufB;   // overlay: bufB dead after w1 GEMM

        tcvt_kernel<<<dim3(64, 16, ecs), 256, 0, stream>>>(
            w1 + (size_t)e0 * 4194304, wt, 1024, 4096);
        dispatch_bf16<<<NTOK, 256, 0, stream>>>(tln, eidxA, pcA, keepA, bufB, e0, ecs);
        gemm_bf16_moe<128, true, true><<<ecs * 5 * 32, 256, 0, stream>>>(
            bufB, wt, b1 + (size_t)e0 * 4096, hB,
            1024, 655360LL, 4194304LL, 2621440LL, 4096LL, 4096,
            ecs - 1, elog, 5, 32);

        tcvt_kernel<<<dim3(16, 64, ecs), 256, 0, stream>>>(
            w2 + (size_t)e0 * 4194304, wt, 4096, 1024);
        gemm_bf16_moe<64, false, false><<<ecs * 5 * 16, 256, 0, stream>>>(
            hB, wt, b2 + (size_t)e0 * 1024, obB,
            4096, 2621440LL, 4194304LL, 655360LL, 1024LL, 1024,
            ecs - 1, elog, 5, 16);

        combine_bf16<<<NTOK, 256, 0, stream>>>(obB, eidxA, pcA, gkA, out, e0, ecs);
    }

    // ===== losses =====
    loss_kernel<<<1, 64, 0, stream>>>(partA, countsA, out + (size_t)NTOK * DMODEL);
}

// Round 11
// 868.973 us; speedup vs baseline: 3.1152x; 1.0870x over previous
//
#include <hip/hip_runtime.h>
#include <cstdint>

// ---------------- problem constants ----------------
constexpr int BATCH  = 8;
constexpr int TSEQ   = 512;
constexpr int DMODEL = 1024;
constexpr int NEXP   = 8;
constexpr int CAPE   = 640;
constexpr int NTOK   = BATCH * TSEQ;        // 4096

typedef _Float16 h16;
typedef __attribute__((ext_vector_type(8))) short bfrag;
typedef __attribute__((ext_vector_type(8))) _Float16 hfrag;
typedef __attribute__((ext_vector_type(4))) float f32x4;

__device__ __forceinline__ unsigned short f2bf(float f) {
    uint32_t u = __float_as_uint(f);
    uint32_t r = (u + 0x7FFFu + ((u >> 16) & 1u)) >> 16;   // RNE
    return (unsigned short)r;
}
__device__ __forceinline__ float bf2f(unsigned short b) {
    return __uint_as_float((uint32_t)b << 16);
}

#define GLL16(SRC, DST) __builtin_amdgcn_global_load_lds( \
    (const __attribute__((address_space(1))) void*)(SRC), \
    (__attribute__((address_space(3))) void*)(DST), 16, 0, 0)

// ---------------- LayerNorm: MODE 0 -> fp32 out; MODE 1 -> f16 hi/lo out ----------------
template<int MODE>
__global__ __launch_bounds__(256) void ln_kernel(const float* __restrict__ in,
    const float* __restrict__ gw, const float* __restrict__ gb,
    float* __restrict__ out, h16* __restrict__ ohi, h16* __restrict__ olo)
{
    int row = blockIdx.x, tid = threadIdx.x;
    const float4 v = *(const float4*)(in + (size_t)row * DMODEL + tid * 4);
    float s  = v.x + v.y + v.z + v.w;
    float ss = v.x*v.x + v.y*v.y + v.z*v.z + v.w*v.w;
#pragma unroll
    for (int o = 1; o < 64; o <<= 1) { s += __shfl_xor(s, o, 64); ss += __shfl_xor(ss, o, 64); }
    __shared__ float rs[4], rss[4];
    int wid = tid >> 6, lane = tid & 63;
    if (lane == 0) { rs[wid] = s; rss[wid] = ss; }
    __syncthreads();
    s  = rs[0] + rs[1] + rs[2] + rs[3];
    ss = rss[0] + rss[1] + rss[2] + rss[3];
    float mean = s * (1.0f / DMODEL);
    float var  = ss * (1.0f / DMODEL) - mean * mean;
    float inv  = rsqrtf(var + 1e-5f);
    float4 w4 = *(const float4*)(gw + tid * 4);
    float4 b4 = *(const float4*)(gb + tid * 4);
    float o[4];
    o[0] = (v.x - mean) * inv * w4.x + b4.x;
    o[1] = (v.y - mean) * inv * w4.y + b4.y;
    o[2] = (v.z - mean) * inv * w4.z + b4.z;
    o[3] = (v.w - mean) * inv * w4.w + b4.w;
    if (MODE == 0) {
        float4 f = {o[0], o[1], o[2], o[3]};
        *(float4*)(out + (size_t)row * DMODEL + tid * 4) = f;
    } else {
        short4 hv, lv;
#pragma unroll
        for (int j = 0; j < 4; ++j) {
            h16 hh = (h16)o[j];
            ((h16*)&hv)[j] = hh;
            ((h16*)&lv)[j] = (h16)(o[j] - (float)hh);
        }
        *(short4*)(ohi + (size_t)row * DMODEL + tid * 4) = hv;
        *(short4*)(olo + (size_t)row * DMODEL + tid * 4) = lv;
    }
}

// ---------------- fp32 -> fp16 hi/lo split ----------------
__global__ __launch_bounds__(256) void split_f16(const float* __restrict__ in,
    h16* __restrict__ hi, h16* __restrict__ lo, int n8)
{
    int i = blockIdx.x * 256 + threadIdx.x;
    if (i >= n8) return;
    const float4* p = (const float4*)in + 2 * (size_t)i;
    float4 v0 = p[0], v1 = p[1];
    float vv[8] = {v0.x, v0.y, v0.z, v0.w, v1.x, v1.y, v1.z, v1.w};
    hfrag h, l;
#pragma unroll
    for (int j = 0; j < 8; ++j) {
        h16 hj = (h16)vv[j];
        h[j] = hj;
        l[j] = (h16)(vv[j] - (float)hj);
    }
    ((hfrag*)hi)[i] = h;
    ((hfrag*)lo)[i] = l;
}

// ---------------- fp16x2 (3-product) NT MFMA GEMM, BK=64 ----------------
template<int OMODE>
__global__ __launch_bounds__(256) void gemm_f16x2_nt(
    const h16* __restrict__ Ahi, const h16* __restrict__ Alo, int lda,
    const h16* __restrict__ Bhi, const h16* __restrict__ Blo, int ldb,
    const float* __restrict__ bias, const float* __restrict__ res,
    float* __restrict__ C, h16* __restrict__ Chi, h16* __restrict__ Clo,
    int K, int ldc)
{
    __shared__ h16 AhL[8192], AlL[8192], BhL[8192], BlL[8192];
    int rowBase = blockIdx.y * 128, colBase = blockIdx.x * 128;
    int t = threadIdx.x, lane = t & 63, wid = t >> 6;
    int wr = (wid >> 1) * 64, wc = (wid & 1) * 64;
    const h16* Ah = Ahi + (size_t)rowBase * lda;
    const h16* Al = Alo + (size_t)rowBase * lda;
    const h16* Bh = Bhi + (size_t)colBase * ldb;
    const h16* Bl = Blo + (size_t)colBase * ldb;
    f32x4 acc[4][4] = {};
    int l15 = lane & 15, g = lane >> 4;

    for (int k0 = 0; k0 < K; k0 += 64) {
        __syncthreads();
#pragma unroll
        for (int cc = 0; cc < 4; ++cc) {
            int c = t + cc * 256;
            int r = c >> 3, sq = (c & 7) ^ (r & 7);
            GLL16(Ah + (size_t)r * lda + k0 + sq * 8, &AhL[c * 8]);
            GLL16(Al + (size_t)r * lda + k0 + sq * 8, &AlL[c * 8]);
            GLL16(Bh + (size_t)r * ldb + k0 + sq * 8, &BhL[c * 8]);
            GLL16(Bl + (size_t)r * ldb + k0 + sq * 8, &BlL[c * 8]);
        }
        __syncthreads();

#pragma unroll
        for (int kk = 0; kk < 2; ++kk) {
            hfrag bh[4], bl[4];
#pragma unroll
            for (int n = 0; n < 4; ++n) {
                int rr = wc + n * 16 + l15;
                int q = ((kk << 2) | g) ^ (rr & 7);
                bh[n] = *(const hfrag*)&BhL[rr * 64 + q * 8];
                bl[n] = *(const hfrag*)&BlL[rr * 64 + q * 8];
            }
#pragma unroll
            for (int m = 0; m < 4; ++m) {
                int rr = wr + m * 16 + l15;
                int q = ((kk << 2) | g) ^ (rr & 7);
                hfrag ah = *(const hfrag*)&AhL[rr * 64 + q * 8];
                hfrag al = *(const hfrag*)&AlL[rr * 64 + q * 8];
#pragma unroll
                for (int n = 0; n < 4; ++n) {
                    acc[m][n] = __builtin_amdgcn_mfma_f32_16x16x32_f16(ah, bh[n], acc[m][n], 0, 0, 0);
                    acc[m][n] = __builtin_amdgcn_mfma_f32_16x16x32_f16(ah, bl[n], acc[m][n], 0, 0, 0);
                    acc[m][n] = __builtin_amdgcn_mfma_f32_16x16x32_f16(al, bh[n], acc[m][n], 0, 0, 0);
                }
            }
        }
    }

    int g4 = g * 4;
#pragma unroll
    for (int m = 0; m < 4; ++m) {
        int row0 = rowBase + wr + m * 16 + g4;
#pragma unroll
        for (int n = 0; n < 4; ++n) {
            int col = colBase + wc + n * 16 + l15;
            float bv = bias[col];
#pragma unroll
            for (int j = 0; j < 4; ++j) {
                float v = acc[m][n][j] + bv;
                if (OMODE == 1) v += res[(size_t)(row0 + j) * ldc + col];
                if (OMODE < 2) {
                    C[(size_t)(row0 + j) * ldc + col] = v;
                } else {
                    h16 hh = (h16)v;
                    Chi[(size_t)(row0 + j) * ldc + col] = hh;
                    Clo[(size_t)(row0 + j) * ldc + col] = (h16)(v - (float)hh);
                }
            }
        }
    }
}

// ---------------- attention QK^T (f16x2, K=64, strided heads) ----------------
template<bool CAUSAL>
__global__ __launch_bounds__(256) void attn_qk(
    const h16* __restrict__ Qh, const h16* __restrict__ Ql, int lda,
    const h16* __restrict__ Kh, const h16* __restrict__ Kl, int ldb,
    h16* __restrict__ Sh, h16* __restrict__ Sl, int zoff)
{
    int rowBase = blockIdx.y * 128, colBase = blockIdx.x * 128;
    if (CAUSAL && colBase >= rowBase + 128) return;
    __shared__ h16 AhL[4096], AlL[4096], BhL[4096], BlL[4096];
    int z = blockIdx.z;
    int bh_ = zoff + z, b = bh_ >> 4, h = bh_ & 15;
    const h16* Ah = Qh + (size_t)(b * 512 + rowBase) * lda + h * 64;
    const h16* Al = Ql + (size_t)(b * 512 + rowBase) * lda + h * 64;
    const h16* Bh = Kh + (size_t)(b * 512 + colBase) * ldb + h * 64;
    const h16* Bl = Kl + (size_t)(b * 512 + colBase) * ldb + h * 64;
    int t = threadIdx.x, lane = t & 63, wid = t >> 6;
    int wr = (wid >> 1) * 64, wc = (wid & 1) * 64;
    int c1 = t, c2 = t + 256;
    int r1 = c1 >> 2, q1 = (c1 & 3) ^ ((r1 + (r1 >> 2)) & 3);
    int r2 = c2 >> 2, q2 = (c2 & 3) ^ ((r2 + (r2 >> 2)) & 3);
    f32x4 acc[4][4] = {};
    int l15 = lane & 15, g = lane >> 4;

    for (int k0 = 0; k0 < 64; k0 += 32) {
        __syncthreads();
        GLL16(Ah + (size_t)r1 * lda + k0 + q1 * 8, &AhL[c1 * 8]);
        GLL16(Ah + (size_t)r2 * lda + k0 + q2 * 8, &AhL[c2 * 8]);
        GLL16(Al + (size_t)r1 * lda + k0 + q1 * 8, &AlL[c1 * 8]);
        GLL16(Al + (size_t)r2 * lda + k0 + q2 * 8, &AlL[c2 * 8]);
        GLL16(Bh + (size_t)r1 * ldb + k0 + q1 * 8, &BhL[c1 * 8]);
        GLL16(Bh + (size_t)r2 * ldb + k0 + q2 * 8, &BhL[c2 * 8]);
        GLL16(Bl + (size_t)r1 * ldb + k0 + q1 * 8, &BlL[c1 * 8]);
        GLL16(Bl + (size_t)r2 * ldb + k0 + q2 * 8, &BlL[c2 * 8]);
        __syncthreads();

        hfrag bh[4], bl[4];
#pragma unroll
        for (int n = 0; n < 4; ++n) {
            int row = wc + n * 16 + l15;
            int sw = (g ^ ((row + (row >> 2)) & 3)) * 8;
            bh[n] = *(const hfrag*)&BhL[row * 32 + sw];
            bl[n] = *(const hfrag*)&BlL[row * 32 + sw];
        }
#pragma unroll
        for (int m = 0; m < 4; ++m) {
            int row = wr + m * 16 + l15;
            int sw = (g ^ ((row + (row >> 2)) & 3)) * 8;
            hfrag ah = *(const hfrag*)&AhL[row * 32 + sw];
            hfrag al = *(const hfrag*)&AlL[row * 32 + sw];
#pragma unroll
            for (int n = 0; n < 4; ++n) {
                acc[m][n] = __builtin_amdgcn_mfma_f32_16x16x32_f16(ah, bh[n], acc[m][n], 0, 0, 0);
                acc[m][n] = __builtin_amdgcn_mfma_f32_16x16x32_f16(ah, bl[n], acc[m][n], 0, 0, 0);
                acc[m][n] = __builtin_amdgcn_mfma_f32_16x16x32_f16(al, bh[n], acc[m][n], 0, 0, 0);
            }
        }
    }

    size_t sbase = (size_t)z * 262144;
    int g4 = g * 4;
#pragma unroll
    for (int m = 0; m < 4; ++m) {
        int row0 = rowBase + wr + m * 16 + g4;
#pragma unroll
        for (int n = 0; n < 4; ++n) {
            int col = colBase + wc + n * 16 + l15;
#pragma unroll
            for (int j = 0; j < 4; ++j) {
                float v = acc[m][n][j] * 0.125f;
                h16 hh = (h16)v;
                Sh[sbase + (size_t)(row0 + j) * 512 + col] = hh;
                Sl[sbase + (size_t)(row0 + j) * 512 + col] = (h16)(v - (float)hh);
            }
        }
    }
}

// ---------------- fused softmax+PV ----------------
template<bool CAUSAL>
__global__ __launch_bounds__(256) void attn_pv(
    const h16* __restrict__ Shg, const h16* __restrict__ Slg,
    const h16* __restrict__ Vh, const h16* __restrict__ Vl,
    h16* __restrict__ Ch, h16* __restrict__ Cl, int bh0)
{
    __shared__ h16 ShL[4096], SlL[4096], VhL[4096], VlL[4096];
    __shared__ float mS[64], iS[64];
    int z = blockIdx.z, bh_ = bh0 + z;
    int rowBase = blockIdx.x * 64;
    const h16* Sa = Shg + (size_t)z * 262144 + (size_t)rowBase * 512;
    const h16* Sb = Slg + (size_t)z * 262144 + (size_t)rowBase * 512;
    const h16* Va = Vh + (size_t)z * 32768;
    const h16* Vb = Vl + (size_t)z * 32768;
    int t = threadIdx.x, lane = t & 63, wid = t >> 6;
    int l15 = lane & 15, g = lane >> 4;

    {
        int tr = t >> 2, tq = t & 3;
        int limit = CAUSAL ? (rowBase + tr + 1) : 512;
        float m = -1e30f, l = 0.f;
        const h16* rh = Sa + (size_t)tr * 512;
        const h16* rl = Sb + (size_t)tr * 512;
        for (int c = 0; c < 16; ++c) {
            int col0 = tq * 8 + c * 32;
            if (col0 >= limit) break;
            hfrag hv = *(const hfrag*)(rh + col0);
            hfrag lv = *(const hfrag*)(rl + col0);
            float s[8]; float cm = -1e30f;
#pragma unroll
            for (int j = 0; j < 8; ++j) {
                float sv = (float)hv[j] + (float)lv[j];
                s[j] = (col0 + j < limit) ? sv : -1e30f;
                cm = fmaxf(cm, s[j]);
            }
            if (cm > m) { l *= __expf(m - cm); m = cm; }
#pragma unroll
            for (int j = 0; j < 8; ++j) l += __expf(s[j] - m);
        }
#pragma unroll
        for (int o = 1; o < 4; o <<= 1) {
            float mo = __shfl_xor(m, o, 64);
            float lo2 = __shfl_xor(l, o, 64);
            float mc = fmaxf(m, mo);
            l = l * __expf(m - mc) + lo2 * __expf(mo - mc);
            m = mc;
        }
        if (tq == 0) { mS[tr] = m; iS[tr] = 1.0f / l; }
    }
    __syncthreads();

    int arow = wid * 16 + l15;
    float am = mS[arow], ai = iS[arow];
    int alim = CAUSAL ? (rowBase + arow + 1) : 512;
    int kend = CAUSAL ? (rowBase + 64) : 512;
    f32x4 acc[4] = {};

    for (int k0 = 0; k0 < kend; k0 += 64) {
        __syncthreads();
#pragma unroll
        for (int cc = 0; cc < 2; ++cc) {
            int c = t + cc * 256;
            int r = c >> 3, sq = (c & 7) ^ (r & 7);
            GLL16(Sa + (size_t)r * 512 + k0 + sq * 8, &ShL[c * 8]);
            GLL16(Sb + (size_t)r * 512 + k0 + sq * 8, &SlL[c * 8]);
            GLL16(Va + (size_t)r * 512 + k0 + sq * 8, &VhL[c * 8]);
            GLL16(Vb + (size_t)r * 512 + k0 + sq * 8, &VlL[c * 8]);
        }
        __syncthreads();

#pragma unroll
        for (int kk = 0; kk < 2; ++kk) {
            int chunk = (kk << 2) | g;
            int aq = chunk ^ (arow & 7);
            hfrag sh_ = *(const hfrag*)&ShL[arow * 64 + aq * 8];
            hfrag sl_ = *(const hfrag*)&SlL[arow * 64 + aq * 8];
            int cbase = k0 + chunk * 8;
            hfrag ph, pl;
#pragma unroll
            for (int j = 0; j < 8; ++j) {
                float s = (float)sh_[j] + (float)sl_[j];
                float p = __expf(s - am) * ai;
                p = (cbase + j < alim) ? p : 0.f;
                h16 hh = (h16)p;
                ph[j] = hh;
                pl[j] = (h16)(p - (float)hh);
            }
#pragma unroll
            for (int n = 0; n < 4; ++n) {
                int brow = n * 16 + l15;
                int bq = chunk ^ (brow & 7);
                hfrag bh = *(const hfrag*)&VhL[brow * 64 + bq * 8];
                hfrag bl = *(const hfrag*)&VlL[brow * 64 + bq * 8];
                acc[n] = __builtin_amdgcn_mfma_f32_16x16x32_f16(ph, bh, acc[n], 0, 0, 0);
                acc[n] = __builtin_amdgcn_mfma_f32_16x16x32_f16(ph, bl, acc[n], 0, 0, 0);
                acc[n] = __builtin_amdgcn_mfma_f32_16x16x32_f16(pl, bh, acc[n], 0, 0, 0);
            }
        }
    }

    int brow = (bh_ >> 4) * 512 + rowBase + wid * 16 + g * 4;
    int bcol = (bh_ & 15) * 64;
#pragma unroll
    for (int n = 0; n < 4; ++n) {
        int col = bcol + n * 16 + l15;
#pragma unroll
        for (int j = 0; j < 4; ++j) {
            float v = acc[n][j];
            h16 hh = (h16)v;
            Ch[(size_t)(brow + j) * 1024 + col] = hh;
            Cl[(size_t)(brow + j) * 1024 + col] = (h16)(v - (float)hh);
        }
    }
}

// ---------------- V-transpose ----------------
__global__ __launch_bounds__(256) void vt_split(
    const h16* __restrict__ inh, const h16* __restrict__ inl, int ld,
    h16* __restrict__ oh, h16* __restrict__ ol)
{
    __shared__ h16 tile[64][68];
    int z = blockIdx.z, b = z >> 4, h = z & 15;
    size_t ibase = ((size_t)b * 512 + blockIdx.x * 64) * ld + h * 64;
    size_t obase = (size_t)z * 32768 + blockIdx.x * 64;
    int tr = threadIdx.x >> 4, tc = (threadIdx.x & 15) * 4;
    const h16* src[2] = {inh, inl};
    h16* dst[2] = {oh, ol};
#pragma unroll
    for (int s = 0; s < 2; ++s) {
        __syncthreads();
#pragma unroll
        for (int i = 0; i < 4; ++i) {
            int tt = tr + i * 16;
            short4 v = *(const short4*)(src[s] + ibase + (size_t)tt * ld + tc);
            tile[tt][tc + 0] = ((h16*)&v)[0];
            tile[tt][tc + 1] = ((h16*)&v)[1];
            tile[tt][tc + 2] = ((h16*)&v)[2];
            tile[tt][tc + 3] = ((h16*)&v)[3];
        }
        __syncthreads();
#pragma unroll
        for (int i = 0; i < 4; ++i) {
            int d = tr + i * 16;
            h16 w[4] = {tile[tc + 0][d], tile[tc + 1][d], tile[tc + 2][d], tile[tc + 3][d]};
            *(short4*)(dst[s] + obase + (size_t)d * 512 + tc) = *(short4*)w;
        }
    }
}

// ---------------- bf16 NT MFMA GEMM (MoE), BK=64, flat grid, expert->XCD pinned ----------------
template<int TN, bool RELU, bool ROWFAST>
__global__ __launch_bounds__(256) void gemm_bf16_moe(
    const unsigned short* __restrict__ A,
    const unsigned short* __restrict__ Bt,
    const float* __restrict__ bias,
    unsigned short* __restrict__ C,
    int K, long long sA, long long sB, long long sC, long long sBias, int ldc,
    int emask, int elog, int nrow, int ncol)
{
    constexpr int NFR = TN / 32;
    __shared__ unsigned short Al[128 * 64];
    __shared__ unsigned short Bl[TN * 64];
    int id = blockIdx.x;
    int e = id & emask;
    int tb = id >> elog;
    int row, col;
    if (ROWFAST) { row = tb % nrow; col = tb / nrow; }
    else         { col = tb % ncol; row = tb / ncol; }

    A    += (size_t)e * sA;
    Bt   += (size_t)e * sB;
    bias += (size_t)e * sBias;
    long long zC = (long long)e * sC;

    int rowBase = row * 128, colBase = col * TN;
    int t = threadIdx.x, lane = t & 63, wid = t >> 6;
    int wr = (wid >> 1) * 64, wc = (wid & 1) * (TN / 2);

    const unsigned short* Ag = A  + (size_t)rowBase * K;
    const unsigned short* Bg = Bt + (size_t)colBase * K;

    f32x4 acc[4][NFR] = {};
    int l15 = lane & 15, g = lane >> 4;

    for (int k0 = 0; k0 < K; k0 += 64) {
        __syncthreads();
#pragma unroll
        for (int cc = 0; cc < 4; ++cc) {
            int c = t + cc * 256;
            int r = c >> 3, sq = (c & 7) ^ (r & 7);
            GLL16(Ag + (size_t)r * K + k0 + sq * 8, &Al[c * 8]);
        }
#pragma unroll
        for (int cc = 0; cc < TN / 32; ++cc) {
            int c = t + cc * 256;
            int r = c >> 3, sq = (c & 7) ^ (r & 7);
            GLL16(Bg + (size_t)r * K + k0 + sq * 8, &Bl[c * 8]);
        }
        __syncthreads();

        bfrag b[2][NFR];
#pragma unroll
        for (int kk = 0; kk < 2; ++kk)
#pragma unroll
            for (int n = 0; n < NFR; ++n) {
                int rr = wc + n * 16 + l15;
                int q = ((kk << 2) | g) ^ (rr & 7);
                b[kk][n] = *(const bfrag*)&Bl[rr * 64 + q * 8];
            }
#pragma unroll
        for (int m = 0; m < 4; ++m) {
            int rr = wr + m * 16 + l15;
#pragma unroll
            for (int kk = 0; kk < 2; ++kk) {
                int q = ((kk << 2) | g) ^ (rr & 7);
                bfrag a = *(const bfrag*)&Al[rr * 64 + q * 8];
#pragma unroll
                for (int n = 0; n < NFR; ++n)
                    acc[m][n] = __builtin_amdgcn_mfma_f32_16x16x32_bf16(a, b[kk][n], acc[m][n], 0, 0, 0);
            }
        }
    }

    int g4 = g * 4;
#pragma unroll
    for (int m = 0; m < 4; ++m) {
        int row0 = rowBase + wr + m * 16 + g4;
#pragma unroll
        for (int n = 0; n < NFR; ++n) {
            int cc = colBase + wc + n * 16 + l15;
            float bv = bias[cc];
#pragma unroll
            for (int j = 0; j < 4; ++j) {
                float v = acc[m][n][j] + bv;
                if (RELU) v = fmaxf(v, 0.f);
                C[zC + (size_t)(row0 + j) * ldc + cc] = f2bf(v);
            }
        }
    }
}

// ---------------- transpose+convert fp32 [R][Cn] -> bf16 [Cn][R] (per z) ----------------
__global__ __launch_bounds__(256) void tcvt_kernel(const float* __restrict__ in,
    unsigned short* __restrict__ out, int R, int Cn)
{
    __shared__ unsigned short tile[64][68];
    size_t zoff = (size_t)blockIdx.z * R * Cn;
    in += zoff; out += zoff;
    int r0 = blockIdx.y * 64, c0 = blockIdx.x * 64;
    int tr = threadIdx.x >> 4, tc = (threadIdx.x & 15) * 4;
#pragma unroll
    for (int i = 0; i < 4; ++i) {
        int r = tr + i * 16;
        float4 v = *(const float4*)&in[(size_t)(r0 + r) * Cn + c0 + tc];
        tile[r][tc + 0] = f2bf(v.x);
        tile[r][tc + 1] = f2bf(v.y);
        tile[r][tc + 2] = f2bf(v.z);
        tile[r][tc + 3] = f2bf(v.w);
    }
    __syncthreads();
#pragma unroll
    for (int i = 0; i < 4; ++i) {
        int c = tr + i * 16;
        ushort4 w;
        w.x = tile[tc + 0][c];
        w.y = tile[tc + 1][c];
        w.z = tile[tc + 2][c];
        w.w = tile[tc + 3][c];
        *(ushort4*)&out[(size_t)(c0 + c) * R + r0 + tc] = w;
    }
}

// ---------------- router: 1024 blocks, one wave per token ----------------
__global__ __launch_bounds__(256) void router_kernel(
    const float* __restrict__ xf, const float* __restrict__ rw, const float* __restrict__ rb,
    const float* __restrict__ tmask,
    int* __restrict__ eidx, float* __restrict__ gate, int* __restrict__ valid,
    float* __restrict__ partials)
{
    int wid = threadIdx.x >> 6, lane = threadIdx.x & 63;
    int tok = blockIdx.x * 4 + wid;
    __shared__ float wpart[4][10];

    const float* xrow = xf + (size_t)tok * DMODEL;
    float acc[8] = {0,0,0,0,0,0,0,0};
#pragma unroll 4
    for (int kk = 0; kk < 16; ++kk) {
        int d = lane + (kk << 6);
        float xd = xrow[d];
        const float4* rp = (const float4*)(rw + (size_t)d * 8);
        float4 r0 = rp[0], r1 = rp[1];
        acc[0] = fmaf(xd, r0.x, acc[0]); acc[1] = fmaf(xd, r0.y, acc[1]);
        acc[2] = fmaf(xd, r0.z, acc[2]); acc[3] = fmaf(xd, r0.w, acc[3]);
        acc[4] = fmaf(xd, r1.x, acc[4]); acc[5] = fmaf(xd, r1.y, acc[5]);
        acc[6] = fmaf(xd, r1.z, acc[6]); acc[7] = fmaf(xd, r1.w, acc[7]);
    }
#pragma unroll
    for (int e = 0; e < 8; ++e)
#pragma unroll
        for (int o = 1; o < 64; o <<= 1) acc[e] += __shfl_xor(acc[e], o, 64);

    if (lane == 0) {
        float l[8]; float m = -1e30f;
#pragma unroll
        for (int e = 0; e < 8; ++e) { l[e] = acc[e] + rb[e]; m = fmaxf(m, l[e]); }
        float se = 0.f;
#pragma unroll
        for (int e = 0; e < 8; ++e) se += expf(l[e] - m);
        int am = 0; float bm = l[0];
#pragma unroll
        for (int e = 1; e < 8; ++e) if (l[e] > bm) { bm = l[e]; am = e; }
        float inv_se = 1.0f / se;
        float g = expf(l[am] - m) * inv_se;
        float vld = (tmask[tok] > 0.f) ? 1.f : 0.f;
        eidx[tok] = am; gate[tok] = g; valid[tok] = (int)vld;
#pragma unroll
        for (int e = 0; e < 8; ++e) wpart[wid][e] = expf(l[e] - m) * inv_se * vld;
        float lse = logf(se) + m;
        wpart[wid][8] = lse * lse * vld;
        wpart[wid][9] = vld;
    }
    __syncthreads();
    if (threadIdx.x == 0) {
        for (int j = 0; j < 10; ++j)
            partials[blockIdx.x * 10 + j] = wpart[0][j] + wpart[1][j] + wpart[2][j] + wpart[3][j];
    }
}

// ---------------- capacity scan ----------------
__global__ __launch_bounds__(256) void scan_kernel(
    const int* __restrict__ eidx, const int* __restrict__ valid, const float* __restrict__ gate,
    int* __restrict__ pc, float* __restrict__ gk, int* __restrict__ keepf,
    int* __restrict__ counts)
{
    __shared__ int cnt[256][8];
    int tid = threadIdx.x;
    int local[8] = {0,0,0,0,0,0,0,0};
    int base = tid * 16;
    for (int i = 0; i < 16; ++i) { int e = eidx[base + i]; local[e] += valid[base + i]; }
#pragma unroll
    for (int e = 0; e < 8; ++e) cnt[tid][e] = local[e];
    __syncthreads();
    if (tid < 8) {
        int run = 0;
        for (int i = 0; i < 256; ++i) { int t = cnt[i][tid]; cnt[i][tid] = run; run += t; }
        counts[tid] = run;
    }
    __syncthreads();
    int off[8];
#pragma unroll
    for (int e = 0; e < 8; ++e) off[e] = cnt[tid][e];
    for (int i = 0; i < 16; ++i) {
        int tok = base + i;
        int e = eidx[tok], v = valid[tok];
        int pos = off[e]; off[e] += v;
        int kp = (v && pos < CAPE) ? 1 : 0;
        pc[tok]    = (pos < CAPE) ? pos : (CAPE - 1);
        keepf[tok] = kp;
        gk[tok]    = kp ? gate[tok] : 0.f;
    }
}

// ---------------- dispatch (expert-range) -> bf16 buffers ----------------
__global__ __launch_bounds__(256) void dispatch_bf16(const float* __restrict__ tln,
    const int* __restrict__ eidx, const int* __restrict__ pc, const int* __restrict__ keepf,
    unsigned short* __restrict__ buf, int e0, int ec)
{
    int tok = blockIdx.x;
    if (!keepf[tok]) return;
    int e = eidx[tok];
    if (e < e0 || e >= e0 + ec) return;
    int p = pc[tok];
    const float4 v = ((const float4*)(tln + (size_t)tok * DMODEL))[threadIdx.x];
    ushort4 o;
    o.x = f2bf(v.x); o.y = f2bf(v.y); o.z = f2bf(v.z); o.w = f2bf(v.w);
    ((ushort4*)(buf + ((size_t)(e - e0) * CAPE + p) * DMODEL))[threadIdx.x] = o;
}

// ---------------- combine add: out += gk * ob (bf16 ob) ----------------
__global__ __launch_bounds__(256) void combine_bf16(const unsigned short* __restrict__ ob,
    const int* __restrict__ eidx, const int* __restrict__ pc, const float* __restrict__ gk,
    float* __restrict__ out, int e0, int ec)
{
    int tok = blockIdx.x;
    int e = eidx[tok];
    if (e < e0 || e >= e0 + ec) return;
    float g = gk[tok];
    int p = pc[tok];
    float4* o = (float4*)(out + (size_t)tok * DMODEL);
    const ushort4 u = ((const ushort4*)(ob + ((size_t)(e - e0) * CAPE + p) * DMODEL))[threadIdx.x];
    float4 a = o[threadIdx.x];
    a.x += g * bf2f(u.x); a.y += g * bf2f(u.y);
    a.z += g * bf2f(u.z); a.w += g * bf2f(u.w);
    o[threadIdx.x] = a;
}

// ---------------- final scalar losses (1024 partials, 16/lane) ----------------
__global__ __launch_bounds__(64) void loss_kernel(const float* __restrict__ partials,
    const int* __restrict__ counts, float* __restrict__ out2)
{
    int lane = threadIdx.x;
    float p[10] = {0,0,0,0,0,0,0,0,0,0};
    for (int r = 0; r < 16; ++r) {
        const float* row = partials + ((size_t)lane * 16 + r) * 10;
#pragma unroll
        for (int j = 0; j < 10; ++j) p[j] += row[j];
    }
#pragma unroll
    for (int j = 0; j < 10; ++j)
#pragma unroll
        for (int o = 1; o < 64; o <<= 1) p[j] += __shfl_xor(p[j], o, 64);
    if (lane == 0) {
        float nv = fmaxf(p[9], 1.f);
        float lb = 0.f;
        for (int e = 0; e < 8; ++e) lb += ((float)counts[e] / nv) * (p[e] / nv);
        lb *= (float)NEXP;
        out2[0] = lb;
        out2[1] = p[8] / nv;
    }
}

// ---------------- host launch ----------------
extern "C" void kernel_launch(void* const* d_in, const int* in_sizes, int n_in,
                              void* d_out, int out_size, void* d_ws, size_t ws_size,
                              hipStream_t stream)
{
    const float* tgt        = (const float*)d_in[0];
    const float* src        = (const float*)d_in[1];
    const float* token_mask = (const float*)d_in[5];
    const float* ln1w = (const float*)d_in[6],  *ln1b = (const float*)d_in[7];
    const float* self_in_w  = (const float*)d_in[8],  *self_in_b  = (const float*)d_in[9];
    const float* self_out_w = (const float*)d_in[10], *self_out_b = (const float*)d_in[11];
    const float* ln2w = (const float*)d_in[12], *ln2b = (const float*)d_in[13];
    const float* enc_in_w   = (const float*)d_in[14], *enc_in_b   = (const float*)d_in[15];
    const float* enc_out_w  = (const float*)d_in[16], *enc_out_b  = (const float*)d_in[17];
    const float* ln3w = (const float*)d_in[18], *ln3b = (const float*)d_in[19];
    const float* rw = (const float*)d_in[20], *rb = (const float*)d_in[21];
    const float* w1 = (const float*)d_in[22], *b1 = (const float*)d_in[23];
    const float* w2 = (const float*)d_in[24], *b2 = (const float*)d_in[25];

    float* out = (float*)d_out;          // residual stream lives HERE
    float* ws  = (float*)d_ws;

    // ---- fixed layout (floats) ----
    float* tln = ws;                         // 4,194,304
    float* ctx = ws + 4194304;               // 4,194,304 (ctx hi/lo f16)
    int*   eidxA   = (int*)(ws + 8388608);
    int*   validA  = eidxA + 4096;
    int*   pcA     = validA + 4096;
    int*   keepA   = pcA + 4096;
    int*   countsA = keepA + 4096;           // 16
    float* gateA   = (float*)(countsA + 16);
    float* gkA     = gateA + 4096;
    float* partA   = gkA + 4096;             // 1024*10
    const size_t POOL_OFF = 8425984;         // floats
    float* pool = ws + POOL_OFF;

    size_t Wf = ws_size / sizeof(float);
    size_t pf = (Wf > POOL_OFF) ? (Wf - POOL_OFF) : 0;

    int bg, zc;
    if      (pf >= 25165824) { bg = 8; zc = 32; }
    else if (pf >= 24117248) { bg = 8; zc = 16; }
    else if (pf >= 13631488) { bg = 4; zc = 16; }
    else                     { bg = 2; zc = 16; }
    int ecs = 1;
    for (int c = 8; c >= 1; c >>= 1)
        if ((size_t)c * 3735552ull <= pf) { ecs = c; break; }
    int elog = (ecs == 8) ? 3 : (ecs == 4) ? 2 : (ecs == 2) ? 1 : 0;

    float* qreg = pool;
    float* vreg = qreg + (size_t)bg * 1572864;
    float* sreg = vreg + (size_t)bg * 524288;

    h16* tlnh = (h16*)tln;
    h16* tlnl = tlnh + 4194304;
    h16* ctxh = (h16*)ctx;
    h16* ctxl = ctxh + 4194304;

    // ================= self attention =================
    ln_kernel<1><<<NTOK, 256, 0, stream>>>(tgt, ln1w, ln1b, nullptr, tlnh, tlnl);

    for (int g0 = 0; g0 < BATCH; g0 += bg) {
        h16* sb  = (h16*)sreg;
        h16* whi = sb, *wlo = sb + 3145728;
        split_f16<<<1536, 256, 0, stream>>>(self_in_w, whi, wlo, 393216);

        h16* qkvh = (h16*)qreg, *qkvl = qkvh + (size_t)bg * 1572864;
        gemm_f16x2_nt<2><<<dim3(24, bg * 4, 1), 256, 0, stream>>>(
            tlnh + (size_t)g0 * 524288, tlnl + (size_t)g0 * 524288, 1024,
            whi, wlo, 1024, self_in_b, nullptr,
            nullptr, qkvh, qkvl, 1024, 3072);

        h16* vth = (h16*)vreg, *vtl = vth + (size_t)bg * 524288;
        vt_split<<<dim3(8, 1, bg * 16), 256, 0, stream>>>(qkvh + 2048, qkvl + 2048, 3072, vth, vtl);

        h16* sh = sb, *sl = sh + (size_t)zc * 262144;
        for (int c0 = 0; c0 < bg * 16; c0 += zc) {
            attn_qk<true><<<dim3(4, 4, zc), 256, 0, stream>>>(
                qkvh, qkvl, 3072, qkvh + 1024, qkvl + 1024, 3072, sh, sl, c0);
            attn_pv<true><<<dim3(8, 1, zc), 256, 0, stream>>>(
                sh, sl, vth + (size_t)c0 * 32768, vtl + (size_t)c0 * 32768,
                ctxh, ctxl, g0 * 16 + c0);
        }
    }
    {
        h16* sb = (h16*)sreg;
        h16* owhi = sb, *owlo = sb + 1048576;
        split_f16<<<512, 256, 0, stream>>>(self_out_w, owhi, owlo, 131072);
        gemm_f16x2_nt<1><<<dim3(8, 32, 1), 256, 0, stream>>>(
            ctxh, ctxl, 1024, owhi, owlo, 1024, self_out_b, tgt,
            out, nullptr, nullptr, 1024, 1024);
    }

    // ================= cross attention =================
    ln_kernel<1><<<NTOK, 256, 0, stream>>>(out, ln2w, ln2b, nullptr, tlnh, tlnl);

    for (int g0 = 0; g0 < BATCH; g0 += bg) {
        h16* sb  = (h16*)sreg;
        h16* shi = sb, *slo = sb + (size_t)bg * 524288;
        h16* ehi = sb + (size_t)bg * 1048576, *elo = ehi + 3145728;
        split_f16<<<bg * 256, 256, 0, stream>>>(src + (size_t)g0 * 524288, shi, slo, bg * 65536);
        split_f16<<<1536, 256, 0, stream>>>(enc_in_w, ehi, elo, 393216);

        h16* q2h  = (h16*)qreg,                 *q2l  = q2h + (size_t)bg * 524288;
        h16* kv2h = q2h + (size_t)bg * 1048576, *kv2l = kv2h + (size_t)bg * 1048576;
        gemm_f16x2_nt<2><<<dim3(8, bg * 4, 1), 256, 0, stream>>>(
            tlnh + (size_t)g0 * 524288, tlnl + (size_t)g0 * 524288, 1024,
            ehi, elo, 1024, enc_in_b, nullptr,
            nullptr, q2h, q2l, 1024, 1024);
        gemm_f16x2_nt<2><<<dim3(16, bg * 4, 1), 256, 0, stream>>>(
            shi, slo, 1024, ehi + 1048576, elo + 1048576, 1024, enc_in_b + 1024, nullptr,
            nullptr, kv2h, kv2l, 1024, 2048);

        h16* vth = (h16*)vreg, *vtl = vth + (size_t)bg * 524288;
        vt_split<<<dim3(8, 1, bg * 16), 256, 0, stream>>>(kv2h + 1024, kv2l + 1024, 2048, vth, vtl);

        h16* sh = sb, *sl = sh + (size_t)zc * 262144;
        for (int c0 = 0; c0 < bg * 16; c0 += zc) {
            attn_qk<false><<<dim3(4, 4, zc), 256, 0, stream>>>(
                q2h, q2l, 1024, kv2h, kv2l, 2048, sh, sl, c0);
            attn_pv<false><<<dim3(8, 1, zc), 256, 0, stream>>>(
                sh, sl, vth + (size_t)c0 * 32768, vtl + (size_t)c0 * 32768,
                ctxh, ctxl, g0 * 16 + c0);
        }
    }
    {
        h16* sb = (h16*)sreg;
        h16* owhi = sb, *owlo = sb + 1048576;
        split_f16<<<512, 256, 0, stream>>>(enc_out_w, owhi, owlo, 131072);
        gemm_f16x2_nt<1><<<dim3(8, 32, 1), 256, 0, stream>>>(
            ctxh, ctxl, 1024, owhi, owlo, 1024, enc_out_b, out,
            out, nullptr, nullptr, 1024, 1024);
    }

    // ================= MoE =================
    ln_kernel<0><<<NTOK, 256, 0, stream>>>(out, ln3w, ln3b, tln, nullptr, nullptr);
    router_kernel<<<1024, 256, 0, stream>>>(tln, rw, rb, token_mask, eidxA, gateA, validA, partA);
    scan_kernel<<<1, 256, 0, stream>>>(eidxA, validA, gateA, pcA, gkA, keepA, countsA);

    for (int e0 = 0; e0 < NEXP; e0 += ecs) {
        unsigned short* wt   = (unsigned short*)pool;
        unsigned short* hB   = (unsigned short*)(pool + (size_t)ecs * 2097152);
        unsigned short* bufB = (unsigned short*)(pool + (size_t)ecs * 3407872);
        unsigned short* obB  = bufB;   // overlay: bufB dead after w1 GEMM

        tcvt_kernel<<<dim3(64, 16, ecs), 256, 0, stream>>>(
            w1 + (size_t)e0 * 4194304, wt, 1024, 4096);
        dispatch_bf16<<<NTOK, 256, 0, stream>>>(tln, eidxA, pcA, keepA, bufB, e0, ecs);
        gemm_bf16_moe<128, true, true><<<ecs * 5 * 32, 256, 0, stream>>>(
            bufB, wt, b1 + (size_t)e0 * 4096, hB,
            1024, 655360LL, 4194304LL, 2621440LL, 4096LL, 4096,
            ecs - 1, elog, 5, 32);

        tcvt_kernel<<<dim3(16, 64, ecs), 256, 0, stream>>>(
            w2 + (size_t)e0 * 4194304, wt, 4096, 1024);
        gemm_bf16_moe<64, false, false><<<ecs * 5 * 16, 256, 0, stream>>>(
            hB, wt, b2 + (size_t)e0 * 1024, obB,
            4096, 2621440LL, 4194304LL, 655360LL, 1024LL, 1024,
            ecs - 1, elog, 5, 16);

        combine_bf16<<<NTOK, 256, 0, stream>>>(obB, eidxA, pcA, gkA, out, e0, ecs);
    }

    // ===== losses =====
    loss_kernel<<<1, 64, 0, stream>>>(partA, countsA, out + (size_t)NTOK * DMODEL);
}

// Round 12
// 838.652 us; speedup vs baseline: 3.2278x; 1.0362x over previous
//
#include <hip/hip_runtime.h>
#include <cstdint>

// ---------------- problem constants ----------------
constexpr int BATCH  = 8;
constexpr int TSEQ   = 512;
constexpr int DMODEL = 1024;
constexpr int NEXP   = 8;
constexpr int CAPE   = 640;
constexpr int NTOK   = BATCH * TSEQ;        // 4096

typedef _Float16 h16;
typedef __attribute__((ext_vector_type(8))) short bfrag;
typedef __attribute__((ext_vector_type(8))) _Float16 hfrag;
typedef __attribute__((ext_vector_type(4))) float f32x4;

__device__ __forceinline__ unsigned short f2bf(float f) {
    uint32_t u = __float_as_uint(f);
    uint32_t r = (u + 0x7FFFu + ((u >> 16) & 1u)) >> 16;   // RNE
    return (unsigned short)r;
}
__device__ __forceinline__ float bf2f(unsigned short b) {
    return __uint_as_float((uint32_t)b << 16);
}

#define GLL16(SRC, DST) __builtin_amdgcn_global_load_lds( \
    (const __attribute__((address_space(1))) void*)(SRC), \
    (__attribute__((address_space(3))) void*)(DST), 16, 0, 0)

// ---------------- LayerNorm: MODE 0 -> fp32 out; MODE 1 -> f16 hi/lo out ----------------
template<int MODE>
__global__ __launch_bounds__(256) void ln_kernel(const float* __restrict__ in,
    const float* __restrict__ gw, const float* __restrict__ gb,
    float* __restrict__ out, h16* __restrict__ ohi, h16* __restrict__ olo)
{
    int row = blockIdx.x, tid = threadIdx.x;
    const float4 v = *(const float4*)(in + (size_t)row * DMODEL + tid * 4);
    float s  = v.x + v.y + v.z + v.w;
    float ss = v.x*v.x + v.y*v.y + v.z*v.z + v.w*v.w;
#pragma unroll
    for (int o = 1; o < 64; o <<= 1) { s += __shfl_xor(s, o, 64); ss += __shfl_xor(ss, o, 64); }
    __shared__ float rs[4], rss[4];
    int wid = tid >> 6, lane = tid & 63;
    if (lane == 0) { rs[wid] = s; rss[wid] = ss; }
    __syncthreads();
    s  = rs[0] + rs[1] + rs[2] + rs[3];
    ss = rss[0] + rss[1] + rss[2] + rss[3];
    float mean = s * (1.0f / DMODEL);
    float var  = ss * (1.0f / DMODEL) - mean * mean;
    float inv  = rsqrtf(var + 1e-5f);
    float4 w4 = *(const float4*)(gw + tid * 4);
    float4 b4 = *(const float4*)(gb + tid * 4);
    float o[4];
    o[0] = (v.x - mean) * inv * w4.x + b4.x;
    o[1] = (v.y - mean) * inv * w4.y + b4.y;
    o[2] = (v.z - mean) * inv * w4.z + b4.z;
    o[3] = (v.w - mean) * inv * w4.w + b4.w;
    if (MODE == 0) {
        float4 f = {o[0], o[1], o[2], o[3]};
        *(float4*)(out + (size_t)row * DMODEL + tid * 4) = f;
    } else {
        short4 hv, lv;
#pragma unroll
        for (int j = 0; j < 4; ++j) {
            h16 hh = (h16)o[j];
            ((h16*)&hv)[j] = hh;
            ((h16*)&lv)[j] = (h16)(o[j] - (float)hh);
        }
        *(short4*)(ohi + (size_t)row * DMODEL + tid * 4) = hv;
        *(short4*)(olo + (size_t)row * DMODEL + tid * 4) = lv;
    }
}

// ---------------- fp32 -> fp16 hi/lo split ----------------
__global__ __launch_bounds__(256) void split_f16(const float* __restrict__ in,
    h16* __restrict__ hi, h16* __restrict__ lo, int n8)
{
    int i = blockIdx.x * 256 + threadIdx.x;
    if (i >= n8) return;
    const float4* p = (const float4*)in + 2 * (size_t)i;
    float4 v0 = p[0], v1 = p[1];
    float vv[8] = {v0.x, v0.y, v0.z, v0.w, v1.x, v1.y, v1.z, v1.w};
    hfrag h, l;
#pragma unroll
    for (int j = 0; j < 8; ++j) {
        h16 hj = (h16)vv[j];
        h[j] = hj;
        l[j] = (h16)(vv[j] - (float)hj);
    }
    ((hfrag*)hi)[i] = h;
    ((hfrag*)lo)[i] = l;
}

// ---------------- fp16x2 (3-product) NT MFMA GEMM, BK=64 ----------------
template<int OMODE>
__global__ __launch_bounds__(256) void gemm_f16x2_nt(
    const h16* __restrict__ Ahi, const h16* __restrict__ Alo, int lda,
    const h16* __restrict__ Bhi, const h16* __restrict__ Blo, int ldb,
    const float* __restrict__ bias, const float* __restrict__ res,
    float* __restrict__ C, h16* __restrict__ Chi, h16* __restrict__ Clo,
    int K, int ldc)
{
    __shared__ h16 AhL[8192], AlL[8192], BhL[8192], BlL[8192];
    int rowBase = blockIdx.y * 128, colBase = blockIdx.x * 128;
    int t = threadIdx.x, lane = t & 63, wid = t >> 6;
    int wr = (wid >> 1) * 64, wc = (wid & 1) * 64;
    const h16* Ah = Ahi + (size_t)rowBase * lda;
    const h16* Al = Alo + (size_t)rowBase * lda;
    const h16* Bh = Bhi + (size_t)colBase * ldb;
    const h16* Bl = Blo + (size_t)colBase * ldb;
    f32x4 acc[4][4] = {};
    int l15 = lane & 15, g = lane >> 4;

    for (int k0 = 0; k0 < K; k0 += 64) {
        __syncthreads();
#pragma unroll
        for (int cc = 0; cc < 4; ++cc) {
            int c = t + cc * 256;
            int r = c >> 3, sq = (c & 7) ^ (r & 7);
            GLL16(Ah + (size_t)r * lda + k0 + sq * 8, &AhL[c * 8]);
            GLL16(Al + (size_t)r * lda + k0 + sq * 8, &AlL[c * 8]);
            GLL16(Bh + (size_t)r * ldb + k0 + sq * 8, &BhL[c * 8]);
            GLL16(Bl + (size_t)r * ldb + k0 + sq * 8, &BlL[c * 8]);
        }
        __syncthreads();

#pragma unroll
        for (int kk = 0; kk < 2; ++kk) {
            hfrag bh[4], bl[4];
#pragma unroll
            for (int n = 0; n < 4; ++n) {
                int rr = wc + n * 16 + l15;
                int q = ((kk << 2) | g) ^ (rr & 7);
                bh[n] = *(const hfrag*)&BhL[rr * 64 + q * 8];
                bl[n] = *(const hfrag*)&BlL[rr * 64 + q * 8];
            }
#pragma unroll
            for (int m = 0; m < 4; ++m) {
                int rr = wr + m * 16 + l15;
                int q = ((kk << 2) | g) ^ (rr & 7);
                hfrag ah = *(const hfrag*)&AhL[rr * 64 + q * 8];
                hfrag al = *(const hfrag*)&AlL[rr * 64 + q * 8];
#pragma unroll
                for (int n = 0; n < 4; ++n) {
                    acc[m][n] = __builtin_amdgcn_mfma_f32_16x16x32_f16(ah, bh[n], acc[m][n], 0, 0, 0);
                    acc[m][n] = __builtin_amdgcn_mfma_f32_16x16x32_f16(ah, bl[n], acc[m][n], 0, 0, 0);
                    acc[m][n] = __builtin_amdgcn_mfma_f32_16x16x32_f16(al, bh[n], acc[m][n], 0, 0, 0);
                }
            }
        }
    }

    int g4 = g * 4;
#pragma unroll
    for (int m = 0; m < 4; ++m) {
        int row0 = rowBase + wr + m * 16 + g4;
#pragma unroll
        for (int n = 0; n < 4; ++n) {
            int col = colBase + wc + n * 16 + l15;
            float bv = bias[col];
#pragma unroll
            for (int j = 0; j < 4; ++j) {
                float v = acc[m][n][j] + bv;
                if (OMODE == 1) v += res[(size_t)(row0 + j) * ldc + col];
                if (OMODE < 2) {
                    C[(size_t)(row0 + j) * ldc + col] = v;
                } else {
                    h16 hh = (h16)v;
                    Chi[(size_t)(row0 + j) * ldc + col] = hh;
                    Clo[(size_t)(row0 + j) * ldc + col] = (h16)(v - (float)hh);
                }
            }
        }
    }
}

// ---------------- attention QK^T (f16x2, K=64 single step, strided heads) ----------------
template<bool CAUSAL>
__global__ __launch_bounds__(256) void attn_qk(
    const h16* __restrict__ Qh, const h16* __restrict__ Ql, int lda,
    const h16* __restrict__ Kh, const h16* __restrict__ Kl, int ldb,
    h16* __restrict__ Sh, h16* __restrict__ Sl, int zoff)
{
    int rowBase = blockIdx.y * 128, colBase = blockIdx.x * 128;
    if (CAUSAL && colBase >= rowBase + 128) return;
    __shared__ h16 AhL[8192], AlL[8192], BhL[8192], BlL[8192];
    int z = blockIdx.z;
    int bh_ = zoff + z, b = bh_ >> 4, h = bh_ & 15;
    const h16* Ah = Qh + (size_t)(b * 512 + rowBase) * lda + h * 64;
    const h16* Al = Ql + (size_t)(b * 512 + rowBase) * lda + h * 64;
    const h16* Bh = Kh + (size_t)(b * 512 + colBase) * ldb + h * 64;
    const h16* Bl = Kl + (size_t)(b * 512 + colBase) * ldb + h * 64;
    int t = threadIdx.x, lane = t & 63, wid = t >> 6;
    int wr = (wid >> 1) * 64, wc = (wid & 1) * 64;
    f32x4 acc[4][4] = {};
    int l15 = lane & 15, g = lane >> 4;

#pragma unroll
    for (int cc = 0; cc < 4; ++cc) {
        int c = t + cc * 256;
        int r = c >> 3, sq = (c & 7) ^ (r & 7);
        GLL16(Ah + (size_t)r * lda + sq * 8, &AhL[c * 8]);
        GLL16(Al + (size_t)r * lda + sq * 8, &AlL[c * 8]);
        GLL16(Bh + (size_t)r * ldb + sq * 8, &BhL[c * 8]);
        GLL16(Bl + (size_t)r * ldb + sq * 8, &BlL[c * 8]);
    }
    __syncthreads();

#pragma unroll
    for (int kk = 0; kk < 2; ++kk) {
        hfrag bh[4], bl[4];
#pragma unroll
        for (int n = 0; n < 4; ++n) {
            int rr = wc + n * 16 + l15;
            int q = ((kk << 2) | g) ^ (rr & 7);
            bh[n] = *(const hfrag*)&BhL[rr * 64 + q * 8];
            bl[n] = *(const hfrag*)&BlL[rr * 64 + q * 8];
        }
#pragma unroll
        for (int m = 0; m < 4; ++m) {
            int rr = wr + m * 16 + l15;
            int q = ((kk << 2) | g) ^ (rr & 7);
            hfrag ah = *(const hfrag*)&AhL[rr * 64 + q * 8];
            hfrag al = *(const hfrag*)&AlL[rr * 64 + q * 8];
#pragma unroll
            for (int n = 0; n < 4; ++n) {
                acc[m][n] = __builtin_amdgcn_mfma_f32_16x16x32_f16(ah, bh[n], acc[m][n], 0, 0, 0);
                acc[m][n] = __builtin_amdgcn_mfma_f32_16x16x32_f16(ah, bl[n], acc[m][n], 0, 0, 0);
                acc[m][n] = __builtin_amdgcn_mfma_f32_16x16x32_f16(al, bh[n], acc[m][n], 0, 0, 0);
            }
        }
    }

    size_t sbase = (size_t)z * 262144;
    int g4 = g * 4;
#pragma unroll
    for (int m = 0; m < 4; ++m) {
        int row0 = rowBase + wr + m * 16 + g4;
#pragma unroll
        for (int n = 0; n < 4; ++n) {
            int col = colBase + wc + n * 16 + l15;
#pragma unroll
            for (int j = 0; j < 4; ++j) {
                float v = acc[m][n][j] * 0.125f;
                h16 hh = (h16)v;
                Sh[sbase + (size_t)(row0 + j) * 512 + col] = hh;
                Sl[sbase + (size_t)(row0 + j) * 512 + col] = (h16)(v - (float)hh);
            }
        }
    }
}

// ---------------- fused softmax+PV ----------------
template<bool CAUSAL>
__global__ __launch_bounds__(256) void attn_pv(
    const h16* __restrict__ Shg, const h16* __restrict__ Slg,
    const h16* __restrict__ Vh, const h16* __restrict__ Vl,
    h16* __restrict__ Ch, h16* __restrict__ Cl, int bh0)
{
    __shared__ h16 ShL[4096], SlL[4096], VhL[4096], VlL[4096];
    __shared__ float mS[64], iS[64];
    int z = blockIdx.z, bh_ = bh0 + z;
    int rowBase = blockIdx.x * 64;
    const h16* Sa = Shg + (size_t)z * 262144 + (size_t)rowBase * 512;
    const h16* Sb = Slg + (size_t)z * 262144 + (size_t)rowBase * 512;
    const h16* Va = Vh + (size_t)z * 32768;
    const h16* Vb = Vl + (size_t)z * 32768;
    int t = threadIdx.x, lane = t & 63, wid = t >> 6;
    int l15 = lane & 15, g = lane >> 4;

    {
        int tr = t >> 2, tq = t & 3;
        int limit = CAUSAL ? (rowBase + tr + 1) : 512;
        float m = -1e30f, l = 0.f;
        const h16* rh = Sa + (size_t)tr * 512;
        const h16* rl = Sb + (size_t)tr * 512;
        for (int c = 0; c < 16; ++c) {
            int col0 = tq * 8 + c * 32;
            if (col0 >= limit) break;
            hfrag hv = *(const hfrag*)(rh + col0);
            hfrag lv = *(const hfrag*)(rl + col0);
            float s[8]; float cm = -1e30f;
#pragma unroll
            for (int j = 0; j < 8; ++j) {
                float sv = (float)hv[j] + (float)lv[j];
                s[j] = (col0 + j < limit) ? sv : -1e30f;
                cm = fmaxf(cm, s[j]);
            }
            if (cm > m) { l *= __expf(m - cm); m = cm; }
#pragma unroll
            for (int j = 0; j < 8; ++j) l += __expf(s[j] - m);
        }
#pragma unroll
        for (int o = 1; o < 4; o <<= 1) {
            float mo = __shfl_xor(m, o, 64);
            float lo2 = __shfl_xor(l, o, 64);
            float mc = fmaxf(m, mo);
            l = l * __expf(m - mc) + lo2 * __expf(mo - mc);
            m = mc;
        }
        if (tq == 0) { mS[tr] = m; iS[tr] = 1.0f / l; }
    }
    __syncthreads();

    int arow = wid * 16 + l15;
    float am = mS[arow], ai = iS[arow];
    int alim = CAUSAL ? (rowBase + arow + 1) : 512;
    int kend = CAUSAL ? (rowBase + 64) : 512;
    f32x4 acc[4] = {};

    for (int k0 = 0; k0 < kend; k0 += 64) {
        __syncthreads();
#pragma unroll
        for (int cc = 0; cc < 2; ++cc) {
            int c = t + cc * 256;
            int r = c >> 3, sq = (c & 7) ^ (r & 7);
            GLL16(Sa + (size_t)r * 512 + k0 + sq * 8, &ShL[c * 8]);
            GLL16(Sb + (size_t)r * 512 + k0 + sq * 8, &SlL[c * 8]);
            GLL16(Va + (size_t)r * 512 + k0 + sq * 8, &VhL[c * 8]);
            GLL16(Vb + (size_t)r * 512 + k0 + sq * 8, &VlL[c * 8]);
        }
        __syncthreads();

#pragma unroll
        for (int kk = 0; kk < 2; ++kk) {
            int chunk = (kk << 2) | g;
            int aq = chunk ^ (arow & 7);
            hfrag sh_ = *(const hfrag*)&ShL[arow * 64 + aq * 8];
            hfrag sl_ = *(const hfrag*)&SlL[arow * 64 + aq * 8];
            int cbase = k0 + chunk * 8;
            hfrag ph, pl;
#pragma unroll
            for (int j = 0; j < 8; ++j) {
                float s = (float)sh_[j] + (float)sl_[j];
                float p = __expf(s - am) * ai;
                p = (cbase + j < alim) ? p : 0.f;
                h16 hh = (h16)p;
                ph[j] = hh;
                pl[j] = (h16)(p - (float)hh);
            }
#pragma unroll
            for (int n = 0; n < 4; ++n) {
                int brow = n * 16 + l15;
                int bq = chunk ^ (brow & 7);
                hfrag bh = *(const hfrag*)&VhL[brow * 64 + bq * 8];
                hfrag bl = *(const hfrag*)&VlL[brow * 64 + bq * 8];
                acc[n] = __builtin_amdgcn_mfma_f32_16x16x32_f16(ph, bh, acc[n], 0, 0, 0);
                acc[n] = __builtin_amdgcn_mfma_f32_16x16x32_f16(ph, bl, acc[n], 0, 0, 0);
                acc[n] = __builtin_amdgcn_mfma_f32_16x16x32_f16(pl, bh, acc[n], 0, 0, 0);
            }
        }
    }

    int brow = (bh_ >> 4) * 512 + rowBase + wid * 16 + g * 4;
    int bcol = (bh_ & 15) * 64;
#pragma unroll
    for (int n = 0; n < 4; ++n) {
        int col = bcol + n * 16 + l15;
#pragma unroll
        for (int j = 0; j < 4; ++j) {
            float v = acc[n][j];
            h16 hh = (h16)v;
            Ch[(size_t)(brow + j) * 1024 + col] = hh;
            Cl[(size_t)(brow + j) * 1024 + col] = (h16)(v - (float)hh);
        }
    }
}

// ---------------- V-transpose ----------------
__global__ __launch_bounds__(256) void vt_split(
    const h16* __restrict__ inh, const h16* __restrict__ inl, int ld,
    h16* __restrict__ oh, h16* __restrict__ ol)
{
    __shared__ h16 tile[64][68];
    int z = blockIdx.z, b = z >> 4, h = z & 15;
    size_t ibase = ((size_t)b * 512 + blockIdx.x * 64) * ld + h * 64;
    size_t obase = (size_t)z * 32768 + blockIdx.x * 64;
    int tr = threadIdx.x >> 4, tc = (threadIdx.x & 15) * 4;
    const h16* src[2] = {inh, inl};
    h16* dst[2] = {oh, ol};
#pragma unroll
    for (int s = 0; s < 2; ++s) {
        __syncthreads();
#pragma unroll
        for (int i = 0; i < 4; ++i) {
            int tt = tr + i * 16;
            short4 v = *(const short4*)(src[s] + ibase + (size_t)tt * ld + tc);
            tile[tt][tc + 0] = ((h16*)&v)[0];
            tile[tt][tc + 1] = ((h16*)&v)[1];
            tile[tt][tc + 2] = ((h16*)&v)[2];
            tile[tt][tc + 3] = ((h16*)&v)[3];
        }
        __syncthreads();
#pragma unroll
        for (int i = 0; i < 4; ++i) {
            int d = tr + i * 16;
            h16 w[4] = {tile[tc + 0][d], tile[tc + 1][d], tile[tc + 2][d], tile[tc + 3][d]};
            *(short4*)(dst[s] + obase + (size_t)d * 512 + tc) = *(short4*)w;
        }
    }
}

// ---------------- bf16 NT MFMA GEMM (MoE), BK=64, flat grid, XCD pinned, K-split, count-skip ----
template<int TN, bool RELU, bool ROWFAST, int KS>
__global__ __launch_bounds__(256) void gemm_bf16_moe(
    const unsigned short* __restrict__ A,
    const unsigned short* __restrict__ Bt,
    const float* __restrict__ bias,
    unsigned short* __restrict__ C,
    int K, long long sA, long long sB, long long sC, long long sBias, int ldc,
    int emask, int elog, int nrow, int ncol,
    const int* __restrict__ counts, int e0, long long sHalf)
{
    constexpr int NFR = TN / 32;
    __shared__ unsigned short Al[128 * 64];
    __shared__ unsigned short Bl[TN * 64];
    int id = blockIdx.x;
    int e = id & emask;
    int tb = id >> elog;
    int half = 0;
    if (KS == 2) {
        int per = nrow * ncol;
        half = (tb >= per) ? 1 : 0;
        tb -= half * per;
    }
    int row, col;
    if (ROWFAST) { row = tb % nrow; col = tb / nrow; }
    else         { col = tb % ncol; row = tb / ncol; }
    int rowBase = row * 128;

    int bound = counts[e0 + e];
    if (bound > CAPE) bound = CAPE;
    if (rowBase >= bound) return;

    A    += (size_t)e * sA;
    Bt   += (size_t)e * sB;
    bias += (size_t)e * sBias;
    long long zC = (long long)e * sC + (long long)half * sHalf;

    int colBase = col * TN;
    int t = threadIdx.x, lane = t & 63, wid = t >> 6;
    int wr = (wid >> 1) * 64, wc = (wid & 1) * (TN / 2);

    const unsigned short* Ag = A  + (size_t)rowBase * K;
    const unsigned short* Bg = Bt + (size_t)colBase * K;

    f32x4 acc[4][NFR] = {};
    int l15 = lane & 15, g = lane >> 4;

    int kb = half * (K / KS), ke = kb + (K / KS);
    for (int k0 = kb; k0 < ke; k0 += 64) {
        __syncthreads();
#pragma unroll
        for (int cc = 0; cc < 4; ++cc) {
            int c = t + cc * 256;
            int r = c >> 3, sq = (c & 7) ^ (r & 7);
            GLL16(Ag + (size_t)r * K + k0 + sq * 8, &Al[c * 8]);
        }
#pragma unroll
        for (int cc = 0; cc < TN / 32; ++cc) {
            int c = t + cc * 256;
            int r = c >> 3, sq = (c & 7) ^ (r & 7);
            GLL16(Bg + (size_t)r * K + k0 + sq * 8, &Bl[c * 8]);
        }
        __syncthreads();

        bfrag b[2][NFR];
#pragma unroll
        for (int kk = 0; kk < 2; ++kk)
#pragma unroll
            for (int n = 0; n < NFR; ++n) {
                int rr = wc + n * 16 + l15;
                int q = ((kk << 2) | g) ^ (rr & 7);
                b[kk][n] = *(const bfrag*)&Bl[rr * 64 + q * 8];
            }
#pragma unroll
        for (int m = 0; m < 4; ++m) {
            int rr = wr + m * 16 + l15;
#pragma unroll
            for (int kk = 0; kk < 2; ++kk) {
                int q = ((kk << 2) | g) ^ (rr & 7);
                bfrag a = *(const bfrag*)&Al[rr * 64 + q * 8];
#pragma unroll
                for (int n = 0; n < NFR; ++n)
                    acc[m][n] = __builtin_amdgcn_mfma_f32_16x16x32_bf16(a, b[kk][n], acc[m][n], 0, 0, 0);
            }
        }
    }

    int g4 = g * 4;
#pragma unroll
    for (int m = 0; m < 4; ++m) {
        int row0 = rowBase + wr + m * 16 + g4;
#pragma unroll
        for (int n = 0; n < NFR; ++n) {
            int cc = colBase + wc + n * 16 + l15;
            float bv = (KS == 1 || half == 0) ? bias[cc] : 0.f;
#pragma unroll
            for (int j = 0; j < 4; ++j) {
                float v = acc[m][n][j] + bv;
                if (RELU) v = fmaxf(v, 0.f);
                C[zC + (size_t)(row0 + j) * ldc + cc] = f2bf(v);
            }
        }
    }
}

// ---------------- transpose+convert fp32 [R][Cn] -> bf16 [Cn][R] (per z) ----------------
__global__ __launch_bounds__(256) void tcvt_kernel(const float* __restrict__ in,
    unsigned short* __restrict__ out, int R, int Cn)
{
    __shared__ unsigned short tile[64][68];
    size_t zoff = (size_t)blockIdx.z * R * Cn;
    in += zoff; out += zoff;
    int r0 = blockIdx.y * 64, c0 = blockIdx.x * 64;
    int tr = threadIdx.x >> 4, tc = (threadIdx.x & 15) * 4;
#pragma unroll
    for (int i = 0; i < 4; ++i) {
        int r = tr + i * 16;
        float4 v = *(const float4*)&in[(size_t)(r0 + r) * Cn + c0 + tc];
        tile[r][tc + 0] = f2bf(v.x);
        tile[r][tc + 1] = f2bf(v.y);
        tile[r][tc + 2] = f2bf(v.z);
        tile[r][tc + 3] = f2bf(v.w);
    }
    __syncthreads();
#pragma unroll
    for (int i = 0; i < 4; ++i) {
        int c = tr + i * 16;
        ushort4 w;
        w.x = tile[tc + 0][c];
        w.y = tile[tc + 1][c];
        w.z = tile[tc + 2][c];
        w.w = tile[tc + 3][c];
        *(ushort4*)&out[(size_t)(c0 + c) * R + r0 + tc] = w;
    }
}

// ---------------- router: 1024 blocks, one wave per token ----------------
__global__ __launch_bounds__(256) void router_kernel(
    const float* __restrict__ xf, const float* __restrict__ rw, const float* __restrict__ rb,
    const float* __restrict__ tmask,
    int* __restrict__ eidx, float* __restrict__ gate, int* __restrict__ valid,
    float* __restrict__ partials)
{
    int wid = threadIdx.x >> 6, lane = threadIdx.x & 63;
    int tok = blockIdx.x * 4 + wid;
    __shared__ float wpart[4][10];

    const float* xrow = xf + (size_t)tok * DMODEL;
    float acc[8] = {0,0,0,0,0,0,0,0};
#pragma unroll 4
    for (int kk = 0; kk < 16; ++kk) {
        int d = lane + (kk << 6);
        float xd = xrow[d];
        const float4* rp = (const float4*)(rw + (size_t)d * 8);
        float4 r0 = rp[0], r1 = rp[1];
        acc[0] = fmaf(xd, r0.x, acc[0]); acc[1] = fmaf(xd, r0.y, acc[1]);
        acc[2] = fmaf(xd, r0.z, acc[2]); acc[3] = fmaf(xd, r0.w, acc[3]);
        acc[4] = fmaf(xd, r1.x, acc[4]); acc[5] = fmaf(xd, r1.y, acc[5]);
        acc[6] = fmaf(xd, r1.z, acc[6]); acc[7] = fmaf(xd, r1.w, acc[7]);
    }
#pragma unroll
    for (int e = 0; e < 8; ++e)
#pragma unroll
        for (int o = 1; o < 64; o <<= 1) acc[e] += __shfl_xor(acc[e], o, 64);

    if (lane == 0) {
        float l[8]; float m = -1e30f;
#pragma unroll
        for (int e = 0; e < 8; ++e) { l[e] = acc[e] + rb[e]; m = fmaxf(m, l[e]); }
        float se = 0.f;
#pragma unroll
        for (int e = 0; e < 8; ++e) se += expf(l[e] - m);
        int am = 0; float bm = l[0];
#pragma unroll
        for (int e = 1; e < 8; ++e) if (l[e] > bm) { bm = l[e]; am = e; }
        float inv_se = 1.0f / se;
        float g = expf(l[am] - m) * inv_se;
        float vld = (tmask[tok] > 0.f) ? 1.f : 0.f;
        eidx[tok] = am; gate[tok] = g; valid[tok] = (int)vld;
#pragma unroll
        for (int e = 0; e < 8; ++e) wpart[wid][e] = expf(l[e] - m) * inv_se * vld;
        float lse = logf(se) + m;
        wpart[wid][8] = lse * lse * vld;
        wpart[wid][9] = vld;
    }
    __syncthreads();
    if (threadIdx.x == 0) {
        for (int j = 0; j < 10; ++j)
            partials[blockIdx.x * 10 + j] = wpart[0][j] + wpart[1][j] + wpart[2][j] + wpart[3][j];
    }
}

// ---------------- capacity scan ----------------
__global__ __launch_bounds__(256) void scan_kernel(
    const int* __restrict__ eidx, const int* __restrict__ valid, const float* __restrict__ gate,
    int* __restrict__ pc, float* __restrict__ gk, int* __restrict__ keepf,
    int* __restrict__ counts)
{
    __shared__ int cnt[256][8];
    int tid = threadIdx.x;
    int local[8] = {0,0,0,0,0,0,0,0};
    int base = tid * 16;
    for (int i = 0; i < 16; ++i) { int e = eidx[base + i]; local[e] += valid[base + i]; }
#pragma unroll
    for (int e = 0; e < 8; ++e) cnt[tid][e] = local[e];
    __syncthreads();
    if (tid < 8) {
        int run = 0;
        for (int i = 0; i < 256; ++i) { int t = cnt[i][tid]; cnt[i][tid] = run; run += t; }
        counts[tid] = run;
    }
    __syncthreads();
    int off[8];
#pragma unroll
    for (int e = 0; e < 8; ++e) off[e] = cnt[tid][e];
    for (int i = 0; i < 16; ++i) {
        int tok = base + i;
        int e = eidx[tok], v = valid[tok];
        int pos = off[e]; off[e] += v;
        int kp = (v && pos < CAPE) ? 1 : 0;
        pc[tok]    = (pos < CAPE) ? pos : (CAPE - 1);
        keepf[tok] = kp;
        gk[tok]    = kp ? gate[tok] : 0.f;
    }
}

// ---------------- dispatch (expert-range) -> bf16 buffers ----------------
__global__ __launch_bounds__(256) void dispatch_bf16(const float* __restrict__ tln,
    const int* __restrict__ eidx, const int* __restrict__ pc, const int* __restrict__ keepf,
    unsigned short* __restrict__ buf, int e0, int ec)
{
    int tok = blockIdx.x;
    if (!keepf[tok]) return;
    int e = eidx[tok];
    if (e < e0 || e >= e0 + ec) return;
    int p = pc[tok];
    const float4 v = ((const float4*)(tln + (size_t)tok * DMODEL))[threadIdx.x];
    ushort4 o;
    o.x = f2bf(v.x); o.y = f2bf(v.y); o.z = f2bf(v.z); o.w = f2bf(v.w);
    ((ushort4*)(buf + ((size_t)(e - e0) * CAPE + p) * DMODEL))[threadIdx.x] = o;
}

// ---------------- combine add: out += gk * (ob0 + ob1) ----------------
__global__ __launch_bounds__(256) void combine_bf16(const unsigned short* __restrict__ ob,
    const int* __restrict__ eidx, const int* __restrict__ pc, const float* __restrict__ gk,
    float* __restrict__ out, int e0, int ec, long long sHalf)
{
    int tok = blockIdx.x;
    int e = eidx[tok];
    if (e < e0 || e >= e0 + ec) return;
    float g = gk[tok];
    int p = pc[tok];
    size_t idx = ((size_t)(e - e0) * CAPE + p) * DMODEL;
    float4* o = (float4*)(out + (size_t)tok * DMODEL);
    const ushort4 u0 = ((const ushort4*)(ob + idx))[threadIdx.x];
    const ushort4 u1 = ((const ushort4*)(ob + sHalf + idx))[threadIdx.x];
    float4 a = o[threadIdx.x];
    a.x += g * (bf2f(u0.x) + bf2f(u1.x));
    a.y += g * (bf2f(u0.y) + bf2f(u1.y));
    a.z += g * (bf2f(u0.z) + bf2f(u1.z));
    a.w += g * (bf2f(u0.w) + bf2f(u1.w));
    o[threadIdx.x] = a;
}

// ---------------- final scalar losses (1024 partials, 16/lane) ----------------
__global__ __launch_bounds__(64) void loss_kernel(const float* __restrict__ partials,
    const int* __restrict__ counts, float* __restrict__ out2)
{
    int lane = threadIdx.x;
    float p[10] = {0,0,0,0,0,0,0,0,0,0};
    for (int r = 0; r < 16; ++r) {
        const float* row = partials + ((size_t)lane * 16 + r) * 10;
#pragma unroll
        for (int j = 0; j < 10; ++j) p[j] += row[j];
    }
#pragma unroll
    for (int j = 0; j < 10; ++j)
#pragma unroll
        for (int o = 1; o < 64; o <<= 1) p[j] += __shfl_xor(p[j], o, 64);
    if (lane == 0) {
        float nv = fmaxf(p[9], 1.f);
        float lb = 0.f;
        for (int e = 0; e < 8; ++e) lb += ((float)counts[e] / nv) * (p[e] / nv);
        lb *= (float)NEXP;
        out2[0] = lb;
        out2[1] = p[8] / nv;
    }
}

// ---------------- host launch ----------------
extern "C" void kernel_launch(void* const* d_in, const int* in_sizes, int n_in,
                              void* d_out, int out_size, void* d_ws, size_t ws_size,
                              hipStream_t stream)
{
    const float* tgt        = (const float*)d_in[0];
    const float* src        = (const float*)d_in[1];
    const float* token_mask = (const float*)d_in[5];
    const float* ln1w = (const float*)d_in[6],  *ln1b = (const float*)d_in[7];
    const float* self_in_w  = (const float*)d_in[8],  *self_in_b  = (const float*)d_in[9];
    const float* self_out_w = (const float*)d_in[10], *self_out_b = (const float*)d_in[11];
    const float* ln2w = (const float*)d_in[12], *ln2b = (const float*)d_in[13];
    const float* enc_in_w   = (const float*)d_in[14], *enc_in_b   = (const float*)d_in[15];
    const float* enc_out_w  = (const float*)d_in[16], *enc_out_b  = (const float*)d_in[17];
    const float* ln3w = (const float*)d_in[18], *ln3b = (const float*)d_in[19];
    const float* rw = (const float*)d_in[20], *rb = (const float*)d_in[21];
    const float* w1 = (const float*)d_in[22], *b1 = (const float*)d_in[23];
    const float* w2 = (const float*)d_in[24], *b2 = (const float*)d_in[25];

    float* out = (float*)d_out;          // residual stream lives HERE
    float* ws  = (float*)d_ws;

    // ---- fixed layout (floats) ----
    float* tln = ws;                         // 4,194,304
    float* ctx = ws + 4194304;               // 4,194,304 (ctx hi/lo f16)
    int*   eidxA   = (int*)(ws + 8388608);
    int*   validA  = eidxA + 4096;
    int*   pcA     = validA + 4096;
    int*   keepA   = pcA + 4096;
    int*   countsA = keepA + 4096;           // 16
    float* gateA   = (float*)(countsA + 16);
    float* gkA     = gateA + 4096;
    float* partA   = gkA + 4096;             // 1024*10
    const size_t POOL_OFF = 8425984;         // floats
    float* pool = ws + POOL_OFF;

    size_t Wf = ws_size / sizeof(float);
    size_t pf = (Wf > POOL_OFF) ? (Wf - POOL_OFF) : 0;

    int bg, zc;
    if      (pf >= 25165824) { bg = 8; zc = 32; }
    else if (pf >= 24117248) { bg = 8; zc = 16; }
    else if (pf >= 13631488) { bg = 4; zc = 16; }
    else                     { bg = 2; zc = 16; }
    // MoE: per expert needs 4,063,232 pool floats (wt + hB + bufB/ob0 + ob1)
    int ecs = 1;
    for (int c = 8; c >= 1; c >>= 1)
        if ((size_t)c * 4063232ull <= pf) { ecs = c; break; }
    int elog = (ecs == 8) ? 3 : (ecs == 4) ? 2 : (ecs == 2) ? 1 : 0;

    float* qreg = pool;
    float* vreg = qreg + (size_t)bg * 1572864;
    float* sreg = vreg + (size_t)bg * 524288;

    h16* tlnh = (h16*)tln;
    h16* tlnl = tlnh + 4194304;
    h16* ctxh = (h16*)ctx;
    h16* ctxl = ctxh + 4194304;

    // ================= self attention =================
    ln_kernel<1><<<NTOK, 256, 0, stream>>>(tgt, ln1w, ln1b, nullptr, tlnh, tlnl);

    for (int g0 = 0; g0 < BATCH; g0 += bg) {
        h16* sb  = (h16*)sreg;
        h16* whi = sb, *wlo = sb + 3145728;
        split_f16<<<1536, 256, 0, stream>>>(self_in_w, whi, wlo, 393216);

        h16* qkvh = (h16*)qreg, *qkvl = qkvh + (size_t)bg * 1572864;
        gemm_f16x2_nt<2><<<dim3(24, bg * 4, 1), 256, 0, stream>>>(
            tlnh + (size_t)g0 * 524288, tlnl + (size_t)g0 * 524288, 1024,
            whi, wlo, 1024, self_in_b, nullptr,
            nullptr, qkvh, qkvl, 1024, 3072);

        h16* vth = (h16*)vreg, *vtl = vth + (size_t)bg * 524288;
        vt_split<<<dim3(8, 1, bg * 16), 256, 0, stream>>>(qkvh + 2048, qkvl + 2048, 3072, vth, vtl);

        h16* sh = sb, *sl = sh + (size_t)zc * 262144;
        for (int c0 = 0; c0 < bg * 16; c0 += zc) {
            attn_qk<true><<<dim3(4, 4, zc), 256, 0, stream>>>(
                qkvh, qkvl, 3072, qkvh + 1024, qkvl + 1024, 3072, sh, sl, c0);
            attn_pv<true><<<dim3(8, 1, zc), 256, 0, stream>>>(
                sh, sl, vth + (size_t)c0 * 32768, vtl + (size_t)c0 * 32768,
                ctxh, ctxl, g0 * 16 + c0);
        }
    }
    {
        h16* sb = (h16*)sreg;
        h16* owhi = sb, *owlo = sb + 1048576;
        split_f16<<<512, 256, 0, stream>>>(self_out_w, owhi, owlo, 131072);
        gemm_f16x2_nt<1><<<dim3(8, 32, 1), 256, 0, stream>>>(
            ctxh, ctxl, 1024, owhi, owlo, 1024, self_out_b, tgt,
            out, nullptr, nullptr, 1024, 1024);
    }

    // ================= cross attention =================
    ln_kernel<1><<<NTOK, 256, 0, stream>>>(out, ln2w, ln2b, nullptr, tlnh, tlnl);

    for (int g0 = 0; g0 < BATCH; g0 += bg) {
        h16* sb  = (h16*)sreg;
        h16* shi = sb, *slo = sb + (size_t)bg * 524288;
        h16* ehi = sb + (size_t)bg * 1048576, *elo = ehi + 3145728;
        split_f16<<<bg * 256, 256, 0, stream>>>(src + (size_t)g0 * 524288, shi, slo, bg * 65536);
        split_f16<<<1536, 256, 0, stream>>>(enc_in_w, ehi, elo, 393216);

        h16* q2h  = (h16*)qreg,                 *q2l  = q2h + (size_t)bg * 524288;
        h16* kv2h = q2h + (size_t)bg * 1048576, *kv2l = kv2h + (size_t)bg * 1048576;
        gemm_f16x2_nt<2><<<dim3(8, bg * 4, 1), 256, 0, stream>>>(
            tlnh + (size_t)g0 * 524288, tlnl + (size_t)g0 * 524288, 1024,
            ehi, elo, 1024, enc_in_b, nullptr,
            nullptr, q2h, q2l, 1024, 1024);
        gemm_f16x2_nt<2><<<dim3(16, bg * 4, 1), 256, 0, stream>>>(
            shi, slo, 1024, ehi + 1048576, elo + 1048576, 1024, enc_in_b + 1024, nullptr,
            nullptr, kv2h, kv2l, 1024, 2048);

        h16* vth = (h16*)vreg, *vtl = vth + (size_t)bg * 524288;
        vt_split<<<dim3(8, 1, bg * 16), 256, 0, stream>>>(kv2h + 1024, kv2l + 1024, 2048, vth, vtl);

        h16* sh = sb, *sl = sh + (size_t)zc * 262144;
        for (int c0 = 0; c0 < bg * 16; c0 += zc) {
            attn_qk<false><<<dim3(4, 4, zc), 256, 0, stream>>>(
                q2h, q2l, 1024, kv2h, kv2l, 2048, sh, sl, c0);
            attn_pv<false><<<dim3(8, 1, zc), 256, 0, stream>>>(
                sh, sl, vth + (size_t)c0 * 32768, vtl + (size_t)c0 * 32768,
                ctxh, ctxl, g0 * 16 + c0);
        }
    }
    {
        h16* sb = (h16*)sreg;
        h16* owhi = sb, *owlo = sb + 1048576;
        split_f16<<<512, 256, 0, stream>>>(enc_out_w, owhi, owlo, 131072);
        gemm_f16x2_nt<1><<<dim3(8, 32, 1), 256, 0, stream>>>(
            ctxh, ctxl, 1024, owhi, owlo, 1024, enc_out_b, out,
            out, nullptr, nullptr, 1024, 1024);
    }

    // ================= MoE =================
    ln_kernel<0><<<NTOK, 256, 0, stream>>>(out, ln3w, ln3b, tln, nullptr, nullptr);
    router_kernel<<<1024, 256, 0, stream>>>(tln, rw, rb, token_mask, eidxA, gateA, validA, partA);
    scan_kernel<<<1, 256, 0, stream>>>(eidxA, validA, gateA, pcA, gkA, keepA, countsA);

    // per-chunk pool layout (floats):
    //   wt   : ecs*2,097,152  (bf16 w1t then w2t, reused)
    //   hB   : ecs*1,310,720  (bf16 [640][4096])
    //   bufB : ecs*327,680    (bf16 [640][1024]); ob0 overlays bufB
    //   ob1  : ecs*327,680    (bf16 [640][1024], K-split half 1)
    long long sHalf = (long long)NEXP; // placeholder, set below per pass
    for (int e0 = 0; e0 < NEXP; e0 += ecs) {
        unsigned short* wt   = (unsigned short*)pool;
        unsigned short* hB   = (unsigned short*)(pool + (size_t)ecs * 2097152);
        unsigned short* bufB = (unsigned short*)(pool + (size_t)ecs * 3407872);
        unsigned short* obB  = bufB;                       // ob0 overlays bufB
        sHalf = (long long)ecs * 655360;                   // shorts between ob0 and ob1

        tcvt_kernel<<<dim3(64, 16, ecs), 256, 0, stream>>>(
            w1 + (size_t)e0 * 4194304, wt, 1024, 4096);
        dispatch_bf16<<<NTOK, 256, 0, stream>>>(tln, eidxA, pcA, keepA, bufB, e0, ecs);
        gemm_bf16_moe<128, true, true, 1><<<ecs * 5 * 32, 256, 0, stream>>>(
            bufB, wt, b1 + (size_t)e0 * 4096, hB,
            1024, 655360LL, 4194304LL, 2621440LL, 4096LL, 4096,
            ecs - 1, elog, 5, 32, countsA, e0, 0LL);

        tcvt_kernel<<<dim3(16, 64, ecs), 256, 0, stream>>>(
            w2 + (size_t)e0 * 4194304, wt, 4096, 1024);
        gemm_bf16_moe<64, false, false, 2><<<ecs * 5 * 16 * 2, 256, 0, stream>>>(
            hB, wt, b2 + (size_t)e0 * 1024, obB,
            4096, 2621440LL, 4194304LL, 655360LL, 1024LL, 1024,
            ecs - 1, elog, 5, 16, countsA, e0, sHalf);

        combine_bf16<<<NTOK, 256, 0, stream>>>(obB, eidxA, pcA, gkA, out, e0, ecs, sHalf);
    }

    // ===== losses =====
    loss_kernel<<<1, 64, 0, stream>>>(partA, countsA, out + (size_t)NTOK * DMODEL);
}

// Round 13
// 778.760 us; speedup vs baseline: 3.4761x; 1.0769x over previous
//
#include <hip/hip_runtime.h>
#include <cstdint>

// ---------------- problem constants ----------------
constexpr int BATCH  = 8;
constexpr int TSEQ   = 512;
constexpr int DMODEL = 1024;
constexpr int NEXP   = 8;
constexpr int CAPE   = 640;
constexpr int NTOK   = BATCH * TSEQ;        // 4096

typedef _Float16 h16;
typedef __attribute__((ext_vector_type(8))) short bfrag;
typedef __attribute__((ext_vector_type(8))) _Float16 hfrag;
typedef __attribute__((ext_vector_type(4))) float f32x4;

__device__ __forceinline__ unsigned short f2bf(float f) {
    uint32_t u = __float_as_uint(f);
    uint32_t r = (u + 0x7FFFu + ((u >> 16) & 1u)) >> 16;   // RNE
    return (unsigned short)r;
}
__device__ __forceinline__ float bf2f(unsigned short b) {
    return __uint_as_float((uint32_t)b << 16);
}

#define GLL16(SRC, DST) __builtin_amdgcn_global_load_lds( \
    (const __attribute__((address_space(1))) void*)(SRC), \
    (__attribute__((address_space(3))) void*)(DST), 16, 0, 0)

// ---------------- LayerNorm: MODE 0 -> fp32 out; MODE 1 -> f16 hi/lo out ----------------
template<int MODE>
__global__ __launch_bounds__(256) void ln_kernel(const float* __restrict__ in,
    const float* __restrict__ gw, const float* __restrict__ gb,
    float* __restrict__ out, h16* __restrict__ ohi, h16* __restrict__ olo)
{
    int row = blockIdx.x, tid = threadIdx.x;
    const float4 v = *(const float4*)(in + (size_t)row * DMODEL + tid * 4);
    float s  = v.x + v.y + v.z + v.w;
    float ss = v.x*v.x + v.y*v.y + v.z*v.z + v.w*v.w;
#pragma unroll
    for (int o = 1; o < 64; o <<= 1) { s += __shfl_xor(s, o, 64); ss += __shfl_xor(ss, o, 64); }
    __shared__ float rs[4], rss[4];
    int wid = tid >> 6, lane = tid & 63;
    if (lane == 0) { rs[wid] = s; rss[wid] = ss; }
    __syncthreads();
    s  = rs[0] + rs[1] + rs[2] + rs[3];
    ss = rss[0] + rss[1] + rss[2] + rss[3];
    float mean = s * (1.0f / DMODEL);
    float var  = ss * (1.0f / DMODEL) - mean * mean;
    float inv  = rsqrtf(var + 1e-5f);
    float4 w4 = *(const float4*)(gw + tid * 4);
    float4 b4 = *(const float4*)(gb + tid * 4);
    float o[4];
    o[0] = (v.x - mean) * inv * w4.x + b4.x;
    o[1] = (v.y - mean) * inv * w4.y + b4.y;
    o[2] = (v.z - mean) * inv * w4.z + b4.z;
    o[3] = (v.w - mean) * inv * w4.w + b4.w;
    if (MODE == 0) {
        float4 f = {o[0], o[1], o[2], o[3]};
        *(float4*)(out + (size_t)row * DMODEL + tid * 4) = f;
    } else {
        short4 hv, lv;
#pragma unroll
        for (int j = 0; j < 4; ++j) {
            h16 hh = (h16)o[j];
            ((h16*)&hv)[j] = hh;
            ((h16*)&lv)[j] = (h16)(o[j] - (float)hh);
        }
        *(short4*)(ohi + (size_t)row * DMODEL + tid * 4) = hv;
        *(short4*)(olo + (size_t)row * DMODEL + tid * 4) = lv;
    }
}

// ---------------- fp32 -> fp16 hi/lo split ----------------
__global__ __launch_bounds__(256) void split_f16(const float* __restrict__ in,
    h16* __restrict__ hi, h16* __restrict__ lo, int n8)
{
    int i = blockIdx.x * 256 + threadIdx.x;
    if (i >= n8) return;
    const float4* p = (const float4*)in + 2 * (size_t)i;
    float4 v0 = p[0], v1 = p[1];
    float vv[8] = {v0.x, v0.y, v0.z, v0.w, v1.x, v1.y, v1.z, v1.w};
    hfrag h, l;
#pragma unroll
    for (int j = 0; j < 8; ++j) {
        h16 hj = (h16)vv[j];
        h[j] = hj;
        l[j] = (h16)(vv[j] - (float)hj);
    }
    ((hfrag*)hi)[i] = h;
    ((hfrag*)lo)[i] = l;
}

// ---------------- fp16x2 (3-product) NT MFMA GEMM, BK=64 ----------------
template<int OMODE>
__global__ __launch_bounds__(256) void gemm_f16x2_nt(
    const h16* __restrict__ Ahi, const h16* __restrict__ Alo, int lda,
    const h16* __restrict__ Bhi, const h16* __restrict__ Blo, int ldb,
    const float* __restrict__ bias, const float* __restrict__ res,
    float* __restrict__ C, h16* __restrict__ Chi, h16* __restrict__ Clo,
    int K, int ldc)
{
    __shared__ h16 AhL[8192], AlL[8192], BhL[8192], BlL[8192];
    int rowBase = blockIdx.y * 128, colBase = blockIdx.x * 128;
    int t = threadIdx.x, lane = t & 63, wid = t >> 6;
    int wr = (wid >> 1) * 64, wc = (wid & 1) * 64;
    const h16* Ah = Ahi + (size_t)rowBase * lda;
    const h16* Al = Alo + (size_t)rowBase * lda;
    const h16* Bh = Bhi + (size_t)colBase * ldb;
    const h16* Bl = Blo + (size_t)colBase * ldb;
    f32x4 acc[4][4] = {};
    int l15 = lane & 15, g = lane >> 4;

    for (int k0 = 0; k0 < K; k0 += 64) {
        __syncthreads();
#pragma unroll
        for (int cc = 0; cc < 4; ++cc) {
            int c = t + cc * 256;
            int r = c >> 3, sq = (c & 7) ^ (r & 7);
            GLL16(Ah + (size_t)r * lda + k0 + sq * 8, &AhL[c * 8]);
            GLL16(Al + (size_t)r * lda + k0 + sq * 8, &AlL[c * 8]);
            GLL16(Bh + (size_t)r * ldb + k0 + sq * 8, &BhL[c * 8]);
            GLL16(Bl + (size_t)r * ldb + k0 + sq * 8, &BlL[c * 8]);
        }
        __syncthreads();

#pragma unroll
        for (int kk = 0; kk < 2; ++kk) {
            hfrag bh[4], bl[4];
#pragma unroll
            for (int n = 0; n < 4; ++n) {
                int rr = wc + n * 16 + l15;
                int q = ((kk << 2) | g) ^ (rr & 7);
                bh[n] = *(const hfrag*)&BhL[rr * 64 + q * 8];
                bl[n] = *(const hfrag*)&BlL[rr * 64 + q * 8];
            }
#pragma unroll
            for (int m = 0; m < 4; ++m) {
                int rr = wr + m * 16 + l15;
                int q = ((kk << 2) | g) ^ (rr & 7);
                hfrag ah = *(const hfrag*)&AhL[rr * 64 + q * 8];
                hfrag al = *(const hfrag*)&AlL[rr * 64 + q * 8];
#pragma unroll
                for (int n = 0; n < 4; ++n) {
                    acc[m][n] = __builtin_amdgcn_mfma_f32_16x16x32_f16(ah, bh[n], acc[m][n], 0, 0, 0);
                    acc[m][n] = __builtin_amdgcn_mfma_f32_16x16x32_f16(ah, bl[n], acc[m][n], 0, 0, 0);
                    acc[m][n] = __builtin_amdgcn_mfma_f32_16x16x32_f16(al, bh[n], acc[m][n], 0, 0, 0);
                }
            }
        }
    }

    int g4 = g * 4;
#pragma unroll
    for (int m = 0; m < 4; ++m) {
        int row0 = rowBase + wr + m * 16 + g4;
#pragma unroll
        for (int n = 0; n < 4; ++n) {
            int col = colBase + wc + n * 16 + l15;
            float bv = bias[col];
#pragma unroll
            for (int j = 0; j < 4; ++j) {
                float v = acc[m][n][j] + bv;
                if (OMODE == 1) v += res[(size_t)(row0 + j) * ldc + col];
                if (OMODE < 2) {
                    C[(size_t)(row0 + j) * ldc + col] = v;
                } else {
                    h16 hh = (h16)v;
                    Chi[(size_t)(row0 + j) * ldc + col] = hh;
                    Clo[(size_t)(row0 + j) * ldc + col] = (h16)(v - (float)hh);
                }
            }
        }
    }
}

// ---------------- attention QK^T (f16x2, K=64 single step) -> single f16 S ----------------
template<bool CAUSAL>
__global__ __launch_bounds__(256) void attn_qk(
    const h16* __restrict__ Qh, const h16* __restrict__ Ql, int lda,
    const h16* __restrict__ Kh, const h16* __restrict__ Kl, int ldb,
    h16* __restrict__ Sh, int zoff)
{
    int rowBase = blockIdx.y * 128, colBase = blockIdx.x * 128;
    if (CAUSAL && colBase >= rowBase + 128) return;
    __shared__ h16 AhL[8192], AlL[8192], BhL[8192], BlL[8192];
    int z = blockIdx.z;
    int bh_ = zoff + z, b = bh_ >> 4, h = bh_ & 15;
    const h16* Ah = Qh + (size_t)(b * 512 + rowBase) * lda + h * 64;
    const h16* Al = Ql + (size_t)(b * 512 + rowBase) * lda + h * 64;
    const h16* Bh = Kh + (size_t)(b * 512 + colBase) * ldb + h * 64;
    const h16* Bl = Kl + (size_t)(b * 512 + colBase) * ldb + h * 64;
    int t = threadIdx.x, lane = t & 63, wid = t >> 6;
    int wr = (wid >> 1) * 64, wc = (wid & 1) * 64;
    f32x4 acc[4][4] = {};
    int l15 = lane & 15, g = lane >> 4;

#pragma unroll
    for (int cc = 0; cc < 4; ++cc) {
        int c = t + cc * 256;
        int r = c >> 3, sq = (c & 7) ^ (r & 7);
        GLL16(Ah + (size_t)r * lda + sq * 8, &AhL[c * 8]);
        GLL16(Al + (size_t)r * lda + sq * 8, &AlL[c * 8]);
        GLL16(Bh + (size_t)r * ldb + sq * 8, &BhL[c * 8]);
        GLL16(Bl + (size_t)r * ldb + sq * 8, &BlL[c * 8]);
    }
    __syncthreads();

#pragma unroll
    for (int kk = 0; kk < 2; ++kk) {
        hfrag bh[4], bl[4];
#pragma unroll
        for (int n = 0; n < 4; ++n) {
            int rr = wc + n * 16 + l15;
            int q = ((kk << 2) | g) ^ (rr & 7);
            bh[n] = *(const hfrag*)&BhL[rr * 64 + q * 8];
            bl[n] = *(const hfrag*)&BlL[rr * 64 + q * 8];
        }
#pragma unroll
        for (int m = 0; m < 4; ++m) {
            int rr = wr + m * 16 + l15;
            int q = ((kk << 2) | g) ^ (rr & 7);
            hfrag ah = *(const hfrag*)&AhL[rr * 64 + q * 8];
            hfrag al = *(const hfrag*)&AlL[rr * 64 + q * 8];
#pragma unroll
            for (int n = 0; n < 4; ++n) {
                acc[m][n] = __builtin_amdgcn_mfma_f32_16x16x32_f16(ah, bh[n], acc[m][n], 0, 0, 0);
                acc[m][n] = __builtin_amdgcn_mfma_f32_16x16x32_f16(ah, bl[n], acc[m][n], 0, 0, 0);
                acc[m][n] = __builtin_amdgcn_mfma_f32_16x16x32_f16(al, bh[n], acc[m][n], 0, 0, 0);
            }
        }
    }

    size_t sbase = (size_t)z * 262144;
    int g4 = g * 4;
#pragma unroll
    for (int m = 0; m < 4; ++m) {
        int row0 = rowBase + wr + m * 16 + g4;
#pragma unroll
        for (int n = 0; n < 4; ++n) {
            int col = colBase + wc + n * 16 + l15;
#pragma unroll
            for (int j = 0; j < 4; ++j)
                Sh[sbase + (size_t)(row0 + j) * 512 + col] = (h16)(acc[m][n][j] * 0.125f);
        }
    }
}

// ---------------- fused softmax+PV (single f16 S & V, P hi/lo in regs) ----------------
template<bool CAUSAL>
__global__ __launch_bounds__(256) void attn_pv(
    const h16* __restrict__ Shg,
    const h16* __restrict__ Vh,
    h16* __restrict__ Ch, h16* __restrict__ Cl, int bh0)
{
    __shared__ h16 ShL[4096], VhL[4096];
    __shared__ float mS[64], iS[64];
    int z = blockIdx.z, bh_ = bh0 + z;
    int rowBase = blockIdx.x * 64;
    const h16* Sa = Shg + (size_t)z * 262144 + (size_t)rowBase * 512;
    const h16* Va = Vh + (size_t)z * 32768;
    int t = threadIdx.x, lane = t & 63, wid = t >> 6;
    int l15 = lane & 15, g = lane >> 4;

    // ---- pass 1: per-row max & sum(exp) (4 lanes per row) ----
    {
        int tr = t >> 2, tq = t & 3;
        int limit = CAUSAL ? (rowBase + tr + 1) : 512;
        float m = -1e30f, l = 0.f;
        const h16* rh = Sa + (size_t)tr * 512;
        for (int c = 0; c < 16; ++c) {
            int col0 = tq * 8 + c * 32;
            if (col0 >= limit) break;
            hfrag hv = *(const hfrag*)(rh + col0);
            float s[8]; float cm = -1e30f;
#pragma unroll
            for (int j = 0; j < 8; ++j) {
                float sv = (float)hv[j];
                s[j] = (col0 + j < limit) ? sv : -1e30f;
                cm = fmaxf(cm, s[j]);
            }
            if (cm > m) { l *= __expf(m - cm); m = cm; }
#pragma unroll
            for (int j = 0; j < 8; ++j) l += __expf(s[j] - m);
        }
#pragma unroll
        for (int o = 1; o < 4; o <<= 1) {
            float mo = __shfl_xor(m, o, 64);
            float lo2 = __shfl_xor(l, o, 64);
            float mc = fmaxf(m, mo);
            l = l * __expf(m - mc) + lo2 * __expf(mo - mc);
            m = mc;
        }
        if (tq == 0) { mS[tr] = m; iS[tr] = 1.0f / l; }
    }
    __syncthreads();

    // ---- pass 2: K-loop, S->P hi/lo in registers, 2-product MFMA ----
    int arow = wid * 16 + l15;
    float am = mS[arow], ai = iS[arow];
    int alim = CAUSAL ? (rowBase + arow + 1) : 512;
    int kend = CAUSAL ? (rowBase + 64) : 512;
    f32x4 acc[4] = {};

    for (int k0 = 0; k0 < kend; k0 += 64) {
        __syncthreads();
#pragma unroll
        for (int cc = 0; cc < 2; ++cc) {
            int c = t + cc * 256;
            int r = c >> 3, sq = (c & 7) ^ (r & 7);
            GLL16(Sa + (size_t)r * 512 + k0 + sq * 8, &ShL[c * 8]);
            GLL16(Va + (size_t)r * 512 + k0 + sq * 8, &VhL[c * 8]);
        }
        __syncthreads();

#pragma unroll
        for (int kk = 0; kk < 2; ++kk) {
            int chunk = (kk << 2) | g;
            int aq = chunk ^ (arow & 7);
            hfrag sh_ = *(const hfrag*)&ShL[arow * 64 + aq * 8];
            int cbase = k0 + chunk * 8;
            hfrag ph, pl;
#pragma unroll
            for (int j = 0; j < 8; ++j) {
                float p = __expf((float)sh_[j] - am) * ai;
                p = (cbase + j < alim) ? p : 0.f;
                h16 hh = (h16)p;
                ph[j] = hh;
                pl[j] = (h16)(p - (float)hh);
            }
#pragma unroll
            for (int n = 0; n < 4; ++n) {
                int brow = n * 16 + l15;
                int bq = chunk ^ (brow & 7);
                hfrag bh = *(const hfrag*)&VhL[brow * 64 + bq * 8];
                acc[n] = __builtin_amdgcn_mfma_f32_16x16x32_f16(ph, bh, acc[n], 0, 0, 0);
                acc[n] = __builtin_amdgcn_mfma_f32_16x16x32_f16(pl, bh, acc[n], 0, 0, 0);
            }
        }
    }

    int brow = (bh_ >> 4) * 512 + rowBase + wid * 16 + g * 4;
    int bcol = (bh_ & 15) * 64;
#pragma unroll
    for (int n = 0; n < 4; ++n) {
        int col = bcol + n * 16 + l15;
#pragma unroll
        for (int j = 0; j < 4; ++j) {
            float v = acc[n][j];
            h16 hh = (h16)v;
            Ch[(size_t)(brow + j) * 1024 + col] = hh;
            Cl[(size_t)(brow + j) * 1024 + col] = (h16)(v - (float)hh);
        }
    }
}

// ---------------- V-transpose (single plane) ----------------
__global__ __launch_bounds__(256) void vt_split(
    const h16* __restrict__ inh, int ld, h16* __restrict__ oh)
{
    __shared__ h16 tile[64][68];
    int z = blockIdx.z, b = z >> 4, h = z & 15;
    size_t ibase = ((size_t)b * 512 + blockIdx.x * 64) * ld + h * 64;
    size_t obase = (size_t)z * 32768 + blockIdx.x * 64;
    int tr = threadIdx.x >> 4, tc = (threadIdx.x & 15) * 4;
#pragma unroll
    for (int i = 0; i < 4; ++i) {
        int tt = tr + i * 16;
        short4 v = *(const short4*)(inh + ibase + (size_t)tt * ld + tc);
        tile[tt][tc + 0] = ((h16*)&v)[0];
        tile[tt][tc + 1] = ((h16*)&v)[1];
        tile[tt][tc + 2] = ((h16*)&v)[2];
        tile[tt][tc + 3] = ((h16*)&v)[3];
    }
    __syncthreads();
#pragma unroll
    for (int i = 0; i < 4; ++i) {
        int d = tr + i * 16;
        h16 w[4] = {tile[tc + 0][d], tile[tc + 1][d], tile[tc + 2][d], tile[tc + 3][d]};
        *(short4*)(oh + obase + (size_t)d * 512 + tc) = *(short4*)w;
    }
}

// ---------------- bf16 NT MFMA GEMM (MoE), BK=64, flat grid, XCD pinned, K-split, count-skip ----
template<int TN, bool RELU, bool ROWFAST, int KS>
__global__ __launch_bounds__(256) void gemm_bf16_moe(
    const unsigned short* __restrict__ A,
    const unsigned short* __restrict__ Bt,
    const float* __restrict__ bias,
    unsigned short* __restrict__ C,
    int K, long long sA, long long sB, long long sC, long long sBias, int ldc,
    int emask, int elog, int nrow, int ncol,
    const int* __restrict__ counts, int e0, long long sHalf)
{
    constexpr int NFR = TN / 32;
    __shared__ unsigned short Al[128 * 64];
    __shared__ unsigned short Bl[TN * 64];
    int id = blockIdx.x;
    int e = id & emask;
    int tb = id >> elog;
    int half = 0;
    if (KS == 2) {
        int per = nrow * ncol;
        half = (tb >= per) ? 1 : 0;
        tb -= half * per;
    }
    int row, col;
    if (ROWFAST) { row = tb % nrow; col = tb / nrow; }
    else         { col = tb % ncol; row = tb / ncol; }
    int rowBase = row * 128;

    int bound = counts[e0 + e];
    if (bound > CAPE) bound = CAPE;
    if (rowBase >= bound) return;

    A    += (size_t)e * sA;
    Bt   += (size_t)e * sB;
    bias += (size_t)e * sBias;
    long long zC = (long long)e * sC + (long long)half * sHalf;

    int colBase = col * TN;
    int t = threadIdx.x, lane = t & 63, wid = t >> 6;
    int wr = (wid >> 1) * 64, wc = (wid & 1) * (TN / 2);

    const unsigned short* Ag = A  + (size_t)rowBase * K;
    const unsigned short* Bg = Bt + (size_t)colBase * K;

    f32x4 acc[4][NFR] = {};
    int l15 = lane & 15, g = lane >> 4;

    int kb = half * (K / KS), ke = kb + (K / KS);
    for (int k0 = kb; k0 < ke; k0 += 64) {
        __syncthreads();
#pragma unroll
        for (int cc = 0; cc < 4; ++cc) {
            int c = t + cc * 256;
            int r = c >> 3, sq = (c & 7) ^ (r & 7);
            GLL16(Ag + (size_t)r * K + k0 + sq * 8, &Al[c * 8]);
        }
#pragma unroll
        for (int cc = 0; cc < TN / 32; ++cc) {
            int c = t + cc * 256;
            int r = c >> 3, sq = (c & 7) ^ (r & 7);
            GLL16(Bg + (size_t)r * K + k0 + sq * 8, &Bl[c * 8]);
        }
        __syncthreads();

        bfrag b[2][NFR];
#pragma unroll
        for (int kk = 0; kk < 2; ++kk)
#pragma unroll
            for (int n = 0; n < NFR; ++n) {
                int rr = wc + n * 16 + l15;
                int q = ((kk << 2) | g) ^ (rr & 7);
                b[kk][n] = *(const bfrag*)&Bl[rr * 64 + q * 8];
            }
#pragma unroll
        for (int m = 0; m < 4; ++m) {
            int rr = wr + m * 16 + l15;
#pragma unroll
            for (int kk = 0; kk < 2; ++kk) {
                int q = ((kk << 2) | g) ^ (rr & 7);
                bfrag a = *(const bfrag*)&Al[rr * 64 + q * 8];
#pragma unroll
                for (int n = 0; n < NFR; ++n)
                    acc[m][n] = __builtin_amdgcn_mfma_f32_16x16x32_bf16(a, b[kk][n], acc[m][n], 0, 0, 0);
            }
        }
    }

    int g4 = g * 4;
#pragma unroll
    for (int m = 0; m < 4; ++m) {
        int row0 = rowBase + wr + m * 16 + g4;
#pragma unroll
        for (int n = 0; n < NFR; ++n) {
            int cc = colBase + wc + n * 16 + l15;
            float bv = (KS == 1 || half == 0) ? bias[cc] : 0.f;
#pragma unroll
            for (int j = 0; j < 4; ++j) {
                float v = acc[m][n][j] + bv;
                if (RELU) v = fmaxf(v, 0.f);
                C[zC + (size_t)(row0 + j) * ldc + cc] = f2bf(v);
            }
        }
    }
}

// ---------------- transpose+convert fp32 [R][Cn] -> bf16 [Cn][R] (per z) ----------------
__global__ __launch_bounds__(256) void tcvt_kernel(const float* __restrict__ in,
    unsigned short* __restrict__ out, int R, int Cn)
{
    __shared__ unsigned short tile[64][68];
    size_t zoff = (size_t)blockIdx.z * R * Cn;
    in += zoff; out += zoff;
    int r0 = blockIdx.y * 64, c0 = blockIdx.x * 64;
    int tr = threadIdx.x >> 4, tc = (threadIdx.x & 15) * 4;
#pragma unroll
    for (int i = 0; i < 4; ++i) {
        int r = tr + i * 16;
        float4 v = *(const float4*)&in[(size_t)(r0 + r) * Cn + c0 + tc];
        tile[r][tc + 0] = f2bf(v.x);
        tile[r][tc + 1] = f2bf(v.y);
        tile[r][tc + 2] = f2bf(v.z);
        tile[r][tc + 3] = f2bf(v.w);
    }
    __syncthreads();
#pragma unroll
    for (int i = 0; i < 4; ++i) {
        int c = tr + i * 16;
        ushort4 w;
        w.x = tile[tc + 0][c];
        w.y = tile[tc + 1][c];
        w.z = tile[tc + 2][c];
        w.w = tile[tc + 3][c];
        *(ushort4*)&out[(size_t)(c0 + c) * R + r0 + tc] = w;
    }
}

// ---------------- router: 1024 blocks, one wave per token ----------------
__global__ __launch_bounds__(256) void router_kernel(
    const float* __restrict__ xf, const float* __restrict__ rw, const float* __restrict__ rb,
    const float* __restrict__ tmask,
    int* __restrict__ eidx, float* __restrict__ gate, int* __restrict__ valid,
    float* __restrict__ partials)
{
    int wid = threadIdx.x >> 6, lane = threadIdx.x & 63;
    int tok = blockIdx.x * 4 + wid;
    __shared__ float wpart[4][10];

    const float* xrow = xf + (size_t)tok * DMODEL;
    float acc[8] = {0,0,0,0,0,0,0,0};
#pragma unroll 4
    for (int kk = 0; kk < 16; ++kk) {
        int d = lane + (kk << 6);
        float xd = xrow[d];
        const float4* rp = (const float4*)(rw + (size_t)d * 8);
        float4 r0 = rp[0], r1 = rp[1];
        acc[0] = fmaf(xd, r0.x, acc[0]); acc[1] = fmaf(xd, r0.y, acc[1]);
        acc[2] = fmaf(xd, r0.z, acc[2]); acc[3] = fmaf(xd, r0.w, acc[3]);
        acc[4] = fmaf(xd, r1.x, acc[4]); acc[5] = fmaf(xd, r1.y, acc[5]);
        acc[6] = fmaf(xd, r1.z, acc[6]); acc[7] = fmaf(xd, r1.w, acc[7]);
    }
#pragma unroll
    for (int e = 0; e < 8; ++e)
#pragma unroll
        for (int o = 1; o < 64; o <<= 1) acc[e] += __shfl_xor(acc[e], o, 64);

    if (lane == 0) {
        float l[8]; float m = -1e30f;
#pragma unroll
        for (int e = 0; e < 8; ++e) { l[e] = acc[e] + rb[e]; m = fmaxf(m, l[e]); }
        float se = 0.f;
#pragma unroll
        for (int e = 0; e < 8; ++e) se += expf(l[e] - m);
        int am = 0; float bm = l[0];
#pragma unroll
        for (int e = 1; e < 8; ++e) if (l[e] > bm) { bm = l[e]; am = e; }
        float inv_se = 1.0f / se;
        float g = expf(l[am] - m) * inv_se;
        float vld = (tmask[tok] > 0.f) ? 1.f : 0.f;
        eidx[tok] = am; gate[tok] = g; valid[tok] = (int)vld;
#pragma unroll
        for (int e = 0; e < 8; ++e) wpart[wid][e] = expf(l[e] - m) * inv_se * vld;
        float lse = logf(se) + m;
        wpart[wid][8] = lse * lse * vld;
        wpart[wid][9] = vld;
    }
    __syncthreads();
    if (threadIdx.x == 0) {
        for (int j = 0; j < 10; ++j)
            partials[blockIdx.x * 10 + j] = wpart[0][j] + wpart[1][j] + wpart[2][j] + wpart[3][j];
    }
}

// ---------------- capacity scan ----------------
__global__ __launch_bounds__(256) void scan_kernel(
    const int* __restrict__ eidx, const int* __restrict__ valid, const float* __restrict__ gate,
    int* __restrict__ pc, float* __restrict__ gk, int* __restrict__ keepf,
    int* __restrict__ counts)
{
    __shared__ int cnt[256][8];
    int tid = threadIdx.x;
    int local[8] = {0,0,0,0,0,0,0,0};
    int base = tid * 16;
    for (int i = 0; i < 16; ++i) { int e = eidx[base + i]; local[e] += valid[base + i]; }
#pragma unroll
    for (int e = 0; e < 8; ++e) cnt[tid][e] = local[e];
    __syncthreads();
    if (tid < 8) {
        int run = 0;
        for (int i = 0; i < 256; ++i) { int t = cnt[i][tid]; cnt[i][tid] = run; run += t; }
        counts[tid] = run;
    }
    __syncthreads();
    int off[8];
#pragma unroll
    for (int e = 0; e < 8; ++e) off[e] = cnt[tid][e];
    for (int i = 0; i < 16; ++i) {
        int tok = base + i;
        int e = eidx[tok], v = valid[tok];
        int pos = off[e]; off[e] += v;
        int kp = (v && pos < CAPE) ? 1 : 0;
        pc[tok]    = (pos < CAPE) ? pos : (CAPE - 1);
        keepf[tok] = kp;
        gk[tok]    = kp ? gate[tok] : 0.f;
    }
}

// ---------------- dispatch (expert-range) -> bf16 buffers ----------------
__global__ __launch_bounds__(256) void dispatch_bf16(const float* __restrict__ tln,
    const int* __restrict__ eidx, const int* __restrict__ pc, const int* __restrict__ keepf,
    unsigned short* __restrict__ buf, int e0, int ec)
{
    int tok = blockIdx.x;
    if (!keepf[tok]) return;
    int e = eidx[tok];
    if (e < e0 || e >= e0 + ec) return;
    int p = pc[tok];
    const float4 v = ((const float4*)(tln + (size_t)tok * DMODEL))[threadIdx.x];
    ushort4 o;
    o.x = f2bf(v.x); o.y = f2bf(v.y); o.z = f2bf(v.z); o.w = f2bf(v.w);
    ((ushort4*)(buf + ((size_t)(e - e0) * CAPE + p) * DMODEL))[threadIdx.x] = o;
}

// ---------------- combine add: out += gk * (ob0 + ob1) ----------------
__global__ __launch_bounds__(256) void combine_bf16(const unsigned short* __restrict__ ob,
    const int* __restrict__ eidx, const int* __restrict__ pc, const float* __restrict__ gk,
    float* __restrict__ out, int e0, int ec, long long sHalf)
{
    int tok = blockIdx.x;
    int e = eidx[tok];
    if (e < e0 || e >= e0 + ec) return;
    float g = gk[tok];
    int p = pc[tok];
    size_t idx = ((size_t)(e - e0) * CAPE + p) * DMODEL;
    float4* o = (float4*)(out + (size_t)tok * DMODEL);
    const ushort4 u0 = ((const ushort4*)(ob + idx))[threadIdx.x];
    const ushort4 u1 = ((const ushort4*)(ob + sHalf + idx))[threadIdx.x];
    float4 a = o[threadIdx.x];
    a.x += g * (bf2f(u0.x) + bf2f(u1.x));
    a.y += g * (bf2f(u0.y) + bf2f(u1.y));
    a.z += g * (bf2f(u0.z) + bf2f(u1.z));
    a.w += g * (bf2f(u0.w) + bf2f(u1.w));
    o[threadIdx.x] = a;
}

// ---------------- final scalar losses (1024 partials, 16/lane) ----------------
__global__ __launch_bounds__(64) void loss_kernel(const float* __restrict__ partials,
    const int* __restrict__ counts, float* __restrict__ out2)
{
    int lane = threadIdx.x;
    float p[10] = {0,0,0,0,0,0,0,0,0,0};
    for (int r = 0; r < 16; ++r) {
        const float* row = partials + ((size_t)lane * 16 + r) * 10;
#pragma unroll
        for (int j = 0; j < 10; ++j) p[j] += row[j];
    }
#pragma unroll
    for (int j = 0; j < 10; ++j)
#pragma unroll
        for (int o = 1; o < 64; o <<= 1) p[j] += __shfl_xor(p[j], o, 64);
    if (lane == 0) {
        float nv = fmaxf(p[9], 1.f);
        float lb = 0.f;
        for (int e = 0; e < 8; ++e) lb += ((float)counts[e] / nv) * (p[e] / nv);
        lb *= (float)NEXP;
        out2[0] = lb;
        out2[1] = p[8] / nv;
    }
}

// ---------------- host launch ----------------
extern "C" void kernel_launch(void* const* d_in, const int* in_sizes, int n_in,
                              void* d_out, int out_size, void* d_ws, size_t ws_size,
                              hipStream_t stream)
{
    const float* tgt        = (const float*)d_in[0];
    const float* src        = (const float*)d_in[1];
    const float* token_mask = (const float*)d_in[5];
    const float* ln1w = (const float*)d_in[6],  *ln1b = (const float*)d_in[7];
    const float* self_in_w  = (const float*)d_in[8],  *self_in_b  = (const float*)d_in[9];
    const float* self_out_w = (const float*)d_in[10], *self_out_b = (const float*)d_in[11];
    const float* ln2w = (const float*)d_in[12], *ln2b = (const float*)d_in[13];
    const float* enc_in_w   = (const float*)d_in[14], *enc_in_b   = (const float*)d_in[15];
    const float* enc_out_w  = (const float*)d_in[16], *enc_out_b  = (const float*)d_in[17];
    const float* ln3w = (const float*)d_in[18], *ln3b = (const float*)d_in[19];
    const float* rw = (const float*)d_in[20], *rb = (const float*)d_in[21];
    const float* w1 = (const float*)d_in[22], *b1 = (const float*)d_in[23];
    const float* w2 = (const float*)d_in[24], *b2 = (const float*)d_in[25];

    float* out = (float*)d_out;          // residual stream lives HERE
    float* ws  = (float*)d_ws;

    // ---- fixed layout (floats) ----
    float* tln = ws;                         // 4,194,304
    float* ctx = ws + 4194304;               // 4,194,304 (ctx hi/lo f16)
    int*   eidxA   = (int*)(ws + 8388608);
    int*   validA  = eidxA + 4096;
    int*   pcA     = validA + 4096;
    int*   keepA   = pcA + 4096;
    int*   countsA = keepA + 4096;           // 16
    float* gateA   = (float*)(countsA + 16);
    float* gkA     = gateA + 4096;
    float* partA   = gkA + 4096;             // 1024*10
    const size_t POOL_OFF = 8425984;         // floats
    float* pool = ws + POOL_OFF;

    size_t Wf = ws_size / sizeof(float);
    size_t pf = (Wf > POOL_OFF) ? (Wf - POOL_OFF) : 0;

    // pool need: qreg bg*1.57M + vreg bg*0.26M + sreg max(6.3M, zc*131072)
    int bg, zc;
    if      (pf >= 20971520) { bg = 8; zc = 32; }
    else if (pf >= 12058624) { bg = 4; zc = 16; }
    else                     { bg = 2; zc = 16; }
    int ecs = 1;
    for (int c = 8; c >= 1; c >>= 1)
        if ((size_t)c * 4063232ull <= pf) { ecs = c; break; }
    int elog = (ecs == 8) ? 3 : (ecs == 4) ? 2 : (ecs == 2) ? 1 : 0;

    float* qreg = pool;
    float* vreg = qreg + (size_t)bg * 1572864;
    float* sreg = vreg + (size_t)bg * 262144;

    h16* tlnh = (h16*)tln;
    h16* tlnl = tlnh + 4194304;
    h16* ctxh = (h16*)ctx;
    h16* ctxl = ctxh + 4194304;

    // ================= self attention =================
    ln_kernel<1><<<NTOK, 256, 0, stream>>>(tgt, ln1w, ln1b, nullptr, tlnh, tlnl);

    for (int g0 = 0; g0 < BATCH; g0 += bg) {
        h16* sb  = (h16*)sreg;
        h16* whi = sb, *wlo = sb + 3145728;
        split_f16<<<1536, 256, 0, stream>>>(self_in_w, whi, wlo, 393216);

        h16* qkvh = (h16*)qreg, *qkvl = qkvh + (size_t)bg * 1572864;
        gemm_f16x2_nt<2><<<dim3(24, bg * 4, 1), 256, 0, stream>>>(
            tlnh + (size_t)g0 * 524288, tlnl + (size_t)g0 * 524288, 1024,
            whi, wlo, 1024, self_in_b, nullptr,
            nullptr, qkvh, qkvl, 1024, 3072);

        h16* vth = (h16*)vreg;
        vt_split<<<dim3(8, 1, bg * 16), 256, 0, stream>>>(qkvh + 2048, 3072, vth);

        h16* sh = sb;
        for (int c0 = 0; c0 < bg * 16; c0 += zc) {
            attn_qk<true><<<dim3(4, 4, zc), 256, 0, stream>>>(
                qkvh, qkvl, 3072, qkvh + 1024, qkvl + 1024, 3072, sh, c0);
            attn_pv<true><<<dim3(8, 1, zc), 256, 0, stream>>>(
                sh, vth + (size_t)c0 * 32768, ctxh, ctxl, g0 * 16 + c0);
        }
    }
    {
        h16* sb = (h16*)sreg;
        h16* owhi = sb, *owlo = sb + 1048576;
        split_f16<<<512, 256, 0, stream>>>(self_out_w, owhi, owlo, 131072);
        gemm_f16x2_nt<1><<<dim3(8, 32, 1), 256, 0, stream>>>(
            ctxh, ctxl, 1024, owhi, owlo, 1024, self_out_b, tgt,
            out, nullptr, nullptr, 1024, 1024);
    }

    // ================= cross attention =================
    ln_kernel<1><<<NTOK, 256, 0, stream>>>(out, ln2w, ln2b, nullptr, tlnh, tlnl);

    for (int g0 = 0; g0 < BATCH; g0 += bg) {
        h16* sb  = (h16*)sreg;
        h16* shi = sb, *slo = sb + (size_t)bg * 524288;
        h16* ehi = sb + (size_t)bg * 1048576, *elo = ehi + 3145728;
        split_f16<<<bg * 256, 256, 0, stream>>>(src + (size_t)g0 * 524288, shi, slo, bg * 65536);
        split_f16<<<1536, 256, 0, stream>>>(enc_in_w, ehi, elo, 393216);

        h16* q2h  = (h16*)qreg,                 *q2l  = q2h + (size_t)bg * 524288;
        h16* kv2h = q2h + (size_t)bg * 1048576, *kv2l = kv2h + (size_t)bg * 1048576;
        gemm_f16x2_nt<2><<<dim3(8, bg * 4, 1), 256, 0, stream>>>(
            tlnh + (size_t)g0 * 524288, tlnl + (size_t)g0 * 524288, 1024,
            ehi, elo, 1024, enc_in_b, nullptr,
            nullptr, q2h, q2l, 1024, 1024);
        gemm_f16x2_nt<2><<<dim3(16, bg * 4, 1), 256, 0, stream>>>(
            shi, slo, 1024, ehi + 1048576, elo + 1048576, 1024, enc_in_b + 1024, nullptr,
            nullptr, kv2h, kv2l, 1024, 2048);

        h16* vth = (h16*)vreg;
        vt_split<<<dim3(8, 1, bg * 16), 256, 0, stream>>>(kv2h + 1024, 2048, vth);

        h16* sh = sb;
        for (int c0 = 0; c0 < bg * 16; c0 += zc) {
            attn_qk<false><<<dim3(4, 4, zc), 256, 0, stream>>>(
                q2h, q2l, 1024, kv2h, kv2l, 2048, sh, c0);
            attn_pv<false><<<dim3(8, 1, zc), 256, 0, stream>>>(
                sh, vth + (size_t)c0 * 32768, ctxh, ctxl, g0 * 16 + c0);
        }
    }
    {
        h16* sb = (h16*)sreg;
        h16* owhi = sb, *owlo = sb + 1048576;
        split_f16<<<512, 256, 0, stream>>>(enc_out_w, owhi, owlo, 131072);
        gemm_f16x2_nt<1><<<dim3(8, 32, 1), 256, 0, stream>>>(
            ctxh, ctxl, 1024, owhi, owlo, 1024, enc_out_b, out,
            out, nullptr, nullptr, 1024, 1024);
    }

    // ================= MoE =================
    ln_kernel<0><<<NTOK, 256, 0, stream>>>(out, ln3w, ln3b, tln, nullptr, nullptr);
    router_kernel<<<1024, 256, 0, stream>>>(tln, rw, rb, token_mask, eidxA, gateA, validA, partA);
    scan_kernel<<<1, 256, 0, stream>>>(eidxA, validA, gateA, pcA, gkA, keepA, countsA);

    long long sHalf = 0;
    for (int e0 = 0; e0 < NEXP; e0 += ecs) {
        unsigned short* wt   = (unsigned short*)pool;
        unsigned short* hB   = (unsigned short*)(pool + (size_t)ecs * 2097152);
        unsigned short* bufB = (unsigned short*)(pool + (size_t)ecs * 3407872);
        unsigned short* obB  = bufB;                       // ob0 overlays bufB
        sHalf = (long long)ecs * 655360;

        tcvt_kernel<<<dim3(64, 16, ecs), 256, 0, stream>>>(
            w1 + (size_t)e0 * 4194304, wt, 1024, 4096);
        dispatch_bf16<<<NTOK, 256, 0, stream>>>(tln, eidxA, pcA, keepA, bufB, e0, ecs);
        gemm_bf16_moe<128, true, true, 1><<<ecs * 5 * 32, 256, 0, stream>>>(
            bufB, wt, b1 + (size_t)e0 * 4096, hB,
            1024, 655360LL, 4194304LL, 2621440LL, 4096LL, 4096,
            ecs - 1, elog, 5, 32, countsA, e0, 0LL);

        tcvt_kernel<<<dim3(16, 64, ecs), 256, 0, stream>>>(
            w2 + (size_t)e0 * 4194304, wt, 4096, 1024);
        gemm_bf16_moe<64, false, false, 2><<<ecs * 5 * 16 * 2, 256, 0, stream>>>(
            hB, wt, b2 + (size_t)e0 * 1024, obB,
            4096, 2621440LL, 4194304LL, 655360LL, 1024LL, 1024,
            ecs - 1, elog, 5, 16, countsA, e0, sHalf);

        combine_bf16<<<NTOK, 256, 0, stream>>>(obB, eidxA, pcA, gkA, out, e0, ecs, sHalf);
    }

    // ===== losses =====
    loss_kernel<<<1, 64, 0, stream>>>(partA, countsA, out + (size_t)NTOK * DMODEL);
}

// Round 14
// 749.825 us; speedup vs baseline: 3.6102x; 1.0386x over previous
//
#include <hip/hip_runtime.h>
#include <cstdint>

// ---------------- problem constants ----------------
constexpr int BATCH  = 8;
constexpr int TSEQ   = 512;
constexpr int DMODEL = 1024;
constexpr int NEXP   = 8;
constexpr int CAPE   = 640;
constexpr int NTOK   = BATCH * TSEQ;        // 4096

typedef _Float16 h16;
typedef __attribute__((ext_vector_type(8))) short bfrag;
typedef __attribute__((ext_vector_type(8))) _Float16 hfrag;
typedef __attribute__((ext_vector_type(4))) float f32x4;

__device__ __forceinline__ unsigned short f2bf(float f) {
    uint32_t u = __float_as_uint(f);
    uint32_t r = (u + 0x7FFFu + ((u >> 16) & 1u)) >> 16;   // RNE
    return (unsigned short)r;
}
__device__ __forceinline__ float bf2f(unsigned short b) {
    return __uint_as_float((uint32_t)b << 16);
}

#define GLL16(SRC, DST) __builtin_amdgcn_global_load_lds( \
    (const __attribute__((address_space(1))) void*)(SRC), \
    (__attribute__((address_space(3))) void*)(DST), 16, 0, 0)

// ---------------- LayerNorm: MODE 1 -> f16 hi/lo out ----------------
__global__ __launch_bounds__(256) void ln_hl(const float* __restrict__ in,
    const float* __restrict__ gw, const float* __restrict__ gb,
    h16* __restrict__ ohi, h16* __restrict__ olo)
{
    int row = blockIdx.x, tid = threadIdx.x;
    const float4 v = *(const float4*)(in + (size_t)row * DMODEL + tid * 4);
    float s  = v.x + v.y + v.z + v.w;
    float ss = v.x*v.x + v.y*v.y + v.z*v.z + v.w*v.w;
#pragma unroll
    for (int o = 1; o < 64; o <<= 1) { s += __shfl_xor(s, o, 64); ss += __shfl_xor(ss, o, 64); }
    __shared__ float rs[4], rss[4];
    int wid = tid >> 6, lane = tid & 63;
    if (lane == 0) { rs[wid] = s; rss[wid] = ss; }
    __syncthreads();
    s  = rs[0] + rs[1] + rs[2] + rs[3];
    ss = rss[0] + rss[1] + rss[2] + rss[3];
    float mean = s * (1.0f / DMODEL);
    float var  = ss * (1.0f / DMODEL) - mean * mean;
    float inv  = rsqrtf(var + 1e-5f);
    float4 w4 = *(const float4*)(gw + tid * 4);
    float4 b4 = *(const float4*)(gb + tid * 4);
    float o[4];
    o[0] = (v.x - mean) * inv * w4.x + b4.x;
    o[1] = (v.y - mean) * inv * w4.y + b4.y;
    o[2] = (v.z - mean) * inv * w4.z + b4.z;
    o[3] = (v.w - mean) * inv * w4.w + b4.w;
    short4 hv, lv;
#pragma unroll
    for (int j = 0; j < 4; ++j) {
        h16 hh = (h16)o[j];
        ((h16*)&hv)[j] = hh;
        ((h16*)&lv)[j] = (h16)(o[j] - (float)hh);
    }
    *(short4*)(ohi + (size_t)row * DMODEL + tid * 4) = hv;
    *(short4*)(olo + (size_t)row * DMODEL + tid * 4) = lv;
}

// ---------------- fp32 -> fp16 hi/lo split ----------------
__global__ __launch_bounds__(256) void split_f16(const float* __restrict__ in,
    h16* __restrict__ hi, h16* __restrict__ lo, int n8)
{
    int i = blockIdx.x * 256 + threadIdx.x;
    if (i >= n8) return;
    const float4* p = (const float4*)in + 2 * (size_t)i;
    float4 v0 = p[0], v1 = p[1];
    float vv[8] = {v0.x, v0.y, v0.z, v0.w, v1.x, v1.y, v1.z, v1.w};
    hfrag h, l;
#pragma unroll
    for (int j = 0; j < 8; ++j) {
        h16 hj = (h16)vv[j];
        h[j] = hj;
        l[j] = (h16)(vv[j] - (float)hj);
    }
    ((hfrag*)hi)[i] = h;
    ((hfrag*)lo)[i] = l;
}

// ---------------- fp16x2 (3-product) NT MFMA GEMM, BK=64 ----------------
template<int OMODE>
__global__ __launch_bounds__(256) void gemm_f16x2_nt(
    const h16* __restrict__ Ahi, const h16* __restrict__ Alo, int lda,
    const h16* __restrict__ Bhi, const h16* __restrict__ Blo, int ldb,
    const float* __restrict__ bias, const float* __restrict__ res,
    float* __restrict__ C, h16* __restrict__ Chi, h16* __restrict__ Clo,
    int K, int ldc)
{
    __shared__ h16 AhL[8192], AlL[8192], BhL[8192], BlL[8192];
    int rowBase = blockIdx.y * 128, colBase = blockIdx.x * 128;
    int t = threadIdx.x, lane = t & 63, wid = t >> 6;
    int wr = (wid >> 1) * 64, wc = (wid & 1) * 64;
    const h16* Ah = Ahi + (size_t)rowBase * lda;
    const h16* Al = Alo + (size_t)rowBase * lda;
    const h16* Bh = Bhi + (size_t)colBase * ldb;
    const h16* Bl = Blo + (size_t)colBase * ldb;
    f32x4 acc[4][4] = {};
    int l15 = lane & 15, g = lane >> 4;

    for (int k0 = 0; k0 < K; k0 += 64) {
        __syncthreads();
#pragma unroll
        for (int cc = 0; cc < 4; ++cc) {
            int c = t + cc * 256;
            int r = c >> 3, sq = (c & 7) ^ (r & 7);
            GLL16(Ah + (size_t)r * lda + k0 + sq * 8, &AhL[c * 8]);
            GLL16(Al + (size_t)r * lda + k0 + sq * 8, &AlL[c * 8]);
            GLL16(Bh + (size_t)r * ldb + k0 + sq * 8, &BhL[c * 8]);
            GLL16(Bl + (size_t)r * ldb + k0 + sq * 8, &BlL[c * 8]);
        }
        __syncthreads();

#pragma unroll
        for (int kk = 0; kk < 2; ++kk) {
            hfrag bh[4], bl[4];
#pragma unroll
            for (int n = 0; n < 4; ++n) {
                int rr = wc + n * 16 + l15;
                int q = ((kk << 2) | g) ^ (rr & 7);
                bh[n] = *(const hfrag*)&BhL[rr * 64 + q * 8];
                bl[n] = *(const hfrag*)&BlL[rr * 64 + q * 8];
            }
#pragma unroll
            for (int m = 0; m < 4; ++m) {
                int rr = wr + m * 16 + l15;
                int q = ((kk << 2) | g) ^ (rr & 7);
                hfrag ah = *(const hfrag*)&AhL[rr * 64 + q * 8];
                hfrag al = *(const hfrag*)&AlL[rr * 64 + q * 8];
#pragma unroll
                for (int n = 0; n < 4; ++n) {
                    acc[m][n] = __builtin_amdgcn_mfma_f32_16x16x32_f16(ah, bh[n], acc[m][n], 0, 0, 0);
                    acc[m][n] = __builtin_amdgcn_mfma_f32_16x16x32_f16(ah, bl[n], acc[m][n], 0, 0, 0);
                    acc[m][n] = __builtin_amdgcn_mfma_f32_16x16x32_f16(al, bh[n], acc[m][n], 0, 0, 0);
                }
            }
        }
    }

    int g4 = g * 4;
#pragma unroll
    for (int m = 0; m < 4; ++m) {
        int row0 = rowBase + wr + m * 16 + g4;
#pragma unroll
        for (int n = 0; n < 4; ++n) {
            int col = colBase + wc + n * 16 + l15;
            float bv = bias[col];
#pragma unroll
            for (int j = 0; j < 4; ++j) {
                float v = acc[m][n][j] + bv;
                if (OMODE == 1) v += res[(size_t)(row0 + j) * ldc + col];
                if (OMODE < 2) {
                    C[(size_t)(row0 + j) * ldc + col] = v;
                } else {
                    h16 hh = (h16)v;
                    Chi[(size_t)(row0 + j) * ldc + col] = hh;
                    Clo[(size_t)(row0 + j) * ldc + col] = (h16)(v - (float)hh);
                }
            }
        }
    }
}

// ---------------- attention QK^T (f16x2, K=64 single step) -> single f16 S ----------------
template<bool CAUSAL>
__global__ __launch_bounds__(256) void attn_qk(
    const h16* __restrict__ Qh, const h16* __restrict__ Ql, int lda,
    const h16* __restrict__ Kh, const h16* __restrict__ Kl, int ldb,
    h16* __restrict__ Sh, int zoff)
{
    int rowBase = blockIdx.y * 128, colBase = blockIdx.x * 128;
    if (CAUSAL && colBase >= rowBase + 128) return;
    __shared__ h16 AhL[8192], AlL[8192], BhL[8192], BlL[8192];
    int z = blockIdx.z;
    int bh_ = zoff + z, b = bh_ >> 4, h = bh_ & 15;
    const h16* Ah = Qh + (size_t)(b * 512 + rowBase) * lda + h * 64;
    const h16* Al = Ql + (size_t)(b * 512 + rowBase) * lda + h * 64;
    const h16* Bh = Kh + (size_t)(b * 512 + colBase) * ldb + h * 64;
    const h16* Bl = Kl + (size_t)(b * 512 + colBase) * ldb + h * 64;
    int t = threadIdx.x, lane = t & 63, wid = t >> 6;
    int wr = (wid >> 1) * 64, wc = (wid & 1) * 64;
    f32x4 acc[4][4] = {};
    int l15 = lane & 15, g = lane >> 4;

#pragma unroll
    for (int cc = 0; cc < 4; ++cc) {
        int c = t + cc * 256;
        int r = c >> 3, sq = (c & 7) ^ (r & 7);
        GLL16(Ah + (size_t)r * lda + sq * 8, &AhL[c * 8]);
        GLL16(Al + (size_t)r * lda + sq * 8, &AlL[c * 8]);
        GLL16(Bh + (size_t)r * ldb + sq * 8, &BhL[c * 8]);
        GLL16(Bl + (size_t)r * ldb + sq * 8, &BlL[c * 8]);
    }
    __syncthreads();

#pragma unroll
    for (int kk = 0; kk < 2; ++kk) {
        hfrag bh[4], bl[4];
#pragma unroll
        for (int n = 0; n < 4; ++n) {
            int rr = wc + n * 16 + l15;
            int q = ((kk << 2) | g) ^ (rr & 7);
            bh[n] = *(const hfrag*)&BhL[rr * 64 + q * 8];
            bl[n] = *(const hfrag*)&BlL[rr * 64 + q * 8];
        }
#pragma unroll
        for (int m = 0; m < 4; ++m) {
            int rr = wr + m * 16 + l15;
            int q = ((kk << 2) | g) ^ (rr & 7);
            hfrag ah = *(const hfrag*)&AhL[rr * 64 + q * 8];
            hfrag al = *(const hfrag*)&AlL[rr * 64 + q * 8];
#pragma unroll
            for (int n = 0; n < 4; ++n) {
                acc[m][n] = __builtin_amdgcn_mfma_f32_16x16x32_f16(ah, bh[n], acc[m][n], 0, 0, 0);
                acc[m][n] = __builtin_amdgcn_mfma_f32_16x16x32_f16(ah, bl[n], acc[m][n], 0, 0, 0);
                acc[m][n] = __builtin_amdgcn_mfma_f32_16x16x32_f16(al, bh[n], acc[m][n], 0, 0, 0);
            }
        }
    }

    size_t sbase = (size_t)z * 262144;
    int g4 = g * 4;
#pragma unroll
    for (int m = 0; m < 4; ++m) {
        int row0 = rowBase + wr + m * 16 + g4;
#pragma unroll
        for (int n = 0; n < 4; ++n) {
            int col = colBase + wc + n * 16 + l15;
#pragma unroll
            for (int j = 0; j < 4; ++j)
                Sh[sbase + (size_t)(row0 + j) * 512 + col] = (h16)(acc[m][n][j] * 0.125f);
        }
    }
}

// ---------------- fused softmax+PV: 512 threads, 8 waves, in-block K-split ----------------
template<bool CAUSAL>
__global__ __launch_bounds__(512) void attn_pv(
    const h16* __restrict__ Shg,
    const h16* __restrict__ Vh,
    h16* __restrict__ Ch, h16* __restrict__ Cl, int bh0)
{
    __shared__ h16 ShL[2][4096], VhL[2][4096];
    __shared__ float red[256][16];
    __shared__ float mS[64], iS[64];
    int z = blockIdx.z, bh_ = bh0 + z;
    int rowBase = blockIdx.x * 64;
    const h16* Sa = Shg + (size_t)z * 262144 + (size_t)rowBase * 512;
    const h16* Va = Vh + (size_t)z * 32768;
    int t = threadIdx.x;
    int wv = t >> 6, lane = t & 63;
    int g2 = wv >> 2, wid = wv & 3, tl = t & 255;
    int l15 = lane & 15, g = lane >> 4;

    // ---- pass 1: per-row max & sum(exp) (8 lanes per row) ----
    {
        int tr = t >> 3, tq = t & 7;
        int limit = CAUSAL ? (rowBase + tr + 1) : 512;
        float m = -1e30f, l = 0.f;
        const h16* rh = Sa + (size_t)tr * 512;
        for (int c = 0; c < 8; ++c) {
            int col0 = tq * 8 + c * 64;
            if (col0 >= limit) break;
            hfrag hv = *(const hfrag*)(rh + col0);
            float s[8]; float cm = -1e30f;
#pragma unroll
            for (int j = 0; j < 8; ++j) {
                float sv = (float)hv[j];
                s[j] = (col0 + j < limit) ? sv : -1e30f;
                cm = fmaxf(cm, s[j]);
            }
            if (cm > m) { l *= __expf(m - cm); m = cm; }
#pragma unroll
            for (int j = 0; j < 8; ++j) l += __expf(s[j] - m);
        }
#pragma unroll
        for (int o = 1; o < 8; o <<= 1) {
            float mo = __shfl_xor(m, o, 64);
            float lo2 = __shfl_xor(l, o, 64);
            float mc = fmaxf(m, mo);
            l = l * __expf(m - mc) + lo2 * __expf(mo - mc);
            m = mc;
        }
        if (tq == 0) { mS[tr] = m; iS[tr] = 1.0f / l; }
    }
    __syncthreads();

    // ---- pass 2: wave-group g2 handles 64-K chunks ci = g2, g2+2, ... ----
    int arow = wid * 16 + l15;
    float am = mS[arow], ai = iS[arow];
    int alim = CAUSAL ? (rowBase + arow + 1) : 512;
    int kend = CAUSAL ? (rowBase + 64) : 512;
    int nck = kend >> 6;
    f32x4 acc[4] = {};

    for (int ci = 0; ci < nck; ci += 2) {
        int myck = ci + g2;
        bool act = myck < nck;
        int k0 = myck << 6;
        __syncthreads();
        if (act) {
#pragma unroll
            for (int cc = 0; cc < 2; ++cc) {
                int c = tl + cc * 256;
                int r = c >> 3, sq = (c & 7) ^ (r & 7);
                GLL16(Sa + (size_t)r * 512 + k0 + sq * 8, &ShL[g2][c * 8]);
                GLL16(Va + (size_t)r * 512 + k0 + sq * 8, &VhL[g2][c * 8]);
            }
        }
        __syncthreads();
        if (act) {
#pragma unroll
            for (int kk = 0; kk < 2; ++kk) {
                int chunk = (kk << 2) | g;
                int aq = chunk ^ (arow & 7);
                hfrag sh_ = *(const hfrag*)&ShL[g2][arow * 64 + aq * 8];
                int cbase = k0 + chunk * 8;
                hfrag ph, pl;
#pragma unroll
                for (int j = 0; j < 8; ++j) {
                    float p = __expf((float)sh_[j] - am) * ai;
                    p = (cbase + j < alim) ? p : 0.f;
                    h16 hh = (h16)p;
                    ph[j] = hh;
                    pl[j] = (h16)(p - (float)hh);
                }
#pragma unroll
                for (int n = 0; n < 4; ++n) {
                    int brow = n * 16 + l15;
                    int bq = chunk ^ (brow & 7);
                    hfrag bh = *(const hfrag*)&VhL[g2][brow * 64 + bq * 8];
                    acc[n] = __builtin_amdgcn_mfma_f32_16x16x32_f16(ph, bh, acc[n], 0, 0, 0);
                    acc[n] = __builtin_amdgcn_mfma_f32_16x16x32_f16(pl, bh, acc[n], 0, 0, 0);
                }
            }
        }
    }

    // ---- cross-group reduce + epilogue ----
    __syncthreads();
    if (g2 == 1) {
#pragma unroll
        for (int n = 0; n < 4; ++n)
#pragma unroll
            for (int j = 0; j < 4; ++j) red[tl][n * 4 + j] = acc[n][j];
    }
    __syncthreads();
    if (g2 == 0) {
        int brow = (bh_ >> 4) * 512 + rowBase + wid * 16 + g * 4;
        int bcol = (bh_ & 15) * 64;
#pragma unroll
        for (int n = 0; n < 4; ++n) {
            int col = bcol + n * 16 + l15;
#pragma unroll
            for (int j = 0; j < 4; ++j) {
                float v = acc[n][j] + red[tl][n * 4 + j];
                h16 hh = (h16)v;
                Ch[(size_t)(brow + j) * 1024 + col] = hh;
                Cl[(size_t)(brow + j) * 1024 + col] = (h16)(v - (float)hh);
            }
        }
    }
}

// ---------------- V-transpose (single plane) ----------------
__global__ __launch_bounds__(256) void vt_split(
    const h16* __restrict__ inh, int ld, h16* __restrict__ oh)
{
    __shared__ h16 tile[64][68];
    int z = blockIdx.z, b = z >> 4, h = z & 15;
    size_t ibase = ((size_t)b * 512 + blockIdx.x * 64) * ld + h * 64;
    size_t obase = (size_t)z * 32768 + blockIdx.x * 64;
    int tr = threadIdx.x >> 4, tc = (threadIdx.x & 15) * 4;
#pragma unroll
    for (int i = 0; i < 4; ++i) {
        int tt = tr + i * 16;
        short4 v = *(const short4*)(inh + ibase + (size_t)tt * ld + tc);
        tile[tt][tc + 0] = ((h16*)&v)[0];
        tile[tt][tc + 1] = ((h16*)&v)[1];
        tile[tt][tc + 2] = ((h16*)&v)[2];
        tile[tt][tc + 3] = ((h16*)&v)[3];
    }
    __syncthreads();
#pragma unroll
    for (int i = 0; i < 4; ++i) {
        int d = tr + i * 16;
        h16 w[4] = {tile[tc + 0][d], tile[tc + 1][d], tile[tc + 2][d], tile[tc + 3][d]};
        *(short4*)(oh + obase + (size_t)d * 512 + tc) = *(short4*)w;
    }
}

// ---------------- bf16 NT MFMA GEMM (MoE), BK=64, flat grid, XCD pinned, K-split, count-skip ----
template<int TN, bool RELU, bool ROWFAST, int KS>
__global__ __launch_bounds__(256) void gemm_bf16_moe(
    const unsigned short* __restrict__ A,
    const unsigned short* __restrict__ Bt,
    const float* __restrict__ bias,
    unsigned short* __restrict__ C,
    int K, long long sA, long long sB, long long sC, long long sBias, int ldc,
    int emask, int elog, int nrow, int ncol,
    const int* __restrict__ counts, int e0, long long sHalf)
{
    constexpr int NFR = TN / 32;
    __shared__ unsigned short Al[128 * 64];
    __shared__ unsigned short Bl[TN * 64];
    int id = blockIdx.x;
    int e = id & emask;
    int tb = id >> elog;
    int half = 0;
    if (KS == 2) {
        int per = nrow * ncol;
        half = (tb >= per) ? 1 : 0;
        tb -= half * per;
    }
    int row, col;
    if (ROWFAST) { row = tb % nrow; col = tb / nrow; }
    else         { col = tb % ncol; row = tb / ncol; }
    int rowBase = row * 128;

    int bound = counts[e0 + e];
    if (bound > CAPE) bound = CAPE;
    if (rowBase >= bound) return;

    A    += (size_t)e * sA;
    Bt   += (size_t)e * sB;
    bias += (size_t)e * sBias;
    long long zC = (long long)e * sC + (long long)half * sHalf;

    int colBase = col * TN;
    int t = threadIdx.x, lane = t & 63, wid = t >> 6;
    int wr = (wid >> 1) * 64, wc = (wid & 1) * (TN / 2);

    const unsigned short* Ag = A  + (size_t)rowBase * K;
    const unsigned short* Bg = Bt + (size_t)colBase * K;

    f32x4 acc[4][NFR] = {};
    int l15 = lane & 15, g = lane >> 4;

    int kb = half * (K / KS), ke = kb + (K / KS);
    for (int k0 = kb; k0 < ke; k0 += 64) {
        __syncthreads();
#pragma unroll
        for (int cc = 0; cc < 4; ++cc) {
            int c = t + cc * 256;
            int r = c >> 3, sq = (c & 7) ^ (r & 7);
            GLL16(Ag + (size_t)r * K + k0 + sq * 8, &Al[c * 8]);
        }
#pragma unroll
        for (int cc = 0; cc < TN / 32; ++cc) {
            int c = t + cc * 256;
            int r = c >> 3, sq = (c & 7) ^ (r & 7);
            GLL16(Bg + (size_t)r * K + k0 + sq * 8, &Bl[c * 8]);
        }
        __syncthreads();

        bfrag b[2][NFR];
#pragma unroll
        for (int kk = 0; kk < 2; ++kk)
#pragma unroll
            for (int n = 0; n < NFR; ++n) {
                int rr = wc + n * 16 + l15;
                int q = ((kk << 2) | g) ^ (rr & 7);
                b[kk][n] = *(const bfrag*)&Bl[rr * 64 + q * 8];
            }
#pragma unroll
        for (int m = 0; m < 4; ++m) {
            int rr = wr + m * 16 + l15;
#pragma unroll
            for (int kk = 0; kk < 2; ++kk) {
                int q = ((kk << 2) | g) ^ (rr & 7);
                bfrag a = *(const bfrag*)&Al[rr * 64 + q * 8];
#pragma unroll
                for (int n = 0; n < NFR; ++n)
                    acc[m][n] = __builtin_amdgcn_mfma_f32_16x16x32_bf16(a, b[kk][n], acc[m][n], 0, 0, 0);
            }
        }
    }

    int g4 = g * 4;
#pragma unroll
    for (int m = 0; m < 4; ++m) {
        int row0 = rowBase + wr + m * 16 + g4;
#pragma unroll
        for (int n = 0; n < NFR; ++n) {
            int cc = colBase + wc + n * 16 + l15;
            float bv = (KS == 1 || half == 0) ? bias[cc] : 0.f;
#pragma unroll
            for (int j = 0; j < 4; ++j) {
                float v = acc[m][n][j] + bv;
                if (RELU) v = fmaxf(v, 0.f);
                C[zC + (size_t)(row0 + j) * ldc + cc] = f2bf(v);
            }
        }
    }
}

// ---------------- transpose+convert fp32 [R][Cn] -> bf16 [Cn][R] (per z) ----------------
__global__ __launch_bounds__(256) void tcvt_kernel(const float* __restrict__ in,
    unsigned short* __restrict__ out, int R, int Cn)
{
    __shared__ unsigned short tile[64][68];
    size_t zoff = (size_t)blockIdx.z * R * Cn;
    in += zoff; out += zoff;
    int r0 = blockIdx.y * 64, c0 = blockIdx.x * 64;
    int tr = threadIdx.x >> 4, tc = (threadIdx.x & 15) * 4;
#pragma unroll
    for (int i = 0; i < 4; ++i) {
        int r = tr + i * 16;
        float4 v = *(const float4*)&in[(size_t)(r0 + r) * Cn + c0 + tc];
        tile[r][tc + 0] = f2bf(v.x);
        tile[r][tc + 1] = f2bf(v.y);
        tile[r][tc + 2] = f2bf(v.z);
        tile[r][tc + 3] = f2bf(v.w);
    }
    __syncthreads();
#pragma unroll
    for (int i = 0; i < 4; ++i) {
        int c = tr + i * 16;
        ushort4 w;
        w.x = tile[tc + 0][c];
        w.y = tile[tc + 1][c];
        w.z = tile[tc + 2][c];
        w.w = tile[tc + 3][c];
        *(ushort4*)&out[(size_t)(c0 + c) * R + r0 + tc] = w;
    }
}

// ---------------- fused LN3 + router: 1024 blocks, one wave per token ----------------
__global__ __launch_bounds__(256) void ln_router(
    const float* __restrict__ xin, const float* __restrict__ gw, const float* __restrict__ gb,
    const float* __restrict__ rw, const float* __restrict__ rb,
    const float* __restrict__ tmask, float* __restrict__ tln,
    int* __restrict__ eidx, float* __restrict__ gate, int* __restrict__ valid,
    float* __restrict__ partials)
{
    int wid = threadIdx.x >> 6, lane = threadIdx.x & 63;
    int tok = blockIdx.x * 4 + wid;
    __shared__ float wpart[4][10];

    const float* xrow = xin + (size_t)tok * DMODEL;
    float xv[16];
    float s = 0.f, ss = 0.f;
#pragma unroll
    for (int kk = 0; kk < 16; ++kk) {
        float x = xrow[lane + (kk << 6)];
        xv[kk] = x; s += x; ss += x * x;
    }
#pragma unroll
    for (int o = 1; o < 64; o <<= 1) { s += __shfl_xor(s, o, 64); ss += __shfl_xor(ss, o, 64); }
    float mean = s * (1.0f / DMODEL);
    float var  = ss * (1.0f / DMODEL) - mean * mean;
    float inv  = rsqrtf(var + 1e-5f);

    float acc[8] = {0,0,0,0,0,0,0,0};
#pragma unroll 4
    for (int kk = 0; kk < 16; ++kk) {
        int d = lane + (kk << 6);
        float xd = (xv[kk] - mean) * inv * gw[d] + gb[d];
        tln[(size_t)tok * DMODEL + d] = xd;
        const float4* rp = (const float4*)(rw + (size_t)d * 8);
        float4 r0 = rp[0], r1 = rp[1];
        acc[0] = fmaf(xd, r0.x, acc[0]); acc[1] = fmaf(xd, r0.y, acc[1]);
        acc[2] = fmaf(xd, r0.z, acc[2]); acc[3] = fmaf(xd, r0.w, acc[3]);
        acc[4] = fmaf(xd, r1.x, acc[4]); acc[5] = fmaf(xd, r1.y, acc[5]);
        acc[6] = fmaf(xd, r1.z, acc[6]); acc[7] = fmaf(xd, r1.w, acc[7]);
    }
#pragma unroll
    for (int e = 0; e < 8; ++e)
#pragma unroll
        for (int o = 1; o < 64; o <<= 1) acc[e] += __shfl_xor(acc[e], o, 64);

    if (lane == 0) {
        float l[8]; float m = -1e30f;
#pragma unroll
        for (int e = 0; e < 8; ++e) { l[e] = acc[e] + rb[e]; m = fmaxf(m, l[e]); }
        float se = 0.f;
#pragma unroll
        for (int e = 0; e < 8; ++e) se += expf(l[e] - m);
        int am = 0; float bm = l[0];
#pragma unroll
        for (int e = 1; e < 8; ++e) if (l[e] > bm) { bm = l[e]; am = e; }
        float inv_se = 1.0f / se;
        float g = expf(l[am] - m) * inv_se;
        float vld = (tmask[tok] > 0.f) ? 1.f : 0.f;
        eidx[tok] = am; gate[tok] = g; valid[tok] = (int)vld;
#pragma unroll
        for (int e = 0; e < 8; ++e) wpart[wid][e] = expf(l[e] - m) * inv_se * vld;
        float lse = logf(se) + m;
        wpart[wid][8] = lse * lse * vld;
        wpart[wid][9] = vld;
    }
    __syncthreads();
    if (threadIdx.x == 0) {
        for (int j = 0; j < 10; ++j)
            partials[blockIdx.x * 10 + j] = wpart[0][j] + wpart[1][j] + wpart[2][j] + wpart[3][j];
    }
}

// ---------------- capacity scan ----------------
__global__ __launch_bounds__(256) void scan_kernel(
    const int* __restrict__ eidx, const int* __restrict__ valid, const float* __restrict__ gate,
    int* __restrict__ pc, float* __restrict__ gk, int* __restrict__ keepf,
    int* __restrict__ counts)
{
    __shared__ int cnt[256][8];
    int tid = threadIdx.x;
    int local[8] = {0,0,0,0,0,0,0,0};
    int base = tid * 16;
    for (int i = 0; i < 16; ++i) { int e = eidx[base + i]; local[e] += valid[base + i]; }
#pragma unroll
    for (int e = 0; e < 8; ++e) cnt[tid][e] = local[e];
    __syncthreads();
    if (tid < 8) {
        int run = 0;
        for (int i = 0; i < 256; ++i) { int t = cnt[i][tid]; cnt[i][tid] = run; run += t; }
        counts[tid] = run;
    }
    __syncthreads();
    int off[8];
#pragma unroll
    for (int e = 0; e < 8; ++e) off[e] = cnt[tid][e];
    for (int i = 0; i < 16; ++i) {
        int tok = base + i;
        int e = eidx[tok], v = valid[tok];
        int pos = off[e]; off[e] += v;
        int kp = (v && pos < CAPE) ? 1 : 0;
        pc[tok]    = (pos < CAPE) ? pos : (CAPE - 1);
        keepf[tok] = kp;
        gk[tok]    = kp ? gate[tok] : 0.f;
    }
}

// ---------------- dispatch (expert-range) -> bf16 buffers ----------------
__global__ __launch_bounds__(256) void dispatch_bf16(const float* __restrict__ tln,
    const int* __restrict__ eidx, const int* __restrict__ pc, const int* __restrict__ keepf,
    unsigned short* __restrict__ buf, int e0, int ec)
{
    int tok = blockIdx.x;
    if (!keepf[tok]) return;
    int e = eidx[tok];
    if (e < e0 || e >= e0 + ec) return;
    int p = pc[tok];
    const float4 v = ((const float4*)(tln + (size_t)tok * DMODEL))[threadIdx.x];
    ushort4 o;
    o.x = f2bf(v.x); o.y = f2bf(v.y); o.z = f2bf(v.z); o.w = f2bf(v.w);
    ((ushort4*)(buf + ((size_t)(e - e0) * CAPE + p) * DMODEL))[threadIdx.x] = o;
}

// ---------------- combine add: out += gk * (ob0 + ob1) ----------------
__global__ __launch_bounds__(256) void combine_bf16(const unsigned short* __restrict__ ob,
    const int* __restrict__ eidx, const int* __restrict__ pc, const float* __restrict__ gk,
    float* __restrict__ out, int e0, int ec, long long sHalf)
{
    int tok = blockIdx.x;
    int e = eidx[tok];
    if (e < e0 || e >= e0 + ec) return;
    float g = gk[tok];
    int p = pc[tok];
    size_t idx = ((size_t)(e - e0) * CAPE + p) * DMODEL;
    float4* o = (float4*)(out + (size_t)tok * DMODEL);
    const ushort4 u0 = ((const ushort4*)(ob + idx))[threadIdx.x];
    const ushort4 u1 = ((const ushort4*)(ob + sHalf + idx))[threadIdx.x];
    float4 a = o[threadIdx.x];
    a.x += g * (bf2f(u0.x) + bf2f(u1.x));
    a.y += g * (bf2f(u0.y) + bf2f(u1.y));
    a.z += g * (bf2f(u0.z) + bf2f(u1.z));
    a.w += g * (bf2f(u0.w) + bf2f(u1.w));
    o[threadIdx.x] = a;
}

// ---------------- final scalar losses (1024 partials, 16/lane) ----------------
__global__ __launch_bounds__(64) void loss_kernel(const float* __restrict__ partials,
    const int* __restrict__ counts, float* __restrict__ out2)
{
    int lane = threadIdx.x;
    float p[10] = {0,0,0,0,0,0,0,0,0,0};
    for (int r = 0; r < 16; ++r) {
        const float* row = partials + ((size_t)lane * 16 + r) * 10;
#pragma unroll
        for (int j = 0; j < 10; ++j) p[j] += row[j];
    }
#pragma unroll
    for (int j = 0; j < 10; ++j)
#pragma unroll
        for (int o = 1; o < 64; o <<= 1) p[j] += __shfl_xor(p[j], o, 64);
    if (lane == 0) {
        float nv = fmaxf(p[9], 1.f);
        float lb = 0.f;
        for (int e = 0; e < 8; ++e) lb += ((float)counts[e] / nv) * (p[e] / nv);
        lb *= (float)NEXP;
        out2[0] = lb;
        out2[1] = p[8] / nv;
    }
}

// ---------------- host launch ----------------
extern "C" void kernel_launch(void* const* d_in, const int* in_sizes, int n_in,
                              void* d_out, int out_size, void* d_ws, size_t ws_size,
                              hipStream_t stream)
{
    const float* tgt        = (const float*)d_in[0];
    const float* src        = (const float*)d_in[1];
    const float* token_mask = (const float*)d_in[5];
    const float* ln1w = (const float*)d_in[6],  *ln1b = (const float*)d_in[7];
    const float* self_in_w  = (const float*)d_in[8],  *self_in_b  = (const float*)d_in[9];
    const float* self_out_w = (const float*)d_in[10], *self_out_b = (const float*)d_in[11];
    const float* ln2w = (const float*)d_in[12], *ln2b = (const float*)d_in[13];
    const float* enc_in_w   = (const float*)d_in[14], *enc_in_b   = (const float*)d_in[15];
    const float* enc_out_w  = (const float*)d_in[16], *enc_out_b  = (const float*)d_in[17];
    const float* ln3w = (const float*)d_in[18], *ln3b = (const float*)d_in[19];
    const float* rw = (const float*)d_in[20], *rb = (const float*)d_in[21];
    const float* w1 = (const float*)d_in[22], *b1 = (const float*)d_in[23];
    const float* w2 = (const float*)d_in[24], *b2 = (const float*)d_in[25];

    float* out = (float*)d_out;          // residual stream lives HERE
    float* ws  = (float*)d_ws;

    // ---- fixed layout (floats) ----
    float* tln = ws;                         // 4,194,304
    float* ctx = ws + 4194304;               // 4,194,304 (ctx hi/lo f16)
    int*   eidxA   = (int*)(ws + 8388608);
    int*   validA  = eidxA + 4096;
    int*   pcA     = validA + 4096;
    int*   keepA   = pcA + 4096;
    int*   countsA = keepA + 4096;           // 16
    float* gateA   = (float*)(countsA + 16);
    float* gkA     = gateA + 4096;
    float* partA   = gkA + 4096;             // 1024*10
    const size_t POOL_OFF = 8425984;         // floats
    float* pool = ws + POOL_OFF;

    size_t Wf = ws_size / sizeof(float);
    size_t pf = (Wf > POOL_OFF) ? (Wf - POOL_OFF) : 0;

    int bg, zc;
    if      (pf >= 20971520) { bg = 8; zc = 32; }
    else if (pf >= 12058624) { bg = 4; zc = 16; }
    else                     { bg = 2; zc = 16; }
    int ecs = 1;
    for (int c = 8; c >= 1; c >>= 1)
        if ((size_t)c * 4063232ull <= pf) { ecs = c; break; }
    int elog = (ecs == 8) ? 3 : (ecs == 4) ? 2 : (ecs == 2) ? 1 : 0;

    float* qreg = pool;
    float* vreg = qreg + (size_t)bg * 1572864;
    float* sreg = vreg + (size_t)bg * 262144;

    h16* tlnh = (h16*)tln;
    h16* tlnl = tlnh + 4194304;
    h16* ctxh = (h16*)ctx;
    h16* ctxl = ctxh + 4194304;

    // ================= self attention =================
    ln_hl<<<NTOK, 256, 0, stream>>>(tgt, ln1w, ln1b, tlnh, tlnl);

    for (int g0 = 0; g0 < BATCH; g0 += bg) {
        h16* sb  = (h16*)sreg;
        h16* whi = sb, *wlo = sb + 3145728;
        split_f16<<<1536, 256, 0, stream>>>(self_in_w, whi, wlo, 393216);

        h16* qkvh = (h16*)qreg, *qkvl = qkvh + (size_t)bg * 1572864;
        gemm_f16x2_nt<2><<<dim3(24, bg * 4, 1), 256, 0, stream>>>(
            tlnh + (size_t)g0 * 524288, tlnl + (size_t)g0 * 524288, 1024,
            whi, wlo, 1024, self_in_b, nullptr,
            nullptr, qkvh, qkvl, 1024, 3072);

        h16* vth = (h16*)vreg;
        vt_split<<<dim3(8, 1, bg * 16), 256, 0, stream>>>(qkvh + 2048, 3072, vth);

        h16* sh = sb;
        for (int c0 = 0; c0 < bg * 16; c0 += zc) {
            attn_qk<true><<<dim3(4, 4, zc), 256, 0, stream>>>(
                qkvh, qkvl, 3072, qkvh + 1024, qkvl + 1024, 3072, sh, c0);
            attn_pv<true><<<dim3(8, 1, zc), 512, 0, stream>>>(
                sh, vth + (size_t)c0 * 32768, ctxh, ctxl, g0 * 16 + c0);
        }
    }
    {
        h16* sb = (h16*)sreg;
        h16* owhi = sb, *owlo = sb + 1048576;
        split_f16<<<512, 256, 0, stream>>>(self_out_w, owhi, owlo, 131072);
        gemm_f16x2_nt<1><<<dim3(8, 32, 1), 256, 0, stream>>>(
            ctxh, ctxl, 1024, owhi, owlo, 1024, self_out_b, tgt,
            out, nullptr, nullptr, 1024, 1024);
    }

    // ================= cross attention =================
    ln_hl<<<NTOK, 256, 0, stream>>>(out, ln2w, ln2b, tlnh, tlnl);

    for (int g0 = 0; g0 < BATCH; g0 += bg) {
        h16* sb  = (h16*)sreg;
        h16* shi = sb, *slo = sb + (size_t)bg * 524288;
        h16* ehi = sb + (size_t)bg * 1048576, *elo = ehi + 3145728;
        split_f16<<<bg * 256, 256, 0, stream>>>(src + (size_t)g0 * 524288, shi, slo, bg * 65536);
        split_f16<<<1536, 256, 0, stream>>>(enc_in_w, ehi, elo, 393216);

        h16* q2h  = (h16*)qreg,                 *q2l  = q2h + (size_t)bg * 524288;
        h16* kv2h = q2h + (size_t)bg * 1048576, *kv2l = kv2h + (size_t)bg * 1048576;
        gemm_f16x2_nt<2><<<dim3(8, bg * 4, 1), 256, 0, stream>>>(
            tlnh + (size_t)g0 * 524288, tlnl + (size_t)g0 * 524288, 1024,
            ehi, elo, 1024, enc_in_b, nullptr,
            nullptr, q2h, q2l, 1024, 1024);
        gemm_f16x2_nt<2><<<dim3(16, bg * 4, 1), 256, 0, stream>>>(
            shi, slo, 1024, ehi + 1048576, elo + 1048576, 1024, enc_in_b + 1024, nullptr,
            nullptr, kv2h, kv2l, 1024, 2048);

        h16* vth = (h16*)vreg;
        vt_split<<<dim3(8, 1, bg * 16), 256, 0, stream>>>(kv2h + 1024, 2048, vth);

        h16* sh = sb;
        for (int c0 = 0; c0 < bg * 16; c0 += zc) {
            attn_qk<false><<<dim3(4, 4, zc), 256, 0, stream>>>(
                q2h, q2l, 1024, kv2h, kv2l, 2048, sh, c0);
            attn_pv<false><<<dim3(8, 1, zc), 512, 0, stream>>>(
                sh, vth + (size_t)c0 * 32768, ctxh, ctxl, g0 * 16 + c0);
        }
    }
    {
        h16* sb = (h16*)sreg;
        h16* owhi = sb, *owlo = sb + 1048576;
        split_f16<<<512, 256, 0, stream>>>(enc_out_w, owhi, owlo, 131072);
        gemm_f16x2_nt<1><<<dim3(8, 32, 1), 256, 0, stream>>>(
            ctxh, ctxl, 1024, owhi, owlo, 1024, enc_out_b, out,
            out, nullptr, nullptr, 1024, 1024);
    }

    // ================= MoE =================
    ln_router<<<1024, 256, 0, stream>>>(out, ln3w, ln3b, rw, rb, token_mask, tln,
                                        eidxA, gateA, validA, partA);
    scan_kernel<<<1, 256, 0, stream>>>(eidxA, validA, gateA, pcA, gkA, keepA, countsA);

    long long sHalf = 0;
    for (int e0 = 0; e0 < NEXP; e0 += ecs) {
        unsigned short* wt   = (unsigned short*)pool;
        unsigned short* hB   = (unsigned short*)(pool + (size_t)ecs * 2097152);
        unsigned short* bufB = (unsigned short*)(pool + (size_t)ecs * 3407872);
        unsigned short* obB  = bufB;                       // ob0 overlays bufB
        sHalf = (long long)ecs * 655360;

        tcvt_kernel<<<dim3(64, 16, ecs), 256, 0, stream>>>(
            w1 + (size_t)e0 * 4194304, wt, 1024, 4096);
        dispatch_bf16<<<NTOK, 256, 0, stream>>>(tln, eidxA, pcA, keepA, bufB, e0, ecs);
        gemm_bf16_moe<128, true, true, 1><<<ecs * 5 * 32, 256, 0, stream>>>(
            bufB, wt, b1 + (size_t)e0 * 4096, hB,
            1024, 655360LL, 4194304LL, 2621440LL, 4096LL, 4096,
            ecs - 1, elog, 5, 32, countsA, e0, 0LL);

        tcvt_kernel<<<dim3(16, 64, ecs), 256, 0, stream>>>(
            w2 + (size_t)e0 * 4194304, wt, 4096, 1024);
        gemm_bf16_moe<64, false, false, 2><<<ecs * 5 * 16 * 2, 256, 0, stream>>>(
            hB, wt, b2 + (size_t)e0 * 1024, obB,
            4096, 2621440LL, 4194304LL, 655360LL, 1024LL, 1024,
            ecs - 1, elog, 5, 16, countsA, e0, sHalf);

        combine_bf16<<<NTOK, 256, 0, stream>>>(obB, eidxA, pcA, gkA, out, e0, ecs, sHalf);
    }

    // ===== losses =====
    loss_kernel<<<1, 64, 0, stream>>>(partA, countsA, out + (size_t)NTOK * DMODEL);
}